// Round 2
// baseline (11826.196 us; speedup 1.0000x reference)
//
#include <hip/hip_runtime.h>
#include <hip/hip_bf16.h>

#define S_LEN  2048
#define HDIM   2048
#define NH_    16
#define DQK_   192
#define QRANK_ 1024
#define KVRANK_ 512
#define KVDN   576    // KV_RANK + D_ROPE
#define KVUPN  4096   // NH*(D_NOPE+D_V)
#define QN_    3072   // NH*D_QK
#define IFF_   1408
#define EXP_   8
#define HG_    2      // heads per attention chunk
#define PD_    4096

typedef __attribute__((ext_vector_type(8))) short   short8_t;
typedef __attribute__((ext_vector_type(8))) __bf16  bf16x8_t;
typedef __attribute__((ext_vector_type(4))) float   f32x4;

static __device__ __forceinline__ float b2f(short s) {
  unsigned int u = ((unsigned int)(unsigned short)s) << 16;
  return __builtin_bit_cast(float, u);
}
static __device__ __forceinline__ short f2b(float f) {
  return __builtin_bit_cast(short, __float2bfloat16(f));
}

// ---------------- dtype detect + convert ----------------
// Reads 2048 words of `embed` as f32. If the data is真 f32 N(0,0.02), nearly all
// magnitudes land in (1e-6, 10). If it is bf16 pairs, the f32 exponent field is
// quasi-random -> ~10% hit rate. flag=1 => inputs are f32.
__global__ void __launch_bounds__(256)
detect_kernel(const void* probe, int* flag) {
  const float* f = (const float*)probe;
  int tid = threadIdx.x;
  int cnt = 0;
  for (int i = tid; i < 2048; i += 256) {
    float v = fabsf(f[i]);
    if (v > 1e-6f && v < 10.0f) cnt++;
  }
  __shared__ int red[256];
  red[tid] = cnt; __syncthreads();
  for (int s = 128; s > 0; s >>= 1) {
    if (tid < s) red[tid] += red[tid + s];
    __syncthreads();
  }
  if (tid == 0) *flag = (red[0] > 1600) ? 1 : 0;
}

// n must be a multiple of 8 (true for every input here).
__global__ void __launch_bounds__(256)
convert_kernel(const void* src, short* dst, long long nchunks, const int* flag) {
  long long idx = (long long)blockIdx.x * 256 + threadIdx.x;
  long long stride = (long long)gridDim.x * 256;
  if (*flag) {
    const f32x4* s = (const f32x4*)src;
    for (long long c = idx; c < nchunks; c += stride) {
      f32x4 a = s[2 * c], b = s[2 * c + 1];
      short8_t o;
      #pragma unroll
      for (int j = 0; j < 4; ++j) { o[j] = f2b(a[j]); o[4 + j] = f2b(b[j]); }
      reinterpret_cast<short8_t*>(dst)[c] = o;
    }
  } else {
    const short8_t* s = (const short8_t*)src;
    for (long long c = idx; c < nchunks; c += stride)
      reinterpret_cast<short8_t*>(dst)[c] = s[c];
  }
}

__global__ void __launch_bounds__(256)
embed_convert_kernel(const int* ids, const void* emb, const int* flag, short* h) {
  int s = blockIdx.x;
  long long row = ids[s];
  int c = threadIdx.x;
  short8_t o;
  if (*flag) {
    const f32x4* src = (const f32x4*)((const float*)emb + row * HDIM);
    f32x4 a = src[2 * c], b = src[2 * c + 1];
    #pragma unroll
    for (int j = 0; j < 4; ++j) { o[j] = f2b(a[j]); o[4 + j] = f2b(b[j]); }
  } else {
    o = reinterpret_cast<const short8_t*>((const short*)emb + row * HDIM)[c];
  }
  reinterpret_cast<short8_t*>(h + (long long)s * HDIM)[c] = o;
}

// ---------------- generic MFMA GEMM ----------------
// A: [M][K] row-major bf16 (lda).  BTRANS=0: B is [K][N] (ldb). BTRANS=1: B is [N][K] (ldb).
// EPI=0: C bf16 store (ldc). EPI=1: C f32 += (ldc).
// Requires M%128==0, K%32==0; N guarded (must be %8==0).
template<int BTRANS, int EPI>
__global__ void __launch_bounds__(256)
gemm_kernel(const short* __restrict__ A, const short* __restrict__ B,
            void* __restrict__ Cv, int M, int N, int K,
            int lda, int ldb, int ldc,
            long long sAb, long long sBb, long long sCb)
{
  __shared__ short shA[128][40];
  __shared__ short shB[128][40];
  const int tid = threadIdx.x;
  const long long bz = blockIdx.z;
  const short* Ab = A + bz * sAb;
  const short* Bb = B + bz * sBb;
  const int m0 = blockIdx.x * 128;
  const int n0 = blockIdx.y * 128;
  const int w = tid >> 6, lane = tid & 63;
  const int wm = (w >> 1) << 6, wn = (w & 1) << 6;
  const int lr = lane & 15, g = lane >> 4;
  const f32x4 vzero = {0.f, 0.f, 0.f, 0.f};
  f32x4 acc[4][4];
  #pragma unroll
  for (int i = 0; i < 4; ++i)
    #pragma unroll
    for (int j = 0; j < 4; ++j) acc[i][j] = vzero;

  for (int k0 = 0; k0 < K; k0 += 32) {
    __syncthreads();
    // stage A tile [128][32]
    #pragma unroll
    for (int i = 0; i < 2; ++i) {
      int c = tid + (i << 8);
      int row = c >> 2, kb = (c & 3) << 3;
      short8_t v = *reinterpret_cast<const short8_t*>(Ab + (long long)(m0 + row) * lda + k0 + kb);
      *reinterpret_cast<short8_t*>(&shA[row][kb]) = v;
    }
    // stage B tile into shB[n][k]
    if (BTRANS) {
      #pragma unroll
      for (int i = 0; i < 2; ++i) {
        int c = tid + (i << 8);
        int row = c >> 2, kb = (c & 3) << 3;
        short8_t v = {0,0,0,0,0,0,0,0};
        if (n0 + row < N)
          v = *reinterpret_cast<const short8_t*>(Bb + (long long)(n0 + row) * ldb + k0 + kb);
        *reinterpret_cast<short8_t*>(&shB[row][kb]) = v;
      }
    } else {
      #pragma unroll
      for (int i = 0; i < 2; ++i) {
        int c = tid + (i << 8);
        int kk = c >> 4, nb = (c & 15) << 3;
        short8_t v = {0,0,0,0,0,0,0,0};
        if (n0 + nb + 8 <= N)
          v = *reinterpret_cast<const short8_t*>(Bb + (long long)(k0 + kk) * ldb + n0 + nb);
        #pragma unroll
        for (int j = 0; j < 8; ++j) shB[nb + j][kk] = v[j];
      }
    }
    __syncthreads();
    short8_t af[4];
    #pragma unroll
    for (int mi = 0; mi < 4; ++mi)
      af[mi] = *reinterpret_cast<const short8_t*>(&shA[wm + (mi << 4) + lr][g << 3]);
    #pragma unroll
    for (int ni = 0; ni < 4; ++ni) {
      short8_t bfr = *reinterpret_cast<const short8_t*>(&shB[wn + (ni << 4) + lr][g << 3]);
      #pragma unroll
      for (int mi = 0; mi < 4; ++mi)
        acc[mi][ni] = __builtin_amdgcn_mfma_f32_16x16x32_bf16(
            __builtin_bit_cast(bf16x8_t, af[mi]),
            __builtin_bit_cast(bf16x8_t, bfr),
            acc[mi][ni], 0, 0, 0);
    }
  }
  const int orow = m0 + wm + (g << 2);
  const int ocol = n0 + wn + lr;
  if (EPI == 0) {
    short* C = reinterpret_cast<short*>(Cv) + bz * sCb;
    #pragma unroll
    for (int ni = 0; ni < 4; ++ni) {
      int col = ocol + (ni << 4);
      if (col >= N) continue;
      #pragma unroll
      for (int mi = 0; mi < 4; ++mi)
        #pragma unroll
        for (int r = 0; r < 4; ++r)
          C[(long long)(orow + (mi << 4) + r) * ldc + col] = f2b(acc[mi][ni][r]);
    }
  } else {
    float* C = reinterpret_cast<float*>(Cv) + bz * sCb;
    #pragma unroll
    for (int ni = 0; ni < 4; ++ni) {
      int col = ocol + (ni << 4);
      if (col >= N) continue;
      #pragma unroll
      for (int mi = 0; mi < 4; ++mi)
        #pragma unroll
        for (int r = 0; r < 4; ++r)
          C[(long long)(orow + (mi << 4) + r) * ldc + col] += acc[mi][ni][r];
    }
  }
}

// ---------------- small kernels ----------------
__global__ void __launch_bounds__(64)
rope_tables_kernel(float* cosT, float* sinT) {
  int s = blockIdx.x, j = threadIdx.x;        // j in [0,64)
  int i = j & 31;
  float inv = powf(10000.0f, -((float)(2 * i) / 64.0f));
  float ang = (float)s * inv;
  cosT[s * 64 + j] = cosf(ang);
  sinT[s * 64 + j] = sinf(ang);
}

__global__ void __launch_bounds__(256)
rmsnorm_bf16_kernel(const short* __restrict__ in, long long istride,
                    const short* __restrict__ w,
                    short* __restrict__ out, long long ostride, int D) {
  const short* x = in + (long long)blockIdx.x * istride;
  short* o = out + (long long)blockIdx.x * ostride;
  const int nc = D >> 3;
  float ss = 0.f;
  for (int c = threadIdx.x; c < nc; c += 256) {
    short8_t v = reinterpret_cast<const short8_t*>(x)[c];
    #pragma unroll
    for (int j = 0; j < 8; ++j) { float f = b2f(v[j]); ss += f * f; }
  }
  __shared__ float red[256];
  red[threadIdx.x] = ss; __syncthreads();
  for (int s2 = 128; s2 > 0; s2 >>= 1) {
    if (threadIdx.x < s2) red[threadIdx.x] += red[threadIdx.x + s2];
    __syncthreads();
  }
  float r = 1.0f / sqrtf(red[0] / (float)D + 1e-6f);
  for (int c = threadIdx.x; c < nc; c += 256) {
    short8_t v = reinterpret_cast<const short8_t*>(x)[c];
    short8_t wv = reinterpret_cast<const short8_t*>(w)[c];
    short8_t ov;
    #pragma unroll
    for (int j = 0; j < 8; ++j) ov[j] = f2b(b2f(wv[j]) * (b2f(v[j]) * r));
    reinterpret_cast<short8_t*>(o)[c] = ov;
  }
}

__global__ void __launch_bounds__(256)
build_qf_kernel(const short* q, const float* cosT, const float* sinT, short* qf) {
  int s = blockIdx.x;
  for (int idx = threadIdx.x; idx < NH_ * DQK_; idx += 256) {
    int h = idx / DQK_, d = idx - h * DQK_;
    const short* qr = q + (long long)s * QN_ + h * DQK_;
    float val;
    if (d < 128) val = b2f(qr[d]);
    else {
      int j = d - 128;
      float c = cosT[s * 64 + j], sn = sinT[s * 64 + j];
      float x0 = b2f(qr[128 + j]);
      float rot = (j < 32) ? -b2f(qr[128 + j + 32]) : b2f(qr[128 + j - 32]);
      val = x0 * c + rot * sn;
    }
    qf[(long long)h * S_LEN * DQK_ + (long long)s * DQK_ + d] = f2b(val);
  }
}

__global__ void __launch_bounds__(256)
build_kf_kernel(const short* kvup, const short* kv, const float* cosT, const float* sinT, short* kf) {
  int s = blockIdx.x;
  for (int idx = threadIdx.x; idx < NH_ * DQK_; idx += 256) {
    int h = idx / DQK_, d = idx - h * DQK_;
    float val;
    if (d < 128) val = b2f(kvup[(long long)s * KVUPN + h * 256 + d]);
    else {
      int j = d - 128;
      float c = cosT[s * 64 + j], sn = sinT[s * 64 + j];
      const short* kr = kv + (long long)s * KVDN + KVRANK_;
      float x0 = b2f(kr[j]);
      float rot = (j < 32) ? -b2f(kr[j + 32]) : b2f(kr[j - 32]);
      val = x0 * c + rot * sn;
    }
    kf[(long long)h * S_LEN * DQK_ + (long long)s * DQK_ + d] = f2b(val);
  }
}

__global__ void __launch_bounds__(256)
softmax_rows_kernel(short* scores, float scale) {
  long long row = blockIdx.x;
  short8_t* p = reinterpret_cast<short8_t*>(scores + row * S_LEN);
  short8_t v = p[threadIdx.x];
  float f[8]; float m = -1e30f;
  #pragma unroll
  for (int j = 0; j < 8; ++j) { f[j] = b2f(v[j]) * scale; m = fmaxf(m, f[j]); }
  __shared__ float red[256];
  red[threadIdx.x] = m; __syncthreads();
  for (int s2 = 128; s2 > 0; s2 >>= 1) {
    if (threadIdx.x < s2) red[threadIdx.x] = fmaxf(red[threadIdx.x], red[threadIdx.x + s2]);
    __syncthreads();
  }
  m = red[0]; __syncthreads();
  float sum = 0.f;
  #pragma unroll
  for (int j = 0; j < 8; ++j) { f[j] = expf(f[j] - m); sum += f[j]; }
  red[threadIdx.x] = sum; __syncthreads();
  for (int s2 = 128; s2 > 0; s2 >>= 1) {
    if (threadIdx.x < s2) red[threadIdx.x] += red[threadIdx.x + s2];
    __syncthreads();
  }
  float inv = 1.0f / red[0];
  short8_t o;
  #pragma unroll
  for (int j = 0; j < 8; ++j) o[j] = f2b(f[j] * inv);
  p[threadIdx.x] = o;
}

__global__ void __launch_bounds__(256)
add_bf16_kernel(short* h, const short* a) {
  long long c = (long long)blockIdx.x * 256 + threadIdx.x;
  short8_t hv = reinterpret_cast<short8_t*>(h)[c];
  short8_t av = reinterpret_cast<const short8_t*>(a)[c];
  short8_t ov;
  #pragma unroll
  for (int j = 0; j < 8; ++j) ov[j] = f2b(b2f(hv[j]) + b2f(av[j]));
  reinterpret_cast<short8_t*>(h)[c] = ov;
}

__global__ void __launch_bounds__(256)
add_f32_kernel(short* h, const float* a) {
  long long c = (long long)blockIdx.x * 256 + threadIdx.x;
  short8_t hv = reinterpret_cast<short8_t*>(h)[c];
  f32x4 a0 = reinterpret_cast<const f32x4*>(a)[2 * c];
  f32x4 a1 = reinterpret_cast<const f32x4*>(a)[2 * c + 1];
  short8_t ov;
  #pragma unroll
  for (int j = 0; j < 4; ++j) {
    ov[j]     = f2b(b2f(hv[j])     + a0[j]);
    ov[4 + j] = f2b(b2f(hv[4 + j]) + a1[j]);
  }
  reinterpret_cast<short8_t*>(h)[c] = ov;
}

__global__ void __launch_bounds__(256)
gate_kernel(const short* x2, const short* gw, short* combine) {
  int t = blockIdx.x;
  int e = threadIdx.x >> 5, j = threadIdx.x & 31;
  const short* x = x2 + (long long)t * HDIM;
  float acc = 0.f;
  for (int k = j; k < HDIM; k += 32) acc += b2f(x[k]) * b2f(gw[(long long)k * EXP_ + e]);
  __shared__ float red[8][32];
  red[e][j] = acc; __syncthreads();
  for (int s2 = 16; s2 > 0; s2 >>= 1) {
    if (j < s2) red[e][j] += red[e][j + s2];
    __syncthreads();
  }
  if (threadIdx.x == 0) {
    float l[8], p[8];
    float m = -1e30f;
    for (int q = 0; q < 8; ++q) { l[q] = b2f(f2b(red[q][0])); m = fmaxf(m, l[q]); }
    float sum = 0.f;
    for (int q = 0; q < 8; ++q) { p[q] = expf(l[q] - m); sum += p[q]; }
    int i0 = 0; for (int q = 1; q < 8; ++q) if (p[q] > p[i0]) i0 = q;
    int i1 = (i0 == 0) ? 1 : 0;
    for (int q = 0; q < 8; ++q) if (q != i0 && p[q] > p[i1]) i1 = q;
    float denom = p[i0] + p[i1];
    short* row = combine + (long long)t * EXP_;
    for (int q = 0; q < 8; ++q) row[q] = 0;
    row[i0] = f2b(p[i0] / denom);
    row[i1] = f2b(p[i1] / denom);
  }
}

__global__ void __launch_bounds__(256)
silu_mul_kernel(short* a, const short* b, const short* combine, int e) {
  int t = blockIdx.x;
  float scale = 1.0f;
  if (combine) scale = b2f(combine[(long long)t * EXP_ + e]);
  int c = threadIdx.x;
  if (c >= IFF_ / 8) return;
  short8_t av = reinterpret_cast<short8_t*>(a + (long long)t * IFF_)[c];
  short8_t bv = reinterpret_cast<const short8_t*>(b + (long long)t * IFF_)[c];
  short8_t ov;
  #pragma unroll
  for (int j = 0; j < 8; ++j) {
    float x = b2f(av[j]);
    float s = x / (1.0f + expf(-x));
    ov[j] = f2b(s * b2f(bv[j]) * scale);
  }
  reinterpret_cast<short8_t*>(a + (long long)t * IFF_)[c] = ov;
}

// ---------------- pooling ----------------
__global__ void __launch_bounds__(256)
gemv_bf16_kernel(const short* a, const short* B, short* out, int K, int N) {
  int n = blockIdx.x * 256 + threadIdx.x;
  if (n >= N) return;
  float acc = 0.f;
  for (int k = 0; k < K; ++k) acc += b2f(a[k]) * b2f(B[(long long)k * N + n]);
  out[n] = f2b(acc);
}

__global__ void __launch_bounds__(256)
gemv_f32_kernel(const float* a, const short* B, float* out, int K, int N) {
  int n = blockIdx.x * 256 + threadIdx.x;
  if (n >= N) return;
  float acc = 0.f;
  for (int k = 0; k < K; ++k) acc += a[k] * b2f(B[(long long)k * N + n]);
  out[n] = acc;
}

__global__ void __launch_bounds__(256)
pool_score_kernel(const short* qv, const short* kmat, float* score) {
  int s = blockIdx.x;
  const short8_t* kr = reinterpret_cast<const short8_t*>(kmat + (long long)s * HDIM);
  const short8_t* qr = reinterpret_cast<const short8_t*>(qv);
  short8_t kv8 = kr[threadIdx.x], qv8 = qr[threadIdx.x];
  float acc = 0.f;
  #pragma unroll
  for (int j = 0; j < 8; ++j) acc += b2f(qv8[j]) * b2f(kv8[j]);
  __shared__ float red[256];
  red[threadIdx.x] = acc; __syncthreads();
  for (int s2 = 128; s2 > 0; s2 >>= 1) {
    if (threadIdx.x < s2) red[threadIdx.x] += red[threadIdx.x + s2];
    __syncthreads();
  }
  if (threadIdx.x == 0) score[s] = b2f(f2b(red[0])) * 0.022097086912079608f; // 1/sqrt(2048)
}

__global__ void __launch_bounds__(256)
softmax_vec_kernel(float* v) {  // 2048 f32, single block, in place
  int tid = threadIdx.x;
  float f[8]; float m = -1e30f;
  #pragma unroll
  for (int i = 0; i < 8; ++i) { f[i] = v[i * 256 + tid]; m = fmaxf(m, f[i]); }
  __shared__ float red[256];
  red[tid] = m; __syncthreads();
  for (int s2 = 128; s2 > 0; s2 >>= 1) {
    if (tid < s2) red[tid] = fmaxf(red[tid], red[tid + s2]);
    __syncthreads();
  }
  m = red[0]; __syncthreads();
  float sum = 0.f;
  #pragma unroll
  for (int i = 0; i < 8; ++i) { f[i] = expf(f[i] - m); sum += f[i]; }
  red[tid] = sum; __syncthreads();
  for (int s2 = 128; s2 > 0; s2 >>= 1) {
    if (tid < s2) red[tid] += red[tid + s2];
    __syncthreads();
  }
  float inv = 1.0f / red[0];
  #pragma unroll
  for (int i = 0; i < 8; ++i) v[i * 256 + tid] = f[i] * inv;
}

__global__ void __launch_bounds__(256)
pool_wsum_kernel(const float* w, const short* v, float* pooled) {
  int hcol = blockIdx.x * 256 + threadIdx.x;
  float acc = 0.f;
  for (int s = 0; s < S_LEN; ++s) acc += w[s] * b2f(v[(long long)s * HDIM + hcol]);
  pooled[hcol] = acc;
}

__global__ void __launch_bounds__(256)
rmsnorm_f32_kernel(const float* x, const short* w, float* out) {  // D=2048, single block
  int tid = threadIdx.x;
  float f[8]; float ss = 0.f;
  #pragma unroll
  for (int i = 0; i < 8; ++i) { f[i] = x[i * 256 + tid]; ss += f[i] * f[i]; }
  __shared__ float red[256];
  red[tid] = ss; __syncthreads();
  for (int s2 = 128; s2 > 0; s2 >>= 1) {
    if (tid < s2) red[tid] += red[tid + s2];
    __syncthreads();
  }
  float r = 1.0f / sqrtf(red[0] / 2048.0f + 1e-6f);
  #pragma unroll
  for (int i = 0; i < 8; ++i) out[i * 256 + tid] = b2f(w[i * 256 + tid]) * (f[i] * r);
}

// ---------------- host ----------------
extern "C" void kernel_launch(void* const* d_in, const int* in_sizes, int n_in,
                              void* d_out, int out_size, void* d_ws, size_t ws_size,
                              hipStream_t stream)
{
  (void)n_in; (void)out_size; (void)ws_size;
  const int* ids = (const int*)d_in[24];

  char* base = (char*)d_ws;
  size_t off = 0;
  auto alloc = [&](size_t bytes) -> void* {
    void* p = base + off;
    off += (bytes + 255) & ~(size_t)255;
    return p;
  };

  // ---- dtype flag + bf16 arena (converted copies of all float inputs except embed) ----
  int* dflag = (int*)alloc(256);
  short* cw[24];
  for (int i = 1; i <= 23; ++i)
    cw[i] = (short*)alloc((size_t)in_sizes[i] * 2);

  float* cosT    = (float*)alloc((size_t)S_LEN * 64 * 4);
  float* sinT    = (float*)alloc((size_t)S_LEN * 64 * 4);
  short* hbuf    = (short*)alloc((size_t)S_LEN * HDIM * 2);
  short* xbuf    = (short*)alloc((size_t)S_LEN * HDIM * 2);
  short* qlat    = (short*)alloc((size_t)S_LEN * QRANK_ * 2);
  short* qlatn   = (short*)alloc((size_t)S_LEN * QRANK_ * 2);
  short* qbuf    = (short*)alloc((size_t)S_LEN * QN_ * 2);
  short* kvbuf   = (short*)alloc((size_t)S_LEN * KVDN * 2);
  short* kvn     = (short*)alloc((size_t)S_LEN * KVRANK_ * 2);
  short* kvup    = (short*)alloc((size_t)S_LEN * KVUPN * 2);
  short* qf      = (short*)alloc((size_t)NH_ * S_LEN * DQK_ * 2);
  short* kf      = (short*)alloc((size_t)NH_ * S_LEN * DQK_ * 2);
  short* scores  = (short*)alloc((size_t)HG_ * S_LEN * S_LEN * 2);
  short* ao      = (short*)alloc((size_t)S_LEN * HDIM * 2);
  short* attnp   = (short*)alloc((size_t)S_LEN * HDIM * 2);
  float* moeacc  = (float*)alloc((size_t)S_LEN * HDIM * 4);
  short* gba     = (short*)alloc((size_t)S_LEN * IFF_ * 2);
  short* gbb     = (short*)alloc((size_t)S_LEN * IFF_ * 2);
  short* combine = (short*)alloc((size_t)S_LEN * EXP_ * 2);
  short* hfin    = (short*)alloc((size_t)S_LEN * HDIM * 2);
  short* kpool   = (short*)alloc((size_t)S_LEN * HDIM * 2);
  short* vpool   = (short*)alloc((size_t)S_LEN * HDIM * 2);
  short* qvec    = (short*)alloc((size_t)HDIM * 2);
  float* pscore  = (float*)alloc((size_t)S_LEN * 4);
  float* pooled  = (float*)alloc((size_t)HDIM * 4);
  float* pooledn = (float*)alloc((size_t)HDIM * 4);

  // detect dtype from embed (random-normal data -> unambiguous)
  detect_kernel<<<1, 256, 0, stream>>>(d_in[0], dflag);
  for (int i = 1; i <= 23; ++i) {
    long long nchunks = (long long)in_sizes[i] / 8;
    int blocks = (int)((nchunks + 255) / 256);
    if (blocks > 2048) blocks = 2048;
    if (blocks < 1) blocks = 1;
    convert_kernel<<<blocks, 256, 0, stream>>>(d_in[i], cw[i], nchunks, dflag);
  }

  const short* ln1w = cw[1],  *qdw = cw[2],  *qnw = cw[3],  *quw = cw[4];
  const short* kvdw = cw[5],  *kvnw = cw[6], *kvuw = cw[7], *opw = cw[8];
  const short* ln2w = cw[9],  *gatw = cw[10];
  const short* rw1 = cw[11],  *rw2 = cw[12], *rw3 = cw[13];
  const short* sw1 = cw[14],  *sw2 = cw[15], *sw3 = cw[16];
  const short* fnww = cw[17], *lqw = cw[18];
  const short* pqww = cw[19], *pkww = cw[20], *pvww = cw[21];
  const short* poww = cw[22], *pnww = cw[23];

  const float qk_scale = 1.0f / sqrtf((float)DQK_);

  auto gemm = [&](int bt, int epi, const short* A, const short* B, void* C,
                  int M, int N, int K, int lda, int ldb, int ldc,
                  int batch, long long sA, long long sB, long long sC) {
    dim3 grid(M / 128, (N + 127) / 128, batch);
    if (bt == 0 && epi == 0)
      gemm_kernel<0,0><<<grid, 256, 0, stream>>>(A, B, C, M, N, K, lda, ldb, ldc, sA, sB, sC);
    else if (bt == 0 && epi == 1)
      gemm_kernel<0,1><<<grid, 256, 0, stream>>>(A, B, C, M, N, K, lda, ldb, ldc, sA, sB, sC);
    else
      gemm_kernel<1,0><<<grid, 256, 0, stream>>>(A, B, C, M, N, K, lda, ldb, ldc, sA, sB, sC);
  };

  rope_tables_kernel<<<S_LEN, 64, 0, stream>>>(cosT, sinT);
  embed_convert_kernel<<<S_LEN, 256, 0, stream>>>(ids, d_in[0], dflag, hbuf);

  for (int l = 0; l < 2; ++l) {
    const short* w_ln1 = ln1w + (size_t)l * HDIM;
    const short* w_qd  = qdw  + (size_t)l * HDIM * QRANK_;
    const short* w_qn  = qnw  + (size_t)l * QRANK_;
    const short* w_qu  = quw  + (size_t)l * QRANK_ * QN_;
    const short* w_kvd = kvdw + (size_t)l * HDIM * KVDN;
    const short* w_kvn = kvnw + (size_t)l * KVRANK_;
    const short* w_kvu = kvuw + (size_t)l * KVRANK_ * KVUPN;
    const short* w_op  = opw  + (size_t)l * HDIM * HDIM;
    const short* w_ln2 = ln2w + (size_t)l * HDIM;
    const short* w_gat = gatw + (size_t)l * HDIM * EXP_;

    // --- attention ---
    rmsnorm_bf16_kernel<<<S_LEN, 256, 0, stream>>>(hbuf, HDIM, w_ln1, xbuf, HDIM, HDIM);
    gemm(0,0, xbuf, w_qd, qlat, S_LEN, QRANK_, HDIM, HDIM, QRANK_, QRANK_, 1, 0, 0, 0);
    rmsnorm_bf16_kernel<<<S_LEN, 256, 0, stream>>>(qlat, QRANK_, w_qn, qlatn, QRANK_, QRANK_);
    gemm(0,0, qlatn, w_qu, qbuf, S_LEN, QN_, QRANK_, QRANK_, QN_, QN_, 1, 0, 0, 0);
    gemm(0,0, xbuf, w_kvd, kvbuf, S_LEN, KVDN, HDIM, HDIM, KVDN, KVDN, 1, 0, 0, 0);
    rmsnorm_bf16_kernel<<<S_LEN, 256, 0, stream>>>(kvbuf, KVDN, w_kvn, kvn, KVRANK_, KVRANK_);
    gemm(0,0, kvn, w_kvu, kvup, S_LEN, KVUPN, KVRANK_, KVRANK_, KVUPN, KVUPN, 1, 0, 0, 0);
    build_qf_kernel<<<S_LEN, 256, 0, stream>>>(qbuf, cosT, sinT, qf);
    build_kf_kernel<<<S_LEN, 256, 0, stream>>>(kvup, kvbuf, cosT, sinT, kf);
    for (int hg = 0; hg < NH_ / HG_; ++hg) {
      gemm(1,0, qf + (size_t)hg * HG_ * S_LEN * DQK_, kf + (size_t)hg * HG_ * S_LEN * DQK_,
           scores, S_LEN, S_LEN, DQK_, DQK_, DQK_, S_LEN, HG_,
           (long long)S_LEN * DQK_, (long long)S_LEN * DQK_, (long long)S_LEN * S_LEN);
      softmax_rows_kernel<<<HG_ * S_LEN, 256, 0, stream>>>(scores, qk_scale);
      gemm(0,0, scores, kvup + hg * HG_ * 256 + 128, ao + hg * HG_ * 128,
           S_LEN, 128, S_LEN, S_LEN, KVUPN, HDIM, HG_,
           (long long)S_LEN * S_LEN, 256, 128);
    }
    gemm(0,0, ao, w_op, attnp, S_LEN, HDIM, HDIM, HDIM, HDIM, HDIM, 1, 0, 0, 0);
    add_bf16_kernel<<<S_LEN, 256, 0, stream>>>(hbuf, attnp);

    // --- MoE ---
    rmsnorm_bf16_kernel<<<S_LEN, 256, 0, stream>>>(hbuf, HDIM, w_ln2, xbuf, HDIM, HDIM);
    gate_kernel<<<S_LEN, 256, 0, stream>>>(xbuf, w_gat, combine);
    hipMemsetAsync(moeacc, 0, (size_t)S_LEN * HDIM * 4, stream);
    for (int j = 0; j < 2; ++j) {
      const short* a1 = sw1 + ((size_t)l * 2 + j) * HDIM * IFF_;
      const short* a3 = sw3 + ((size_t)l * 2 + j) * HDIM * IFF_;
      const short* a2 = sw2 + ((size_t)l * 2 + j) * IFF_ * HDIM;
      gemm(0,0, xbuf, a1, gba, S_LEN, IFF_, HDIM, HDIM, IFF_, IFF_, 1, 0, 0, 0);
      gemm(0,0, xbuf, a3, gbb, S_LEN, IFF_, HDIM, HDIM, IFF_, IFF_, 1, 0, 0, 0);
      silu_mul_kernel<<<S_LEN, 256, 0, stream>>>(gba, gbb, (const short*)nullptr, 0);
      gemm(0,1, gba, a2, moeacc, S_LEN, HDIM, IFF_, IFF_, HDIM, HDIM, 1, 0, 0, 0);
    }
    for (int e = 0; e < 8; ++e) {
      const short* a1 = rw1 + ((size_t)l * 8 + e) * HDIM * IFF_;
      const short* a3 = rw3 + ((size_t)l * 8 + e) * HDIM * IFF_;
      const short* a2 = rw2 + ((size_t)l * 8 + e) * IFF_ * HDIM;
      gemm(0,0, xbuf, a1, gba, S_LEN, IFF_, HDIM, HDIM, IFF_, IFF_, 1, 0, 0, 0);
      gemm(0,0, xbuf, a3, gbb, S_LEN, IFF_, HDIM, HDIM, IFF_, IFF_, 1, 0, 0, 0);
      silu_mul_kernel<<<S_LEN, 256, 0, stream>>>(gba, gbb, combine, e);
      gemm(0,1, gba, a2, moeacc, S_LEN, HDIM, IFF_, IFF_, HDIM, HDIM, 1, 0, 0, 0);
    }
    add_f32_kernel<<<S_LEN, 256, 0, stream>>>(hbuf, moeacc);
  }

  // --- attention pooling head ---
  rmsnorm_bf16_kernel<<<S_LEN, 256, 0, stream>>>(hbuf, HDIM, fnww, hfin, HDIM, HDIM);
  gemm(0,0, hfin, pkww, kpool, S_LEN, HDIM, HDIM, HDIM, HDIM, HDIM, 1, 0, 0, 0);
  gemm(0,0, hfin, pvww, vpool, S_LEN, HDIM, HDIM, HDIM, HDIM, HDIM, 1, 0, 0, 0);
  gemv_bf16_kernel<<<HDIM / 256, 256, 0, stream>>>(lqw, pqww, qvec, HDIM, HDIM);
  pool_score_kernel<<<S_LEN, 256, 0, stream>>>(qvec, kpool, pscore);
  softmax_vec_kernel<<<1, 256, 0, stream>>>(pscore);
  pool_wsum_kernel<<<HDIM / 256, 256, 0, stream>>>(pscore, vpool, pooled);
  rmsnorm_f32_kernel<<<1, 256, 0, stream>>>(pooled, pnww, pooledn);
  gemv_f32_kernel<<<PD_ / 256, 256, 0, stream>>>(pooledn, poww, (float*)d_out, HDIM, PD_);
}

// Round 3
// 6350.978 us; speedup vs baseline: 1.8621x; 1.8621x over previous
//
#include <hip/hip_runtime.h>
#include <hip/hip_bf16.h>

#define S_LEN  2048
#define HDIM   2048
#define NH_    16
#define DQK_   192
#define QRANK_ 1024
#define KVRANK_ 512
#define KVDN   576    // KV_RANK + D_ROPE
#define KVUPN  4096   // NH*(D_NOPE+D_V)
#define QN_    3072   // NH*D_QK
#define IFF_   1408
#define EXP_   8
#define HG_    4      // heads per attention chunk
#define PD_    4096

typedef __attribute__((ext_vector_type(8))) short   short8_t;
typedef __attribute__((ext_vector_type(8))) __bf16  bf16x8_t;
typedef __attribute__((ext_vector_type(4))) float   f32x4;

static __device__ __forceinline__ float b2f(short s) {
  unsigned int u = ((unsigned int)(unsigned short)s) << 16;
  return __builtin_bit_cast(float, u);
}
static __device__ __forceinline__ short f2b(float f) {
  return __builtin_bit_cast(short, __float2bfloat16(f));
}

// ---------------- dtype detect + convert ----------------
__global__ void __launch_bounds__(256)
detect_kernel(const void* probe, int* flag) {
  const float* f = (const float*)probe;
  int tid = threadIdx.x;
  int cnt = 0;
  for (int i = tid; i < 2048; i += 256) {
    float v = fabsf(f[i]);
    if (v > 1e-6f && v < 10.0f) cnt++;
  }
  __shared__ int red[256];
  red[tid] = cnt; __syncthreads();
  for (int s = 128; s > 0; s >>= 1) {
    if (tid < s) red[tid] += red[tid + s];
    __syncthreads();
  }
  if (tid == 0) *flag = (red[0] > 1600) ? 1 : 0;
}

__global__ void __launch_bounds__(256)
convert_kernel(const void* src, short* dst, long long nchunks, const int* flag) {
  long long idx = (long long)blockIdx.x * 256 + threadIdx.x;
  long long stride = (long long)gridDim.x * 256;
  if (*flag) {
    const f32x4* s = (const f32x4*)src;
    for (long long c = idx; c < nchunks; c += stride) {
      f32x4 a = s[2 * c], b = s[2 * c + 1];
      short8_t o;
      #pragma unroll
      for (int j = 0; j < 4; ++j) { o[j] = f2b(a[j]); o[4 + j] = f2b(b[j]); }
      reinterpret_cast<short8_t*>(dst)[c] = o;
    }
  } else {
    const short8_t* s = (const short8_t*)src;
    for (long long c = idx; c < nchunks; c += stride)
      reinterpret_cast<short8_t*>(dst)[c] = s[c];
  }
}

// transpose-convert one batch of slabs: src slab [R][C] (f32/bf16) -> dst slab [C][R] bf16
// grid: (C/32, R/32, nslabs), block 256. R,C multiples of 32.
__global__ void __launch_bounds__(256)
transconv_kernel(const void* src, short* dst, int R, int C, const int* flag) {
  long long zoff = (long long)blockIdx.z * R * C;
  int r0 = blockIdx.y * 32, c0 = blockIdx.x * 32;
  int tx = threadIdx.x & 31, ty = threadIdx.x >> 5;   // ty in [0,8)
  __shared__ short tile[32][33];
  if (*flag) {
    const float* s = (const float*)src + zoff;
    #pragma unroll
    for (int i = 0; i < 4; ++i)
      tile[ty + i * 8][tx] = f2b(s[(long long)(r0 + ty + i * 8) * C + c0 + tx]);
  } else {
    const short* s = (const short*)src + zoff;
    #pragma unroll
    for (int i = 0; i < 4; ++i)
      tile[ty + i * 8][tx] = s[(long long)(r0 + ty + i * 8) * C + c0 + tx];
  }
  __syncthreads();
  short* d = dst + zoff;
  #pragma unroll
  for (int i = 0; i < 4; ++i)
    d[(long long)(c0 + ty + i * 8) * R + r0 + tx] = tile[tx][ty + i * 8];
}

__global__ void __launch_bounds__(256)
embed_convert_kernel(const int* ids, const void* emb, const int* flag, short* h) {
  int s = blockIdx.x;
  long long row = ids[s];
  int c = threadIdx.x;
  short8_t o;
  if (*flag) {
    const f32x4* src = (const f32x4*)((const float*)emb + row * HDIM);
    f32x4 a = src[2 * c], b = src[2 * c + 1];
    #pragma unroll
    for (int j = 0; j < 4; ++j) { o[j] = f2b(a[j]); o[4 + j] = f2b(b[j]); }
  } else {
    o = reinterpret_cast<const short8_t*>((const short*)emb + row * HDIM)[c];
  }
  reinterpret_cast<short8_t*>(h + (long long)s * HDIM)[c] = o;
}

// ---------------- MFMA GEMM (B always [N][K] "transposed") ----------------
// A: [M][K] row-major bf16 (lda). B: [N][K] row-major bf16 (ldb).
// EPI=0: C bf16 store (ldc). EPI=1: C f32 += (ldc).
// M%128==0, K%32==0; N%8==0, guarded.
template<int EPI>
__global__ void __launch_bounds__(256)
gemm_kernel(const short* __restrict__ A, const short* __restrict__ B,
            void* __restrict__ Cv, int M, int N, int K,
            int lda, int ldb, int ldc,
            long long sAb, long long sBb, long long sCb)
{
  __shared__ short shA[128][40];
  __shared__ short shB[128][40];
  const int tid = threadIdx.x;
  const long long bz = blockIdx.z;
  const short* Ab = A + bz * sAb;
  const short* Bb = B + bz * sBb;
  const int m0 = blockIdx.x * 128;
  const int n0 = blockIdx.y * 128;
  const int w = tid >> 6, lane = tid & 63;
  const int wm = (w >> 1) << 6, wn = (w & 1) << 6;
  const int lr = lane & 15, g = lane >> 4;
  const f32x4 vzero = {0.f, 0.f, 0.f, 0.f};
  f32x4 acc[4][4];
  #pragma unroll
  for (int i = 0; i < 4; ++i)
    #pragma unroll
    for (int j = 0; j < 4; ++j) acc[i][j] = vzero;

  for (int k0 = 0; k0 < K; k0 += 32) {
    __syncthreads();
    #pragma unroll
    for (int i = 0; i < 2; ++i) {
      int c = tid + (i << 8);
      int row = c >> 2, kb = (c & 3) << 3;
      short8_t v = *reinterpret_cast<const short8_t*>(Ab + (long long)(m0 + row) * lda + k0 + kb);
      *reinterpret_cast<short8_t*>(&shA[row][kb]) = v;
    }
    #pragma unroll
    for (int i = 0; i < 2; ++i) {
      int c = tid + (i << 8);
      int row = c >> 2, kb = (c & 3) << 3;
      short8_t v = {0,0,0,0,0,0,0,0};
      if (n0 + row < N)
        v = *reinterpret_cast<const short8_t*>(Bb + (long long)(n0 + row) * ldb + k0 + kb);
      *reinterpret_cast<short8_t*>(&shB[row][kb]) = v;
    }
    __syncthreads();
    short8_t af[4];
    #pragma unroll
    for (int mi = 0; mi < 4; ++mi)
      af[mi] = *reinterpret_cast<const short8_t*>(&shA[wm + (mi << 4) + lr][g << 3]);
    #pragma unroll
    for (int ni = 0; ni < 4; ++ni) {
      short8_t bfr = *reinterpret_cast<const short8_t*>(&shB[wn + (ni << 4) + lr][g << 3]);
      #pragma unroll
      for (int mi = 0; mi < 4; ++mi)
        acc[mi][ni] = __builtin_amdgcn_mfma_f32_16x16x32_bf16(
            __builtin_bit_cast(bf16x8_t, af[mi]),
            __builtin_bit_cast(bf16x8_t, bfr),
            acc[mi][ni], 0, 0, 0);
    }
  }
  const int orow = m0 + wm + (g << 2);
  const int ocol = n0 + wn + lr;
  if (EPI == 0) {
    short* C = reinterpret_cast<short*>(Cv) + bz * sCb;
    #pragma unroll
    for (int ni = 0; ni < 4; ++ni) {
      int col = ocol + (ni << 4);
      if (col >= N) continue;
      #pragma unroll
      for (int mi = 0; mi < 4; ++mi)
        #pragma unroll
        for (int r = 0; r < 4; ++r)
          C[(long long)(orow + (mi << 4) + r) * ldc + col] = f2b(acc[mi][ni][r]);
    }
  } else {
    float* C = reinterpret_cast<float*>(Cv) + bz * sCb;
    #pragma unroll
    for (int ni = 0; ni < 4; ++ni) {
      int col = ocol + (ni << 4);
      if (col >= N) continue;
      #pragma unroll
      for (int mi = 0; mi < 4; ++mi)
        #pragma unroll
        for (int r = 0; r < 4; ++r)
          C[(long long)(orow + (mi << 4) + r) * ldc + col] += acc[mi][ni][r];
    }
  }
}

// ---------------- small kernels ----------------
__global__ void __launch_bounds__(64)
rope_tables_kernel(float* cosT, float* sinT) {
  int s = blockIdx.x, j = threadIdx.x;
  int i = j & 31;
  float inv = powf(10000.0f, -((float)(2 * i) / 64.0f));
  float ang = (float)s * inv;
  cosT[s * 64 + j] = cosf(ang);
  sinT[s * 64 + j] = sinf(ang);
}

__global__ void __launch_bounds__(256)
rmsnorm_bf16_kernel(const short* __restrict__ in, long long istride,
                    const short* __restrict__ w,
                    short* __restrict__ out, long long ostride, int D) {
  const short* x = in + (long long)blockIdx.x * istride;
  short* o = out + (long long)blockIdx.x * ostride;
  const int nc = D >> 3;
  float ss = 0.f;
  for (int c = threadIdx.x; c < nc; c += 256) {
    short8_t v = reinterpret_cast<const short8_t*>(x)[c];
    #pragma unroll
    for (int j = 0; j < 8; ++j) { float f = b2f(v[j]); ss += f * f; }
  }
  __shared__ float red[256];
  red[threadIdx.x] = ss; __syncthreads();
  for (int s2 = 128; s2 > 0; s2 >>= 1) {
    if (threadIdx.x < s2) red[threadIdx.x] += red[threadIdx.x + s2];
    __syncthreads();
  }
  float r = 1.0f / sqrtf(red[0] / (float)D + 1e-6f);
  for (int c = threadIdx.x; c < nc; c += 256) {
    short8_t v = reinterpret_cast<const short8_t*>(x)[c];
    short8_t wv = reinterpret_cast<const short8_t*>(w)[c];
    short8_t ov;
    #pragma unroll
    for (int j = 0; j < 8; ++j) ov[j] = f2b(b2f(wv[j]) * (b2f(v[j]) * r));
    reinterpret_cast<short8_t*>(o)[c] = ov;
  }
}

__global__ void __launch_bounds__(256)
build_qf_kernel(const short* q, const float* cosT, const float* sinT, short* qf) {
  int s = blockIdx.x;
  for (int idx = threadIdx.x; idx < NH_ * DQK_; idx += 256) {
    int h = idx / DQK_, d = idx - h * DQK_;
    const short* qr = q + (long long)s * QN_ + h * DQK_;
    float val;
    if (d < 128) val = b2f(qr[d]);
    else {
      int j = d - 128;
      float c = cosT[s * 64 + j], sn = sinT[s * 64 + j];
      float x0 = b2f(qr[128 + j]);
      float rot = (j < 32) ? -b2f(qr[128 + j + 32]) : b2f(qr[128 + j - 32]);
      val = x0 * c + rot * sn;
    }
    qf[(long long)h * S_LEN * DQK_ + (long long)s * DQK_ + d] = f2b(val);
  }
}

__global__ void __launch_bounds__(256)
build_kf_kernel(const short* kvup, const short* kv, const float* cosT, const float* sinT, short* kf) {
  int s = blockIdx.x;
  for (int idx = threadIdx.x; idx < NH_ * DQK_; idx += 256) {
    int h = idx / DQK_, d = idx - h * DQK_;
    float val;
    if (d < 128) val = b2f(kvup[(long long)s * KVUPN + h * 256 + d]);
    else {
      int j = d - 128;
      float c = cosT[s * 64 + j], sn = sinT[s * 64 + j];
      const short* kr = kv + (long long)s * KVDN + KVRANK_;
      float x0 = b2f(kr[j]);
      float rot = (j < 32) ? -b2f(kr[j + 32]) : b2f(kr[j - 32]);
      val = x0 * c + rot * sn;
    }
    kf[(long long)h * S_LEN * DQK_ + (long long)s * DQK_ + d] = f2b(val);
  }
}

// transpose V (head-sliced cols of kvup) into vT[h][128][S]
__global__ void __launch_bounds__(256)
transpose_v_kernel(const short* kvup, short* vT) {
  int h = blockIdx.z;
  int r0 = blockIdx.y * 32, c0 = blockIdx.x * 32;   // r over S, c over 128
  int tx = threadIdx.x & 31, ty = threadIdx.x >> 5;
  __shared__ short tile[32][33];
  #pragma unroll
  for (int i = 0; i < 4; ++i)
    tile[ty + i * 8][tx] =
        kvup[(long long)(r0 + ty + i * 8) * KVUPN + h * 256 + 128 + c0 + tx];
  __syncthreads();
  short* d = vT + (long long)h * 128 * S_LEN;
  #pragma unroll
  for (int i = 0; i < 4; ++i)
    d[(long long)(c0 + ty + i * 8) * S_LEN + r0 + tx] = tile[tx][ty + i * 8];
}

__global__ void __launch_bounds__(256)
softmax_rows_kernel(short* scores, float scale) {
  long long row = blockIdx.x;
  short8_t* p = reinterpret_cast<short8_t*>(scores + row * S_LEN);
  short8_t v = p[threadIdx.x];
  float f[8]; float m = -1e30f;
  #pragma unroll
  for (int j = 0; j < 8; ++j) { f[j] = b2f(v[j]) * scale; m = fmaxf(m, f[j]); }
  __shared__ float red[256];
  red[threadIdx.x] = m; __syncthreads();
  for (int s2 = 128; s2 > 0; s2 >>= 1) {
    if (threadIdx.x < s2) red[threadIdx.x] = fmaxf(red[threadIdx.x], red[threadIdx.x + s2]);
    __syncthreads();
  }
  m = red[0]; __syncthreads();
  float sum = 0.f;
  #pragma unroll
  for (int j = 0; j < 8; ++j) { f[j] = expf(f[j] - m); sum += f[j]; }
  red[threadIdx.x] = sum; __syncthreads();
  for (int s2 = 128; s2 > 0; s2 >>= 1) {
    if (threadIdx.x < s2) red[threadIdx.x] += red[threadIdx.x + s2];
    __syncthreads();
  }
  float inv = 1.0f / red[0];
  short8_t o;
  #pragma unroll
  for (int j = 0; j < 8; ++j) o[j] = f2b(f[j] * inv);
  p[threadIdx.x] = o;
}

__global__ void __launch_bounds__(256)
add_bf16_kernel(short* h, const short* a) {
  long long c = (long long)blockIdx.x * 256 + threadIdx.x;
  short8_t hv = reinterpret_cast<short8_t*>(h)[c];
  short8_t av = reinterpret_cast<const short8_t*>(a)[c];
  short8_t ov;
  #pragma unroll
  for (int j = 0; j < 8; ++j) ov[j] = f2b(b2f(hv[j]) + b2f(av[j]));
  reinterpret_cast<short8_t*>(h)[c] = ov;
}

__global__ void __launch_bounds__(256)
add_f32_kernel(short* h, const float* a) {
  long long c = (long long)blockIdx.x * 256 + threadIdx.x;
  short8_t hv = reinterpret_cast<short8_t*>(h)[c];
  f32x4 a0 = reinterpret_cast<const f32x4*>(a)[2 * c];
  f32x4 a1 = reinterpret_cast<const f32x4*>(a)[2 * c + 1];
  short8_t ov;
  #pragma unroll
  for (int j = 0; j < 4; ++j) {
    ov[j]     = f2b(b2f(hv[j])     + a0[j]);
    ov[4 + j] = f2b(b2f(hv[4 + j]) + a1[j]);
  }
  reinterpret_cast<short8_t*>(h)[c] = ov;
}

__global__ void __launch_bounds__(256)
gate_kernel(const short* x2, const short* gw, short* combine) {
  int t = blockIdx.x;
  int e = threadIdx.x >> 5, j = threadIdx.x & 31;
  const short* x = x2 + (long long)t * HDIM;
  float acc = 0.f;
  for (int k = j; k < HDIM; k += 32) acc += b2f(x[k]) * b2f(gw[(long long)k * EXP_ + e]);
  __shared__ float red[8][32];
  red[e][j] = acc; __syncthreads();
  for (int s2 = 16; s2 > 0; s2 >>= 1) {
    if (j < s2) red[e][j] += red[e][j + s2];
    __syncthreads();
  }
  if (threadIdx.x == 0) {
    float l[8], p[8];
    float m = -1e30f;
    for (int q = 0; q < 8; ++q) { l[q] = b2f(f2b(red[q][0])); m = fmaxf(m, l[q]); }
    float sum = 0.f;
    for (int q = 0; q < 8; ++q) { p[q] = expf(l[q] - m); sum += p[q]; }
    int i0 = 0; for (int q = 1; q < 8; ++q) if (p[q] > p[i0]) i0 = q;
    int i1 = (i0 == 0) ? 1 : 0;
    for (int q = 0; q < 8; ++q) if (q != i0 && p[q] > p[i1]) i1 = q;
    float denom = p[i0] + p[i1];
    short* row = combine + (long long)t * EXP_;
    for (int q = 0; q < 8; ++q) row[q] = 0;
    row[i0] = f2b(p[i0] / denom);
    row[i1] = f2b(p[i1] / denom);
  }
}

__global__ void __launch_bounds__(256)
silu_mul_kernel(short* a, const short* b, const short* combine, int e) {
  int t = blockIdx.x;
  float scale = 1.0f;
  if (combine) scale = b2f(combine[(long long)t * EXP_ + e]);
  int c = threadIdx.x;
  if (c >= IFF_ / 8) return;
  short8_t av = reinterpret_cast<short8_t*>(a + (long long)t * IFF_)[c];
  short8_t bv = reinterpret_cast<const short8_t*>(b + (long long)t * IFF_)[c];
  short8_t ov;
  #pragma unroll
  for (int j = 0; j < 8; ++j) {
    float x = b2f(av[j]);
    float s = x / (1.0f + expf(-x));
    ov[j] = f2b(s * b2f(bv[j]) * scale);
  }
  reinterpret_cast<short8_t*>(a + (long long)t * IFF_)[c] = ov;
}

// ---------------- pooling (all row-contiguous, one block per output) ----------------
// out[n] = sum_k a[k] * BT[n][k].  AF32: a is f32 else bf16. OUTBF16: store bf16 else f32.
template<int AF32, int OUTBF16>
__global__ void __launch_bounds__(256)
gemv_bt_kernel(const void* a, const short* __restrict__ BT, void* out, int K) {
  int n = blockIdx.x;
  const short8_t* row = reinterpret_cast<const short8_t*>(BT + (long long)n * K);
  float acc = 0.f;
  for (int c = threadIdx.x; c < (K >> 3); c += 256) {
    short8_t v = row[c];
    if (AF32) {
      f32x4 a0 = reinterpret_cast<const f32x4*>(a)[2 * c];
      f32x4 a1 = reinterpret_cast<const f32x4*>(a)[2 * c + 1];
      #pragma unroll
      for (int j = 0; j < 4; ++j) {
        acc += a0[j] * b2f(v[j]);
        acc += a1[j] * b2f(v[4 + j]);
      }
    } else {
      short8_t av = reinterpret_cast<const short8_t*>(a)[c];
      #pragma unroll
      for (int j = 0; j < 8; ++j) acc += b2f(av[j]) * b2f(v[j]);
    }
  }
  __shared__ float red[256];
  red[threadIdx.x] = acc; __syncthreads();
  for (int s2 = 128; s2 > 0; s2 >>= 1) {
    if (threadIdx.x < s2) red[threadIdx.x] += red[threadIdx.x + s2];
    __syncthreads();
  }
  if (threadIdx.x == 0) {
    if (OUTBF16) ((short*)out)[n] = f2b(red[0]);
    else         ((float*)out)[n] = red[0];
  }
}

__global__ void __launch_bounds__(256)
pool_score_kernel(const short* qv, const short* kmat, float* score) {
  int s = blockIdx.x;
  const short8_t* kr = reinterpret_cast<const short8_t*>(kmat + (long long)s * HDIM);
  const short8_t* qr = reinterpret_cast<const short8_t*>(qv);
  short8_t kv8 = kr[threadIdx.x], qv8 = qr[threadIdx.x];
  float acc = 0.f;
  #pragma unroll
  for (int j = 0; j < 8; ++j) acc += b2f(qv8[j]) * b2f(kv8[j]);
  __shared__ float red[256];
  red[threadIdx.x] = acc; __syncthreads();
  for (int s2 = 128; s2 > 0; s2 >>= 1) {
    if (threadIdx.x < s2) red[threadIdx.x] += red[threadIdx.x + s2];
    __syncthreads();
  }
  if (threadIdx.x == 0) score[s] = b2f(f2b(red[0])) * 0.022097086912079608f; // 1/sqrt(2048)
}

__global__ void __launch_bounds__(256)
softmax_vec_kernel(float* v) {
  int tid = threadIdx.x;
  float f[8]; float m = -1e30f;
  #pragma unroll
  for (int i = 0; i < 8; ++i) { f[i] = v[i * 256 + tid]; m = fmaxf(m, f[i]); }
  __shared__ float red[256];
  red[tid] = m; __syncthreads();
  for (int s2 = 128; s2 > 0; s2 >>= 1) {
    if (tid < s2) red[tid] = fmaxf(red[tid], red[tid + s2]);
    __syncthreads();
  }
  m = red[0]; __syncthreads();
  float sum = 0.f;
  #pragma unroll
  for (int i = 0; i < 8; ++i) { f[i] = expf(f[i] - m); sum += f[i]; }
  red[tid] = sum; __syncthreads();
  for (int s2 = 128; s2 > 0; s2 >>= 1) {
    if (tid < s2) red[tid] += red[tid + s2];
    __syncthreads();
  }
  float inv = 1.0f / red[0];
  #pragma unroll
  for (int i = 0; i < 8; ++i) v[i * 256 + tid] = f[i] * inv;
}

// pooled[h] = sum_s w[s] * vT[h][s]   (vT row-contiguous)
__global__ void __launch_bounds__(256)
pool_wsum_t_kernel(const float* w, const short* vT, float* pooled) {
  int h = blockIdx.x;
  const short8_t* row = reinterpret_cast<const short8_t*>(vT + (long long)h * S_LEN);
  int c = threadIdx.x;
  short8_t v = row[c];
  f32x4 w0 = reinterpret_cast<const f32x4*>(w)[2 * c];
  f32x4 w1 = reinterpret_cast<const f32x4*>(w)[2 * c + 1];
  float acc = 0.f;
  #pragma unroll
  for (int j = 0; j < 4; ++j) {
    acc += w0[j] * b2f(v[j]);
    acc += w1[j] * b2f(v[4 + j]);
  }
  __shared__ float red[256];
  red[threadIdx.x] = acc; __syncthreads();
  for (int s2 = 128; s2 > 0; s2 >>= 1) {
    if (threadIdx.x < s2) red[threadIdx.x] += red[threadIdx.x + s2];
    __syncthreads();
  }
  if (threadIdx.x == 0) pooled[h] = red[0];
}

__global__ void __launch_bounds__(256)
rmsnorm_f32_kernel(const float* x, const short* w, float* out) {
  int tid = threadIdx.x;
  float f[8]; float ss = 0.f;
  #pragma unroll
  for (int i = 0; i < 8; ++i) { f[i] = x[i * 256 + tid]; ss += f[i] * f[i]; }
  __shared__ float red[256];
  red[tid] = ss; __syncthreads();
  for (int s2 = 128; s2 > 0; s2 >>= 1) {
    if (tid < s2) red[tid] += red[tid + s2];
    __syncthreads();
  }
  float r = 1.0f / sqrtf(red[0] / 2048.0f + 1e-6f);
  #pragma unroll
  for (int i = 0; i < 8; ++i) out[i * 256 + tid] = b2f(w[i * 256 + tid]) * (f[i] * r);
}

// ---------------- host ----------------
extern "C" void kernel_launch(void* const* d_in, const int* in_sizes, int n_in,
                              void* d_out, int out_size, void* d_ws, size_t ws_size,
                              hipStream_t stream)
{
  (void)n_in; (void)out_size; (void)ws_size;
  const int* ids = (const int*)d_in[24];

  char* base = (char*)d_ws;
  size_t off = 0;
  auto alloc = [&](size_t bytes) -> void* {
    void* p = base + off;
    off += (bytes + 255) & ~(size_t)255;
    return p;
  };

  int* dflag = (int*)alloc(256);

  // transposed weights [N][K]
  short* qdwT  = (short*)alloc((size_t)2 * QRANK_ * HDIM * 2);
  short* quwT  = (short*)alloc((size_t)2 * QN_ * QRANK_ * 2);
  short* kvdwT = (short*)alloc((size_t)2 * KVDN * HDIM * 2);
  short* kvuwT = (short*)alloc((size_t)2 * KVUPN * KVRANK_ * 2);
  short* opwT  = (short*)alloc((size_t)2 * HDIM * HDIM * 2);
  short* rw1T  = (short*)alloc((size_t)16 * IFF_ * HDIM * 2);
  short* rw2T  = (short*)alloc((size_t)16 * HDIM * IFF_ * 2);
  short* rw3T  = (short*)alloc((size_t)16 * IFF_ * HDIM * 2);
  short* sw1T  = (short*)alloc((size_t)4 * IFF_ * HDIM * 2);
  short* sw2T  = (short*)alloc((size_t)4 * HDIM * IFF_ * 2);
  short* sw3T  = (short*)alloc((size_t)4 * IFF_ * HDIM * 2);
  short* pqwT  = (short*)alloc((size_t)HDIM * HDIM * 2);
  short* pkwT  = (short*)alloc((size_t)HDIM * HDIM * 2);
  short* pvwT  = (short*)alloc((size_t)HDIM * HDIM * 2);
  short* powT  = (short*)alloc((size_t)PD_ * HDIM * 2);
  // plain-converted small weights
  short* ln1w = (short*)alloc((size_t)in_sizes[1] * 2);
  short* qnw  = (short*)alloc((size_t)in_sizes[3] * 2);
  short* kvnw = (short*)alloc((size_t)in_sizes[6] * 2);
  short* ln2w = (short*)alloc((size_t)in_sizes[9] * 2);
  short* gatw = (short*)alloc((size_t)in_sizes[10] * 2);
  short* fnww = (short*)alloc((size_t)in_sizes[17] * 2);
  short* lqw  = (short*)alloc((size_t)in_sizes[18] * 2);
  short* pnww = (short*)alloc((size_t)in_sizes[23] * 2);

  float* cosT    = (float*)alloc((size_t)S_LEN * 64 * 4);
  float* sinT    = (float*)alloc((size_t)S_LEN * 64 * 4);
  short* hbuf    = (short*)alloc((size_t)S_LEN * HDIM * 2);
  short* xbuf    = (short*)alloc((size_t)S_LEN * HDIM * 2);
  short* qlat    = (short*)alloc((size_t)S_LEN * QRANK_ * 2);
  short* qlatn   = (short*)alloc((size_t)S_LEN * QRANK_ * 2);
  short* qbuf    = (short*)alloc((size_t)S_LEN * QN_ * 2);
  short* kvbuf   = (short*)alloc((size_t)S_LEN * KVDN * 2);
  short* kvn     = (short*)alloc((size_t)S_LEN * KVRANK_ * 2);
  short* kvup    = (short*)alloc((size_t)S_LEN * KVUPN * 2);
  short* qf      = (short*)alloc((size_t)NH_ * S_LEN * DQK_ * 2);
  short* kf      = (short*)alloc((size_t)NH_ * S_LEN * DQK_ * 2);
  short* vT      = (short*)alloc((size_t)NH_ * 128 * S_LEN * 2);
  short* scores  = (short*)alloc((size_t)HG_ * S_LEN * S_LEN * 2);
  short* ao      = (short*)alloc((size_t)S_LEN * HDIM * 2);
  short* attnp   = (short*)alloc((size_t)S_LEN * HDIM * 2);
  float* moeacc  = (float*)alloc((size_t)S_LEN * HDIM * 4);
  short* gba     = (short*)alloc((size_t)S_LEN * IFF_ * 2);
  short* gbb     = (short*)alloc((size_t)S_LEN * IFF_ * 2);
  short* combine = (short*)alloc((size_t)S_LEN * EXP_ * 2);
  short* hfin    = (short*)alloc((size_t)S_LEN * HDIM * 2);
  short* kpool   = (short*)alloc((size_t)S_LEN * HDIM * 2);
  short* vpoolT  = (short*)alloc((size_t)HDIM * S_LEN * 2);
  short* qvec    = (short*)alloc((size_t)HDIM * 2);
  float* pscore  = (float*)alloc((size_t)S_LEN * 4);
  float* pooled  = (float*)alloc((size_t)HDIM * 4);
  float* pooledn = (float*)alloc((size_t)HDIM * 4);

  detect_kernel<<<1, 256, 0, stream>>>(d_in[0], dflag);

  auto tconv = [&](const void* src, short* dst, int R, int C, int nslabs) {
    dim3 grid(C / 32, R / 32, nslabs);
    transconv_kernel<<<grid, 256, 0, stream>>>(src, dst, R, C, dflag);
  };
  auto pconv = [&](const void* src, short* dst, long long n) {
    long long nchunks = n / 8;
    int blocks = (int)((nchunks + 255) / 256);
    if (blocks > 2048) blocks = 2048;
    if (blocks < 1) blocks = 1;
    convert_kernel<<<blocks, 256, 0, stream>>>(src, dst, nchunks, dflag);
  };

  tconv(d_in[2],  qdwT,  HDIM,   QRANK_, 2);
  tconv(d_in[4],  quwT,  QRANK_, QN_,    2);
  tconv(d_in[5],  kvdwT, HDIM,   KVDN,   2);
  tconv(d_in[7],  kvuwT, KVRANK_,KVUPN,  2);
  tconv(d_in[8],  opwT,  HDIM,   HDIM,   2);
  tconv(d_in[11], rw1T,  HDIM,   IFF_,   16);
  tconv(d_in[12], rw2T,  IFF_,   HDIM,   16);
  tconv(d_in[13], rw3T,  HDIM,   IFF_,   16);
  tconv(d_in[14], sw1T,  HDIM,   IFF_,   4);
  tconv(d_in[15], sw2T,  IFF_,   HDIM,   4);
  tconv(d_in[16], sw3T,  HDIM,   IFF_,   4);
  tconv(d_in[19], pqwT,  HDIM,   HDIM,   1);
  tconv(d_in[20], pkwT,  HDIM,   HDIM,   1);
  tconv(d_in[21], pvwT,  HDIM,   HDIM,   1);
  tconv(d_in[22], powT,  HDIM,   PD_,    1);
  pconv(d_in[1],  ln1w, in_sizes[1]);
  pconv(d_in[3],  qnw,  in_sizes[3]);
  pconv(d_in[6],  kvnw, in_sizes[6]);
  pconv(d_in[9],  ln2w, in_sizes[9]);
  pconv(d_in[10], gatw, in_sizes[10]);
  pconv(d_in[17], fnww, in_sizes[17]);
  pconv(d_in[18], lqw,  in_sizes[18]);
  pconv(d_in[23], pnww, in_sizes[23]);

  const float qk_scale = 1.0f / sqrtf((float)DQK_);

  auto gemm = [&](int epi, const short* A, const short* B, void* C,
                  int M, int N, int K, int lda, int ldb, int ldc,
                  int batch, long long sA, long long sB, long long sC) {
    dim3 grid(M / 128, (N + 127) / 128, batch);
    if (epi == 0)
      gemm_kernel<0><<<grid, 256, 0, stream>>>(A, B, C, M, N, K, lda, ldb, ldc, sA, sB, sC);
    else
      gemm_kernel<1><<<grid, 256, 0, stream>>>(A, B, C, M, N, K, lda, ldb, ldc, sA, sB, sC);
  };

  rope_tables_kernel<<<S_LEN, 64, 0, stream>>>(cosT, sinT);
  embed_convert_kernel<<<S_LEN, 256, 0, stream>>>(ids, d_in[0], dflag, hbuf);

  for (int l = 0; l < 2; ++l) {
    const short* w_ln1 = ln1w + (size_t)l * HDIM;
    const short* w_qdT = qdwT + (size_t)l * QRANK_ * HDIM;
    const short* w_qn  = qnw  + (size_t)l * QRANK_;
    const short* w_quT = quwT + (size_t)l * QN_ * QRANK_;
    const short* w_kvdT= kvdwT+ (size_t)l * KVDN * HDIM;
    const short* w_kvn = kvnw + (size_t)l * KVRANK_;
    const short* w_kvuT= kvuwT+ (size_t)l * KVUPN * KVRANK_;
    const short* w_opT = opwT + (size_t)l * HDIM * HDIM;
    const short* w_ln2 = ln2w + (size_t)l * HDIM;
    const short* w_gat = gatw + (size_t)l * HDIM * EXP_;

    // --- attention ---
    rmsnorm_bf16_kernel<<<S_LEN, 256, 0, stream>>>(hbuf, HDIM, w_ln1, xbuf, HDIM, HDIM);
    gemm(0, xbuf, w_qdT, qlat, S_LEN, QRANK_, HDIM, HDIM, HDIM, QRANK_, 1, 0, 0, 0);
    rmsnorm_bf16_kernel<<<S_LEN, 256, 0, stream>>>(qlat, QRANK_, w_qn, qlatn, QRANK_, QRANK_);
    gemm(0, qlatn, w_quT, qbuf, S_LEN, QN_, QRANK_, QRANK_, QRANK_, QN_, 1, 0, 0, 0);
    gemm(0, xbuf, w_kvdT, kvbuf, S_LEN, KVDN, HDIM, HDIM, HDIM, KVDN, 1, 0, 0, 0);
    rmsnorm_bf16_kernel<<<S_LEN, 256, 0, stream>>>(kvbuf, KVDN, w_kvn, kvn, KVRANK_, KVRANK_);
    gemm(0, kvn, w_kvuT, kvup, S_LEN, KVUPN, KVRANK_, KVRANK_, KVRANK_, KVUPN, 1, 0, 0, 0);
    build_qf_kernel<<<S_LEN, 256, 0, stream>>>(qbuf, cosT, sinT, qf);
    build_kf_kernel<<<S_LEN, 256, 0, stream>>>(kvup, kvbuf, cosT, sinT, kf);
    {
      dim3 tg(128 / 32, S_LEN / 32, NH_);
      transpose_v_kernel<<<tg, 256, 0, stream>>>(kvup, vT);
    }
    for (int hg = 0; hg < NH_ / HG_; ++hg) {
      gemm(0, qf + (size_t)hg * HG_ * S_LEN * DQK_, kf + (size_t)hg * HG_ * S_LEN * DQK_,
           scores, S_LEN, S_LEN, DQK_, DQK_, DQK_, S_LEN, HG_,
           (long long)S_LEN * DQK_, (long long)S_LEN * DQK_, (long long)S_LEN * S_LEN);
      softmax_rows_kernel<<<HG_ * S_LEN, 256, 0, stream>>>(scores, qk_scale);
      gemm(0, scores, vT + (size_t)hg * HG_ * 128 * S_LEN, ao + hg * HG_ * 128,
           S_LEN, 128, S_LEN, S_LEN, S_LEN, HDIM, HG_,
           (long long)S_LEN * S_LEN, (long long)128 * S_LEN, 128);
    }
    gemm(0, ao, w_opT, attnp, S_LEN, HDIM, HDIM, HDIM, HDIM, HDIM, 1, 0, 0, 0);
    add_bf16_kernel<<<S_LEN, 256, 0, stream>>>(hbuf, attnp);

    // --- MoE ---
    rmsnorm_bf16_kernel<<<S_LEN, 256, 0, stream>>>(hbuf, HDIM, w_ln2, xbuf, HDIM, HDIM);
    gate_kernel<<<S_LEN, 256, 0, stream>>>(xbuf, w_gat, combine);
    hipMemsetAsync(moeacc, 0, (size_t)S_LEN * HDIM * 4, stream);
    for (int j = 0; j < 2; ++j) {
      const short* a1 = sw1T + ((size_t)l * 2 + j) * IFF_ * HDIM;
      const short* a3 = sw3T + ((size_t)l * 2 + j) * IFF_ * HDIM;
      const short* a2 = sw2T + ((size_t)l * 2 + j) * HDIM * IFF_;
      gemm(0, xbuf, a1, gba, S_LEN, IFF_, HDIM, HDIM, HDIM, IFF_, 1, 0, 0, 0);
      gemm(0, xbuf, a3, gbb, S_LEN, IFF_, HDIM, HDIM, HDIM, IFF_, 1, 0, 0, 0);
      silu_mul_kernel<<<S_LEN, 256, 0, stream>>>(gba, gbb, (const short*)nullptr, 0);
      gemm(1, gba, a2, moeacc, S_LEN, HDIM, IFF_, IFF_, IFF_, HDIM, 1, 0, 0, 0);
    }
    for (int e = 0; e < 8; ++e) {
      const short* a1 = rw1T + ((size_t)l * 8 + e) * IFF_ * HDIM;
      const short* a3 = rw3T + ((size_t)l * 8 + e) * IFF_ * HDIM;
      const short* a2 = rw2T + ((size_t)l * 8 + e) * HDIM * IFF_;
      gemm(0, xbuf, a1, gba, S_LEN, IFF_, HDIM, HDIM, HDIM, IFF_, 1, 0, 0, 0);
      gemm(0, xbuf, a3, gbb, S_LEN, IFF_, HDIM, HDIM, HDIM, IFF_, 1, 0, 0, 0);
      silu_mul_kernel<<<S_LEN, 256, 0, stream>>>(gba, gbb, combine, e);
      gemm(1, gba, a2, moeacc, S_LEN, HDIM, IFF_, IFF_, IFF_, HDIM, 1, 0, 0, 0);
    }
    add_f32_kernel<<<S_LEN, 256, 0, stream>>>(hbuf, moeacc);
  }

  // --- attention pooling head ---
  rmsnorm_bf16_kernel<<<S_LEN, 256, 0, stream>>>(hbuf, HDIM, fnww, hfin, HDIM, HDIM);
  gemm(0, hfin, pkwT, kpool, S_LEN, HDIM, HDIM, HDIM, HDIM, HDIM, 1, 0, 0, 0);
  gemm(0, pvwT, hfin, vpoolT, HDIM, S_LEN, HDIM, HDIM, HDIM, S_LEN, 1, 0, 0, 0);
  gemv_bt_kernel<0,1><<<HDIM, 256, 0, stream>>>(lqw, pqwT, qvec, HDIM);
  pool_score_kernel<<<S_LEN, 256, 0, stream>>>(qvec, kpool, pscore);
  softmax_vec_kernel<<<1, 256, 0, stream>>>(pscore);
  pool_wsum_t_kernel<<<HDIM, 256, 0, stream>>>(pscore, vpoolT, pooled);
  rmsnorm_f32_kernel<<<1, 256, 0, stream>>>(pooled, pnww, pooledn);
  gemv_bt_kernel<1,0><<<PD_, 256, 0, stream>>>(pooledn, powT, (float*)d_out, HDIM);
}

// Round 4
// 3907.311 us; speedup vs baseline: 3.0267x; 1.6254x over previous
//
#include <hip/hip_runtime.h>
#include <hip/hip_bf16.h>

#define S_LEN  2048
#define HDIM   2048
#define NH_    16
#define DQK_   192
#define QRANK_ 1024
#define KVRANK_ 512
#define KVDN   576    // KV_RANK + D_ROPE
#define KVUPN  4096   // NH*(D_NOPE+D_V)
#define QN_    3072   // NH*D_QK
#define IFF_   1408
#define EXP_   8
#define HG_    4      // heads per attention chunk
#define PD_    4096

typedef __attribute__((ext_vector_type(8))) short   short8_t;
typedef __attribute__((ext_vector_type(8))) __bf16  bf16x8_t;
typedef __attribute__((ext_vector_type(4))) float   f32x4;

static __device__ __forceinline__ float b2f(short s) {
  unsigned int u = ((unsigned int)(unsigned short)s) << 16;
  return __builtin_bit_cast(float, u);
}
static __device__ __forceinline__ short f2b(float f) {
  return __builtin_bit_cast(short, __float2bfloat16(f));
}

// ---------------- dtype detect + convert ----------------
__global__ void __launch_bounds__(256)
detect_kernel(const void* probe, int* flag) {
  const float* f = (const float*)probe;
  int tid = threadIdx.x;
  int cnt = 0;
  for (int i = tid; i < 2048; i += 256) {
    float v = fabsf(f[i]);
    if (v > 1e-6f && v < 10.0f) cnt++;
  }
  __shared__ int red[256];
  red[tid] = cnt; __syncthreads();
  for (int s = 128; s > 0; s >>= 1) {
    if (tid < s) red[tid] += red[tid + s];
    __syncthreads();
  }
  if (tid == 0) *flag = (red[0] > 1600) ? 1 : 0;
}

__global__ void __launch_bounds__(256)
convert_kernel(const void* src, short* dst, long long nchunks, const int* flag) {
  long long idx = (long long)blockIdx.x * 256 + threadIdx.x;
  long long stride = (long long)gridDim.x * 256;
  if (*flag) {
    const f32x4* s = (const f32x4*)src;
    for (long long c = idx; c < nchunks; c += stride) {
      f32x4 a = s[2 * c], b = s[2 * c + 1];
      short8_t o;
      #pragma unroll
      for (int j = 0; j < 4; ++j) { o[j] = f2b(a[j]); o[4 + j] = f2b(b[j]); }
      reinterpret_cast<short8_t*>(dst)[c] = o;
    }
  } else {
    const short8_t* s = (const short8_t*)src;
    for (long long c = idx; c < nchunks; c += stride)
      reinterpret_cast<short8_t*>(dst)[c] = s[c];
  }
}

// transpose-convert: src slab [R][C] (f32/bf16) -> dst slab [C][R] bf16
__global__ void __launch_bounds__(256)
transconv_kernel(const void* src, short* dst, int R, int C, const int* flag) {
  long long zoff = (long long)blockIdx.z * R * C;
  int r0 = blockIdx.y * 32, c0 = blockIdx.x * 32;
  int tx = threadIdx.x & 31, ty = threadIdx.x >> 5;
  __shared__ short tile[32][33];
  if (*flag) {
    const float* s = (const float*)src + zoff;
    #pragma unroll
    for (int i = 0; i < 4; ++i)
      tile[ty + i * 8][tx] = f2b(s[(long long)(r0 + ty + i * 8) * C + c0 + tx]);
  } else {
    const short* s = (const short*)src + zoff;
    #pragma unroll
    for (int i = 0; i < 4; ++i)
      tile[ty + i * 8][tx] = s[(long long)(r0 + ty + i * 8) * C + c0 + tx];
  }
  __syncthreads();
  short* d = dst + zoff;
  #pragma unroll
  for (int i = 0; i < 4; ++i)
    d[(long long)(c0 + ty + i * 8) * R + r0 + tx] = tile[tx][ty + i * 8];
}

__global__ void __launch_bounds__(256)
embed_convert_kernel(const int* ids, const void* emb, const int* flag, short* h) {
  int s = blockIdx.x;
  long long row = ids[s];
  int c = threadIdx.x;
  short8_t o;
  if (*flag) {
    const f32x4* src = (const f32x4*)((const float*)emb + row * HDIM);
    f32x4 a = src[2 * c], b = src[2 * c + 1];
    #pragma unroll
    for (int j = 0; j < 4; ++j) { o[j] = f2b(a[j]); o[4 + j] = f2b(b[j]); }
  } else {
    o = reinterpret_cast<const short8_t*>((const short*)emb + row * HDIM)[c];
  }
  reinterpret_cast<short8_t*>(h + (long long)s * HDIM)[c] = o;
}

// ---------------- MFMA GEMM (B always [N][K]) ----------------
template<int EPI>
__global__ void __launch_bounds__(256)
gemm_kernel(const short* __restrict__ A, const short* __restrict__ B,
            void* __restrict__ Cv, int M, int N, int K,
            int lda, int ldb, int ldc,
            long long sAb, long long sBb, long long sCb)
{
  __shared__ short shA[128][40];
  __shared__ short shB[128][40];
  const int tid = threadIdx.x;
  const long long bz = blockIdx.z;
  const short* Ab = A + bz * sAb;
  const short* Bb = B + bz * sBb;
  const int m0 = blockIdx.x * 128;
  const int n0 = blockIdx.y * 128;
  const int w = tid >> 6, lane = tid & 63;
  const int wm = (w >> 1) << 6, wn = (w & 1) << 6;
  const int lr = lane & 15, g = lane >> 4;
  const f32x4 vzero = {0.f, 0.f, 0.f, 0.f};
  f32x4 acc[4][4];
  #pragma unroll
  for (int i = 0; i < 4; ++i)
    #pragma unroll
    for (int j = 0; j < 4; ++j) acc[i][j] = vzero;

  for (int k0 = 0; k0 < K; k0 += 32) {
    __syncthreads();
    #pragma unroll
    for (int i = 0; i < 2; ++i) {
      int c = tid + (i << 8);
      int row = c >> 2, kb = (c & 3) << 3;
      short8_t v = *reinterpret_cast<const short8_t*>(Ab + (long long)(m0 + row) * lda + k0 + kb);
      *reinterpret_cast<short8_t*>(&shA[row][kb]) = v;
    }
    #pragma unroll
    for (int i = 0; i < 2; ++i) {
      int c = tid + (i << 8);
      int row = c >> 2, kb = (c & 3) << 3;
      short8_t v = {0,0,0,0,0,0,0,0};
      if (n0 + row < N)
        v = *reinterpret_cast<const short8_t*>(Bb + (long long)(n0 + row) * ldb + k0 + kb);
      *reinterpret_cast<short8_t*>(&shB[row][kb]) = v;
    }
    __syncthreads();
    short8_t af[4];
    #pragma unroll
    for (int mi = 0; mi < 4; ++mi)
      af[mi] = *reinterpret_cast<const short8_t*>(&shA[wm + (mi << 4) + lr][g << 3]);
    #pragma unroll
    for (int ni = 0; ni < 4; ++ni) {
      short8_t bfr = *reinterpret_cast<const short8_t*>(&shB[wn + (ni << 4) + lr][g << 3]);
      #pragma unroll
      for (int mi = 0; mi < 4; ++mi)
        acc[mi][ni] = __builtin_amdgcn_mfma_f32_16x16x32_bf16(
            __builtin_bit_cast(bf16x8_t, af[mi]),
            __builtin_bit_cast(bf16x8_t, bfr),
            acc[mi][ni], 0, 0, 0);
    }
  }
  const int orow = m0 + wm + (g << 2);
  const int ocol = n0 + wn + lr;
  if (EPI == 0) {
    short* C = reinterpret_cast<short*>(Cv) + bz * sCb;
    #pragma unroll
    for (int ni = 0; ni < 4; ++ni) {
      int col = ocol + (ni << 4);
      if (col >= N) continue;
      #pragma unroll
      for (int mi = 0; mi < 4; ++mi)
        #pragma unroll
        for (int r = 0; r < 4; ++r)
          C[(long long)(orow + (mi << 4) + r) * ldc + col] = f2b(acc[mi][ni][r]);
    }
  } else {
    float* C = reinterpret_cast<float*>(Cv) + bz * sCb;
    #pragma unroll
    for (int ni = 0; ni < 4; ++ni) {
      int col = ocol + (ni << 4);
      if (col >= N) continue;
      #pragma unroll
      for (int mi = 0; mi < 4; ++mi)
        #pragma unroll
        for (int r = 0; r < 4; ++r)
          C[(long long)(orow + (mi << 4) + r) * ldc + col] += acc[mi][ni][r];
    }
  }
}

// ---------------- sparse MoE gather GEMM ----------------
// z = expert. GATHER=1: A row = src[elist[e][row]] (lda stride), C compact.
// GATHER=0: A compact (per-expert slab), C compact. C bf16, rows >= cnt[e] skipped.
template<int GATHER>
__global__ void __launch_bounds__(256)
moe_gemm_kernel(const short* __restrict__ A, const int* __restrict__ elist,
                const int* __restrict__ cnt, const short* __restrict__ B,
                short* __restrict__ C, int N, int K,
                int lda, int ldb, int ldc,
                long long sAe, long long sBe, long long sCe)
{
  const int e = blockIdx.z;
  const int cnt_e = cnt[e];
  const int m0 = blockIdx.x * 128;
  if (m0 >= cnt_e) return;
  const short* Bb = B + (long long)e * sBe;
  short* Cb = C + (long long)e * sCe;
  const int n0 = blockIdx.y * 128;
  const int tid = threadIdx.x;
  const int w = tid >> 6, lane = tid & 63;
  const int wm = (w >> 1) << 6, wn = (w & 1) << 6;
  const int lr = lane & 15, g = lane >> 4;

  // per-thread A-staging rows are fixed: rows tid>>2 and (tid+256)>>2
  long long arow[2];
  #pragma unroll
  for (int i = 0; i < 2; ++i) {
    int row = (tid + (i << 8)) >> 2;
    if (GATHER) {
      int p = m0 + row; if (p > cnt_e - 1) p = cnt_e - 1;
      arow[i] = (long long)elist[e * S_LEN + p] * lda;
    } else {
      arow[i] = (long long)e * sAe + (long long)(m0 + row) * lda;
    }
  }

  __shared__ short shA[128][40];
  __shared__ short shB[128][40];
  const f32x4 vzero = {0.f, 0.f, 0.f, 0.f};
  f32x4 acc[4][4];
  #pragma unroll
  for (int i = 0; i < 4; ++i)
    #pragma unroll
    for (int j = 0; j < 4; ++j) acc[i][j] = vzero;

  for (int k0 = 0; k0 < K; k0 += 32) {
    __syncthreads();
    #pragma unroll
    for (int i = 0; i < 2; ++i) {
      int c = tid + (i << 8);
      int row = c >> 2, kb = (c & 3) << 3;
      short8_t v = *reinterpret_cast<const short8_t*>(A + arow[i] + k0 + kb);
      *reinterpret_cast<short8_t*>(&shA[row][kb]) = v;
    }
    #pragma unroll
    for (int i = 0; i < 2; ++i) {
      int c = tid + (i << 8);
      int row = c >> 2, kb = (c & 3) << 3;
      short8_t v = *reinterpret_cast<const short8_t*>(Bb + (long long)(n0 + row) * ldb + k0 + kb);
      *reinterpret_cast<short8_t*>(&shB[row][kb]) = v;
    }
    __syncthreads();
    short8_t af[4];
    #pragma unroll
    for (int mi = 0; mi < 4; ++mi)
      af[mi] = *reinterpret_cast<const short8_t*>(&shA[wm + (mi << 4) + lr][g << 3]);
    #pragma unroll
    for (int ni = 0; ni < 4; ++ni) {
      short8_t bfr = *reinterpret_cast<const short8_t*>(&shB[wn + (ni << 4) + lr][g << 3]);
      #pragma unroll
      for (int mi = 0; mi < 4; ++mi)
        acc[mi][ni] = __builtin_amdgcn_mfma_f32_16x16x32_bf16(
            __builtin_bit_cast(bf16x8_t, af[mi]),
            __builtin_bit_cast(bf16x8_t, bfr),
            acc[mi][ni], 0, 0, 0);
    }
  }
  const int orow = m0 + wm + (g << 2);
  const int ocol = n0 + wn + lr;
  #pragma unroll
  for (int ni = 0; ni < 4; ++ni) {
    int col = ocol + (ni << 4);
    #pragma unroll
    for (int mi = 0; mi < 4; ++mi) {
      int rbase = orow + (mi << 4);
      #pragma unroll
      for (int r = 0; r < 4; ++r)
        if (rbase + r < cnt_e)
          Cb[(long long)(rbase + r) * ldc + col] = f2b(acc[mi][ni][r]);
    }
  }
}

// ---------------- small kernels ----------------
__global__ void __launch_bounds__(64)
rope_tables_kernel(float* cosT, float* sinT) {
  int s = blockIdx.x, j = threadIdx.x;
  int i = j & 31;
  float inv = powf(10000.0f, -((float)(2 * i) / 64.0f));
  float ang = (float)s * inv;
  cosT[s * 64 + j] = cosf(ang);
  sinT[s * 64 + j] = sinf(ang);
}

__global__ void __launch_bounds__(256)
rmsnorm_bf16_kernel(const short* __restrict__ in, long long istride,
                    const short* __restrict__ w,
                    short* __restrict__ out, long long ostride, int D) {
  const short* x = in + (long long)blockIdx.x * istride;
  short* o = out + (long long)blockIdx.x * ostride;
  const int nc = D >> 3;
  float ss = 0.f;
  for (int c = threadIdx.x; c < nc; c += 256) {
    short8_t v = reinterpret_cast<const short8_t*>(x)[c];
    #pragma unroll
    for (int j = 0; j < 8; ++j) { float f = b2f(v[j]); ss += f * f; }
  }
  __shared__ float red[256];
  red[threadIdx.x] = ss; __syncthreads();
  for (int s2 = 128; s2 > 0; s2 >>= 1) {
    if (threadIdx.x < s2) red[threadIdx.x] += red[threadIdx.x + s2];
    __syncthreads();
  }
  float r = 1.0f / sqrtf(red[0] / (float)D + 1e-6f);
  for (int c = threadIdx.x; c < nc; c += 256) {
    short8_t v = reinterpret_cast<const short8_t*>(x)[c];
    short8_t wv = reinterpret_cast<const short8_t*>(w)[c];
    short8_t ov;
    #pragma unroll
    for (int j = 0; j < 8; ++j) ov[j] = f2b(b2f(wv[j]) * (b2f(v[j]) * r));
    reinterpret_cast<short8_t*>(o)[c] = ov;
  }
}

__global__ void __launch_bounds__(256)
build_qf_kernel(const short* q, const float* cosT, const float* sinT, short* qf) {
  int s = blockIdx.x;
  for (int idx = threadIdx.x; idx < NH_ * DQK_; idx += 256) {
    int h = idx / DQK_, d = idx - h * DQK_;
    const short* qr = q + (long long)s * QN_ + h * DQK_;
    float val;
    if (d < 128) val = b2f(qr[d]);
    else {
      int j = d - 128;
      float c = cosT[s * 64 + j], sn = sinT[s * 64 + j];
      float x0 = b2f(qr[128 + j]);
      float rot = (j < 32) ? -b2f(qr[128 + j + 32]) : b2f(qr[128 + j - 32]);
      val = x0 * c + rot * sn;
    }
    qf[(long long)h * S_LEN * DQK_ + (long long)s * DQK_ + d] = f2b(val);
  }
}

__global__ void __launch_bounds__(256)
build_kf_kernel(const short* kvup, const short* kv, const float* cosT, const float* sinT, short* kf) {
  int s = blockIdx.x;
  for (int idx = threadIdx.x; idx < NH_ * DQK_; idx += 256) {
    int h = idx / DQK_, d = idx - h * DQK_;
    float val;
    if (d < 128) val = b2f(kvup[(long long)s * KVUPN + h * 256 + d]);
    else {
      int j = d - 128;
      float c = cosT[s * 64 + j], sn = sinT[s * 64 + j];
      const short* kr = kv + (long long)s * KVDN + KVRANK_;
      float x0 = b2f(kr[j]);
      float rot = (j < 32) ? -b2f(kr[j + 32]) : b2f(kr[j - 32]);
      val = x0 * c + rot * sn;
    }
    kf[(long long)h * S_LEN * DQK_ + (long long)s * DQK_ + d] = f2b(val);
  }
}

__global__ void __launch_bounds__(256)
transpose_v_kernel(const short* kvup, short* vT) {
  int h = blockIdx.z;
  int r0 = blockIdx.y * 32, c0 = blockIdx.x * 32;
  int tx = threadIdx.x & 31, ty = threadIdx.x >> 5;
  __shared__ short tile[32][33];
  #pragma unroll
  for (int i = 0; i < 4; ++i)
    tile[ty + i * 8][tx] =
        kvup[(long long)(r0 + ty + i * 8) * KVUPN + h * 256 + 128 + c0 + tx];
  __syncthreads();
  short* d = vT + (long long)h * 128 * S_LEN;
  #pragma unroll
  for (int i = 0; i < 4; ++i)
    d[(long long)(c0 + ty + i * 8) * S_LEN + r0 + tx] = tile[tx][ty + i * 8];
}

__global__ void __launch_bounds__(256)
softmax_rows_kernel(short* scores, float scale) {
  long long row = blockIdx.x;
  short8_t* p = reinterpret_cast<short8_t*>(scores + row * S_LEN);
  short8_t v = p[threadIdx.x];
  float f[8]; float m = -1e30f;
  #pragma unroll
  for (int j = 0; j < 8; ++j) { f[j] = b2f(v[j]) * scale; m = fmaxf(m, f[j]); }
  __shared__ float red[256];
  red[threadIdx.x] = m; __syncthreads();
  for (int s2 = 128; s2 > 0; s2 >>= 1) {
    if (threadIdx.x < s2) red[threadIdx.x] = fmaxf(red[threadIdx.x], red[threadIdx.x + s2]);
    __syncthreads();
  }
  m = red[0]; __syncthreads();
  float sum = 0.f;
  #pragma unroll
  for (int j = 0; j < 8; ++j) { f[j] = expf(f[j] - m); sum += f[j]; }
  red[threadIdx.x] = sum; __syncthreads();
  for (int s2 = 128; s2 > 0; s2 >>= 1) {
    if (threadIdx.x < s2) red[threadIdx.x] += red[threadIdx.x + s2];
    __syncthreads();
  }
  float inv = 1.0f / red[0];
  short8_t o;
  #pragma unroll
  for (int j = 0; j < 8; ++j) o[j] = f2b(f[j] * inv);
  p[threadIdx.x] = o;
}

__global__ void __launch_bounds__(256)
add_bf16_kernel(short* h, const short* a) {
  long long c = (long long)blockIdx.x * 256 + threadIdx.x;
  short8_t hv = reinterpret_cast<short8_t*>(h)[c];
  short8_t av = reinterpret_cast<const short8_t*>(a)[c];
  short8_t ov;
  #pragma unroll
  for (int j = 0; j < 8; ++j) ov[j] = f2b(b2f(hv[j]) + b2f(av[j]));
  reinterpret_cast<short8_t*>(h)[c] = ov;
}

// gate + top2 + compact list build
__global__ void __launch_bounds__(256)
gate_kernel(const short* x2, const short* gw, int* cnt, int* elist, float* ewt, int* tok2slot) {
  int t = blockIdx.x;
  int e = threadIdx.x >> 5, j = threadIdx.x & 31;
  const short* x = x2 + (long long)t * HDIM;
  float acc = 0.f;
  for (int k = j; k < HDIM; k += 32) acc += b2f(x[k]) * b2f(gw[(long long)k * EXP_ + e]);
  __shared__ float red[8][32];
  red[e][j] = acc; __syncthreads();
  for (int s2 = 16; s2 > 0; s2 >>= 1) {
    if (j < s2) red[e][j] += red[e][j + s2];
    __syncthreads();
  }
  if (threadIdx.x == 0) {
    float l[8], p[8];
    float m = -1e30f;
    for (int q = 0; q < 8; ++q) { l[q] = b2f(f2b(red[q][0])); m = fmaxf(m, l[q]); }
    float sum = 0.f;
    for (int q = 0; q < 8; ++q) { p[q] = expf(l[q] - m); sum += p[q]; }
    int i0 = 0; for (int q = 1; q < 8; ++q) if (p[q] > p[i0]) i0 = q;
    int i1 = (i0 == 0) ? 1 : 0;
    for (int q = 0; q < 8; ++q) if (q != i0 && p[q] > p[i1]) i1 = q;
    float denom = p[i0] + p[i1];
    float w0 = b2f(f2b(p[i0] / denom));   // match bf16 combine rounding
    float w1 = b2f(f2b(p[i1] / denom));
    int pos0 = atomicAdd(&cnt[i0], 1);
    int pos1 = atomicAdd(&cnt[i1], 1);
    elist[i0 * S_LEN + pos0] = t;  ewt[i0 * S_LEN + pos0] = w0;
    elist[i1 * S_LEN + pos1] = t;  ewt[i1 * S_LEN + pos1] = w1;
    int4* slot = (int4*)tok2slot;
    slot[t] = make_int4(i0, pos0, i1, pos1);
  }
}

// silu over compact routed buffers, applying combine weight
__global__ void __launch_bounds__(256)
silu_moe_kernel(short* a, const short* b, const int* cnt, const float* ewt) {
  int pos = blockIdx.x, e = blockIdx.y;
  if (pos >= cnt[e]) return;
  float scale = ewt[e * S_LEN + pos];
  int c = threadIdx.x;
  if (c >= IFF_ / 8) return;
  long long roff = ((long long)e * S_LEN + pos) * IFF_;
  short8_t av = reinterpret_cast<short8_t*>(a + roff)[c];
  short8_t bv = reinterpret_cast<const short8_t*>(b + roff)[c];
  short8_t ov;
  #pragma unroll
  for (int j = 0; j < 8; ++j) {
    float x = b2f(av[j]);
    float s = x / (1.0f + expf(-x));
    ov[j] = f2b(s * b2f(bv[j]) * scale);
  }
  reinterpret_cast<short8_t*>(a + roff)[c] = ov;
}

// dense shared-expert silu (no weight)
__global__ void __launch_bounds__(256)
silu_mul_kernel(short* a, const short* b) {
  int t = blockIdx.x;
  int c = threadIdx.x;
  if (c >= IFF_ / 8) return;
  short8_t av = reinterpret_cast<short8_t*>(a + (long long)t * IFF_)[c];
  short8_t bv = reinterpret_cast<const short8_t*>(b + (long long)t * IFF_)[c];
  short8_t ov;
  #pragma unroll
  for (int j = 0; j < 8; ++j) {
    float x = b2f(av[j]);
    float s = x / (1.0f + expf(-x));
    ov[j] = f2b(s * b2f(bv[j]));
  }
  reinterpret_cast<short8_t*>(a + (long long)t * IFF_)[c] = ov;
}

// hbuf += moeacc(shared,f32) + routed_out[e0][pos0] + routed_out[e1][pos1]
__global__ void __launch_bounds__(256)
moe_combine_kernel(short* h, const float* moeacc, const short* routed,
                   const int* tok2slot) {
  int t = blockIdx.x;
  const int4 sl = ((const int4*)tok2slot)[t];
  const short8_t* r0 = reinterpret_cast<const short8_t*>(
      routed + ((long long)sl.x * S_LEN + sl.y) * HDIM);
  const short8_t* r1 = reinterpret_cast<const short8_t*>(
      routed + ((long long)sl.z * S_LEN + sl.w) * HDIM);
  long long c = (long long)t * 256 + threadIdx.x;
  short8_t hv = reinterpret_cast<short8_t*>(h)[c];
  f32x4 m0 = reinterpret_cast<const f32x4*>(moeacc)[2 * c];
  f32x4 m1 = reinterpret_cast<const f32x4*>(moeacc)[2 * c + 1];
  short8_t v0 = r0[threadIdx.x], v1 = r1[threadIdx.x];
  short8_t ov;
  #pragma unroll
  for (int j = 0; j < 4; ++j) {
    ov[j]     = f2b(b2f(hv[j])     + (m0[j] + b2f(v0[j])     + b2f(v1[j])));
    ov[4 + j] = f2b(b2f(hv[4 + j]) + (m1[j] + b2f(v0[4 + j]) + b2f(v1[4 + j])));
  }
  reinterpret_cast<short8_t*>(h)[c] = ov;
}

// ---------------- pooling ----------------
template<int AF32, int OUTBF16>
__global__ void __launch_bounds__(256)
gemv_bt_kernel(const void* a, const short* __restrict__ BT, void* out, int K) {
  int n = blockIdx.x;
  const short8_t* row = reinterpret_cast<const short8_t*>(BT + (long long)n * K);
  float acc = 0.f;
  for (int c = threadIdx.x; c < (K >> 3); c += 256) {
    short8_t v = row[c];
    if (AF32) {
      f32x4 a0 = reinterpret_cast<const f32x4*>(a)[2 * c];
      f32x4 a1 = reinterpret_cast<const f32x4*>(a)[2 * c + 1];
      #pragma unroll
      for (int j = 0; j < 4; ++j) {
        acc += a0[j] * b2f(v[j]);
        acc += a1[j] * b2f(v[4 + j]);
      }
    } else {
      short8_t av = reinterpret_cast<const short8_t*>(a)[c];
      #pragma unroll
      for (int j = 0; j < 8; ++j) acc += b2f(av[j]) * b2f(v[j]);
    }
  }
  __shared__ float red[256];
  red[threadIdx.x] = acc; __syncthreads();
  for (int s2 = 128; s2 > 0; s2 >>= 1) {
    if (threadIdx.x < s2) red[threadIdx.x] += red[threadIdx.x + s2];
    __syncthreads();
  }
  if (threadIdx.x == 0) {
    if (OUTBF16) ((short*)out)[n] = f2b(red[0]);
    else         ((float*)out)[n] = red[0];
  }
}

__global__ void __launch_bounds__(256)
pool_score_kernel(const short* qv, const short* kmat, float* score) {
  int s = blockIdx.x;
  const short8_t* kr = reinterpret_cast<const short8_t*>(kmat + (long long)s * HDIM);
  const short8_t* qr = reinterpret_cast<const short8_t*>(qv);
  short8_t kv8 = kr[threadIdx.x], qv8 = qr[threadIdx.x];
  float acc = 0.f;
  #pragma unroll
  for (int j = 0; j < 8; ++j) acc += b2f(qv8[j]) * b2f(kv8[j]);
  __shared__ float red[256];
  red[threadIdx.x] = acc; __syncthreads();
  for (int s2 = 128; s2 > 0; s2 >>= 1) {
    if (threadIdx.x < s2) red[threadIdx.x] += red[threadIdx.x + s2];
    __syncthreads();
  }
  if (threadIdx.x == 0) score[s] = b2f(f2b(red[0])) * 0.022097086912079608f;
}

__global__ void __launch_bounds__(256)
softmax_vec_kernel(float* v) {
  int tid = threadIdx.x;
  float f[8]; float m = -1e30f;
  #pragma unroll
  for (int i = 0; i < 8; ++i) { f[i] = v[i * 256 + tid]; m = fmaxf(m, f[i]); }
  __shared__ float red[256];
  red[tid] = m; __syncthreads();
  for (int s2 = 128; s2 > 0; s2 >>= 1) {
    if (tid < s2) red[tid] = fmaxf(red[tid], red[tid + s2]);
    __syncthreads();
  }
  m = red[0]; __syncthreads();
  float sum = 0.f;
  #pragma unroll
  for (int i = 0; i < 8; ++i) { f[i] = expf(f[i] - m); sum += f[i]; }
  red[tid] = sum; __syncthreads();
  for (int s2 = 128; s2 > 0; s2 >>= 1) {
    if (tid < s2) red[tid] += red[tid + s2];
    __syncthreads();
  }
  float inv = 1.0f / red[0];
  #pragma unroll
  for (int i = 0; i < 8; ++i) v[i * 256 + tid] = f[i] * inv;
}

__global__ void __launch_bounds__(256)
pool_wsum_t_kernel(const float* w, const short* vT, float* pooled) {
  int h = blockIdx.x;
  const short8_t* row = reinterpret_cast<const short8_t*>(vT + (long long)h * S_LEN);
  int c = threadIdx.x;
  short8_t v = row[c];
  f32x4 w0 = reinterpret_cast<const f32x4*>(w)[2 * c];
  f32x4 w1 = reinterpret_cast<const f32x4*>(w)[2 * c + 1];
  float acc = 0.f;
  #pragma unroll
  for (int j = 0; j < 4; ++j) {
    acc += w0[j] * b2f(v[j]);
    acc += w1[j] * b2f(v[4 + j]);
  }
  __shared__ float red[256];
  red[threadIdx.x] = acc; __syncthreads();
  for (int s2 = 128; s2 > 0; s2 >>= 1) {
    if (threadIdx.x < s2) red[threadIdx.x] += red[threadIdx.x + s2];
    __syncthreads();
  }
  if (threadIdx.x == 0) pooled[h] = red[0];
}

__global__ void __launch_bounds__(256)
rmsnorm_f32_kernel(const float* x, const short* w, float* out) {
  int tid = threadIdx.x;
  float f[8]; float ss = 0.f;
  #pragma unroll
  for (int i = 0; i < 8; ++i) { f[i] = x[i * 256 + tid]; ss += f[i] * f[i]; }
  __shared__ float red[256];
  red[tid] = ss; __syncthreads();
  for (int s2 = 128; s2 > 0; s2 >>= 1) {
    if (tid < s2) red[tid] += red[tid + s2];
    __syncthreads();
  }
  float r = 1.0f / sqrtf(red[0] / 2048.0f + 1e-6f);
  #pragma unroll
  for (int i = 0; i < 8; ++i) out[i * 256 + tid] = b2f(w[i * 256 + tid]) * (f[i] * r);
}

// ---------------- host ----------------
extern "C" void kernel_launch(void* const* d_in, const int* in_sizes, int n_in,
                              void* d_out, int out_size, void* d_ws, size_t ws_size,
                              hipStream_t stream)
{
  (void)n_in; (void)out_size; (void)ws_size;
  const int* ids = (const int*)d_in[24];

  char* base = (char*)d_ws;
  size_t off = 0;
  auto alloc = [&](size_t bytes) -> void* {
    void* p = base + off;
    off += (bytes + 255) & ~(size_t)255;
    return p;
  };

  int* dflag = (int*)alloc(256);

  // transposed weights [N][K]
  short* qdwT  = (short*)alloc((size_t)2 * QRANK_ * HDIM * 2);
  short* quwT  = (short*)alloc((size_t)2 * QN_ * QRANK_ * 2);
  short* kvdwT = (short*)alloc((size_t)2 * KVDN * HDIM * 2);
  short* kvuwT = (short*)alloc((size_t)2 * KVUPN * KVRANK_ * 2);
  short* opwT  = (short*)alloc((size_t)2 * HDIM * HDIM * 2);
  short* rw1T  = (short*)alloc((size_t)16 * IFF_ * HDIM * 2);
  short* rw2T  = (short*)alloc((size_t)16 * HDIM * IFF_ * 2);
  short* rw3T  = (short*)alloc((size_t)16 * IFF_ * HDIM * 2);
  short* sw1T  = (short*)alloc((size_t)4 * IFF_ * HDIM * 2);
  short* sw2T  = (short*)alloc((size_t)4 * HDIM * IFF_ * 2);
  short* sw3T  = (short*)alloc((size_t)4 * IFF_ * HDIM * 2);
  short* pqwT  = (short*)alloc((size_t)HDIM * HDIM * 2);
  short* pkwT  = (short*)alloc((size_t)HDIM * HDIM * 2);
  short* pvwT  = (short*)alloc((size_t)HDIM * HDIM * 2);
  short* powT  = (short*)alloc((size_t)PD_ * HDIM * 2);
  short* ln1w = (short*)alloc((size_t)in_sizes[1] * 2);
  short* qnw  = (short*)alloc((size_t)in_sizes[3] * 2);
  short* kvnw = (short*)alloc((size_t)in_sizes[6] * 2);
  short* ln2w = (short*)alloc((size_t)in_sizes[9] * 2);
  short* gatw = (short*)alloc((size_t)in_sizes[10] * 2);
  short* fnww = (short*)alloc((size_t)in_sizes[17] * 2);
  short* lqw  = (short*)alloc((size_t)in_sizes[18] * 2);
  short* pnww = (short*)alloc((size_t)in_sizes[23] * 2);

  float* cosT    = (float*)alloc((size_t)S_LEN * 64 * 4);
  float* sinT    = (float*)alloc((size_t)S_LEN * 64 * 4);
  short* hbuf    = (short*)alloc((size_t)S_LEN * HDIM * 2);
  short* xbuf    = (short*)alloc((size_t)S_LEN * HDIM * 2);
  short* qlat    = (short*)alloc((size_t)S_LEN * QRANK_ * 2);
  short* qlatn   = (short*)alloc((size_t)S_LEN * QRANK_ * 2);
  short* qbuf    = (short*)alloc((size_t)S_LEN * QN_ * 2);
  short* kvbuf   = (short*)alloc((size_t)S_LEN * KVDN * 2);
  short* kvn     = (short*)alloc((size_t)S_LEN * KVRANK_ * 2);
  short* kvup    = (short*)alloc((size_t)S_LEN * KVUPN * 2);
  short* qf      = (short*)alloc((size_t)NH_ * S_LEN * DQK_ * 2);
  short* kf      = (short*)alloc((size_t)NH_ * S_LEN * DQK_ * 2);
  short* vT      = (short*)alloc((size_t)NH_ * 128 * S_LEN * 2);
  short* scores  = (short*)alloc((size_t)HG_ * S_LEN * S_LEN * 2);
  short* ao      = (short*)alloc((size_t)S_LEN * HDIM * 2);
  short* attnp   = (short*)alloc((size_t)S_LEN * HDIM * 2);
  float* moeacc  = (float*)alloc((size_t)S_LEN * HDIM * 4);
  short* gba     = (short*)alloc((size_t)S_LEN * IFF_ * 2);
  short* gbb     = (short*)alloc((size_t)S_LEN * IFF_ * 2);
  short* hfin    = (short*)alloc((size_t)S_LEN * HDIM * 2);
  short* kpool   = (short*)alloc((size_t)S_LEN * HDIM * 2);
  short* vpoolT  = (short*)alloc((size_t)HDIM * S_LEN * 2);
  short* qvec    = (short*)alloc((size_t)HDIM * 2);
  float* pscore  = (float*)alloc((size_t)S_LEN * 4);
  float* pooled  = (float*)alloc((size_t)HDIM * 4);
  float* pooledn = (float*)alloc((size_t)HDIM * 4);
  // sparse MoE structures
  int*   ecnt    = (int*)alloc(64);
  int*   elist   = (int*)alloc((size_t)EXP_ * S_LEN * 4);
  float* ewt     = (float*)alloc((size_t)EXP_ * S_LEN * 4);
  int*   tok2slot= (int*)alloc((size_t)S_LEN * 16);
  short* gba_e   = (short*)alloc((size_t)EXP_ * S_LEN * IFF_ * 2);
  short* gbb_e   = (short*)alloc((size_t)EXP_ * S_LEN * IFF_ * 2);
  short* routed  = (short*)alloc((size_t)EXP_ * S_LEN * HDIM * 2);

  detect_kernel<<<1, 256, 0, stream>>>(d_in[0], dflag);

  auto tconv = [&](const void* src, short* dst, int R, int C, int nslabs) {
    dim3 grid(C / 32, R / 32, nslabs);
    transconv_kernel<<<grid, 256, 0, stream>>>(src, dst, R, C, dflag);
  };
  auto pconv = [&](const void* src, short* dst, long long n) {
    long long nchunks = n / 8;
    int blocks = (int)((nchunks + 255) / 256);
    if (blocks > 2048) blocks = 2048;
    if (blocks < 1) blocks = 1;
    convert_kernel<<<blocks, 256, 0, stream>>>(src, dst, nchunks, dflag);
  };

  tconv(d_in[2],  qdwT,  HDIM,   QRANK_, 2);
  tconv(d_in[4],  quwT,  QRANK_, QN_,    2);
  tconv(d_in[5],  kvdwT, HDIM,   KVDN,   2);
  tconv(d_in[7],  kvuwT, KVRANK_,KVUPN,  2);
  tconv(d_in[8],  opwT,  HDIM,   HDIM,   2);
  tconv(d_in[11], rw1T,  HDIM,   IFF_,   16);
  tconv(d_in[12], rw2T,  IFF_,   HDIM,   16);
  tconv(d_in[13], rw3T,  HDIM,   IFF_,   16);
  tconv(d_in[14], sw1T,  HDIM,   IFF_,   4);
  tconv(d_in[15], sw2T,  IFF_,   HDIM,   4);
  tconv(d_in[16], sw3T,  HDIM,   IFF_,   4);
  tconv(d_in[19], pqwT,  HDIM,   HDIM,   1);
  tconv(d_in[20], pkwT,  HDIM,   HDIM,   1);
  tconv(d_in[21], pvwT,  HDIM,   HDIM,   1);
  tconv(d_in[22], powT,  HDIM,   PD_,    1);
  pconv(d_in[1],  ln1w, in_sizes[1]);
  pconv(d_in[3],  qnw,  in_sizes[3]);
  pconv(d_in[6],  kvnw, in_sizes[6]);
  pconv(d_in[9],  ln2w, in_sizes[9]);
  pconv(d_in[10], gatw, in_sizes[10]);
  pconv(d_in[17], fnww, in_sizes[17]);
  pconv(d_in[18], lqw,  in_sizes[18]);
  pconv(d_in[23], pnww, in_sizes[23]);

  const float qk_scale = 1.0f / sqrtf((float)DQK_);

  auto gemm = [&](int epi, const short* A, const short* B, void* C,
                  int M, int N, int K, int lda, int ldb, int ldc,
                  int batch, long long sA, long long sB, long long sC) {
    dim3 grid(M / 128, (N + 127) / 128, batch);
    if (epi == 0)
      gemm_kernel<0><<<grid, 256, 0, stream>>>(A, B, C, M, N, K, lda, ldb, ldc, sA, sB, sC);
    else
      gemm_kernel<1><<<grid, 256, 0, stream>>>(A, B, C, M, N, K, lda, ldb, ldc, sA, sB, sC);
  };

  rope_tables_kernel<<<S_LEN, 64, 0, stream>>>(cosT, sinT);
  embed_convert_kernel<<<S_LEN, 256, 0, stream>>>(ids, d_in[0], dflag, hbuf);

  for (int l = 0; l < 2; ++l) {
    const short* w_ln1 = ln1w + (size_t)l * HDIM;
    const short* w_qdT = qdwT + (size_t)l * QRANK_ * HDIM;
    const short* w_qn  = qnw  + (size_t)l * QRANK_;
    const short* w_quT = quwT + (size_t)l * QN_ * QRANK_;
    const short* w_kvdT= kvdwT+ (size_t)l * KVDN * HDIM;
    const short* w_kvn = kvnw + (size_t)l * KVRANK_;
    const short* w_kvuT= kvuwT+ (size_t)l * KVUPN * KVRANK_;
    const short* w_opT = opwT + (size_t)l * HDIM * HDIM;
    const short* w_ln2 = ln2w + (size_t)l * HDIM;
    const short* w_gat = gatw + (size_t)l * HDIM * EXP_;

    // --- attention ---
    rmsnorm_bf16_kernel<<<S_LEN, 256, 0, stream>>>(hbuf, HDIM, w_ln1, xbuf, HDIM, HDIM);
    gemm(0, xbuf, w_qdT, qlat, S_LEN, QRANK_, HDIM, HDIM, HDIM, QRANK_, 1, 0, 0, 0);
    rmsnorm_bf16_kernel<<<S_LEN, 256, 0, stream>>>(qlat, QRANK_, w_qn, qlatn, QRANK_, QRANK_);
    gemm(0, qlatn, w_quT, qbuf, S_LEN, QN_, QRANK_, QRANK_, QRANK_, QN_, 1, 0, 0, 0);
    gemm(0, xbuf, w_kvdT, kvbuf, S_LEN, KVDN, HDIM, HDIM, HDIM, KVDN, 1, 0, 0, 0);
    rmsnorm_bf16_kernel<<<S_LEN, 256, 0, stream>>>(kvbuf, KVDN, w_kvn, kvn, KVRANK_, KVRANK_);
    gemm(0, kvn, w_kvuT, kvup, S_LEN, KVUPN, KVRANK_, KVRANK_, KVRANK_, KVUPN, 1, 0, 0, 0);
    build_qf_kernel<<<S_LEN, 256, 0, stream>>>(qbuf, cosT, sinT, qf);
    build_kf_kernel<<<S_LEN, 256, 0, stream>>>(kvup, kvbuf, cosT, sinT, kf);
    {
      dim3 tg(128 / 32, S_LEN / 32, NH_);
      transpose_v_kernel<<<tg, 256, 0, stream>>>(kvup, vT);
    }
    for (int hg = 0; hg < NH_ / HG_; ++hg) {
      gemm(0, qf + (size_t)hg * HG_ * S_LEN * DQK_, kf + (size_t)hg * HG_ * S_LEN * DQK_,
           scores, S_LEN, S_LEN, DQK_, DQK_, DQK_, S_LEN, HG_,
           (long long)S_LEN * DQK_, (long long)S_LEN * DQK_, (long long)S_LEN * S_LEN);
      softmax_rows_kernel<<<HG_ * S_LEN, 256, 0, stream>>>(scores, qk_scale);
      gemm(0, scores, vT + (size_t)hg * HG_ * 128 * S_LEN, ao + hg * HG_ * 128,
           S_LEN, 128, S_LEN, S_LEN, S_LEN, HDIM, HG_,
           (long long)S_LEN * S_LEN, (long long)128 * S_LEN, 128);
    }
    gemm(0, ao, w_opT, attnp, S_LEN, HDIM, HDIM, HDIM, HDIM, HDIM, 1, 0, 0, 0);
    add_bf16_kernel<<<S_LEN, 256, 0, stream>>>(hbuf, attnp);

    // --- MoE ---
    rmsnorm_bf16_kernel<<<S_LEN, 256, 0, stream>>>(hbuf, HDIM, w_ln2, xbuf, HDIM, HDIM);
    hipMemsetAsync(ecnt, 0, 64, stream);
    gate_kernel<<<S_LEN, 256, 0, stream>>>(xbuf, w_gat, ecnt, elist, ewt, tok2slot);
    hipMemsetAsync(moeacc, 0, (size_t)S_LEN * HDIM * 4, stream);
    // shared experts (dense)
    for (int j = 0; j < 2; ++j) {
      const short* a1 = sw1T + ((size_t)l * 2 + j) * IFF_ * HDIM;
      const short* a3 = sw3T + ((size_t)l * 2 + j) * IFF_ * HDIM;
      const short* a2 = sw2T + ((size_t)l * 2 + j) * HDIM * IFF_;
      gemm(0, xbuf, a1, gba, S_LEN, IFF_, HDIM, HDIM, HDIM, IFF_, 1, 0, 0, 0);
      gemm(0, xbuf, a3, gbb, S_LEN, IFF_, HDIM, HDIM, HDIM, IFF_, 1, 0, 0, 0);
      silu_mul_kernel<<<S_LEN, 256, 0, stream>>>(gba, gbb);
      gemm(1, gba, a2, moeacc, S_LEN, HDIM, IFF_, IFF_, IFF_, HDIM, 1, 0, 0, 0);
    }
    // routed experts (sparse, batched over z=expert, early-exit)
    {
      const short* b1 = rw1T + (size_t)l * 8 * IFF_ * HDIM;
      const short* b3 = rw3T + (size_t)l * 8 * IFF_ * HDIM;
      const short* b2 = rw2T + (size_t)l * 8 * HDIM * IFF_;
      dim3 g13(S_LEN / 128, IFF_ / 128, EXP_);
      moe_gemm_kernel<1><<<g13, 256, 0, stream>>>(
          xbuf, elist, ecnt, b1, gba_e, IFF_, HDIM, HDIM, HDIM, IFF_,
          (long long)S_LEN * IFF_, (long long)IFF_ * HDIM, (long long)S_LEN * IFF_);
      moe_gemm_kernel<1><<<g13, 256, 0, stream>>>(
          xbuf, elist, ecnt, b3, gbb_e, IFF_, HDIM, HDIM, HDIM, IFF_,
          (long long)S_LEN * IFF_, (long long)IFF_ * HDIM, (long long)S_LEN * IFF_);
      dim3 gs(S_LEN, EXP_);
      silu_moe_kernel<<<gs, 256, 0, stream>>>(gba_e, gbb_e, ecnt, ewt);
      dim3 g2(S_LEN / 128, HDIM / 128, EXP_);
      moe_gemm_kernel<0><<<g2, 256, 0, stream>>>(
          gba_e, elist, ecnt, b2, routed, HDIM, IFF_, IFF_, IFF_, HDIM,
          (long long)S_LEN * IFF_, (long long)HDIM * IFF_, (long long)S_LEN * HDIM);
      moe_combine_kernel<<<S_LEN, 256, 0, stream>>>(hbuf, moeacc, routed, tok2slot);
    }
  }

  // --- attention pooling head ---
  rmsnorm_bf16_kernel<<<S_LEN, 256, 0, stream>>>(hbuf, HDIM, fnww, hfin, HDIM, HDIM);
  gemm(0, hfin, pkwT, kpool, S_LEN, HDIM, HDIM, HDIM, HDIM, HDIM, 1, 0, 0, 0);
  gemm(0, pvwT, hfin, vpoolT, HDIM, S_LEN, HDIM, HDIM, HDIM, S_LEN, 1, 0, 0, 0);
  gemv_bt_kernel<0,1><<<HDIM, 256, 0, stream>>>(lqw, pqwT, qvec, HDIM);
  pool_score_kernel<<<S_LEN, 256, 0, stream>>>(qvec, kpool, pscore);
  softmax_vec_kernel<<<1, 256, 0, stream>>>(pscore);
  pool_wsum_t_kernel<<<HDIM, 256, 0, stream>>>(pscore, vpoolT, pooled);
  rmsnorm_f32_kernel<<<1, 256, 0, stream>>>(pooled, pnww, pooledn);
  gemv_bt_kernel<1,0><<<PD_, 256, 0, stream>>>(pooledn, powT, (float*)d_out, HDIM);
}

// Round 5
// 2624.701 us; speedup vs baseline: 4.5057x; 1.4887x over previous
//
#include <hip/hip_runtime.h>
#include <hip/hip_bf16.h>

#define S_LEN  2048
#define HDIM   2048
#define NH_    16
#define DQK_   192
#define QRANK_ 1024
#define KVRANK_ 512
#define KVDN   576    // KV_RANK + D_ROPE
#define KVUPN  4096   // NH*(D_NOPE+D_V)
#define QN_    3072   // NH*D_QK
#define IFF_   1408
#define EXP_   8
#define HG_    16     // heads per attention chunk (all)
#define PD_    4096

typedef __attribute__((ext_vector_type(8))) short   short8_t;
typedef __attribute__((ext_vector_type(8))) __bf16  bf16x8_t;
typedef __attribute__((ext_vector_type(4))) float   f32x4;

static __device__ __forceinline__ float b2f(short s) {
  unsigned int u = ((unsigned int)(unsigned short)s) << 16;
  return __builtin_bit_cast(float, u);
}
static __device__ __forceinline__ short f2b(float f) {
  return __builtin_bit_cast(short, __float2bfloat16(f));
}

// async global->LDS, 16B per lane. LDS dest = wave-uniform base + lane*16.
static __device__ __forceinline__ void gload16(const void* g, void* l) {
  __builtin_amdgcn_global_load_lds(
      (const __attribute__((address_space(1))) void*)g,
      (__attribute__((address_space(3))) void*)l,
      16, 0, 0);
}

// ---------------- dtype detect + convert ----------------
__global__ void __launch_bounds__(256)
detect_kernel(const void* probe, int* flag) {
  const float* f = (const float*)probe;
  int tid = threadIdx.x;
  int cnt = 0;
  for (int i = tid; i < 2048; i += 256) {
    float v = fabsf(f[i]);
    if (v > 1e-6f && v < 10.0f) cnt++;
  }
  __shared__ int red[256];
  red[tid] = cnt; __syncthreads();
  for (int s = 128; s > 0; s >>= 1) {
    if (tid < s) red[tid] += red[tid + s];
    __syncthreads();
  }
  if (tid == 0) *flag = (red[0] > 1600) ? 1 : 0;
}

__global__ void __launch_bounds__(256)
convert_kernel(const void* src, short* dst, long long nchunks, const int* flag) {
  long long idx = (long long)blockIdx.x * 256 + threadIdx.x;
  long long stride = (long long)gridDim.x * 256;
  if (*flag) {
    const f32x4* s = (const f32x4*)src;
    for (long long c = idx; c < nchunks; c += stride) {
      f32x4 a = s[2 * c], b = s[2 * c + 1];
      short8_t o;
      #pragma unroll
      for (int j = 0; j < 4; ++j) { o[j] = f2b(a[j]); o[4 + j] = f2b(b[j]); }
      reinterpret_cast<short8_t*>(dst)[c] = o;
    }
  } else {
    const short8_t* s = (const short8_t*)src;
    for (long long c = idx; c < nchunks; c += stride)
      reinterpret_cast<short8_t*>(dst)[c] = s[c];
  }
}

// transpose-convert: src slab [R][C] (f32/bf16) -> dst slab [C][R] bf16
__global__ void __launch_bounds__(256)
transconv_kernel(const void* src, short* dst, int R, int C, const int* flag) {
  long long zoff = (long long)blockIdx.z * R * C;
  int r0 = blockIdx.y * 32, c0 = blockIdx.x * 32;
  int tx = threadIdx.x & 31, ty = threadIdx.x >> 5;
  __shared__ short tile[32][33];
  if (*flag) {
    const float* s = (const float*)src + zoff;
    #pragma unroll
    for (int i = 0; i < 4; ++i)
      tile[ty + i * 8][tx] = f2b(s[(long long)(r0 + ty + i * 8) * C + c0 + tx]);
  } else {
    const short* s = (const short*)src + zoff;
    #pragma unroll
    for (int i = 0; i < 4; ++i)
      tile[ty + i * 8][tx] = s[(long long)(r0 + ty + i * 8) * C + c0 + tx];
  }
  __syncthreads();
  short* d = dst + zoff;
  #pragma unroll
  for (int i = 0; i < 4; ++i)
    d[(long long)(c0 + ty + i * 8) * R + r0 + tx] = tile[tx][ty + i * 8];
}

__global__ void __launch_bounds__(256)
embed_convert_kernel(const int* ids, const void* emb, const int* flag, short* h) {
  int s = blockIdx.x;
  long long row = ids[s];
  int c = threadIdx.x;
  short8_t o;
  if (*flag) {
    const f32x4* src = (const f32x4*)((const float*)emb + row * HDIM);
    f32x4 a = src[2 * c], b = src[2 * c + 1];
    #pragma unroll
    for (int j = 0; j < 4; ++j) { o[j] = f2b(a[j]); o[4 + j] = f2b(b[j]); }
  } else {
    o = reinterpret_cast<const short8_t*>((const short*)emb + row * HDIM)[c];
  }
  reinterpret_cast<short8_t*>(h + (long long)s * HDIM)[c] = o;
}

// ---------------- MFMA GEMM (B always [N][K]) ----------------
// global_load_lds staging: LDS linear [128][32], wave w covers rows w*16+r*64+..
template<int EPI>
__global__ void __launch_bounds__(256)
gemm_kernel(const short* __restrict__ A, const short* __restrict__ B,
            void* __restrict__ Cv, int M, int N, int K,
            int lda, int ldb, int ldc,
            long long sAb, long long sBb, long long sCb)
{
  __shared__ short shA[128][32];
  __shared__ short shB[128][32];
  const int tid = threadIdx.x;
  const long long bz = blockIdx.z;
  const short* Ab = A + bz * sAb;
  const short* Bb = B + bz * sBb;
  const int m0 = blockIdx.x * 128;
  const int n0 = blockIdx.y * 128;
  const int w = tid >> 6, lane = tid & 63;
  const int wm = (w >> 1) << 6, wn = (w & 1) << 6;
  const int lr = lane & 15, g = lane >> 4;
  const int srow = lane >> 2;         // 0..15
  const int scol = (lane & 3) << 3;   // 0,8,16,24
  const f32x4 vzero = {0.f, 0.f, 0.f, 0.f};
  f32x4 acc[4][4];
  #pragma unroll
  for (int i = 0; i < 4; ++i)
    #pragma unroll
    for (int j = 0; j < 4; ++j) acc[i][j] = vzero;

  for (int k0 = 0; k0 < K; k0 += 32) {
    __syncthreads();
    #pragma unroll
    for (int r = 0; r < 2; ++r) {
      int row = (w << 4) + (r << 6) + srow;
      gload16(Ab + (long long)(m0 + row) * lda + k0 + scol, &shA[(w << 4) + (r << 6)][0]);
      gload16(Bb + (long long)(n0 + row) * ldb + k0 + scol, &shB[(w << 4) + (r << 6)][0]);
    }
    __syncthreads();
    short8_t af[4];
    #pragma unroll
    for (int mi = 0; mi < 4; ++mi)
      af[mi] = *reinterpret_cast<const short8_t*>(&shA[wm + (mi << 4) + lr][g << 3]);
    #pragma unroll
    for (int ni = 0; ni < 4; ++ni) {
      short8_t bfr = *reinterpret_cast<const short8_t*>(&shB[wn + (ni << 4) + lr][g << 3]);
      #pragma unroll
      for (int mi = 0; mi < 4; ++mi)
        acc[mi][ni] = __builtin_amdgcn_mfma_f32_16x16x32_bf16(
            __builtin_bit_cast(bf16x8_t, af[mi]),
            __builtin_bit_cast(bf16x8_t, bfr),
            acc[mi][ni], 0, 0, 0);
    }
  }
  const int orow = m0 + wm + (g << 2);
  const int ocol = n0 + wn + lr;
  if (EPI == 0) {
    short* C = reinterpret_cast<short*>(Cv) + bz * sCb;
    #pragma unroll
    for (int ni = 0; ni < 4; ++ni) {
      int col = ocol + (ni << 4);
      if (col >= N) continue;
      #pragma unroll
      for (int mi = 0; mi < 4; ++mi)
        #pragma unroll
        for (int r = 0; r < 4; ++r)
          C[(long long)(orow + (mi << 4) + r) * ldc + col] = f2b(acc[mi][ni][r]);
    }
  } else {
    float* C = reinterpret_cast<float*>(Cv) + bz * sCb;
    #pragma unroll
    for (int ni = 0; ni < 4; ++ni) {
      int col = ocol + (ni << 4);
      if (col >= N) continue;
      #pragma unroll
      for (int mi = 0; mi < 4; ++mi)
        #pragma unroll
        for (int r = 0; r < 4; ++r)
          C[(long long)(orow + (mi << 4) + r) * ldc + col] += acc[mi][ni][r];
    }
  }
}

// ---------------- sparse MoE gather GEMM ----------------
template<int GATHER>
__global__ void __launch_bounds__(256)
moe_gemm_kernel(const short* __restrict__ A, const int* __restrict__ elist,
                const int* __restrict__ cnt, const short* __restrict__ B,
                short* __restrict__ C, int N, int K,
                int lda, int ldb, int ldc,
                long long sAe, long long sBe, long long sCe)
{
  const int e = blockIdx.z;
  const int cnt_e = cnt[e];
  const int m0 = blockIdx.x * 128;
  if (m0 >= cnt_e) return;
  const short* Bb = B + (long long)e * sBe;
  short* Cb = C + (long long)e * sCe;
  const int n0 = blockIdx.y * 128;
  const int tid = threadIdx.x;
  const int w = tid >> 6, lane = tid & 63;
  const int wm = (w >> 1) << 6, wn = (w & 1) << 6;
  const int lr = lane & 15, g = lane >> 4;
  const int srow = lane >> 2;
  const int scol = (lane & 3) << 3;

  long long arow[2];
  #pragma unroll
  for (int r = 0; r < 2; ++r) {
    int row = m0 + (w << 4) + (r << 6) + srow;
    if (GATHER) {
      int p = row > cnt_e - 1 ? cnt_e - 1 : row;
      arow[r] = (long long)elist[e * S_LEN + p] * lda;
    } else {
      arow[r] = (long long)e * sAe + (long long)row * lda;
    }
  }

  __shared__ short shA[128][32];
  __shared__ short shB[128][32];
  const f32x4 vzero = {0.f, 0.f, 0.f, 0.f};
  f32x4 acc[4][4];
  #pragma unroll
  for (int i = 0; i < 4; ++i)
    #pragma unroll
    for (int j = 0; j < 4; ++j) acc[i][j] = vzero;

  for (int k0 = 0; k0 < K; k0 += 32) {
    __syncthreads();
    #pragma unroll
    for (int r = 0; r < 2; ++r) {
      int row = (w << 4) + (r << 6);
      gload16(A + arow[r] + k0 + scol, &shA[row][0]);
      gload16(Bb + (long long)(n0 + row + srow) * ldb + k0 + scol, &shB[row][0]);
    }
    __syncthreads();
    short8_t af[4];
    #pragma unroll
    for (int mi = 0; mi < 4; ++mi)
      af[mi] = *reinterpret_cast<const short8_t*>(&shA[wm + (mi << 4) + lr][g << 3]);
    #pragma unroll
    for (int ni = 0; ni < 4; ++ni) {
      short8_t bfr = *reinterpret_cast<const short8_t*>(&shB[wn + (ni << 4) + lr][g << 3]);
      #pragma unroll
      for (int mi = 0; mi < 4; ++mi)
        acc[mi][ni] = __builtin_amdgcn_mfma_f32_16x16x32_bf16(
            __builtin_bit_cast(bf16x8_t, af[mi]),
            __builtin_bit_cast(bf16x8_t, bfr),
            acc[mi][ni], 0, 0, 0);
    }
  }
  const int orow = m0 + wm + (g << 2);
  const int ocol = n0 + wn + lr;
  #pragma unroll
  for (int ni = 0; ni < 4; ++ni) {
    int col = ocol + (ni << 4);
    #pragma unroll
    for (int mi = 0; mi < 4; ++mi) {
      int rbase = orow + (mi << 4);
      #pragma unroll
      for (int r = 0; r < 4; ++r)
        if (rbase + r < cnt_e)
          Cb[(long long)(rbase + r) * ldc + col] = f2b(acc[mi][ni][r]);
    }
  }
}

// ---------------- small kernels ----------------
__global__ void __launch_bounds__(64)
rope_tables_kernel(float* cosT, float* sinT) {
  int s = blockIdx.x, j = threadIdx.x;
  int i = j & 31;
  float inv = powf(10000.0f, -((float)(2 * i) / 64.0f));
  float ang = (float)s * inv;
  cosT[s * 64 + j] = cosf(ang);
  sinT[s * 64 + j] = sinf(ang);
}

__global__ void __launch_bounds__(256)
rmsnorm_bf16_kernel(const short* __restrict__ in, long long istride,
                    const short* __restrict__ w,
                    short* __restrict__ out, long long ostride, int D) {
  const short* x = in + (long long)blockIdx.x * istride;
  short* o = out + (long long)blockIdx.x * ostride;
  const int nc = D >> 3;
  float ss = 0.f;
  for (int c = threadIdx.x; c < nc; c += 256) {
    short8_t v = reinterpret_cast<const short8_t*>(x)[c];
    #pragma unroll
    for (int j = 0; j < 8; ++j) { float f = b2f(v[j]); ss += f * f; }
  }
  __shared__ float red[256];
  red[threadIdx.x] = ss; __syncthreads();
  for (int s2 = 128; s2 > 0; s2 >>= 1) {
    if (threadIdx.x < s2) red[threadIdx.x] += red[threadIdx.x + s2];
    __syncthreads();
  }
  float r = 1.0f / sqrtf(red[0] / (float)D + 1e-6f);
  for (int c = threadIdx.x; c < nc; c += 256) {
    short8_t v = reinterpret_cast<const short8_t*>(x)[c];
    short8_t wv = reinterpret_cast<const short8_t*>(w)[c];
    short8_t ov;
    #pragma unroll
    for (int j = 0; j < 8; ++j) ov[j] = f2b(b2f(wv[j]) * (b2f(v[j]) * r));
    reinterpret_cast<short8_t*>(o)[c] = ov;
  }
}

__global__ void __launch_bounds__(256)
build_qf_kernel(const short* q, const float* cosT, const float* sinT, short* qf) {
  int s = blockIdx.x;
  for (int idx = threadIdx.x; idx < NH_ * DQK_; idx += 256) {
    int h = idx / DQK_, d = idx - h * DQK_;
    const short* qr = q + (long long)s * QN_ + h * DQK_;
    float val;
    if (d < 128) val = b2f(qr[d]);
    else {
      int j = d - 128;
      float c = cosT[s * 64 + j], sn = sinT[s * 64 + j];
      float x0 = b2f(qr[128 + j]);
      float rot = (j < 32) ? -b2f(qr[128 + j + 32]) : b2f(qr[128 + j - 32]);
      val = x0 * c + rot * sn;
    }
    qf[(long long)h * S_LEN * DQK_ + (long long)s * DQK_ + d] = f2b(val);
  }
}

__global__ void __launch_bounds__(256)
build_kf_kernel(const short* kvup, const short* kv, const float* cosT, const float* sinT, short* kf) {
  int s = blockIdx.x;
  for (int idx = threadIdx.x; idx < NH_ * DQK_; idx += 256) {
    int h = idx / DQK_, d = idx - h * DQK_;
    float val;
    if (d < 128) val = b2f(kvup[(long long)s * KVUPN + h * 256 + d]);
    else {
      int j = d - 128;
      float c = cosT[s * 64 + j], sn = sinT[s * 64 + j];
      const short* kr = kv + (long long)s * KVDN + KVRANK_;
      float x0 = b2f(kr[j]);
      float rot = (j < 32) ? -b2f(kr[j + 32]) : b2f(kr[j - 32]);
      val = x0 * c + rot * sn;
    }
    kf[(long long)h * S_LEN * DQK_ + (long long)s * DQK_ + d] = f2b(val);
  }
}

__global__ void __launch_bounds__(256)
transpose_v_kernel(const short* kvup, short* vT) {
  int h = blockIdx.z;
  int r0 = blockIdx.y * 32, c0 = blockIdx.x * 32;
  int tx = threadIdx.x & 31, ty = threadIdx.x >> 5;
  __shared__ short tile[32][33];
  #pragma unroll
  for (int i = 0; i < 4; ++i)
    tile[ty + i * 8][tx] =
        kvup[(long long)(r0 + ty + i * 8) * KVUPN + h * 256 + 128 + c0 + tx];
  __syncthreads();
  short* d = vT + (long long)h * 128 * S_LEN;
  #pragma unroll
  for (int i = 0; i < 4; ++i)
    d[(long long)(c0 + ty + i * 8) * S_LEN + r0 + tx] = tile[tx][ty + i * 8];
}

__global__ void __launch_bounds__(256)
softmax_rows_kernel(short* scores, float scale) {
  long long row = blockIdx.x;
  short8_t* p = reinterpret_cast<short8_t*>(scores + row * S_LEN);
  short8_t v = p[threadIdx.x];
  float f[8]; float m = -1e30f;
  #pragma unroll
  for (int j = 0; j < 8; ++j) { f[j] = b2f(v[j]) * scale; m = fmaxf(m, f[j]); }
  __shared__ float red[256];
  red[threadIdx.x] = m; __syncthreads();
  for (int s2 = 128; s2 > 0; s2 >>= 1) {
    if (threadIdx.x < s2) red[threadIdx.x] = fmaxf(red[threadIdx.x], red[threadIdx.x + s2]);
    __syncthreads();
  }
  m = red[0]; __syncthreads();
  float sum = 0.f;
  #pragma unroll
  for (int j = 0; j < 8; ++j) { f[j] = expf(f[j] - m); sum += f[j]; }
  red[threadIdx.x] = sum; __syncthreads();
  for (int s2 = 128; s2 > 0; s2 >>= 1) {
    if (threadIdx.x < s2) red[threadIdx.x] += red[threadIdx.x + s2];
    __syncthreads();
  }
  float inv = 1.0f / red[0];
  short8_t o;
  #pragma unroll
  for (int j = 0; j < 8; ++j) o[j] = f2b(f[j] * inv);
  p[threadIdx.x] = o;
}

__global__ void __launch_bounds__(256)
add_bf16_kernel(short* h, const short* a) {
  long long c = (long long)blockIdx.x * 256 + threadIdx.x;
  short8_t hv = reinterpret_cast<short8_t*>(h)[c];
  short8_t av = reinterpret_cast<const short8_t*>(a)[c];
  short8_t ov;
  #pragma unroll
  for (int j = 0; j < 8; ++j) ov[j] = f2b(b2f(hv[j]) + b2f(av[j]));
  reinterpret_cast<short8_t*>(h)[c] = ov;
}

// gate + top2 + compact list build
__global__ void __launch_bounds__(256)
gate_kernel(const short* x2, const short* gw, int* cnt, int* elist, float* ewt, int* tok2slot) {
  int t = blockIdx.x;
  int e = threadIdx.x >> 5, j = threadIdx.x & 31;
  const short* x = x2 + (long long)t * HDIM;
  float acc = 0.f;
  for (int k = j; k < HDIM; k += 32) acc += b2f(x[k]) * b2f(gw[(long long)k * EXP_ + e]);
  __shared__ float red[8][32];
  red[e][j] = acc; __syncthreads();
  for (int s2 = 16; s2 > 0; s2 >>= 1) {
    if (j < s2) red[e][j] += red[e][j + s2];
    __syncthreads();
  }
  if (threadIdx.x == 0) {
    float l[8], p[8];
    float m = -1e30f;
    for (int q = 0; q < 8; ++q) { l[q] = b2f(f2b(red[q][0])); m = fmaxf(m, l[q]); }
    float sum = 0.f;
    for (int q = 0; q < 8; ++q) { p[q] = expf(l[q] - m); sum += p[q]; }
    int i0 = 0; for (int q = 1; q < 8; ++q) if (p[q] > p[i0]) i0 = q;
    int i1 = (i0 == 0) ? 1 : 0;
    for (int q = 0; q < 8; ++q) if (q != i0 && p[q] > p[i1]) i1 = q;
    float denom = p[i0] + p[i1];
    float w0 = b2f(f2b(p[i0] / denom));
    float w1 = b2f(f2b(p[i1] / denom));
    int pos0 = atomicAdd(&cnt[i0], 1);
    int pos1 = atomicAdd(&cnt[i1], 1);
    elist[i0 * S_LEN + pos0] = t;  ewt[i0 * S_LEN + pos0] = w0;
    elist[i1 * S_LEN + pos1] = t;  ewt[i1 * S_LEN + pos1] = w1;
    int4* slot = (int4*)tok2slot;
    slot[t] = make_int4(i0, pos0, i1, pos1);
  }
}

// silu over compact routed buffers, applying combine weight
__global__ void __launch_bounds__(256)
silu_moe_kernel(short* a, const short* b, const int* cnt, const float* ewt) {
  int pos = blockIdx.x, e = blockIdx.y;
  if (pos >= cnt[e]) return;
  float scale = ewt[e * S_LEN + pos];
  int c = threadIdx.x;
  if (c >= IFF_ / 8) return;
  long long roff = ((long long)e * S_LEN + pos) * IFF_;
  short8_t av = reinterpret_cast<short8_t*>(a + roff)[c];
  short8_t bv = reinterpret_cast<const short8_t*>(b + roff)[c];
  short8_t ov;
  #pragma unroll
  for (int j = 0; j < 8; ++j) {
    float x = b2f(av[j]);
    float s = x / (1.0f + expf(-x));
    ov[j] = f2b(s * b2f(bv[j]) * scale);
  }
  reinterpret_cast<short8_t*>(a + roff)[c] = ov;
}

// shared-expert silu over [2][S][IFF] slabs
__global__ void __launch_bounds__(256)
silu_sh_kernel(short* a, const short* b) {
  long long roff = ((long long)blockIdx.y * S_LEN + blockIdx.x) * IFF_;
  int c = threadIdx.x;
  if (c >= IFF_ / 8) return;
  short8_t av = reinterpret_cast<short8_t*>(a + roff)[c];
  short8_t bv = reinterpret_cast<const short8_t*>(b + roff)[c];
  short8_t ov;
  #pragma unroll
  for (int j = 0; j < 8; ++j) {
    float x = b2f(av[j]);
    float s = x / (1.0f + expf(-x));
    ov[j] = f2b(s * b2f(bv[j]));
  }
  reinterpret_cast<short8_t*>(a + roff)[c] = ov;
}

// hbuf += sh0 + sh1 + routed[e0][pos0] + routed[e1][pos1]   (f32 sum, one round)
__global__ void __launch_bounds__(256)
moe_combine_kernel(short* h, const short* shared_out, const short* routed,
                   const int* tok2slot) {
  int t = blockIdx.x;
  const int4 sl = ((const int4*)tok2slot)[t];
  const short8_t* s0 = reinterpret_cast<const short8_t*>(shared_out + (long long)t * HDIM);
  const short8_t* s1 = reinterpret_cast<const short8_t*>(shared_out + ((long long)S_LEN + t) * HDIM);
  const short8_t* r0 = reinterpret_cast<const short8_t*>(
      routed + ((long long)sl.x * S_LEN + sl.y) * HDIM);
  const short8_t* r1 = reinterpret_cast<const short8_t*>(
      routed + ((long long)sl.z * S_LEN + sl.w) * HDIM);
  long long c = (long long)t * 256 + threadIdx.x;
  short8_t hv = reinterpret_cast<short8_t*>(h)[c];
  short8_t a0 = s0[threadIdx.x], a1 = s1[threadIdx.x];
  short8_t v0 = r0[threadIdx.x], v1 = r1[threadIdx.x];
  short8_t ov;
  #pragma unroll
  for (int j = 0; j < 8; ++j)
    ov[j] = f2b(b2f(hv[j]) + (b2f(a0[j]) + b2f(a1[j]) + b2f(v0[j]) + b2f(v1[j])));
  reinterpret_cast<short8_t*>(h)[c] = ov;
}

// ---------------- pooling ----------------
template<int AF32, int OUTBF16>
__global__ void __launch_bounds__(256)
gemv_bt_kernel(const void* a, const short* __restrict__ BT, void* out, int K) {
  int n = blockIdx.x;
  const short8_t* row = reinterpret_cast<const short8_t*>(BT + (long long)n * K);
  float acc = 0.f;
  for (int c = threadIdx.x; c < (K >> 3); c += 256) {
    short8_t v = row[c];
    if (AF32) {
      f32x4 a0 = reinterpret_cast<const f32x4*>(a)[2 * c];
      f32x4 a1 = reinterpret_cast<const f32x4*>(a)[2 * c + 1];
      #pragma unroll
      for (int j = 0; j < 4; ++j) {
        acc += a0[j] * b2f(v[j]);
        acc += a1[j] * b2f(v[4 + j]);
      }
    } else {
      short8_t av = reinterpret_cast<const short8_t*>(a)[c];
      #pragma unroll
      for (int j = 0; j < 8; ++j) acc += b2f(av[j]) * b2f(v[j]);
    }
  }
  __shared__ float red[256];
  red[threadIdx.x] = acc; __syncthreads();
  for (int s2 = 128; s2 > 0; s2 >>= 1) {
    if (threadIdx.x < s2) red[threadIdx.x] += red[threadIdx.x + s2];
    __syncthreads();
  }
  if (threadIdx.x == 0) {
    if (OUTBF16) ((short*)out)[n] = f2b(red[0]);
    else         ((float*)out)[n] = red[0];
  }
}

__global__ void __launch_bounds__(256)
pool_score_kernel(const short* qv, const short* kmat, float* score) {
  int s = blockIdx.x;
  const short8_t* kr = reinterpret_cast<const short8_t*>(kmat + (long long)s * HDIM);
  const short8_t* qr = reinterpret_cast<const short8_t*>(qv);
  short8_t kv8 = kr[threadIdx.x], qv8 = qr[threadIdx.x];
  float acc = 0.f;
  #pragma unroll
  for (int j = 0; j < 8; ++j) acc += b2f(qv8[j]) * b2f(kv8[j]);
  __shared__ float red[256];
  red[threadIdx.x] = acc; __syncthreads();
  for (int s2 = 128; s2 > 0; s2 >>= 1) {
    if (threadIdx.x < s2) red[threadIdx.x] += red[threadIdx.x + s2];
    __syncthreads();
  }
  if (threadIdx.x == 0) score[s] = b2f(f2b(red[0])) * 0.022097086912079608f;
}

__global__ void __launch_bounds__(256)
softmax_vec_kernel(float* v) {
  int tid = threadIdx.x;
  float f[8]; float m = -1e30f;
  #pragma unroll
  for (int i = 0; i < 8; ++i) { f[i] = v[i * 256 + tid]; m = fmaxf(m, f[i]); }
  __shared__ float red[256];
  red[tid] = m; __syncthreads();
  for (int s2 = 128; s2 > 0; s2 >>= 1) {
    if (tid < s2) red[tid] = fmaxf(red[tid], red[tid + s2]);
    __syncthreads();
  }
  m = red[0]; __syncthreads();
  float sum = 0.f;
  #pragma unroll
  for (int i = 0; i < 8; ++i) { f[i] = expf(f[i] - m); sum += f[i]; }
  red[tid] = sum; __syncthreads();
  for (int s2 = 128; s2 > 0; s2 >>= 1) {
    if (tid < s2) red[tid] += red[tid + s2];
    __syncthreads();
  }
  float inv = 1.0f / red[0];
  #pragma unroll
  for (int i = 0; i < 8; ++i) v[i * 256 + tid] = f[i] * inv;
}

__global__ void __launch_bounds__(256)
pool_wsum_t_kernel(const float* w, const short* vT, float* pooled) {
  int h = blockIdx.x;
  const short8_t* row = reinterpret_cast<const short8_t*>(vT + (long long)h * S_LEN);
  int c = threadIdx.x;
  short8_t v = row[c];
  f32x4 w0 = reinterpret_cast<const f32x4*>(w)[2 * c];
  f32x4 w1 = reinterpret_cast<const f32x4*>(w)[2 * c + 1];
  float acc = 0.f;
  #pragma unroll
  for (int j = 0; j < 4; ++j) {
    acc += w0[j] * b2f(v[j]);
    acc += w1[j] * b2f(v[4 + j]);
  }
  __shared__ float red[256];
  red[threadIdx.x] = acc; __syncthreads();
  for (int s2 = 128; s2 > 0; s2 >>= 1) {
    if (threadIdx.x < s2) red[threadIdx.x] += red[threadIdx.x + s2];
    __syncthreads();
  }
  if (threadIdx.x == 0) pooled[h] = red[0];
}

__global__ void __launch_bounds__(256)
rmsnorm_f32_kernel(const float* x, const short* w, float* out) {
  int tid = threadIdx.x;
  float f[8]; float ss = 0.f;
  #pragma unroll
  for (int i = 0; i < 8; ++i) { f[i] = x[i * 256 + tid]; ss += f[i] * f[i]; }
  __shared__ float red[256];
  red[tid] = ss; __syncthreads();
  for (int s2 = 128; s2 > 0; s2 >>= 1) {
    if (tid < s2) red[tid] += red[tid + s2];
    __syncthreads();
  }
  float r = 1.0f / sqrtf(red[0] / 2048.0f + 1e-6f);
  #pragma unroll
  for (int i = 0; i < 8; ++i) out[i * 256 + tid] = b2f(w[i * 256 + tid]) * (f[i] * r);
}

// ---------------- host ----------------
extern "C" void kernel_launch(void* const* d_in, const int* in_sizes, int n_in,
                              void* d_out, int out_size, void* d_ws, size_t ws_size,
                              hipStream_t stream)
{
  (void)n_in; (void)out_size; (void)ws_size;
  const int* ids = (const int*)d_in[24];

  char* base = (char*)d_ws;
  size_t off = 0;
  auto alloc = [&](size_t bytes) -> void* {
    void* p = base + off;
    off += (bytes + 255) & ~(size_t)255;
    return p;
  };

  int* dflag = (int*)alloc(256);

  short* qdwT  = (short*)alloc((size_t)2 * QRANK_ * HDIM * 2);
  short* quwT  = (short*)alloc((size_t)2 * QN_ * QRANK_ * 2);
  short* kvdwT = (short*)alloc((size_t)2 * KVDN * HDIM * 2);
  short* kvuwT = (short*)alloc((size_t)2 * KVUPN * KVRANK_ * 2);
  short* opwT  = (short*)alloc((size_t)2 * HDIM * HDIM * 2);
  short* rw1T  = (short*)alloc((size_t)16 * IFF_ * HDIM * 2);
  short* rw2T  = (short*)alloc((size_t)16 * HDIM * IFF_ * 2);
  short* rw3T  = (short*)alloc((size_t)16 * IFF_ * HDIM * 2);
  short* sw1T  = (short*)alloc((size_t)4 * IFF_ * HDIM * 2);
  short* sw2T  = (short*)alloc((size_t)4 * HDIM * IFF_ * 2);
  short* sw3T  = (short*)alloc((size_t)4 * IFF_ * HDIM * 2);
  short* pqwT  = (short*)alloc((size_t)HDIM * HDIM * 2);
  short* pkwT  = (short*)alloc((size_t)HDIM * HDIM * 2);
  short* pvwT  = (short*)alloc((size_t)HDIM * HDIM * 2);
  short* powT  = (short*)alloc((size_t)PD_ * HDIM * 2);
  short* ln1w = (short*)alloc((size_t)in_sizes[1] * 2);
  short* qnw  = (short*)alloc((size_t)in_sizes[3] * 2);
  short* kvnw = (short*)alloc((size_t)in_sizes[6] * 2);
  short* ln2w = (short*)alloc((size_t)in_sizes[9] * 2);
  short* gatw = (short*)alloc((size_t)in_sizes[10] * 2);
  short* fnww = (short*)alloc((size_t)in_sizes[17] * 2);
  short* lqw  = (short*)alloc((size_t)in_sizes[18] * 2);
  short* pnww = (short*)alloc((size_t)in_sizes[23] * 2);

  float* cosT    = (float*)alloc((size_t)S_LEN * 64 * 4);
  float* sinT    = (float*)alloc((size_t)S_LEN * 64 * 4);
  short* hbuf    = (short*)alloc((size_t)S_LEN * HDIM * 2);
  short* xbuf    = (short*)alloc((size_t)S_LEN * HDIM * 2);
  short* qlat    = (short*)alloc((size_t)S_LEN * QRANK_ * 2);
  short* qlatn   = (short*)alloc((size_t)S_LEN * QRANK_ * 2);
  short* qbuf    = (short*)alloc((size_t)S_LEN * QN_ * 2);
  short* kvbuf   = (short*)alloc((size_t)S_LEN * KVDN * 2);
  short* kvn     = (short*)alloc((size_t)S_LEN * KVRANK_ * 2);
  short* kvup    = (short*)alloc((size_t)S_LEN * KVUPN * 2);
  short* qf      = (short*)alloc((size_t)NH_ * S_LEN * DQK_ * 2);
  short* kf      = (short*)alloc((size_t)NH_ * S_LEN * DQK_ * 2);
  short* vT      = (short*)alloc((size_t)NH_ * 128 * S_LEN * 2);
  short* scores  = (short*)alloc((size_t)HG_ * S_LEN * S_LEN * 2);
  short* ao      = (short*)alloc((size_t)S_LEN * HDIM * 2);
  short* attnp   = (short*)alloc((size_t)S_LEN * HDIM * 2);
  short* hfin    = (short*)alloc((size_t)S_LEN * HDIM * 2);
  short* kpool   = (short*)alloc((size_t)S_LEN * HDIM * 2);
  short* vpoolT  = (short*)alloc((size_t)HDIM * S_LEN * 2);
  short* qvec    = (short*)alloc((size_t)HDIM * 2);
  float* pscore  = (float*)alloc((size_t)S_LEN * 4);
  float* pooled  = (float*)alloc((size_t)HDIM * 4);
  float* pooledn = (float*)alloc((size_t)HDIM * 4);
  // MoE
  int*   ecnt    = (int*)alloc(64);
  int*   elist   = (int*)alloc((size_t)EXP_ * S_LEN * 4);
  float* ewt     = (float*)alloc((size_t)EXP_ * S_LEN * 4);
  int*   tok2slot= (int*)alloc((size_t)S_LEN * 16);
  short* gba_e   = (short*)alloc((size_t)EXP_ * S_LEN * IFF_ * 2);
  short* gbb_e   = (short*)alloc((size_t)EXP_ * S_LEN * IFF_ * 2);
  short* routed  = (short*)alloc((size_t)EXP_ * S_LEN * HDIM * 2);
  short* gsh1    = (short*)alloc((size_t)2 * S_LEN * IFF_ * 2);
  short* gsh3    = (short*)alloc((size_t)2 * S_LEN * IFF_ * 2);
  short* shared_out = (short*)alloc((size_t)2 * S_LEN * HDIM * 2);

  detect_kernel<<<1, 256, 0, stream>>>(d_in[0], dflag);

  auto tconv = [&](const void* src, short* dst, int R, int C, int nslabs) {
    dim3 grid(C / 32, R / 32, nslabs);
    transconv_kernel<<<grid, 256, 0, stream>>>(src, dst, R, C, dflag);
  };
  auto pconv = [&](const void* src, short* dst, long long n) {
    long long nchunks = n / 8;
    int blocks = (int)((nchunks + 255) / 256);
    if (blocks > 2048) blocks = 2048;
    if (blocks < 1) blocks = 1;
    convert_kernel<<<blocks, 256, 0, stream>>>(src, dst, nchunks, dflag);
  };

  tconv(d_in[2],  qdwT,  HDIM,   QRANK_, 2);
  tconv(d_in[4],  quwT,  QRANK_, QN_,    2);
  tconv(d_in[5],  kvdwT, HDIM,   KVDN,   2);
  tconv(d_in[7],  kvuwT, KVRANK_,KVUPN,  2);
  tconv(d_in[8],  opwT,  HDIM,   HDIM,   2);
  tconv(d_in[11], rw1T,  HDIM,   IFF_,   16);
  tconv(d_in[12], rw2T,  IFF_,   HDIM,   16);
  tconv(d_in[13], rw3T,  HDIM,   IFF_,   16);
  tconv(d_in[14], sw1T,  HDIM,   IFF_,   4);
  tconv(d_in[15], sw2T,  IFF_,   HDIM,   4);
  tconv(d_in[16], sw3T,  HDIM,   IFF_,   4);
  tconv(d_in[19], pqwT,  HDIM,   HDIM,   1);
  tconv(d_in[20], pkwT,  HDIM,   HDIM,   1);
  tconv(d_in[21], pvwT,  HDIM,   HDIM,   1);
  tconv(d_in[22], powT,  HDIM,   PD_,    1);
  pconv(d_in[1],  ln1w, in_sizes[1]);
  pconv(d_in[3],  qnw,  in_sizes[3]);
  pconv(d_in[6],  kvnw, in_sizes[6]);
  pconv(d_in[9],  ln2w, in_sizes[9]);
  pconv(d_in[10], gatw, in_sizes[10]);
  pconv(d_in[17], fnww, in_sizes[17]);
  pconv(d_in[18], lqw,  in_sizes[18]);
  pconv(d_in[23], pnww, in_sizes[23]);

  const float qk_scale = 1.0f / sqrtf((float)DQK_);

  auto gemm = [&](int epi, const short* A, const short* B, void* C,
                  int M, int N, int K, int lda, int ldb, int ldc,
                  int batch, long long sA, long long sB, long long sC) {
    dim3 grid(M / 128, (N + 127) / 128, batch);
    if (epi == 0)
      gemm_kernel<0><<<grid, 256, 0, stream>>>(A, B, C, M, N, K, lda, ldb, ldc, sA, sB, sC);
    else
      gemm_kernel<1><<<grid, 256, 0, stream>>>(A, B, C, M, N, K, lda, ldb, ldc, sA, sB, sC);
  };

  rope_tables_kernel<<<S_LEN, 64, 0, stream>>>(cosT, sinT);
  embed_convert_kernel<<<S_LEN, 256, 0, stream>>>(ids, d_in[0], dflag, hbuf);

  for (int l = 0; l < 2; ++l) {
    const short* w_ln1 = ln1w + (size_t)l * HDIM;
    const short* w_qdT = qdwT + (size_t)l * QRANK_ * HDIM;
    const short* w_qn  = qnw  + (size_t)l * QRANK_;
    const short* w_quT = quwT + (size_t)l * QN_ * QRANK_;
    const short* w_kvdT= kvdwT+ (size_t)l * KVDN * HDIM;
    const short* w_kvn = kvnw + (size_t)l * KVRANK_;
    const short* w_kvuT= kvuwT+ (size_t)l * KVUPN * KVRANK_;
    const short* w_opT = opwT + (size_t)l * HDIM * HDIM;
    const short* w_ln2 = ln2w + (size_t)l * HDIM;
    const short* w_gat = gatw + (size_t)l * HDIM * EXP_;

    // --- attention ---
    rmsnorm_bf16_kernel<<<S_LEN, 256, 0, stream>>>(hbuf, HDIM, w_ln1, xbuf, HDIM, HDIM);
    gemm(0, xbuf, w_qdT, qlat, S_LEN, QRANK_, HDIM, HDIM, HDIM, QRANK_, 1, 0, 0, 0);
    rmsnorm_bf16_kernel<<<S_LEN, 256, 0, stream>>>(qlat, QRANK_, w_qn, qlatn, QRANK_, QRANK_);
    gemm(0, qlatn, w_quT, qbuf, S_LEN, QN_, QRANK_, QRANK_, QRANK_, QN_, 1, 0, 0, 0);
    gemm(0, xbuf, w_kvdT, kvbuf, S_LEN, KVDN, HDIM, HDIM, HDIM, KVDN, 1, 0, 0, 0);
    rmsnorm_bf16_kernel<<<S_LEN, 256, 0, stream>>>(kvbuf, KVDN, w_kvn, kvn, KVRANK_, KVRANK_);
    gemm(0, kvn, w_kvuT, kvup, S_LEN, KVUPN, KVRANK_, KVRANK_, KVRANK_, KVUPN, 1, 0, 0, 0);
    build_qf_kernel<<<S_LEN, 256, 0, stream>>>(qbuf, cosT, sinT, qf);
    build_kf_kernel<<<S_LEN, 256, 0, stream>>>(kvup, kvbuf, cosT, sinT, kf);
    {
      dim3 tg(128 / 32, S_LEN / 32, NH_);
      transpose_v_kernel<<<tg, 256, 0, stream>>>(kvup, vT);
    }
    // all 16 heads batched
    gemm(0, qf, kf, scores, S_LEN, S_LEN, DQK_, DQK_, DQK_, S_LEN, NH_,
         (long long)S_LEN * DQK_, (long long)S_LEN * DQK_, (long long)S_LEN * S_LEN);
    softmax_rows_kernel<<<NH_ * S_LEN, 256, 0, stream>>>(scores, qk_scale);
    gemm(0, scores, vT, ao, S_LEN, 128, S_LEN, S_LEN, S_LEN, HDIM, NH_,
         (long long)S_LEN * S_LEN, (long long)128 * S_LEN, 128);
    gemm(0, ao, w_opT, attnp, S_LEN, HDIM, HDIM, HDIM, HDIM, HDIM, 1, 0, 0, 0);
    add_bf16_kernel<<<S_LEN, 256, 0, stream>>>(hbuf, attnp);

    // --- MoE ---
    rmsnorm_bf16_kernel<<<S_LEN, 256, 0, stream>>>(hbuf, HDIM, w_ln2, xbuf, HDIM, HDIM);
    hipMemsetAsync(ecnt, 0, 64, stream);
    gate_kernel<<<S_LEN, 256, 0, stream>>>(xbuf, w_gat, ecnt, elist, ewt, tok2slot);
    // shared experts batched z=2
    {
      const short* a1 = sw1T + (size_t)l * 2 * IFF_ * HDIM;
      const short* a3 = sw3T + (size_t)l * 2 * IFF_ * HDIM;
      const short* a2 = sw2T + (size_t)l * 2 * HDIM * IFF_;
      gemm(0, xbuf, a1, gsh1, S_LEN, IFF_, HDIM, HDIM, HDIM, IFF_, 2,
           0, (long long)IFF_ * HDIM, (long long)S_LEN * IFF_);
      gemm(0, xbuf, a3, gsh3, S_LEN, IFF_, HDIM, HDIM, HDIM, IFF_, 2,
           0, (long long)IFF_ * HDIM, (long long)S_LEN * IFF_);
      dim3 gs(S_LEN, 2);
      silu_sh_kernel<<<gs, 256, 0, stream>>>(gsh1, gsh3);
      gemm(0, gsh1, a2, shared_out, S_LEN, HDIM, IFF_, IFF_, IFF_, HDIM, 2,
           (long long)S_LEN * IFF_, (long long)HDIM * IFF_, (long long)S_LEN * HDIM);
    }
    // routed experts (sparse)
    {
      const short* b1 = rw1T + (size_t)l * 8 * IFF_ * HDIM;
      const short* b3 = rw3T + (size_t)l * 8 * IFF_ * HDIM;
      const short* b2 = rw2T + (size_t)l * 8 * HDIM * IFF_;
      dim3 g13(S_LEN / 128, IFF_ / 128, EXP_);
      moe_gemm_kernel<1><<<g13, 256, 0, stream>>>(
          xbuf, elist, ecnt, b1, gba_e, IFF_, HDIM, HDIM, HDIM, IFF_,
          (long long)S_LEN * IFF_, (long long)IFF_ * HDIM, (long long)S_LEN * IFF_);
      moe_gemm_kernel<1><<<g13, 256, 0, stream>>>(
          xbuf, elist, ecnt, b3, gbb_e, IFF_, HDIM, HDIM, HDIM, IFF_,
          (long long)S_LEN * IFF_, (long long)IFF_ * HDIM, (long long)S_LEN * IFF_);
      dim3 gs(S_LEN, EXP_);
      silu_moe_kernel<<<gs, 256, 0, stream>>>(gba_e, gbb_e, ecnt, ewt);
      dim3 g2(S_LEN / 128, HDIM / 128, EXP_);
      moe_gemm_kernel<0><<<g2, 256, 0, stream>>>(
          gba_e, elist, ecnt, b2, routed, HDIM, IFF_, IFF_, IFF_, HDIM,
          (long long)S_LEN * IFF_, (long long)HDIM * IFF_, (long long)S_LEN * HDIM);
      moe_combine_kernel<<<S_LEN, 256, 0, stream>>>(hbuf, shared_out, routed, tok2slot);
    }
  }

  // --- attention pooling head ---
  rmsnorm_bf16_kernel<<<S_LEN, 256, 0, stream>>>(hbuf, HDIM, fnww, hfin, HDIM, HDIM);
  gemm(0, hfin, pkwT, kpool, S_LEN, HDIM, HDIM, HDIM, HDIM, HDIM, 1, 0, 0, 0);
  gemm(0, pvwT, hfin, vpoolT, HDIM, S_LEN, HDIM, HDIM, HDIM, S_LEN, 1, 0, 0, 0);
  gemv_bt_kernel<0,1><<<HDIM, 256, 0, stream>>>(lqw, pqwT, qvec, HDIM);
  pool_score_kernel<<<S_LEN, 256, 0, stream>>>(qvec, kpool, pscore);
  softmax_vec_kernel<<<1, 256, 0, stream>>>(pscore);
  pool_wsum_t_kernel<<<HDIM, 256, 0, stream>>>(pscore, vpoolT, pooled);
  rmsnorm_f32_kernel<<<1, 256, 0, stream>>>(pooled, pnww, pooledn);
  gemv_bt_kernel<1,0><<<PD_, 256, 0, stream>>>(pooledn, powT, (float*)d_out, HDIM);
}

// Round 6
// 2475.502 us; speedup vs baseline: 4.7773x; 1.0603x over previous
//
#include <hip/hip_runtime.h>
#include <hip/hip_bf16.h>

#define S_LEN  2048
#define HDIM   2048
#define NH_    16
#define DQK_   192
#define QRANK_ 1024
#define KVRANK_ 512
#define KVDN   576
#define DCAT   1600   // QRANK + KVDN merged down-proj width
#define KVUPN  4096
#define QN_    3072
#define IFF_   1408
#define EXP_   8
#define PD_    4096

typedef __attribute__((ext_vector_type(8))) short   short8_t;
typedef __attribute__((ext_vector_type(8))) __bf16  bf16x8_t;
typedef __attribute__((ext_vector_type(4))) float   f32x4;

static __device__ __forceinline__ float b2f(short s) {
  unsigned int u = ((unsigned int)(unsigned short)s) << 16;
  return __builtin_bit_cast(float, u);
}
static __device__ __forceinline__ short f2b(float f) {
  return __builtin_bit_cast(short, __float2bfloat16(f));
}

static __device__ __forceinline__ void gload16(const void* g, void* l) {
  __builtin_amdgcn_global_load_lds(
      (const __attribute__((address_space(1))) void*)g,
      (__attribute__((address_space(3))) void*)l,
      16, 0, 0);
}
static __device__ __forceinline__ void wait_vm4() { asm volatile("s_waitcnt vmcnt(4)" ::: "memory"); }
static __device__ __forceinline__ void wait_vm0() { asm volatile("s_waitcnt vmcnt(0)" ::: "memory"); }

// ---------------- dtype detect + convert ----------------
__global__ void __launch_bounds__(256)
detect_kernel(const void* probe, int* flag) {
  const float* f = (const float*)probe;
  int tid = threadIdx.x;
  int cnt = 0;
  for (int i = tid; i < 2048; i += 256) {
    float v = fabsf(f[i]);
    if (v > 1e-6f && v < 10.0f) cnt++;
  }
  __shared__ int red[256];
  red[tid] = cnt; __syncthreads();
  for (int s = 128; s > 0; s >>= 1) {
    if (tid < s) red[tid] += red[tid + s];
    __syncthreads();
  }
  if (tid == 0) *flag = (red[0] > 1600) ? 1 : 0;
}

__global__ void __launch_bounds__(256)
convert_kernel(const void* src, short* dst, long long nchunks, const int* flag) {
  long long idx = (long long)blockIdx.x * 256 + threadIdx.x;
  long long stride = (long long)gridDim.x * 256;
  if (*flag) {
    const f32x4* s = (const f32x4*)src;
    for (long long c = idx; c < nchunks; c += stride) {
      f32x4 a = s[2 * c], b = s[2 * c + 1];
      short8_t o;
      #pragma unroll
      for (int j = 0; j < 4; ++j) { o[j] = f2b(a[j]); o[4 + j] = f2b(b[j]); }
      reinterpret_cast<short8_t*>(dst)[c] = o;
    }
  } else {
    const short8_t* s = (const short8_t*)src;
    for (long long c = idx; c < nchunks; c += stride)
      reinterpret_cast<short8_t*>(dst)[c] = s[c];
  }
}

// transpose-convert: src slab [R][C] (f32/bf16) -> dst slab [C][R] bf16
__global__ void __launch_bounds__(256)
transconv_kernel(const void* src, short* dst, int R, int C, const int* flag,
                 long long sSrc, long long sDst) {
  long long zs = (long long)blockIdx.z * sSrc;
  long long zd = (long long)blockIdx.z * sDst;
  int r0 = blockIdx.y * 32, c0 = blockIdx.x * 32;
  int tx = threadIdx.x & 31, ty = threadIdx.x >> 5;
  __shared__ short tile[32][33];
  if (*flag) {
    const float* s = (const float*)src + zs;
    #pragma unroll
    for (int i = 0; i < 4; ++i)
      tile[ty + i * 8][tx] = f2b(s[(long long)(r0 + ty + i * 8) * C + c0 + tx]);
  } else {
    const short* s = (const short*)src + zs;
    #pragma unroll
    for (int i = 0; i < 4; ++i)
      tile[ty + i * 8][tx] = s[(long long)(r0 + ty + i * 8) * C + c0 + tx];
  }
  __syncthreads();
  short* d = dst + zd;
  #pragma unroll
  for (int i = 0; i < 4; ++i)
    d[(long long)(c0 + ty + i * 8) * R + r0 + tx] = tile[tx][ty + i * 8];
}

__global__ void __launch_bounds__(256)
embed_convert_kernel(const int* ids, const void* emb, const int* flag, short* h) {
  int s = blockIdx.x;
  long long row = ids[s];
  int c = threadIdx.x;
  short8_t o;
  if (*flag) {
    const f32x4* src = (const f32x4*)((const float*)emb + row * HDIM);
    f32x4 a = src[2 * c], b = src[2 * c + 1];
    #pragma unroll
    for (int j = 0; j < 4; ++j) { o[j] = f2b(a[j]); o[4 + j] = f2b(b[j]); }
  } else {
    o = reinterpret_cast<const short8_t*>((const short*)emb + row * HDIM)[c];
  }
  reinterpret_cast<short8_t*>(h + (long long)s * HDIM)[c] = o;
}

// ---------------- pipelined MFMA GEMM (B always [N][K]) ----------------
// 3-buffer LDS, counted vmcnt(4), one raw barrier per K-step.
template<int EPI>
__global__ void __launch_bounds__(256)
gemm_kernel(const short* __restrict__ A, const short* __restrict__ B,
            void* __restrict__ Cv, int M, int N, int K,
            int lda, int ldb, int ldc,
            long long sAb, long long sBb, long long sCb)
{
  __shared__ short shA[3][128][32];
  __shared__ short shB[3][128][32];
  const int tid = threadIdx.x;
  const long long bz = blockIdx.z;
  const short* Ab = A + bz * sAb;
  const short* Bb = B + bz * sBb;
  const int m0 = blockIdx.x * 128;
  const int n0 = blockIdx.y * 128;
  const int w = tid >> 6, lane = tid & 63;
  const int wm = (w >> 1) << 6, wn = (w & 1) << 6;
  const int lr = lane & 15, g = lane >> 4;
  const int srow = lane >> 2;
  const int scol = (lane & 3) << 3;
  const f32x4 vzero = {0.f, 0.f, 0.f, 0.f};
  f32x4 acc[4][4];
  #pragma unroll
  for (int i = 0; i < 4; ++i)
    #pragma unroll
    for (int j = 0; j < 4; ++j) acc[i][j] = vzero;

  const int nt = K >> 5;
#define STAGE_G(bi, kk) do { \
    _Pragma("unroll") \
    for (int r = 0; r < 2; ++r) { \
      int rowb = (w << 4) + (r << 6); \
      gload16(Ab + (long long)(m0 + rowb + srow) * lda + (kk) + scol, &shA[bi][rowb][0]); \
      gload16(Bb + (long long)(n0 + rowb + srow) * ldb + (kk) + scol, &shB[bi][rowb][0]); \
    } } while (0)

  STAGE_G(0, 0);
  if (nt > 1) STAGE_G(1, 32);
  int cur = 0, i2 = 2;
  for (int t = 0; t < nt; ++t) {
    if (t + 1 < nt) wait_vm4(); else wait_vm0();
    __builtin_amdgcn_s_barrier();
    if (t + 2 < nt) STAGE_G(i2, (t + 2) << 5);
    short8_t af[4];
    #pragma unroll
    for (int mi = 0; mi < 4; ++mi)
      af[mi] = *reinterpret_cast<const short8_t*>(&shA[cur][wm + (mi << 4) + lr][g << 3]);
    __builtin_amdgcn_s_setprio(1);
    #pragma unroll
    for (int ni = 0; ni < 4; ++ni) {
      short8_t bfr = *reinterpret_cast<const short8_t*>(&shB[cur][wn + (ni << 4) + lr][g << 3]);
      #pragma unroll
      for (int mi = 0; mi < 4; ++mi)
        acc[mi][ni] = __builtin_amdgcn_mfma_f32_16x16x32_bf16(
            __builtin_bit_cast(bf16x8_t, af[mi]),
            __builtin_bit_cast(bf16x8_t, bfr),
            acc[mi][ni], 0, 0, 0);
    }
    __builtin_amdgcn_s_setprio(0);
    cur = (cur == 2) ? 0 : cur + 1;
    i2  = (i2 == 2) ? 0 : i2 + 1;
  }
#undef STAGE_G
  const int orow = m0 + wm + (g << 2);
  const int ocol = n0 + wn + lr;
  if (EPI == 0) {
    short* C = reinterpret_cast<short*>(Cv) + bz * sCb;
    #pragma unroll
    for (int ni = 0; ni < 4; ++ni) {
      int col = ocol + (ni << 4);
      if (col >= N) continue;
      #pragma unroll
      for (int mi = 0; mi < 4; ++mi)
        #pragma unroll
        for (int r = 0; r < 4; ++r)
          C[(long long)(orow + (mi << 4) + r) * ldc + col] = f2b(acc[mi][ni][r]);
    }
  } else {
    float* C = reinterpret_cast<float*>(Cv) + bz * sCb;
    #pragma unroll
    for (int ni = 0; ni < 4; ++ni) {
      int col = ocol + (ni << 4);
      if (col >= N) continue;
      #pragma unroll
      for (int mi = 0; mi < 4; ++mi)
        #pragma unroll
        for (int r = 0; r < 4; ++r)
          C[(long long)(orow + (mi << 4) + r) * ldc + col] += acc[mi][ni][r];
    }
  }
}

// ---------------- pipelined sparse MoE gather GEMM ----------------
template<int GATHER>
__global__ void __launch_bounds__(256)
moe_gemm_kernel(const short* __restrict__ A, const int* __restrict__ elist,
                const int* __restrict__ cnt, const short* __restrict__ B,
                short* __restrict__ C, int N, int K,
                int lda, int ldb, int ldc,
                long long sAe, long long sBe, long long sCe)
{
  const int e = blockIdx.z;
  const int cnt_e = cnt[e];
  const int m0 = blockIdx.x * 128;
  if (m0 >= cnt_e) return;
  const short* Bb = B + (long long)e * sBe;
  short* Cb = C + (long long)e * sCe;
  const int n0 = blockIdx.y * 128;
  const int tid = threadIdx.x;
  const int w = tid >> 6, lane = tid & 63;
  const int wm = (w >> 1) << 6, wn = (w & 1) << 6;
  const int lr = lane & 15, g = lane >> 4;
  const int srow = lane >> 2;
  const int scol = (lane & 3) << 3;

  long long arow[2];
  #pragma unroll
  for (int r = 0; r < 2; ++r) {
    int row = m0 + (w << 4) + (r << 6) + srow;
    if (GATHER) {
      int p = row > cnt_e - 1 ? cnt_e - 1 : row;
      arow[r] = (long long)elist[e * S_LEN + p] * lda;
    } else {
      arow[r] = (long long)e * sAe + (long long)row * lda;
    }
  }

  __shared__ short shA[3][128][32];
  __shared__ short shB[3][128][32];
  const f32x4 vzero = {0.f, 0.f, 0.f, 0.f};
  f32x4 acc[4][4];
  #pragma unroll
  for (int i = 0; i < 4; ++i)
    #pragma unroll
    for (int j = 0; j < 4; ++j) acc[i][j] = vzero;

  const int nt = K >> 5;
#define STAGE_M(bi, kk) do { \
    _Pragma("unroll") \
    for (int r = 0; r < 2; ++r) { \
      int rowb = (w << 4) + (r << 6); \
      gload16(A + arow[r] + (kk) + scol, &shA[bi][rowb][0]); \
      gload16(Bb + (long long)(n0 + rowb + srow) * ldb + (kk) + scol, &shB[bi][rowb][0]); \
    } } while (0)

  STAGE_M(0, 0);
  if (nt > 1) STAGE_M(1, 32);
  int cur = 0, i2 = 2;
  for (int t = 0; t < nt; ++t) {
    if (t + 1 < nt) wait_vm4(); else wait_vm0();
    __builtin_amdgcn_s_barrier();
    if (t + 2 < nt) STAGE_M(i2, (t + 2) << 5);
    short8_t af[4];
    #pragma unroll
    for (int mi = 0; mi < 4; ++mi)
      af[mi] = *reinterpret_cast<const short8_t*>(&shA[cur][wm + (mi << 4) + lr][g << 3]);
    __builtin_amdgcn_s_setprio(1);
    #pragma unroll
    for (int ni = 0; ni < 4; ++ni) {
      short8_t bfr = *reinterpret_cast<const short8_t*>(&shB[cur][wn + (ni << 4) + lr][g << 3]);
      #pragma unroll
      for (int mi = 0; mi < 4; ++mi)
        acc[mi][ni] = __builtin_amdgcn_mfma_f32_16x16x32_bf16(
            __builtin_bit_cast(bf16x8_t, af[mi]),
            __builtin_bit_cast(bf16x8_t, bfr),
            acc[mi][ni], 0, 0, 0);
    }
    __builtin_amdgcn_s_setprio(0);
    cur = (cur == 2) ? 0 : cur + 1;
    i2  = (i2 == 2) ? 0 : i2 + 1;
  }
#undef STAGE_M
  const int orow = m0 + wm + (g << 2);
  const int ocol = n0 + wn + lr;
  #pragma unroll
  for (int ni = 0; ni < 4; ++ni) {
    int col = ocol + (ni << 4);
    #pragma unroll
    for (int mi = 0; mi < 4; ++mi) {
      int rbase = orow + (mi << 4);
      #pragma unroll
      for (int r = 0; r < 4; ++r)
        if (rbase + r < cnt_e)
          Cb[(long long)(rbase + r) * ldc + col] = f2b(acc[mi][ni][r]);
    }
  }
}

// ---------------- small kernels ----------------
__global__ void __launch_bounds__(64)
rope_tables_kernel(float* cosT, float* sinT) {
  int s = blockIdx.x, j = threadIdx.x;
  int i = j & 31;
  float inv = powf(10000.0f, -((float)(2 * i) / 64.0f));
  float ang = (float)s * inv;
  cosT[s * 64 + j] = cosf(ang);
  sinT[s * 64 + j] = sinf(ang);
}

__global__ void __launch_bounds__(256)
rmsnorm_bf16_kernel(const short* __restrict__ in, long long istride,
                    const short* __restrict__ w,
                    short* __restrict__ out, long long ostride, int D) {
  const short* x = in + (long long)blockIdx.x * istride;
  short* o = out + (long long)blockIdx.x * ostride;
  const int nc = D >> 3;
  float ss = 0.f;
  for (int c = threadIdx.x; c < nc; c += 256) {
    short8_t v = reinterpret_cast<const short8_t*>(x)[c];
    #pragma unroll
    for (int j = 0; j < 8; ++j) { float f = b2f(v[j]); ss += f * f; }
  }
  __shared__ float red[256];
  red[threadIdx.x] = ss; __syncthreads();
  for (int s2 = 128; s2 > 0; s2 >>= 1) {
    if (threadIdx.x < s2) red[threadIdx.x] += red[threadIdx.x + s2];
    __syncthreads();
  }
  float r = 1.0f / sqrtf(red[0] / (float)D + 1e-6f);
  for (int c = threadIdx.x; c < nc; c += 256) {
    short8_t v = reinterpret_cast<const short8_t*>(x)[c];
    short8_t wv = reinterpret_cast<const short8_t*>(w)[c];
    short8_t ov;
    #pragma unroll
    for (int j = 0; j < 8; ++j) ov[j] = f2b(b2f(wv[j]) * (b2f(v[j]) * r));
    reinterpret_cast<short8_t*>(o)[c] = ov;
  }
}

__global__ void __launch_bounds__(256)
build_qf_kernel(const short* q, const float* cosT, const float* sinT, short* qf) {
  int s = blockIdx.x;
  for (int idx = threadIdx.x; idx < NH_ * DQK_; idx += 256) {
    int h = idx / DQK_, d = idx - h * DQK_;
    const short* qr = q + (long long)s * QN_ + h * DQK_;
    float val;
    if (d < 128) val = b2f(qr[d]);
    else {
      int j = d - 128;
      float c = cosT[s * 64 + j], sn = sinT[s * 64 + j];
      float x0 = b2f(qr[128 + j]);
      float rot = (j < 32) ? -b2f(qr[128 + j + 32]) : b2f(qr[128 + j - 32]);
      val = x0 * c + rot * sn;
    }
    qf[(long long)h * S_LEN * DQK_ + (long long)s * DQK_ + d] = f2b(val);
  }
}

__global__ void __launch_bounds__(256)
build_kf_kernel(const short* kvup, const short* krope, long long kstride,
                const float* cosT, const float* sinT, short* kf) {
  int s = blockIdx.x;
  for (int idx = threadIdx.x; idx < NH_ * DQK_; idx += 256) {
    int h = idx / DQK_, d = idx - h * DQK_;
    float val;
    if (d < 128) val = b2f(kvup[(long long)s * KVUPN + h * 256 + d]);
    else {
      int j = d - 128;
      float c = cosT[s * 64 + j], sn = sinT[s * 64 + j];
      const short* kr = krope + (long long)s * kstride;
      float x0 = b2f(kr[j]);
      float rot = (j < 32) ? -b2f(kr[j + 32]) : b2f(kr[j - 32]);
      val = x0 * c + rot * sn;
    }
    kf[(long long)h * S_LEN * DQK_ + (long long)s * DQK_ + d] = f2b(val);
  }
}

__global__ void __launch_bounds__(256)
transpose_v_kernel(const short* kvup, short* vT) {
  int h = blockIdx.z;
  int r0 = blockIdx.y * 32, c0 = blockIdx.x * 32;
  int tx = threadIdx.x & 31, ty = threadIdx.x >> 5;
  __shared__ short tile[32][33];
  #pragma unroll
  for (int i = 0; i < 4; ++i)
    tile[ty + i * 8][tx] =
        kvup[(long long)(r0 + ty + i * 8) * KVUPN + h * 256 + 128 + c0 + tx];
  __syncthreads();
  short* d = vT + (long long)h * 128 * S_LEN;
  #pragma unroll
  for (int i = 0; i < 4; ++i)
    d[(long long)(c0 + ty + i * 8) * S_LEN + r0 + tx] = tile[tx][ty + i * 8];
}

__global__ void __launch_bounds__(256)
softmax_rows_kernel(short* scores, float scale) {
  long long row = blockIdx.x;
  short8_t* p = reinterpret_cast<short8_t*>(scores + row * S_LEN);
  short8_t v = p[threadIdx.x];
  float f[8]; float m = -1e30f;
  #pragma unroll
  for (int j = 0; j < 8; ++j) { f[j] = b2f(v[j]) * scale; m = fmaxf(m, f[j]); }
  __shared__ float red[256];
  red[threadIdx.x] = m; __syncthreads();
  for (int s2 = 128; s2 > 0; s2 >>= 1) {
    if (threadIdx.x < s2) red[threadIdx.x] = fmaxf(red[threadIdx.x], red[threadIdx.x + s2]);
    __syncthreads();
  }
  m = red[0]; __syncthreads();
  float sum = 0.f;
  #pragma unroll
  for (int j = 0; j < 8; ++j) { f[j] = expf(f[j] - m); sum += f[j]; }
  red[threadIdx.x] = sum; __syncthreads();
  for (int s2 = 128; s2 > 0; s2 >>= 1) {
    if (threadIdx.x < s2) red[threadIdx.x] += red[threadIdx.x + s2];
    __syncthreads();
  }
  float inv = 1.0f / red[0];
  short8_t o;
  #pragma unroll
  for (int j = 0; j < 8; ++j) o[j] = f2b(f[j] * inv);
  p[threadIdx.x] = o;
}

__global__ void __launch_bounds__(256)
add_bf16_kernel(short* h, const short* a) {
  long long c = (long long)blockIdx.x * 256 + threadIdx.x;
  short8_t hv = reinterpret_cast<short8_t*>(h)[c];
  short8_t av = reinterpret_cast<const short8_t*>(a)[c];
  short8_t ov;
  #pragma unroll
  for (int j = 0; j < 8; ++j) ov[j] = f2b(b2f(hv[j]) + b2f(av[j]));
  reinterpret_cast<short8_t*>(h)[c] = ov;
}

__global__ void __launch_bounds__(256)
gate_kernel(const short* x2, const short* gw, int* cnt, int* elist, float* ewt, int* tok2slot) {
  int t = blockIdx.x;
  int e = threadIdx.x >> 5, j = threadIdx.x & 31;
  const short* x = x2 + (long long)t * HDIM;
  float acc = 0.f;
  for (int k = j; k < HDIM; k += 32) acc += b2f(x[k]) * b2f(gw[(long long)k * EXP_ + e]);
  __shared__ float red[8][32];
  red[e][j] = acc; __syncthreads();
  for (int s2 = 16; s2 > 0; s2 >>= 1) {
    if (j < s2) red[e][j] += red[e][j + s2];
    __syncthreads();
  }
  if (threadIdx.x == 0) {
    float l[8], p[8];
    float m = -1e30f;
    for (int q = 0; q < 8; ++q) { l[q] = b2f(f2b(red[q][0])); m = fmaxf(m, l[q]); }
    float sum = 0.f;
    for (int q = 0; q < 8; ++q) { p[q] = expf(l[q] - m); sum += p[q]; }
    int i0 = 0; for (int q = 1; q < 8; ++q) if (p[q] > p[i0]) i0 = q;
    int i1 = (i0 == 0) ? 1 : 0;
    for (int q = 0; q < 8; ++q) if (q != i0 && p[q] > p[i1]) i1 = q;
    float denom = p[i0] + p[i1];
    float w0 = b2f(f2b(p[i0] / denom));
    float w1 = b2f(f2b(p[i1] / denom));
    int pos0 = atomicAdd(&cnt[i0], 1);
    int pos1 = atomicAdd(&cnt[i1], 1);
    elist[i0 * S_LEN + pos0] = t;  ewt[i0 * S_LEN + pos0] = w0;
    elist[i1 * S_LEN + pos1] = t;  ewt[i1 * S_LEN + pos1] = w1;
    int4* slot = (int4*)tok2slot;
    slot[t] = make_int4(i0, pos0, i1, pos1);
  }
}

__global__ void __launch_bounds__(256)
silu_moe_kernel(short* a, const short* b, const int* cnt, const float* ewt) {
  int pos = blockIdx.x, e = blockIdx.y;
  if (pos >= cnt[e]) return;
  float scale = ewt[e * S_LEN + pos];
  int c = threadIdx.x;
  if (c >= IFF_ / 8) return;
  long long roff = ((long long)e * S_LEN + pos) * IFF_;
  short8_t av = reinterpret_cast<short8_t*>(a + roff)[c];
  short8_t bv = reinterpret_cast<const short8_t*>(b + roff)[c];
  short8_t ov;
  #pragma unroll
  for (int j = 0; j < 8; ++j) {
    float x = b2f(av[j]);
    float s = x / (1.0f + expf(-x));
    ov[j] = f2b(s * b2f(bv[j]) * scale);
  }
  reinterpret_cast<short8_t*>(a + roff)[c] = ov;
}

__global__ void __launch_bounds__(256)
silu_sh_kernel(short* a, const short* b) {
  long long roff = ((long long)blockIdx.y * S_LEN + blockIdx.x) * IFF_;
  int c = threadIdx.x;
  if (c >= IFF_ / 8) return;
  short8_t av = reinterpret_cast<short8_t*>(a + roff)[c];
  short8_t bv = reinterpret_cast<const short8_t*>(b + roff)[c];
  short8_t ov;
  #pragma unroll
  for (int j = 0; j < 8; ++j) {
    float x = b2f(av[j]);
    float s = x / (1.0f + expf(-x));
    ov[j] = f2b(s * b2f(bv[j]));
  }
  reinterpret_cast<short8_t*>(a + roff)[c] = ov;
}

__global__ void __launch_bounds__(256)
moe_combine_kernel(short* h, const short* shared_out, const short* routed,
                   const int* tok2slot) {
  int t = blockIdx.x;
  const int4 sl = ((const int4*)tok2slot)[t];
  const short8_t* s0 = reinterpret_cast<const short8_t*>(shared_out + (long long)t * HDIM);
  const short8_t* s1 = reinterpret_cast<const short8_t*>(shared_out + ((long long)S_LEN + t) * HDIM);
  const short8_t* r0 = reinterpret_cast<const short8_t*>(
      routed + ((long long)sl.x * S_LEN + sl.y) * HDIM);
  const short8_t* r1 = reinterpret_cast<const short8_t*>(
      routed + ((long long)sl.z * S_LEN + sl.w) * HDIM);
  long long c = (long long)t * 256 + threadIdx.x;
  short8_t hv = reinterpret_cast<short8_t*>(h)[c];
  short8_t a0 = s0[threadIdx.x], a1 = s1[threadIdx.x];
  short8_t v0 = r0[threadIdx.x], v1 = r1[threadIdx.x];
  short8_t ov;
  #pragma unroll
  for (int j = 0; j < 8; ++j)
    ov[j] = f2b(b2f(hv[j]) + (b2f(a0[j]) + b2f(a1[j]) + b2f(v0[j]) + b2f(v1[j])));
  reinterpret_cast<short8_t*>(h)[c] = ov;
}

// ---------------- pooling ----------------
template<int AF32, int OUTBF16>
__global__ void __launch_bounds__(256)
gemv_bt_kernel(const void* a, const short* __restrict__ BT, void* out, int K) {
  int n = blockIdx.x;
  const short8_t* row = reinterpret_cast<const short8_t*>(BT + (long long)n * K);
  float acc = 0.f;
  for (int c = threadIdx.x; c < (K >> 3); c += 256) {
    short8_t v = row[c];
    if (AF32) {
      f32x4 a0 = reinterpret_cast<const f32x4*>(a)[2 * c];
      f32x4 a1 = reinterpret_cast<const f32x4*>(a)[2 * c + 1];
      #pragma unroll
      for (int j = 0; j < 4; ++j) {
        acc += a0[j] * b2f(v[j]);
        acc += a1[j] * b2f(v[4 + j]);
      }
    } else {
      short8_t av = reinterpret_cast<const short8_t*>(a)[c];
      #pragma unroll
      for (int j = 0; j < 8; ++j) acc += b2f(av[j]) * b2f(v[j]);
    }
  }
  __shared__ float red[256];
  red[threadIdx.x] = acc; __syncthreads();
  for (int s2 = 128; s2 > 0; s2 >>= 1) {
    if (threadIdx.x < s2) red[threadIdx.x] += red[threadIdx.x + s2];
    __syncthreads();
  }
  if (threadIdx.x == 0) {
    if (OUTBF16) ((short*)out)[n] = f2b(red[0]);
    else         ((float*)out)[n] = red[0];
  }
}

__global__ void __launch_bounds__(256)
pool_score_kernel(const short* qv, const short* kmat, float* score) {
  int s = blockIdx.x;
  const short8_t* kr = reinterpret_cast<const short8_t*>(kmat + (long long)s * HDIM);
  const short8_t* qr = reinterpret_cast<const short8_t*>(qv);
  short8_t kv8 = kr[threadIdx.x], qv8 = qr[threadIdx.x];
  float acc = 0.f;
  #pragma unroll
  for (int j = 0; j < 8; ++j) acc += b2f(qv8[j]) * b2f(kv8[j]);
  __shared__ float red[256];
  red[threadIdx.x] = acc; __syncthreads();
  for (int s2 = 128; s2 > 0; s2 >>= 1) {
    if (threadIdx.x < s2) red[threadIdx.x] += red[threadIdx.x + s2];
    __syncthreads();
  }
  if (threadIdx.x == 0) score[s] = b2f(f2b(red[0])) * 0.022097086912079608f;
}

__global__ void __launch_bounds__(256)
softmax_vec_kernel(float* v) {
  int tid = threadIdx.x;
  float f[8]; float m = -1e30f;
  #pragma unroll
  for (int i = 0; i < 8; ++i) { f[i] = v[i * 256 + tid]; m = fmaxf(m, f[i]); }
  __shared__ float red[256];
  red[tid] = m; __syncthreads();
  for (int s2 = 128; s2 > 0; s2 >>= 1) {
    if (tid < s2) red[tid] = fmaxf(red[tid], red[tid + s2]);
    __syncthreads();
  }
  m = red[0]; __syncthreads();
  float sum = 0.f;
  #pragma unroll
  for (int i = 0; i < 8; ++i) { f[i] = expf(f[i] - m); sum += f[i]; }
  red[tid] = sum; __syncthreads();
  for (int s2 = 128; s2 > 0; s2 >>= 1) {
    if (tid < s2) red[tid] += red[tid + s2];
    __syncthreads();
  }
  float inv = 1.0f / red[0];
  #pragma unroll
  for (int i = 0; i < 8; ++i) v[i * 256 + tid] = f[i] * inv;
}

__global__ void __launch_bounds__(256)
pool_wsum_t_kernel(const float* w, const short* vT, float* pooled) {
  int h = blockIdx.x;
  const short8_t* row = reinterpret_cast<const short8_t*>(vT + (long long)h * S_LEN);
  int c = threadIdx.x;
  short8_t v = row[c];
  f32x4 w0 = reinterpret_cast<const f32x4*>(w)[2 * c];
  f32x4 w1 = reinterpret_cast<const f32x4*>(w)[2 * c + 1];
  float acc = 0.f;
  #pragma unroll
  for (int j = 0; j < 4; ++j) {
    acc += w0[j] * b2f(v[j]);
    acc += w1[j] * b2f(v[4 + j]);
  }
  __shared__ float red[256];
  red[threadIdx.x] = acc; __syncthreads();
  for (int s2 = 128; s2 > 0; s2 >>= 1) {
    if (threadIdx.x < s2) red[threadIdx.x] += red[threadIdx.x + s2];
    __syncthreads();
  }
  if (threadIdx.x == 0) pooled[h] = red[0];
}

__global__ void __launch_bounds__(256)
rmsnorm_f32_kernel(const float* x, const short* w, float* out) {
  int tid = threadIdx.x;
  float f[8]; float ss = 0.f;
  #pragma unroll
  for (int i = 0; i < 8; ++i) { f[i] = x[i * 256 + tid]; ss += f[i] * f[i]; }
  __shared__ float red[256];
  red[tid] = ss; __syncthreads();
  for (int s2 = 128; s2 > 0; s2 >>= 1) {
    if (tid < s2) red[tid] += red[tid + s2];
    __syncthreads();
  }
  float r = 1.0f / sqrtf(red[0] / 2048.0f + 1e-6f);
  #pragma unroll
  for (int i = 0; i < 8; ++i) out[i * 256 + tid] = b2f(w[i * 256 + tid]) * (f[i] * r);
}

// ---------------- host ----------------
extern "C" void kernel_launch(void* const* d_in, const int* in_sizes, int n_in,
                              void* d_out, int out_size, void* d_ws, size_t ws_size,
                              hipStream_t stream)
{
  (void)n_in; (void)out_size; (void)ws_size;
  const int* ids = (const int*)d_in[24];

  char* base = (char*)d_ws;
  size_t off = 0;
  auto alloc = [&](size_t bytes) -> void* {
    void* p = base + off;
    off += (bytes + 255) & ~(size_t)255;
    return p;
  };

  int* dflag = (int*)alloc(256);

  short* qkvdwT = (short*)alloc((size_t)2 * DCAT * HDIM * 2);   // merged q_down+kv_down [N=1600][K=2048]
  short* quwT  = (short*)alloc((size_t)2 * QN_ * QRANK_ * 2);
  short* kvuwT = (short*)alloc((size_t)2 * KVUPN * KVRANK_ * 2);
  short* opwT  = (short*)alloc((size_t)2 * HDIM * HDIM * 2);
  short* rw1T  = (short*)alloc((size_t)16 * IFF_ * HDIM * 2);
  short* rw2T  = (short*)alloc((size_t)16 * HDIM * IFF_ * 2);
  short* rw3T  = (short*)alloc((size_t)16 * IFF_ * HDIM * 2);
  short* sw1T  = (short*)alloc((size_t)4 * IFF_ * HDIM * 2);
  short* sw2T  = (short*)alloc((size_t)4 * HDIM * IFF_ * 2);
  short* sw3T  = (short*)alloc((size_t)4 * IFF_ * HDIM * 2);
  short* pqwT  = (short*)alloc((size_t)HDIM * HDIM * 2);
  short* pkwT  = (short*)alloc((size_t)HDIM * HDIM * 2);
  short* pvwT  = (short*)alloc((size_t)HDIM * HDIM * 2);
  short* powT  = (short*)alloc((size_t)PD_ * HDIM * 2);
  short* ln1w = (short*)alloc((size_t)in_sizes[1] * 2);
  short* qnw  = (short*)alloc((size_t)in_sizes[3] * 2);
  short* kvnw = (short*)alloc((size_t)in_sizes[6] * 2);
  short* ln2w = (short*)alloc((size_t)in_sizes[9] * 2);
  short* gatw = (short*)alloc((size_t)in_sizes[10] * 2);
  short* fnww = (short*)alloc((size_t)in_sizes[17] * 2);
  short* lqw  = (short*)alloc((size_t)in_sizes[18] * 2);
  short* pnww = (short*)alloc((size_t)in_sizes[23] * 2);

  float* cosT    = (float*)alloc((size_t)S_LEN * 64 * 4);
  float* sinT    = (float*)alloc((size_t)S_LEN * 64 * 4);
  short* hbuf    = (short*)alloc((size_t)S_LEN * HDIM * 2);
  short* xbuf    = (short*)alloc((size_t)S_LEN * HDIM * 2);
  short* dcat    = (short*)alloc((size_t)S_LEN * DCAT * 2);   // [S][1600] = qlat | kv
  short* qlatn   = (short*)alloc((size_t)S_LEN * QRANK_ * 2);
  short* qbuf    = (short*)alloc((size_t)S_LEN * QN_ * 2);
  short* kvn     = (short*)alloc((size_t)S_LEN * KVRANK_ * 2);
  short* kvup    = (short*)alloc((size_t)S_LEN * KVUPN * 2);
  short* qf      = (short*)alloc((size_t)NH_ * S_LEN * DQK_ * 2);
  short* kf      = (short*)alloc((size_t)NH_ * S_LEN * DQK_ * 2);
  short* vT      = (short*)alloc((size_t)NH_ * 128 * S_LEN * 2);
  short* scores  = (short*)alloc((size_t)NH_ * S_LEN * S_LEN * 2);
  short* ao      = (short*)alloc((size_t)S_LEN * HDIM * 2);
  short* attnp   = (short*)alloc((size_t)S_LEN * HDIM * 2);
  short* hfin    = (short*)alloc((size_t)S_LEN * HDIM * 2);
  short* kpool   = (short*)alloc((size_t)S_LEN * HDIM * 2);
  short* vpoolT  = (short*)alloc((size_t)HDIM * S_LEN * 2);
  short* qvec    = (short*)alloc((size_t)HDIM * 2);
  float* pscore  = (float*)alloc((size_t)S_LEN * 4);
  float* pooled  = (float*)alloc((size_t)HDIM * 4);
  float* pooledn = (float*)alloc((size_t)HDIM * 4);
  int*   ecnt    = (int*)alloc(64);
  int*   elist   = (int*)alloc((size_t)EXP_ * S_LEN * 4);
  float* ewt     = (float*)alloc((size_t)EXP_ * S_LEN * 4);
  int*   tok2slot= (int*)alloc((size_t)S_LEN * 16);
  short* gba_e   = (short*)alloc((size_t)EXP_ * S_LEN * IFF_ * 2);
  short* gbb_e   = (short*)alloc((size_t)EXP_ * S_LEN * IFF_ * 2);
  short* routed  = (short*)alloc((size_t)EXP_ * S_LEN * HDIM * 2);
  short* gsh1    = (short*)alloc((size_t)2 * S_LEN * IFF_ * 2);
  short* gsh3    = (short*)alloc((size_t)2 * S_LEN * IFF_ * 2);
  short* shared_out = (short*)alloc((size_t)2 * S_LEN * HDIM * 2);

  detect_kernel<<<1, 256, 0, stream>>>(d_in[0], dflag);

  auto tconv = [&](const void* src, short* dst, int R, int C, int nslabs,
                   long long sSrc, long long sDst) {
    dim3 grid(C / 32, R / 32, nslabs);
    transconv_kernel<<<grid, 256, 0, stream>>>(src, dst, R, C, dflag, sSrc, sDst);
  };
  auto pconv = [&](const void* src, short* dst, long long n) {
    long long nchunks = n / 8;
    int blocks = (int)((nchunks + 255) / 256);
    if (blocks > 2048) blocks = 2048;
    if (blocks < 1) blocks = 1;
    convert_kernel<<<blocks, 256, 0, stream>>>(src, dst, nchunks, dflag);
  };

  // merged down-proj: q part rows [0,1024), kv part rows [1024,1600) of each layer slab
  tconv(d_in[2], qkvdwT, HDIM, QRANK_, 2,
        (long long)HDIM * QRANK_, (long long)DCAT * HDIM);
  tconv(d_in[5], qkvdwT + (size_t)QRANK_ * HDIM, HDIM, KVDN, 2,
        (long long)HDIM * KVDN, (long long)DCAT * HDIM);
  tconv(d_in[4],  quwT,  QRANK_, QN_,  2, (long long)QRANK_ * QN_,  (long long)QN_ * QRANK_);
  tconv(d_in[7],  kvuwT, KVRANK_,KVUPN,2, (long long)KVRANK_ * KVUPN,(long long)KVUPN * KVRANK_);
  tconv(d_in[8],  opwT,  HDIM,   HDIM, 2, (long long)HDIM * HDIM,   (long long)HDIM * HDIM);
  tconv(d_in[11], rw1T,  HDIM,   IFF_, 16,(long long)HDIM * IFF_,   (long long)IFF_ * HDIM);
  tconv(d_in[12], rw2T,  IFF_,   HDIM, 16,(long long)IFF_ * HDIM,   (long long)HDIM * IFF_);
  tconv(d_in[13], rw3T,  HDIM,   IFF_, 16,(long long)HDIM * IFF_,   (long long)IFF_ * HDIM);
  tconv(d_in[14], sw1T,  HDIM,   IFF_, 4, (long long)HDIM * IFF_,   (long long)IFF_ * HDIM);
  tconv(d_in[15], sw2T,  IFF_,   HDIM, 4, (long long)IFF_ * HDIM,   (long long)HDIM * IFF_);
  tconv(d_in[16], sw3T,  HDIM,   IFF_, 4, (long long)HDIM * IFF_,   (long long)IFF_ * HDIM);
  tconv(d_in[19], pqwT,  HDIM,   HDIM, 1, 0, 0);
  tconv(d_in[20], pkwT,  HDIM,   HDIM, 1, 0, 0);
  tconv(d_in[21], pvwT,  HDIM,   HDIM, 1, 0, 0);
  tconv(d_in[22], powT,  HDIM,   PD_,  1, 0, 0);
  pconv(d_in[1],  ln1w, in_sizes[1]);
  pconv(d_in[3],  qnw,  in_sizes[3]);
  pconv(d_in[6],  kvnw, in_sizes[6]);
  pconv(d_in[9],  ln2w, in_sizes[9]);
  pconv(d_in[10], gatw, in_sizes[10]);
  pconv(d_in[17], fnww, in_sizes[17]);
  pconv(d_in[18], lqw,  in_sizes[18]);
  pconv(d_in[23], pnww, in_sizes[23]);

  const float qk_scale = 1.0f / sqrtf((float)DQK_);

  auto gemm = [&](int epi, const short* A, const short* B, void* C,
                  int M, int N, int K, int lda, int ldb, int ldc,
                  int batch, long long sA, long long sB, long long sC) {
    dim3 grid(M / 128, (N + 127) / 128, batch);
    if (epi == 0)
      gemm_kernel<0><<<grid, 256, 0, stream>>>(A, B, C, M, N, K, lda, ldb, ldc, sA, sB, sC);
    else
      gemm_kernel<1><<<grid, 256, 0, stream>>>(A, B, C, M, N, K, lda, ldb, ldc, sA, sB, sC);
  };

  rope_tables_kernel<<<S_LEN, 64, 0, stream>>>(cosT, sinT);
  embed_convert_kernel<<<S_LEN, 256, 0, stream>>>(ids, d_in[0], dflag, hbuf);

  for (int l = 0; l < 2; ++l) {
    const short* w_ln1  = ln1w + (size_t)l * HDIM;
    const short* w_qkvT = qkvdwT + (size_t)l * DCAT * HDIM;
    const short* w_qn   = qnw  + (size_t)l * QRANK_;
    const short* w_quT  = quwT + (size_t)l * QN_ * QRANK_;
    const short* w_kvn  = kvnw + (size_t)l * KVRANK_;
    const short* w_kvuT = kvuwT+ (size_t)l * KVUPN * KVRANK_;
    const short* w_opT  = opwT + (size_t)l * HDIM * HDIM;
    const short* w_ln2  = ln2w + (size_t)l * HDIM;
    const short* w_gat  = gatw + (size_t)l * HDIM * EXP_;

    // --- attention ---
    rmsnorm_bf16_kernel<<<S_LEN, 256, 0, stream>>>(hbuf, HDIM, w_ln1, xbuf, HDIM, HDIM);
    gemm(0, xbuf, w_qkvT, dcat, S_LEN, DCAT, HDIM, HDIM, HDIM, DCAT, 1, 0, 0, 0);
    rmsnorm_bf16_kernel<<<S_LEN, 256, 0, stream>>>(dcat, DCAT, w_qn, qlatn, QRANK_, QRANK_);
    gemm(0, qlatn, w_quT, qbuf, S_LEN, QN_, QRANK_, QRANK_, QRANK_, QN_, 1, 0, 0, 0);
    rmsnorm_bf16_kernel<<<S_LEN, 256, 0, stream>>>(dcat + QRANK_, DCAT, w_kvn, kvn, KVRANK_, KVRANK_);
    gemm(0, kvn, w_kvuT, kvup, S_LEN, KVUPN, KVRANK_, KVRANK_, KVRANK_, KVUPN, 1, 0, 0, 0);
    build_qf_kernel<<<S_LEN, 256, 0, stream>>>(qbuf, cosT, sinT, qf);
    build_kf_kernel<<<S_LEN, 256, 0, stream>>>(kvup, dcat + QRANK_ + KVRANK_, DCAT, cosT, sinT, kf);
    {
      dim3 tg(128 / 32, S_LEN / 32, NH_);
      transpose_v_kernel<<<tg, 256, 0, stream>>>(kvup, vT);
    }
    gemm(0, qf, kf, scores, S_LEN, S_LEN, DQK_, DQK_, DQK_, S_LEN, NH_,
         (long long)S_LEN * DQK_, (long long)S_LEN * DQK_, (long long)S_LEN * S_LEN);
    softmax_rows_kernel<<<NH_ * S_LEN, 256, 0, stream>>>(scores, qk_scale);
    gemm(0, scores, vT, ao, S_LEN, 128, S_LEN, S_LEN, S_LEN, HDIM, NH_,
         (long long)S_LEN * S_LEN, (long long)128 * S_LEN, 128);
    gemm(0, ao, w_opT, attnp, S_LEN, HDIM, HDIM, HDIM, HDIM, HDIM, 1, 0, 0, 0);
    add_bf16_kernel<<<S_LEN, 256, 0, stream>>>(hbuf, attnp);

    // --- MoE ---
    rmsnorm_bf16_kernel<<<S_LEN, 256, 0, stream>>>(hbuf, HDIM, w_ln2, xbuf, HDIM, HDIM);
    hipMemsetAsync(ecnt, 0, 64, stream);
    gate_kernel<<<S_LEN, 256, 0, stream>>>(xbuf, w_gat, ecnt, elist, ewt, tok2slot);
    {
      const short* a1 = sw1T + (size_t)l * 2 * IFF_ * HDIM;
      const short* a3 = sw3T + (size_t)l * 2 * IFF_ * HDIM;
      const short* a2 = sw2T + (size_t)l * 2 * HDIM * IFF_;
      gemm(0, xbuf, a1, gsh1, S_LEN, IFF_, HDIM, HDIM, HDIM, IFF_, 2,
           0, (long long)IFF_ * HDIM, (long long)S_LEN * IFF_);
      gemm(0, xbuf, a3, gsh3, S_LEN, IFF_, HDIM, HDIM, HDIM, IFF_, 2,
           0, (long long)IFF_ * HDIM, (long long)S_LEN * IFF_);
      dim3 gs(S_LEN, 2);
      silu_sh_kernel<<<gs, 256, 0, stream>>>(gsh1, gsh3);
      gemm(0, gsh1, a2, shared_out, S_LEN, HDIM, IFF_, IFF_, IFF_, HDIM, 2,
           (long long)S_LEN * IFF_, (long long)HDIM * IFF_, (long long)S_LEN * HDIM);
    }
    {
      const short* b1 = rw1T + (size_t)l * 8 * IFF_ * HDIM;
      const short* b3 = rw3T + (size_t)l * 8 * IFF_ * HDIM;
      const short* b2 = rw2T + (size_t)l * 8 * HDIM * IFF_;
      dim3 g13(S_LEN / 128, IFF_ / 128, EXP_);
      moe_gemm_kernel<1><<<g13, 256, 0, stream>>>(
          xbuf, elist, ecnt, b1, gba_e, IFF_, HDIM, HDIM, HDIM, IFF_,
          (long long)S_LEN * IFF_, (long long)IFF_ * HDIM, (long long)S_LEN * IFF_);
      moe_gemm_kernel<1><<<g13, 256, 0, stream>>>(
          xbuf, elist, ecnt, b3, gbb_e, IFF_, HDIM, HDIM, HDIM, IFF_,
          (long long)S_LEN * IFF_, (long long)IFF_ * HDIM, (long long)S_LEN * IFF_);
      dim3 gs(S_LEN, EXP_);
      silu_moe_kernel<<<gs, 256, 0, stream>>>(gba_e, gbb_e, ecnt, ewt);
      dim3 g2(S_LEN / 128, HDIM / 128, EXP_);
      moe_gemm_kernel<0><<<g2, 256, 0, stream>>>(
          gba_e, elist, ecnt, b2, routed, HDIM, IFF_, IFF_, IFF_, HDIM,
          (long long)S_LEN * IFF_, (long long)HDIM * IFF_, (long long)S_LEN * HDIM);
      moe_combine_kernel<<<S_LEN, 256, 0, stream>>>(hbuf, shared_out, routed, tok2slot);
    }
  }

  // --- attention pooling head ---
  rmsnorm_bf16_kernel<<<S_LEN, 256, 0, stream>>>(hbuf, HDIM, fnww, hfin, HDIM, HDIM);
  gemm(0, hfin, pkwT, kpool, S_LEN, HDIM, HDIM, HDIM, HDIM, HDIM, 1, 0, 0, 0);
  gemm(0, pvwT, hfin, vpoolT, HDIM, S_LEN, HDIM, HDIM, HDIM, S_LEN, 1, 0, 0, 0);
  gemv_bt_kernel<0,1><<<HDIM, 256, 0, stream>>>(lqw, pqwT, qvec, HDIM);
  pool_score_kernel<<<S_LEN, 256, 0, stream>>>(qvec, kpool, pscore);
  softmax_vec_kernel<<<1, 256, 0, stream>>>(pscore);
  pool_wsum_t_kernel<<<HDIM, 256, 0, stream>>>(pscore, vpoolT, pooled);
  rmsnorm_f32_kernel<<<1, 256, 0, stream>>>(pooled, pnww, pooledn);
  gemv_bt_kernel<1,0><<<PD_, 256, 0, stream>>>(pooledn, powT, (float*)d_out, HDIM);
}

// Round 7
// 2226.886 us; speedup vs baseline: 5.3106x; 1.1116x over previous
//
#include <hip/hip_runtime.h>
#include <hip/hip_bf16.h>

#define S_LEN  2048
#define HDIM   2048
#define NH_    16
#define DQK_   192
#define QRANK_ 1024
#define KVRANK_ 512
#define KVDN   576
#define DCAT   1600   // QRANK + KVDN merged down-proj width
#define KVUPN  4096
#define QN_    3072
#define IFF_   1408
#define EXP_   8
#define PD_    4096

typedef __attribute__((ext_vector_type(8))) short   short8_t;
typedef __attribute__((ext_vector_type(8))) __bf16  bf16x8_t;
typedef __attribute__((ext_vector_type(4))) float   f32x4;

static __device__ __forceinline__ float b2f(short s) {
  unsigned int u = ((unsigned int)(unsigned short)s) << 16;
  return __builtin_bit_cast(float, u);
}
static __device__ __forceinline__ short f2b(float f) {
  return __builtin_bit_cast(short, __float2bfloat16(f));
}

static __device__ __forceinline__ void gload16(const void* g, void* l) {
  __builtin_amdgcn_global_load_lds(
      (const __attribute__((address_space(1))) void*)g,
      (__attribute__((address_space(3))) void*)l,
      16, 0, 0);
}
static __device__ __forceinline__ void wait_vm4() { asm volatile("s_waitcnt vmcnt(4)" ::: "memory"); }
static __device__ __forceinline__ void wait_vm0() { asm volatile("s_waitcnt vmcnt(0)" ::: "memory"); }

// ---------------- dtype detect + convert ----------------
__global__ void __launch_bounds__(256)
detect_kernel(const void* probe, int* flag) {
  const float* f = (const float*)probe;
  int tid = threadIdx.x;
  int cnt = 0;
  for (int i = tid; i < 2048; i += 256) {
    float v = fabsf(f[i]);
    if (v > 1e-6f && v < 10.0f) cnt++;
  }
  __shared__ int red[256];
  red[tid] = cnt; __syncthreads();
  for (int s = 128; s > 0; s >>= 1) {
    if (tid < s) red[tid] += red[tid + s];
    __syncthreads();
  }
  if (tid == 0) *flag = (red[0] > 1600) ? 1 : 0;
}

__global__ void __launch_bounds__(256)
convert_kernel(const void* src, short* dst, long long nchunks, const int* flag) {
  long long idx = (long long)blockIdx.x * 256 + threadIdx.x;
  long long stride = (long long)gridDim.x * 256;
  if (*flag) {
    const f32x4* s = (const f32x4*)src;
    for (long long c = idx; c < nchunks; c += stride) {
      f32x4 a = s[2 * c], b = s[2 * c + 1];
      short8_t o;
      #pragma unroll
      for (int j = 0; j < 4; ++j) { o[j] = f2b(a[j]); o[4 + j] = f2b(b[j]); }
      reinterpret_cast<short8_t*>(dst)[c] = o;
    }
  } else {
    const short8_t* s = (const short8_t*)src;
    for (long long c = idx; c < nchunks; c += stride)
      reinterpret_cast<short8_t*>(dst)[c] = s[c];
  }
}

// transpose-convert: src slab [R][C] (f32/bf16) -> dst slab [C][R] bf16
__global__ void __launch_bounds__(256)
transconv_kernel(const void* src, short* dst, int R, int C, const int* flag,
                 long long sSrc, long long sDst) {
  long long zs = (long long)blockIdx.z * sSrc;
  long long zd = (long long)blockIdx.z * sDst;
  int r0 = blockIdx.y * 32, c0 = blockIdx.x * 32;
  int tx = threadIdx.x & 31, ty = threadIdx.x >> 5;
  __shared__ short tile[32][33];
  if (*flag) {
    const float* s = (const float*)src + zs;
    #pragma unroll
    for (int i = 0; i < 4; ++i)
      tile[ty + i * 8][tx] = f2b(s[(long long)(r0 + ty + i * 8) * C + c0 + tx]);
  } else {
    const short* s = (const short*)src + zs;
    #pragma unroll
    for (int i = 0; i < 4; ++i)
      tile[ty + i * 8][tx] = s[(long long)(r0 + ty + i * 8) * C + c0 + tx];
  }
  __syncthreads();
  short* d = dst + zd;
  #pragma unroll
  for (int i = 0; i < 4; ++i)
    d[(long long)(c0 + ty + i * 8) * R + r0 + tx] = tile[tx][ty + i * 8];
}

__global__ void __launch_bounds__(256)
embed_convert_kernel(const int* ids, const void* emb, const int* flag, short* h) {
  int s = blockIdx.x;
  long long row = ids[s];
  int c = threadIdx.x;
  short8_t o;
  if (*flag) {
    const f32x4* src = (const f32x4*)((const float*)emb + row * HDIM);
    f32x4 a = src[2 * c], b = src[2 * c + 1];
    #pragma unroll
    for (int j = 0; j < 4; ++j) { o[j] = f2b(a[j]); o[4 + j] = f2b(b[j]); }
  } else {
    o = reinterpret_cast<const short8_t*>((const short*)emb + row * HDIM)[c];
  }
  reinterpret_cast<short8_t*>(h + (long long)s * HDIM)[c] = o;
}

// ---------------- pipelined MFMA GEMM (B always [N][K], bf16 C) ----------------
// 3-buffer LDS staging + counted vmcnt(4); LDS-retiled vectorized epilogue.
__global__ void __launch_bounds__(256)
gemm_kernel(const short* __restrict__ A, const short* __restrict__ B,
            short* __restrict__ Cv, int M, int N, int K,
            int lda, int ldb, int ldc,
            long long sAb, long long sBb, long long sCb)
{
  __shared__ short smem[24576];   // 48KB: [0,12288) = A(3 bufs), [12288,24576) = B
  short* shA = smem;
  short* shB = smem + 12288;
  const int tid = threadIdx.x;
  const long long bz = blockIdx.z;
  const short* Ab = A + bz * sAb;
  const short* Bb = B + bz * sBb;
  const int m0 = blockIdx.x * 128;
  const int n0 = blockIdx.y * 128;
  const int w = tid >> 6, lane = tid & 63;
  const int wm = (w >> 1) << 6, wn = (w & 1) << 6;
  const int lr = lane & 15, g = lane >> 4;
  const int srow = lane >> 2;
  const int scol = (lane & 3) << 3;
  const f32x4 vzero = {0.f, 0.f, 0.f, 0.f};
  f32x4 acc[4][4];
  #pragma unroll
  for (int i = 0; i < 4; ++i)
    #pragma unroll
    for (int j = 0; j < 4; ++j) acc[i][j] = vzero;

  const int nt = K >> 5;
#define STAGE_G(bi, kk) do { \
    _Pragma("unroll") \
    for (int r = 0; r < 2; ++r) { \
      int rowb = (w << 4) + (r << 6); \
      gload16(Ab + (long long)(m0 + rowb + srow) * lda + (kk) + scol, &shA[(bi) * 4096 + rowb * 32]); \
      gload16(Bb + (long long)(n0 + rowb + srow) * ldb + (kk) + scol, &shB[(bi) * 4096 + rowb * 32]); \
    } } while (0)

  STAGE_G(0, 0);
  if (nt > 1) STAGE_G(1, 32);
  int cur = 0, i2 = 2;
  for (int t = 0; t < nt; ++t) {
    if (t + 1 < nt) wait_vm4(); else wait_vm0();
    __builtin_amdgcn_s_barrier();
    if (t + 2 < nt) STAGE_G(i2, (t + 2) << 5);
    short8_t af[4];
    #pragma unroll
    for (int mi = 0; mi < 4; ++mi)
      af[mi] = *reinterpret_cast<const short8_t*>(&shA[cur * 4096 + (wm + (mi << 4) + lr) * 32 + (g << 3)]);
    __builtin_amdgcn_s_setprio(1);
    #pragma unroll
    for (int ni = 0; ni < 4; ++ni) {
      short8_t bfr = *reinterpret_cast<const short8_t*>(&shB[cur * 4096 + (wn + (ni << 4) + lr) * 32 + (g << 3)]);
      #pragma unroll
      for (int mi = 0; mi < 4; ++mi)
        acc[mi][ni] = __builtin_amdgcn_mfma_f32_16x16x32_bf16(
            __builtin_bit_cast(bf16x8_t, af[mi]),
            __builtin_bit_cast(bf16x8_t, bfr),
            acc[mi][ni], 0, 0, 0);
    }
    __builtin_amdgcn_s_setprio(0);
    cur = (cur == 2) ? 0 : cur + 1;
    i2  = (i2 == 2) ? 0 : i2 + 1;
  }
#undef STAGE_G
  // ---- retiled epilogue: acc -> LDS [128][136] -> short8 global stores ----
  __syncthreads();
  #pragma unroll
  for (int ni = 0; ni < 4; ++ni)
    #pragma unroll
    for (int mi = 0; mi < 4; ++mi)
      #pragma unroll
      for (int r = 0; r < 4; ++r)
        smem[(wm + (mi << 4) + (g << 2) + r) * 136 + wn + (ni << 4) + lr] = f2b(acc[mi][ni][r]);
  __syncthreads();
  {
    short* C = Cv + bz * sCb;
    int row = tid >> 1, half = (tid & 1) << 6;
    #pragma unroll
    for (int j = 0; j < 8; ++j) {
      int col = n0 + half + (j << 3);
      if (col + 8 <= N) {
        short8_t v = *reinterpret_cast<const short8_t*>(&smem[row * 136 + half + (j << 3)]);
        *reinterpret_cast<short8_t*>(&C[(long long)(m0 + row) * ldc + col]) = v;
      }
    }
  }
}

// ---------------- pipelined sparse MoE gather GEMM ----------------
template<int GATHER>
__global__ void __launch_bounds__(256)
moe_gemm_kernel(const short* __restrict__ A, const int* __restrict__ elist,
                const int* __restrict__ cnt, const short* __restrict__ B,
                short* __restrict__ C, int N, int K,
                int lda, int ldb, int ldc,
                long long sAe, long long sBe, long long sCe)
{
  const int e = blockIdx.z;
  const int cnt_e = cnt[e];
  const int m0 = blockIdx.x * 128;
  if (m0 >= cnt_e) return;
  const short* Bb = B + (long long)e * sBe;
  short* Cb = C + (long long)e * sCe;
  const int n0 = blockIdx.y * 128;
  const int tid = threadIdx.x;
  const int w = tid >> 6, lane = tid & 63;
  const int wm = (w >> 1) << 6, wn = (w & 1) << 6;
  const int lr = lane & 15, g = lane >> 4;
  const int srow = lane >> 2;
  const int scol = (lane & 3) << 3;

  long long arow[2];
  #pragma unroll
  for (int r = 0; r < 2; ++r) {
    int row = m0 + (w << 4) + (r << 6) + srow;
    if (GATHER) {
      int p = row > cnt_e - 1 ? cnt_e - 1 : row;
      arow[r] = (long long)elist[e * S_LEN + p] * lda;
    } else {
      arow[r] = (long long)e * sAe + (long long)row * lda;
    }
  }

  __shared__ short smem[24576];
  short* shA = smem;
  short* shB = smem + 12288;
  const f32x4 vzero = {0.f, 0.f, 0.f, 0.f};
  f32x4 acc[4][4];
  #pragma unroll
  for (int i = 0; i < 4; ++i)
    #pragma unroll
    for (int j = 0; j < 4; ++j) acc[i][j] = vzero;

  const int nt = K >> 5;
#define STAGE_M(bi, kk) do { \
    _Pragma("unroll") \
    for (int r = 0; r < 2; ++r) { \
      int rowb = (w << 4) + (r << 6); \
      gload16(A + arow[r] + (kk) + scol, &shA[(bi) * 4096 + rowb * 32]); \
      gload16(Bb + (long long)(n0 + rowb + srow) * ldb + (kk) + scol, &shB[(bi) * 4096 + rowb * 32]); \
    } } while (0)

  STAGE_M(0, 0);
  if (nt > 1) STAGE_M(1, 32);
  int cur = 0, i2 = 2;
  for (int t = 0; t < nt; ++t) {
    if (t + 1 < nt) wait_vm4(); else wait_vm0();
    __builtin_amdgcn_s_barrier();
    if (t + 2 < nt) STAGE_M(i2, (t + 2) << 5);
    short8_t af[4];
    #pragma unroll
    for (int mi = 0; mi < 4; ++mi)
      af[mi] = *reinterpret_cast<const short8_t*>(&shA[cur * 4096 + (wm + (mi << 4) + lr) * 32 + (g << 3)]);
    __builtin_amdgcn_s_setprio(1);
    #pragma unroll
    for (int ni = 0; ni < 4; ++ni) {
      short8_t bfr = *reinterpret_cast<const short8_t*>(&shB[cur * 4096 + (wn + (ni << 4) + lr) * 32 + (g << 3)]);
      #pragma unroll
      for (int mi = 0; mi < 4; ++mi)
        acc[mi][ni] = __builtin_amdgcn_mfma_f32_16x16x32_bf16(
            __builtin_bit_cast(bf16x8_t, af[mi]),
            __builtin_bit_cast(bf16x8_t, bfr),
            acc[mi][ni], 0, 0, 0);
    }
    __builtin_amdgcn_s_setprio(0);
    cur = (cur == 2) ? 0 : cur + 1;
    i2  = (i2 == 2) ? 0 : i2 + 1;
  }
#undef STAGE_M
  __syncthreads();
  #pragma unroll
  for (int ni = 0; ni < 4; ++ni)
    #pragma unroll
    for (int mi = 0; mi < 4; ++mi)
      #pragma unroll
      for (int r = 0; r < 4; ++r)
        smem[(wm + (mi << 4) + (g << 2) + r) * 136 + wn + (ni << 4) + lr] = f2b(acc[mi][ni][r]);
  __syncthreads();
  {
    int row = tid >> 1, half = (tid & 1) << 6;
    if (m0 + row < cnt_e) {
      #pragma unroll
      for (int j = 0; j < 8; ++j) {
        int col = n0 + half + (j << 3);
        short8_t v = *reinterpret_cast<const short8_t*>(&smem[row * 136 + half + (j << 3)]);
        *reinterpret_cast<short8_t*>(&Cb[(long long)(m0 + row) * ldc + col]) = v;
      }
    }
  }
}

// ---------------- small kernels ----------------
__global__ void __launch_bounds__(64)
rope_tables_kernel(float* cosT, float* sinT) {
  int s = blockIdx.x, j = threadIdx.x;
  int i = j & 31;
  float inv = powf(10000.0f, -((float)(2 * i) / 64.0f));
  float ang = (float)s * inv;
  cosT[s * 64 + j] = cosf(ang);
  sinT[s * 64 + j] = sinf(ang);
}

__global__ void __launch_bounds__(256)
rmsnorm_bf16_kernel(const short* __restrict__ in, long long istride,
                    const short* __restrict__ w,
                    short* __restrict__ out, long long ostride, int D) {
  const short* x = in + (long long)blockIdx.x * istride;
  short* o = out + (long long)blockIdx.x * ostride;
  const int nc = D >> 3;
  float ss = 0.f;
  for (int c = threadIdx.x; c < nc; c += 256) {
    short8_t v = reinterpret_cast<const short8_t*>(x)[c];
    #pragma unroll
    for (int j = 0; j < 8; ++j) { float f = b2f(v[j]); ss += f * f; }
  }
  __shared__ float red[256];
  red[threadIdx.x] = ss; __syncthreads();
  for (int s2 = 128; s2 > 0; s2 >>= 1) {
    if (threadIdx.x < s2) red[threadIdx.x] += red[threadIdx.x + s2];
    __syncthreads();
  }
  float r = 1.0f / sqrtf(red[0] / (float)D + 1e-6f);
  for (int c = threadIdx.x; c < nc; c += 256) {
    short8_t v = reinterpret_cast<const short8_t*>(x)[c];
    short8_t wv = reinterpret_cast<const short8_t*>(w)[c];
    short8_t ov;
    #pragma unroll
    for (int j = 0; j < 8; ++j) ov[j] = f2b(b2f(wv[j]) * (b2f(v[j]) * r));
    reinterpret_cast<short8_t*>(o)[c] = ov;
  }
}

__global__ void __launch_bounds__(256)
build_qf_kernel(const short* q, const float* cosT, const float* sinT, short* qf) {
  int s = blockIdx.x;
  for (int idx = threadIdx.x; idx < NH_ * DQK_; idx += 256) {
    int h = idx / DQK_, d = idx - h * DQK_;
    const short* qr = q + (long long)s * QN_ + h * DQK_;
    float val;
    if (d < 128) val = b2f(qr[d]);
    else {
      int j = d - 128;
      float c = cosT[s * 64 + j], sn = sinT[s * 64 + j];
      float x0 = b2f(qr[128 + j]);
      float rot = (j < 32) ? -b2f(qr[128 + j + 32]) : b2f(qr[128 + j - 32]);
      val = x0 * c + rot * sn;
    }
    qf[(long long)h * S_LEN * DQK_ + (long long)s * DQK_ + d] = f2b(val);
  }
}

__global__ void __launch_bounds__(256)
build_kf_kernel(const short* kvup, const short* krope, long long kstride,
                const float* cosT, const float* sinT, short* kf) {
  int s = blockIdx.x;
  for (int idx = threadIdx.x; idx < NH_ * DQK_; idx += 256) {
    int h = idx / DQK_, d = idx - h * DQK_;
    float val;
    if (d < 128) val = b2f(kvup[(long long)s * KVUPN + h * 256 + d]);
    else {
      int j = d - 128;
      float c = cosT[s * 64 + j], sn = sinT[s * 64 + j];
      const short* kr = krope + (long long)s * kstride;
      float x0 = b2f(kr[j]);
      float rot = (j < 32) ? -b2f(kr[j + 32]) : b2f(kr[j - 32]);
      val = x0 * c + rot * sn;
    }
    kf[(long long)h * S_LEN * DQK_ + (long long)s * DQK_ + d] = f2b(val);
  }
}

__global__ void __launch_bounds__(256)
transpose_v_kernel(const short* kvup, short* vT) {
  int h = blockIdx.z;
  int r0 = blockIdx.y * 32, c0 = blockIdx.x * 32;
  int tx = threadIdx.x & 31, ty = threadIdx.x >> 5;
  __shared__ short tile[32][33];
  #pragma unroll
  for (int i = 0; i < 4; ++i)
    tile[ty + i * 8][tx] =
        kvup[(long long)(r0 + ty + i * 8) * KVUPN + h * 256 + 128 + c0 + tx];
  __syncthreads();
  short* d = vT + (long long)h * 128 * S_LEN;
  #pragma unroll
  for (int i = 0; i < 4; ++i)
    d[(long long)(c0 + ty + i * 8) * S_LEN + r0 + tx] = tile[tx][ty + i * 8];
}

__global__ void __launch_bounds__(256)
softmax_rows_kernel(short* scores, float scale) {
  long long row = blockIdx.x;
  short8_t* p = reinterpret_cast<short8_t*>(scores + row * S_LEN);
  short8_t v = p[threadIdx.x];
  float f[8]; float m = -1e30f;
  #pragma unroll
  for (int j = 0; j < 8; ++j) { f[j] = b2f(v[j]) * scale; m = fmaxf(m, f[j]); }
  __shared__ float red[256];
  red[threadIdx.x] = m; __syncthreads();
  for (int s2 = 128; s2 > 0; s2 >>= 1) {
    if (threadIdx.x < s2) red[threadIdx.x] = fmaxf(red[threadIdx.x], red[threadIdx.x + s2]);
    __syncthreads();
  }
  m = red[0]; __syncthreads();
  float sum = 0.f;
  #pragma unroll
  for (int j = 0; j < 8; ++j) { f[j] = expf(f[j] - m); sum += f[j]; }
  red[threadIdx.x] = sum; __syncthreads();
  for (int s2 = 128; s2 > 0; s2 >>= 1) {
    if (threadIdx.x < s2) red[threadIdx.x] += red[threadIdx.x + s2];
    __syncthreads();
  }
  float inv = 1.0f / red[0];
  short8_t o;
  #pragma unroll
  for (int j = 0; j < 8; ++j) o[j] = f2b(f[j] * inv);
  p[threadIdx.x] = o;
}

__global__ void __launch_bounds__(256)
add_bf16_kernel(short* h, const short* a) {
  long long c = (long long)blockIdx.x * 256 + threadIdx.x;
  short8_t hv = reinterpret_cast<short8_t*>(h)[c];
  short8_t av = reinterpret_cast<const short8_t*>(a)[c];
  short8_t ov;
  #pragma unroll
  for (int j = 0; j < 8; ++j) ov[j] = f2b(b2f(hv[j]) + b2f(av[j]));
  reinterpret_cast<short8_t*>(h)[c] = ov;
}

__global__ void __launch_bounds__(256)
gate_kernel(const short* x2, const short* gw, int* cnt, int* elist, float* ewt, int* tok2slot) {
  int t = blockIdx.x;
  int e = threadIdx.x >> 5, j = threadIdx.x & 31;
  const short* x = x2 + (long long)t * HDIM;
  float acc = 0.f;
  for (int k = j; k < HDIM; k += 32) acc += b2f(x[k]) * b2f(gw[(long long)k * EXP_ + e]);
  __shared__ float red[8][32];
  red[e][j] = acc; __syncthreads();
  for (int s2 = 16; s2 > 0; s2 >>= 1) {
    if (j < s2) red[e][j] += red[e][j + s2];
    __syncthreads();
  }
  if (threadIdx.x == 0) {
    float l[8], p[8];
    float m = -1e30f;
    for (int q = 0; q < 8; ++q) { l[q] = b2f(f2b(red[q][0])); m = fmaxf(m, l[q]); }
    float sum = 0.f;
    for (int q = 0; q < 8; ++q) { p[q] = expf(l[q] - m); sum += p[q]; }
    int i0 = 0; for (int q = 1; q < 8; ++q) if (p[q] > p[i0]) i0 = q;
    int i1 = (i0 == 0) ? 1 : 0;
    for (int q = 0; q < 8; ++q) if (q != i0 && p[q] > p[i1]) i1 = q;
    float denom = p[i0] + p[i1];
    float w0 = b2f(f2b(p[i0] / denom));
    float w1 = b2f(f2b(p[i1] / denom));
    int pos0 = atomicAdd(&cnt[i0], 1);
    int pos1 = atomicAdd(&cnt[i1], 1);
    elist[i0 * S_LEN + pos0] = t;  ewt[i0 * S_LEN + pos0] = w0;
    elist[i1 * S_LEN + pos1] = t;  ewt[i1 * S_LEN + pos1] = w1;
    int4* slot = (int4*)tok2slot;
    slot[t] = make_int4(i0, pos0, i1, pos1);
  }
}

__global__ void __launch_bounds__(256)
silu_moe_kernel(short* a, const short* b, const int* cnt, const float* ewt) {
  int pos = blockIdx.x, e = blockIdx.y;
  if (pos >= cnt[e]) return;
  float scale = ewt[e * S_LEN + pos];
  int c = threadIdx.x;
  if (c >= IFF_ / 8) return;
  long long roff = ((long long)e * S_LEN + pos) * IFF_;
  short8_t av = reinterpret_cast<short8_t*>(a + roff)[c];
  short8_t bv = reinterpret_cast<const short8_t*>(b + roff)[c];
  short8_t ov;
  #pragma unroll
  for (int j = 0; j < 8; ++j) {
    float x = b2f(av[j]);
    float s = x / (1.0f + expf(-x));
    ov[j] = f2b(s * b2f(bv[j]) * scale);
  }
  reinterpret_cast<short8_t*>(a + roff)[c] = ov;
}

__global__ void __launch_bounds__(256)
silu_sh_kernel(short* a, const short* b) {
  long long roff = ((long long)blockIdx.y * S_LEN + blockIdx.x) * IFF_;
  int c = threadIdx.x;
  if (c >= IFF_ / 8) return;
  short8_t av = reinterpret_cast<short8_t*>(a + roff)[c];
  short8_t bv = reinterpret_cast<const short8_t*>(b + roff)[c];
  short8_t ov;
  #pragma unroll
  for (int j = 0; j < 8; ++j) {
    float x = b2f(av[j]);
    float s = x / (1.0f + expf(-x));
    ov[j] = f2b(s * b2f(bv[j]));
  }
  reinterpret_cast<short8_t*>(a + roff)[c] = ov;
}

__global__ void __launch_bounds__(256)
moe_combine_kernel(short* h, const short* shared_out, const short* routed,
                   const int* tok2slot) {
  int t = blockIdx.x;
  const int4 sl = ((const int4*)tok2slot)[t];
  const short8_t* s0 = reinterpret_cast<const short8_t*>(shared_out + (long long)t * HDIM);
  const short8_t* s1 = reinterpret_cast<const short8_t*>(shared_out + ((long long)S_LEN + t) * HDIM);
  const short8_t* r0 = reinterpret_cast<const short8_t*>(
      routed + ((long long)sl.x * S_LEN + sl.y) * HDIM);
  const short8_t* r1 = reinterpret_cast<const short8_t*>(
      routed + ((long long)sl.z * S_LEN + sl.w) * HDIM);
  long long c = (long long)t * 256 + threadIdx.x;
  short8_t hv = reinterpret_cast<short8_t*>(h)[c];
  short8_t a0 = s0[threadIdx.x], a1 = s1[threadIdx.x];
  short8_t v0 = r0[threadIdx.x], v1 = r1[threadIdx.x];
  short8_t ov;
  #pragma unroll
  for (int j = 0; j < 8; ++j)
    ov[j] = f2b(b2f(hv[j]) + (b2f(a0[j]) + b2f(a1[j]) + b2f(v0[j]) + b2f(v1[j])));
  reinterpret_cast<short8_t*>(h)[c] = ov;
}

// ---------------- pooling ----------------
template<int AF32, int OUTBF16>
__global__ void __launch_bounds__(256)
gemv_bt_kernel(const void* a, const short* __restrict__ BT, void* out, int K) {
  int n = blockIdx.x;
  const short8_t* row = reinterpret_cast<const short8_t*>(BT + (long long)n * K);
  float acc = 0.f;
  for (int c = threadIdx.x; c < (K >> 3); c += 256) {
    short8_t v = row[c];
    if (AF32) {
      f32x4 a0 = reinterpret_cast<const f32x4*>(a)[2 * c];
      f32x4 a1 = reinterpret_cast<const f32x4*>(a)[2 * c + 1];
      #pragma unroll
      for (int j = 0; j < 4; ++j) {
        acc += a0[j] * b2f(v[j]);
        acc += a1[j] * b2f(v[4 + j]);
      }
    } else {
      short8_t av = reinterpret_cast<const short8_t*>(a)[c];
      #pragma unroll
      for (int j = 0; j < 8; ++j) acc += b2f(av[j]) * b2f(v[j]);
    }
  }
  __shared__ float red[256];
  red[threadIdx.x] = acc; __syncthreads();
  for (int s2 = 128; s2 > 0; s2 >>= 1) {
    if (threadIdx.x < s2) red[threadIdx.x] += red[threadIdx.x + s2];
    __syncthreads();
  }
  if (threadIdx.x == 0) {
    if (OUTBF16) ((short*)out)[n] = f2b(red[0]);
    else         ((float*)out)[n] = red[0];
  }
}

__global__ void __launch_bounds__(256)
pool_score_kernel(const short* qv, const short* kmat, float* score) {
  int s = blockIdx.x;
  const short8_t* kr = reinterpret_cast<const short8_t*>(kmat + (long long)s * HDIM);
  const short8_t* qr = reinterpret_cast<const short8_t*>(qv);
  short8_t kv8 = kr[threadIdx.x], qv8 = qr[threadIdx.x];
  float acc = 0.f;
  #pragma unroll
  for (int j = 0; j < 8; ++j) acc += b2f(qv8[j]) * b2f(kv8[j]);
  __shared__ float red[256];
  red[threadIdx.x] = acc; __syncthreads();
  for (int s2 = 128; s2 > 0; s2 >>= 1) {
    if (threadIdx.x < s2) red[threadIdx.x] += red[threadIdx.x + s2];
    __syncthreads();
  }
  if (threadIdx.x == 0) score[s] = b2f(f2b(red[0])) * 0.022097086912079608f;
}

__global__ void __launch_bounds__(256)
softmax_vec_kernel(float* v) {
  int tid = threadIdx.x;
  float f[8]; float m = -1e30f;
  #pragma unroll
  for (int i = 0; i < 8; ++i) { f[i] = v[i * 256 + tid]; m = fmaxf(m, f[i]); }
  __shared__ float red[256];
  red[tid] = m; __syncthreads();
  for (int s2 = 128; s2 > 0; s2 >>= 1) {
    if (tid < s2) red[tid] = fmaxf(red[tid], red[tid + s2]);
    __syncthreads();
  }
  m = red[0]; __syncthreads();
  float sum = 0.f;
  #pragma unroll
  for (int i = 0; i < 8; ++i) { f[i] = expf(f[i] - m); sum += f[i]; }
  red[tid] = sum; __syncthreads();
  for (int s2 = 128; s2 > 0; s2 >>= 1) {
    if (tid < s2) red[tid] += red[tid + s2];
    __syncthreads();
  }
  float inv = 1.0f / red[0];
  #pragma unroll
  for (int i = 0; i < 8; ++i) v[i * 256 + tid] = f[i] * inv;
}

__global__ void __launch_bounds__(256)
pool_wsum_t_kernel(const float* w, const short* vT, float* pooled) {
  int h = blockIdx.x;
  const short8_t* row = reinterpret_cast<const short8_t*>(vT + (long long)h * S_LEN);
  int c = threadIdx.x;
  short8_t v = row[c];
  f32x4 w0 = reinterpret_cast<const f32x4*>(w)[2 * c];
  f32x4 w1 = reinterpret_cast<const f32x4*>(w)[2 * c + 1];
  float acc = 0.f;
  #pragma unroll
  for (int j = 0; j < 4; ++j) {
    acc += w0[j] * b2f(v[j]);
    acc += w1[j] * b2f(v[4 + j]);
  }
  __shared__ float red[256];
  red[threadIdx.x] = acc; __syncthreads();
  for (int s2 = 128; s2 > 0; s2 >>= 1) {
    if (threadIdx.x < s2) red[threadIdx.x] += red[threadIdx.x + s2];
    __syncthreads();
  }
  if (threadIdx.x == 0) pooled[h] = red[0];
}

__global__ void __launch_bounds__(256)
rmsnorm_f32_kernel(const float* x, const short* w, float* out) {
  int tid = threadIdx.x;
  float f[8]; float ss = 0.f;
  #pragma unroll
  for (int i = 0; i < 8; ++i) { f[i] = x[i * 256 + tid]; ss += f[i] * f[i]; }
  __shared__ float red[256];
  red[tid] = ss; __syncthreads();
  for (int s2 = 128; s2 > 0; s2 >>= 1) {
    if (tid < s2) red[tid] += red[tid + s2];
    __syncthreads();
  }
  float r = 1.0f / sqrtf(red[0] / 2048.0f + 1e-6f);
  #pragma unroll
  for (int i = 0; i < 8; ++i) out[i * 256 + tid] = b2f(w[i * 256 + tid]) * (f[i] * r);
}

// ---------------- host ----------------
extern "C" void kernel_launch(void* const* d_in, const int* in_sizes, int n_in,
                              void* d_out, int out_size, void* d_ws, size_t ws_size,
                              hipStream_t stream)
{
  (void)n_in; (void)out_size; (void)ws_size;
  const int* ids = (const int*)d_in[24];

  char* base = (char*)d_ws;
  size_t off = 0;
  auto alloc = [&](size_t bytes) -> void* {
    void* p = base + off;
    off += (bytes + 255) & ~(size_t)255;
    return p;
  };

  int* dflag = (int*)alloc(256);

  short* qkvdwT = (short*)alloc((size_t)2 * DCAT * HDIM * 2);
  short* quwT  = (short*)alloc((size_t)2 * QN_ * QRANK_ * 2);
  short* kvuwT = (short*)alloc((size_t)2 * KVUPN * KVRANK_ * 2);
  short* opwT  = (short*)alloc((size_t)2 * HDIM * HDIM * 2);
  short* rw1T  = (short*)alloc((size_t)16 * IFF_ * HDIM * 2);
  short* rw2T  = (short*)alloc((size_t)16 * HDIM * IFF_ * 2);
  short* rw3T  = (short*)alloc((size_t)16 * IFF_ * HDIM * 2);
  short* sw1T  = (short*)alloc((size_t)4 * IFF_ * HDIM * 2);
  short* sw2T  = (short*)alloc((size_t)4 * HDIM * IFF_ * 2);
  short* sw3T  = (short*)alloc((size_t)4 * IFF_ * HDIM * 2);
  short* pqwT  = (short*)alloc((size_t)HDIM * HDIM * 2);
  short* pkwT  = (short*)alloc((size_t)HDIM * HDIM * 2);
  short* pvwT  = (short*)alloc((size_t)HDIM * HDIM * 2);
  short* powT  = (short*)alloc((size_t)PD_ * HDIM * 2);
  short* ln1w = (short*)alloc((size_t)in_sizes[1] * 2);
  short* qnw  = (short*)alloc((size_t)in_sizes[3] * 2);
  short* kvnw = (short*)alloc((size_t)in_sizes[6] * 2);
  short* ln2w = (short*)alloc((size_t)in_sizes[9] * 2);
  short* gatw = (short*)alloc((size_t)in_sizes[10] * 2);
  short* fnww = (short*)alloc((size_t)in_sizes[17] * 2);
  short* lqw  = (short*)alloc((size_t)in_sizes[18] * 2);
  short* pnww = (short*)alloc((size_t)in_sizes[23] * 2);

  float* cosT    = (float*)alloc((size_t)S_LEN * 64 * 4);
  float* sinT    = (float*)alloc((size_t)S_LEN * 64 * 4);
  short* hbuf    = (short*)alloc((size_t)S_LEN * HDIM * 2);
  short* xbuf    = (short*)alloc((size_t)S_LEN * HDIM * 2);
  short* dcat    = (short*)alloc((size_t)S_LEN * DCAT * 2);
  short* qlatn   = (short*)alloc((size_t)S_LEN * QRANK_ * 2);
  short* qbuf    = (short*)alloc((size_t)S_LEN * QN_ * 2);
  short* kvn     = (short*)alloc((size_t)S_LEN * KVRANK_ * 2);
  short* kvup    = (short*)alloc((size_t)S_LEN * KVUPN * 2);
  short* qf      = (short*)alloc((size_t)NH_ * S_LEN * DQK_ * 2);
  short* kf      = (short*)alloc((size_t)NH_ * S_LEN * DQK_ * 2);
  short* vT      = (short*)alloc((size_t)NH_ * 128 * S_LEN * 2);
  short* scores  = (short*)alloc((size_t)NH_ * S_LEN * S_LEN * 2);
  short* ao      = (short*)alloc((size_t)S_LEN * HDIM * 2);
  short* attnp   = (short*)alloc((size_t)S_LEN * HDIM * 2);
  short* hfin    = (short*)alloc((size_t)S_LEN * HDIM * 2);
  short* kpool   = (short*)alloc((size_t)S_LEN * HDIM * 2);
  short* vpoolT  = (short*)alloc((size_t)HDIM * S_LEN * 2);
  short* qvec    = (short*)alloc((size_t)HDIM * 2);
  float* pscore  = (float*)alloc((size_t)S_LEN * 4);
  float* pooled  = (float*)alloc((size_t)HDIM * 4);
  float* pooledn = (float*)alloc((size_t)HDIM * 4);
  int*   ecnt    = (int*)alloc(64);
  int*   elist   = (int*)alloc((size_t)EXP_ * S_LEN * 4);
  float* ewt     = (float*)alloc((size_t)EXP_ * S_LEN * 4);
  int*   tok2slot= (int*)alloc((size_t)S_LEN * 16);
  short* gba_e   = (short*)alloc((size_t)EXP_ * S_LEN * IFF_ * 2);
  short* gbb_e   = (short*)alloc((size_t)EXP_ * S_LEN * IFF_ * 2);
  short* routed  = (short*)alloc((size_t)EXP_ * S_LEN * HDIM * 2);
  short* gsh1    = (short*)alloc((size_t)2 * S_LEN * IFF_ * 2);
  short* gsh3    = (short*)alloc((size_t)2 * S_LEN * IFF_ * 2);
  short* shared_out = (short*)alloc((size_t)2 * S_LEN * HDIM * 2);

  detect_kernel<<<1, 256, 0, stream>>>(d_in[0], dflag);

  auto tconv = [&](const void* src, short* dst, int R, int C, int nslabs,
                   long long sSrc, long long sDst) {
    dim3 grid(C / 32, R / 32, nslabs);
    transconv_kernel<<<grid, 256, 0, stream>>>(src, dst, R, C, dflag, sSrc, sDst);
  };
  auto pconv = [&](const void* src, short* dst, long long n) {
    long long nchunks = n / 8;
    int blocks = (int)((nchunks + 255) / 256);
    if (blocks > 2048) blocks = 2048;
    if (blocks < 1) blocks = 1;
    convert_kernel<<<blocks, 256, 0, stream>>>(src, dst, nchunks, dflag);
  };

  tconv(d_in[2], qkvdwT, HDIM, QRANK_, 2,
        (long long)HDIM * QRANK_, (long long)DCAT * HDIM);
  tconv(d_in[5], qkvdwT + (size_t)QRANK_ * HDIM, HDIM, KVDN, 2,
        (long long)HDIM * KVDN, (long long)DCAT * HDIM);
  tconv(d_in[4],  quwT,  QRANK_, QN_,  2, (long long)QRANK_ * QN_,  (long long)QN_ * QRANK_);
  tconv(d_in[7],  kvuwT, KVRANK_,KVUPN,2, (long long)KVRANK_ * KVUPN,(long long)KVUPN * KVRANK_);
  tconv(d_in[8],  opwT,  HDIM,   HDIM, 2, (long long)HDIM * HDIM,   (long long)HDIM * HDIM);
  tconv(d_in[11], rw1T,  HDIM,   IFF_, 16,(long long)HDIM * IFF_,   (long long)IFF_ * HDIM);
  tconv(d_in[12], rw2T,  IFF_,   HDIM, 16,(long long)IFF_ * HDIM,   (long long)HDIM * IFF_);
  tconv(d_in[13], rw3T,  HDIM,   IFF_, 16,(long long)HDIM * IFF_,   (long long)IFF_ * HDIM);
  tconv(d_in[14], sw1T,  HDIM,   IFF_, 4, (long long)HDIM * IFF_,   (long long)IFF_ * HDIM);
  tconv(d_in[15], sw2T,  IFF_,   HDIM, 4, (long long)IFF_ * HDIM,   (long long)HDIM * IFF_);
  tconv(d_in[16], sw3T,  HDIM,   IFF_, 4, (long long)HDIM * IFF_,   (long long)IFF_ * HDIM);
  tconv(d_in[19], pqwT,  HDIM,   HDIM, 1, 0, 0);
  tconv(d_in[20], pkwT,  HDIM,   HDIM, 1, 0, 0);
  tconv(d_in[21], pvwT,  HDIM,   HDIM, 1, 0, 0);
  tconv(d_in[22], powT,  HDIM,   PD_,  1, 0, 0);
  pconv(d_in[1],  ln1w, in_sizes[1]);
  pconv(d_in[3],  qnw,  in_sizes[3]);
  pconv(d_in[6],  kvnw, in_sizes[6]);
  pconv(d_in[9],  ln2w, in_sizes[9]);
  pconv(d_in[10], gatw, in_sizes[10]);
  pconv(d_in[17], fnww, in_sizes[17]);
  pconv(d_in[18], lqw,  in_sizes[18]);
  pconv(d_in[23], pnww, in_sizes[23]);

  const float qk_scale = 1.0f / sqrtf((float)DQK_);

  auto gemm = [&](const short* A, const short* B, short* C,
                  int M, int N, int K, int lda, int ldb, int ldc,
                  int batch, long long sA, long long sB, long long sC) {
    dim3 grid(M / 128, (N + 127) / 128, batch);
    gemm_kernel<<<grid, 256, 0, stream>>>(A, B, C, M, N, K, lda, ldb, ldc, sA, sB, sC);
  };

  rope_tables_kernel<<<S_LEN, 64, 0, stream>>>(cosT, sinT);
  embed_convert_kernel<<<S_LEN, 256, 0, stream>>>(ids, d_in[0], dflag, hbuf);

  for (int l = 0; l < 2; ++l) {
    const short* w_ln1  = ln1w + (size_t)l * HDIM;
    const short* w_qkvT = qkvdwT + (size_t)l * DCAT * HDIM;
    const short* w_qn   = qnw  + (size_t)l * QRANK_;
    const short* w_quT  = quwT + (size_t)l * QN_ * QRANK_;
    const short* w_kvn  = kvnw + (size_t)l * KVRANK_;
    const short* w_kvuT = kvuwT+ (size_t)l * KVUPN * KVRANK_;
    const short* w_opT  = opwT + (size_t)l * HDIM * HDIM;
    const short* w_ln2  = ln2w + (size_t)l * HDIM;
    const short* w_gat  = gatw + (size_t)l * HDIM * EXP_;

    // --- attention ---
    rmsnorm_bf16_kernel<<<S_LEN, 256, 0, stream>>>(hbuf, HDIM, w_ln1, xbuf, HDIM, HDIM);
    gemm(xbuf, w_qkvT, dcat, S_LEN, DCAT, HDIM, HDIM, HDIM, DCAT, 1, 0, 0, 0);
    rmsnorm_bf16_kernel<<<S_LEN, 256, 0, stream>>>(dcat, DCAT, w_qn, qlatn, QRANK_, QRANK_);
    gemm(qlatn, w_quT, qbuf, S_LEN, QN_, QRANK_, QRANK_, QRANK_, QN_, 1, 0, 0, 0);
    rmsnorm_bf16_kernel<<<S_LEN, 256, 0, stream>>>(dcat + QRANK_, DCAT, w_kvn, kvn, KVRANK_, KVRANK_);
    gemm(kvn, w_kvuT, kvup, S_LEN, KVUPN, KVRANK_, KVRANK_, KVRANK_, KVUPN, 1, 0, 0, 0);
    build_qf_kernel<<<S_LEN, 256, 0, stream>>>(qbuf, cosT, sinT, qf);
    build_kf_kernel<<<S_LEN, 256, 0, stream>>>(kvup, dcat + QRANK_ + KVRANK_, DCAT, cosT, sinT, kf);
    {
      dim3 tg(128 / 32, S_LEN / 32, NH_);
      transpose_v_kernel<<<tg, 256, 0, stream>>>(kvup, vT);
    }
    gemm(qf, kf, scores, S_LEN, S_LEN, DQK_, DQK_, DQK_, S_LEN, NH_,
         (long long)S_LEN * DQK_, (long long)S_LEN * DQK_, (long long)S_LEN * S_LEN);
    softmax_rows_kernel<<<NH_ * S_LEN, 256, 0, stream>>>(scores, qk_scale);
    gemm(scores, vT, ao, S_LEN, 128, S_LEN, S_LEN, S_LEN, HDIM, NH_,
         (long long)S_LEN * S_LEN, (long long)128 * S_LEN, 128);
    gemm(ao, w_opT, attnp, S_LEN, HDIM, HDIM, HDIM, HDIM, HDIM, 1, 0, 0, 0);
    add_bf16_kernel<<<S_LEN, 256, 0, stream>>>(hbuf, attnp);

    // --- MoE ---
    rmsnorm_bf16_kernel<<<S_LEN, 256, 0, stream>>>(hbuf, HDIM, w_ln2, xbuf, HDIM, HDIM);
    hipMemsetAsync(ecnt, 0, 64, stream);
    gate_kernel<<<S_LEN, 256, 0, stream>>>(xbuf, w_gat, ecnt, elist, ewt, tok2slot);
    {
      const short* a1 = sw1T + (size_t)l * 2 * IFF_ * HDIM;
      const short* a3 = sw3T + (size_t)l * 2 * IFF_ * HDIM;
      const short* a2 = sw2T + (size_t)l * 2 * HDIM * IFF_;
      gemm(xbuf, a1, gsh1, S_LEN, IFF_, HDIM, HDIM, HDIM, IFF_, 2,
           0, (long long)IFF_ * HDIM, (long long)S_LEN * IFF_);
      gemm(xbuf, a3, gsh3, S_LEN, IFF_, HDIM, HDIM, HDIM, IFF_, 2,
           0, (long long)IFF_ * HDIM, (long long)S_LEN * IFF_);
      dim3 gs(S_LEN, 2);
      silu_sh_kernel<<<gs, 256, 0, stream>>>(gsh1, gsh3);
      gemm(gsh1, a2, shared_out, S_LEN, HDIM, IFF_, IFF_, IFF_, HDIM, 2,
           (long long)S_LEN * IFF_, (long long)HDIM * IFF_, (long long)S_LEN * HDIM);
    }
    {
      const short* b1 = rw1T + (size_t)l * 8 * IFF_ * HDIM;
      const short* b3 = rw3T + (size_t)l * 8 * IFF_ * HDIM;
      const short* b2 = rw2T + (size_t)l * 8 * HDIM * IFF_;
      dim3 g13(S_LEN / 128, IFF_ / 128, EXP_);
      moe_gemm_kernel<1><<<g13, 256, 0, stream>>>(
          xbuf, elist, ecnt, b1, gba_e, IFF_, HDIM, HDIM, HDIM, IFF_,
          (long long)S_LEN * IFF_, (long long)IFF_ * HDIM, (long long)S_LEN * IFF_);
      moe_gemm_kernel<1><<<g13, 256, 0, stream>>>(
          xbuf, elist, ecnt, b3, gbb_e, IFF_, HDIM, HDIM, HDIM, IFF_,
          (long long)S_LEN * IFF_, (long long)IFF_ * HDIM, (long long)S_LEN * IFF_);
      dim3 gs(S_LEN, EXP_);
      silu_moe_kernel<<<gs, 256, 0, stream>>>(gba_e, gbb_e, ecnt, ewt);
      dim3 g2(S_LEN / 128, HDIM / 128, EXP_);
      moe_gemm_kernel<0><<<g2, 256, 0, stream>>>(
          gba_e, elist, ecnt, b2, routed, HDIM, IFF_, IFF_, IFF_, HDIM,
          (long long)S_LEN * IFF_, (long long)HDIM * IFF_, (long long)S_LEN * HDIM);
      moe_combine_kernel<<<S_LEN, 256, 0, stream>>>(hbuf, shared_out, routed, tok2slot);
    }
  }

  // --- attention pooling head ---
  rmsnorm_bf16_kernel<<<S_LEN, 256, 0, stream>>>(hbuf, HDIM, fnww, hfin, HDIM, HDIM);
  gemm(hfin, pkwT, kpool, S_LEN, HDIM, HDIM, HDIM, HDIM, HDIM, 1, 0, 0, 0);
  gemm(pvwT, hfin, vpoolT, HDIM, S_LEN, HDIM, HDIM, HDIM, S_LEN, 1, 0, 0, 0);
  gemv_bt_kernel<0,1><<<HDIM, 256, 0, stream>>>(lqw, pqwT, qvec, HDIM);
  pool_score_kernel<<<S_LEN, 256, 0, stream>>>(qvec, kpool, pscore);
  softmax_vec_kernel<<<1, 256, 0, stream>>>(pscore);
  pool_wsum_t_kernel<<<HDIM, 256, 0, stream>>>(pscore, vpoolT, pooled);
  rmsnorm_f32_kernel<<<1, 256, 0, stream>>>(pooled, pnww, pooledn);
  gemv_bt_kernel<1,0><<<PD_, 256, 0, stream>>>(pooledn, powT, (float*)d_out, HDIM);
}

// Round 9
// 2196.016 us; speedup vs baseline: 5.3853x; 1.0141x over previous
//
#include <hip/hip_runtime.h>
#include <hip/hip_bf16.h>

#define S_LEN  2048
#define HDIM   2048
#define NH_    16
#define DQK_   192
#define QRANK_ 1024
#define KVRANK_ 512
#define KVDN   576
#define DCAT   1600   // QRANK + KVDN merged down-proj width
#define KVUPN  4096
#define QN_    3072
#define IFF_   1408
#define EXP_   8
#define PD_    4096

typedef __attribute__((ext_vector_type(8))) short   short8_t;
typedef __attribute__((ext_vector_type(8))) __bf16  bf16x8_t;
typedef __attribute__((ext_vector_type(4))) float   f32x4;

static __device__ __forceinline__ float b2f(short s) {
  unsigned int u = ((unsigned int)(unsigned short)s) << 16;
  return __builtin_bit_cast(float, u);
}
static __device__ __forceinline__ short f2b(float f) {
  return __builtin_bit_cast(short, __float2bfloat16(f));
}

static __device__ __forceinline__ void gload16(const void* g, void* l) {
  __builtin_amdgcn_global_load_lds(
      (const __attribute__((address_space(1))) void*)g,
      (__attribute__((address_space(3))) void*)l,
      16, 0, 0);
}
static __device__ __forceinline__ void wait_vm4() { asm volatile("s_waitcnt vmcnt(4)" ::: "memory"); }
static __device__ __forceinline__ void wait_vm2() { asm volatile("s_waitcnt vmcnt(2)" ::: "memory"); }
static __device__ __forceinline__ void wait_vm0() { asm volatile("s_waitcnt vmcnt(0)" ::: "memory"); }

// ---------------- dtype detect + convert ----------------
__global__ void __launch_bounds__(256)
detect_kernel(const void* probe, int* flag) {
  const float* f = (const float*)probe;
  int tid = threadIdx.x;
  int cnt = 0;
  for (int i = tid; i < 2048; i += 256) {
    float v = fabsf(f[i]);
    if (v > 1e-6f && v < 10.0f) cnt++;
  }
  __shared__ int red[256];
  red[tid] = cnt; __syncthreads();
  for (int s = 128; s > 0; s >>= 1) {
    if (tid < s) red[tid] += red[tid + s];
    __syncthreads();
  }
  if (tid == 0) *flag = (red[0] > 1600) ? 1 : 0;
}

__global__ void __launch_bounds__(256)
convert_kernel(const void* src, short* dst, long long nchunks, const int* flag) {
  long long idx = (long long)blockIdx.x * 256 + threadIdx.x;
  long long stride = (long long)gridDim.x * 256;
  if (*flag) {
    const f32x4* s = (const f32x4*)src;
    for (long long c = idx; c < nchunks; c += stride) {
      f32x4 a = s[2 * c], b = s[2 * c + 1];
      short8_t o;
      #pragma unroll
      for (int j = 0; j < 4; ++j) { o[j] = f2b(a[j]); o[4 + j] = f2b(b[j]); }
      reinterpret_cast<short8_t*>(dst)[c] = o;
    }
  } else {
    const short8_t* s = (const short8_t*)src;
    for (long long c = idx; c < nchunks; c += stride)
      reinterpret_cast<short8_t*>(dst)[c] = s[c];
  }
}

// transpose-convert: src slab [R][C] (f32/bf16) -> dst slab [C][R] bf16
__global__ void __launch_bounds__(256)
transconv_kernel(const void* src, short* dst, int R, int C, const int* flag,
                 long long sSrc, long long sDst) {
  long long zs = (long long)blockIdx.z * sSrc;
  long long zd = (long long)blockIdx.z * sDst;
  int r0 = blockIdx.y * 32, c0 = blockIdx.x * 32;
  int tx = threadIdx.x & 31, ty = threadIdx.x >> 5;
  __shared__ short tile[32][33];
  if (*flag) {
    const float* s = (const float*)src + zs;
    #pragma unroll
    for (int i = 0; i < 4; ++i)
      tile[ty + i * 8][tx] = f2b(s[(long long)(r0 + ty + i * 8) * C + c0 + tx]);
  } else {
    const short* s = (const short*)src + zs;
    #pragma unroll
    for (int i = 0; i < 4; ++i)
      tile[ty + i * 8][tx] = s[(long long)(r0 + ty + i * 8) * C + c0 + tx];
  }
  __syncthreads();
  short* d = dst + zd;
  #pragma unroll
  for (int i = 0; i < 4; ++i)
    d[(long long)(c0 + ty + i * 8) * R + r0 + tx] = tile[tx][ty + i * 8];
}

__global__ void __launch_bounds__(256)
embed_convert_kernel(const int* ids, const void* emb, const int* flag, short* h) {
  int s = blockIdx.x;
  long long row = ids[s];
  int c = threadIdx.x;
  short8_t o;
  if (*flag) {
    const f32x4* src = (const f32x4*)((const float*)emb + row * HDIM);
    f32x4 a = src[2 * c], b = src[2 * c + 1];
    #pragma unroll
    for (int j = 0; j < 4; ++j) { o[j] = f2b(a[j]); o[4 + j] = f2b(b[j]); }
  } else {
    o = reinterpret_cast<const short8_t*>((const short*)emb + row * HDIM)[c];
  }
  reinterpret_cast<short8_t*>(h + (long long)s * HDIM)[c] = o;
}

// ---------------- pipelined MFMA GEMM (B always [N][K], bf16 C) ----------------
// 3-buffer LDS staging + counted vmcnt(4); XOR-swizzled chunks; LDS-retiled epilogue.
__global__ void __launch_bounds__(256)
gemm_kernel(const short* __restrict__ A, const short* __restrict__ B,
            short* __restrict__ Cv, int M, int N, int K,
            int lda, int ldb, int ldc,
            long long sAb, long long sBb, long long sCb)
{
  __shared__ short smem[24576];   // 48KB: [0,12288) = A(3 bufs), [12288,24576) = B
  short* shA = smem;
  short* shB = smem + 12288;
  const int tid = threadIdx.x;
  const long long bz = blockIdx.z;
  const short* Ab = A + bz * sAb;
  const short* Bb = B + bz * sBb;
  const int m0 = blockIdx.x * 128;
  const int n0 = blockIdx.y * 128;
  const int w = tid >> 6, lane = tid & 63;
  const int wm = (w >> 1) << 6, wn = (w & 1) << 6;
  const int lr = lane & 15, g = lane >> 4;
  const int srow = lane >> 2;
  const int sunit = ((lane & 3) ^ ((lane >> 3) & 3)) << 3;  // swizzled source chunk
  const int rsw = ((g ^ ((lr >> 1) & 3)) << 3);             // swizzled read chunk
  const f32x4 vzero = {0.f, 0.f, 0.f, 0.f};
  f32x4 acc[4][4];
  #pragma unroll
  for (int i = 0; i < 4; ++i)
    #pragma unroll
    for (int j = 0; j < 4; ++j) acc[i][j] = vzero;

  const int nt = K >> 5;
#define STAGE_G(bi, kk) do { \
    _Pragma("unroll") \
    for (int r = 0; r < 2; ++r) { \
      int rowb = (w << 4) + (r << 6); \
      gload16(Ab + (long long)(m0 + rowb + srow) * lda + (kk) + sunit, &shA[(bi) * 4096 + rowb * 32]); \
      gload16(Bb + (long long)(n0 + rowb + srow) * ldb + (kk) + sunit, &shB[(bi) * 4096 + rowb * 32]); \
    } } while (0)

  STAGE_G(0, 0);
  if (nt > 1) STAGE_G(1, 32);
  int cur = 0, i2 = 2;
  for (int t = 0; t < nt; ++t) {
    if (t + 1 < nt) wait_vm4(); else wait_vm0();
    __builtin_amdgcn_s_barrier();
    if (t + 2 < nt) STAGE_G(i2, (t + 2) << 5);
    short8_t af[4];
    #pragma unroll
    for (int mi = 0; mi < 4; ++mi)
      af[mi] = *reinterpret_cast<const short8_t*>(&shA[cur * 4096 + (wm + (mi << 4) + lr) * 32 + rsw]);
    __builtin_amdgcn_s_setprio(1);
    #pragma unroll
    for (int ni = 0; ni < 4; ++ni) {
      short8_t bfr = *reinterpret_cast<const short8_t*>(&shB[cur * 4096 + (wn + (ni << 4) + lr) * 32 + rsw]);
      #pragma unroll
      for (int mi = 0; mi < 4; ++mi)
        acc[mi][ni] = __builtin_amdgcn_mfma_f32_16x16x32_bf16(
            __builtin_bit_cast(bf16x8_t, af[mi]),
            __builtin_bit_cast(bf16x8_t, bfr),
            acc[mi][ni], 0, 0, 0);
    }
    __builtin_amdgcn_s_setprio(0);
    cur = (cur == 2) ? 0 : cur + 1;
    i2  = (i2 == 2) ? 0 : i2 + 1;
  }
#undef STAGE_G
  // ---- retiled epilogue: acc -> LDS [128][136] -> short8 global stores ----
  __syncthreads();
  #pragma unroll
  for (int ni = 0; ni < 4; ++ni)
    #pragma unroll
    for (int mi = 0; mi < 4; ++mi)
      #pragma unroll
      for (int r = 0; r < 4; ++r)
        smem[(wm + (mi << 4) + (g << 2) + r) * 136 + wn + (ni << 4) + lr] = f2b(acc[mi][ni][r]);
  __syncthreads();
  {
    short* C = Cv + bz * sCb;
    int row = tid >> 1, half = (tid & 1) << 6;
    #pragma unroll
    for (int j = 0; j < 8; ++j) {
      int col = n0 + half + (j << 3);
      if (col + 8 <= N) {
        short8_t v = *reinterpret_cast<const short8_t*>(&smem[row * 136 + half + (j << 3)]);
        *reinterpret_cast<short8_t*>(&C[(long long)(m0 + row) * ldc + col]) = v;
      }
    }
  }
}

// ---------------- pipelined sparse MoE gather GEMM ----------------
template<int GATHER>
__global__ void __launch_bounds__(256)
moe_gemm_kernel(const short* __restrict__ A, const int* __restrict__ elist,
                const int* __restrict__ cnt, const short* __restrict__ B,
                short* __restrict__ C, int N, int K,
                int lda, int ldb, int ldc,
                long long sAe, long long sBe, long long sCe)
{
  const int e = blockIdx.z;
  const int cnt_e = cnt[e];
  const int m0 = blockIdx.x * 128;
  if (m0 >= cnt_e) return;
  const short* Bb = B + (long long)e * sBe;
  short* Cb = C + (long long)e * sCe;
  const int n0 = blockIdx.y * 128;
  const int tid = threadIdx.x;
  const int w = tid >> 6, lane = tid & 63;
  const int wm = (w >> 1) << 6, wn = (w & 1) << 6;
  const int lr = lane & 15, g = lane >> 4;
  const int srow = lane >> 2;
  const int sunit = ((lane & 3) ^ ((lane >> 3) & 3)) << 3;
  const int rsw = ((g ^ ((lr >> 1) & 3)) << 3);

  long long arow[2];
  #pragma unroll
  for (int r = 0; r < 2; ++r) {
    int row = m0 + (w << 4) + (r << 6) + srow;
    if (GATHER) {
      int p = row > cnt_e - 1 ? cnt_e - 1 : row;
      arow[r] = (long long)elist[e * S_LEN + p] * lda;
    } else {
      arow[r] = (long long)e * sAe + (long long)row * lda;
    }
  }

  __shared__ short smem[24576];
  short* shA = smem;
  short* shB = smem + 12288;
  const f32x4 vzero = {0.f, 0.f, 0.f, 0.f};
  f32x4 acc[4][4];
  #pragma unroll
  for (int i = 0; i < 4; ++i)
    #pragma unroll
    for (int j = 0; j < 4; ++j) acc[i][j] = vzero;

  const int nt = K >> 5;
#define STAGE_M(bi, kk) do { \
    _Pragma("unroll") \
    for (int r = 0; r < 2; ++r) { \
      int rowb = (w << 4) + (r << 6); \
      gload16(A + arow[r] + (kk) + sunit, &shA[(bi) * 4096 + rowb * 32]); \
      gload16(Bb + (long long)(n0 + rowb + srow) * ldb + (kk) + sunit, &shB[(bi) * 4096 + rowb * 32]); \
    } } while (0)

  STAGE_M(0, 0);
  if (nt > 1) STAGE_M(1, 32);
  int cur = 0, i2 = 2;
  for (int t = 0; t < nt; ++t) {
    if (t + 1 < nt) wait_vm4(); else wait_vm0();
    __builtin_amdgcn_s_barrier();
    if (t + 2 < nt) STAGE_M(i2, (t + 2) << 5);
    short8_t af[4];
    #pragma unroll
    for (int mi = 0; mi < 4; ++mi)
      af[mi] = *reinterpret_cast<const short8_t*>(&shA[cur * 4096 + (wm + (mi << 4) + lr) * 32 + rsw]);
    __builtin_amdgcn_s_setprio(1);
    #pragma unroll
    for (int ni = 0; ni < 4; ++ni) {
      short8_t bfr = *reinterpret_cast<const short8_t*>(&shB[cur * 4096 + (wn + (ni << 4) + lr) * 32 + rsw]);
      #pragma unroll
      for (int mi = 0; mi < 4; ++mi)
        acc[mi][ni] = __builtin_amdgcn_mfma_f32_16x16x32_bf16(
            __builtin_bit_cast(bf16x8_t, af[mi]),
            __builtin_bit_cast(bf16x8_t, bfr),
            acc[mi][ni], 0, 0, 0);
    }
    __builtin_amdgcn_s_setprio(0);
    cur = (cur == 2) ? 0 : cur + 1;
    i2  = (i2 == 2) ? 0 : i2 + 1;
  }
#undef STAGE_M
  __syncthreads();
  #pragma unroll
  for (int ni = 0; ni < 4; ++ni)
    #pragma unroll
    for (int mi = 0; mi < 4; ++mi)
      #pragma unroll
      for (int r = 0; r < 4; ++r)
        smem[(wm + (mi << 4) + (g << 2) + r) * 136 + wn + (ni << 4) + lr] = f2b(acc[mi][ni][r]);
  __syncthreads();
  {
    int row = tid >> 1, half = (tid & 1) << 6;
    if (m0 + row < cnt_e) {
      #pragma unroll
      for (int j = 0; j < 8; ++j) {
        int col = n0 + half + (j << 3);
        short8_t v = *reinterpret_cast<const short8_t*>(&smem[row * 136 + half + (j << 3)]);
        *reinterpret_cast<short8_t*>(&Cb[(long long)(m0 + row) * ldc + col]) = v;
      }
    }
  }
}

// ---------------- flash attention ----------------
// grid (16 q-tiles, 16 heads), 256 threads (4 waves), wave w owns rows w*32..w*32+31.
// LDS (shorts): qs[128][200] @0, ks[2][128][32] @25600, ps[128][136] @33792, vs[2][128][32] @51200.
// Q and P are stored PRE-SWIZZLED (logical chunk c -> physical (c&3)^((row>>1)&3) within
// each 4-chunk block) so the rsw fragment read recovers logical chunks, matching K/V
// which go through the gload16 source-swizzle path (rule: both-sides-or-neither).
__global__ void __launch_bounds__(256, 1)
flash_kernel(const short* __restrict__ qf, const short* __restrict__ kf,
             const short* __restrict__ vT, short* __restrict__ ao, float scale)
{
  __shared__ short smem[59392];
  const int tid = threadIdx.x;
  const int h = blockIdx.y;
  const int q0 = blockIdx.x << 7;
  const int w = tid >> 6, lane = tid & 63;
  const int lr = lane & 15, g = lane >> 4;
  const int rb = w << 5;
  const int srow = lane >> 2;
  const int sunit = ((lane & 3) ^ ((lane >> 3) & 3)) << 3;
  const int rsw = ((g ^ ((lr >> 1) & 3)) << 3);
  const short* qh = qf + (long long)h * S_LEN * DQK_;
  const short* kh = kf + (long long)h * S_LEN * DQK_;
  const short* vh = vT + (long long)h * 128 * S_LEN;

  // load Q tile -> qs[128][200], swizzled store
  #pragma unroll
  for (int i = 0; i < 12; ++i) {
    int c = tid + (i << 8);
    int row = c / 24, cc = c % 24;
    int dchunk = (cc & ~3) | ((cc & 3) ^ ((row >> 1) & 3));
    *reinterpret_cast<short8_t*>(&smem[row * 200 + (dchunk << 3)]) =
        *reinterpret_cast<const short8_t*>(qh + (long long)(q0 + row) * DQK_ + (cc << 3));
  }

  const f32x4 vzero = {0.f, 0.f, 0.f, 0.f};
  f32x4 oacc[2][8];
  #pragma unroll
  for (int mi = 0; mi < 2; ++mi)
    #pragma unroll
    for (int ni = 0; ni < 8; ++ni) oacc[mi][ni] = vzero;
  float mrow[2][4], lrow[2][4];
  #pragma unroll
  for (int mi = 0; mi < 2; ++mi)
    #pragma unroll
    for (int rr = 0; rr < 4; ++rr) { mrow[mi][rr] = -3e38f; lrow[mi][rr] = 0.f; }

  __syncthreads();

  for (int kt = 0; kt < 16; ++kt) {
    const short* kbase = kh + (long long)(kt << 7) * DQK_;
    // ---- S = Q K^T ----
    f32x4 sacc[2][8];
    #pragma unroll
    for (int mi = 0; mi < 2; ++mi)
      #pragma unroll
      for (int ni = 0; ni < 8; ++ni) sacc[mi][ni] = vzero;
#define STAGE_K(bi, kk) do { \
    _Pragma("unroll") \
    for (int r = 0; r < 2; ++r) { \
      int rowb = (w << 4) + (r << 6); \
      gload16(kbase + (long long)(rowb + srow) * DQK_ + (kk) * 32 + sunit, \
              &smem[25600 + (bi) * 4096 + rowb * 32]); \
    } } while (0)
    STAGE_K(0, 0);
    for (int ks = 0; ks < 6; ++ks) {
      if (ks < 5) { STAGE_K((ks + 1) & 1, ks + 1); wait_vm2(); }
      else wait_vm0();
      __builtin_amdgcn_s_barrier();
      const int kb = 25600 + (ks & 1) * 4096;
      short8_t aq[2];
      #pragma unroll
      for (int mi = 0; mi < 2; ++mi)
        aq[mi] = *reinterpret_cast<const short8_t*>(
            &smem[(rb + (mi << 4) + lr) * 200 + ks * 32 + rsw]);
      __builtin_amdgcn_s_setprio(1);
      #pragma unroll
      for (int ni = 0; ni < 8; ++ni) {
        short8_t bk = *reinterpret_cast<const short8_t*>(&smem[kb + ((ni << 4) + lr) * 32 + rsw]);
        #pragma unroll
        for (int mi = 0; mi < 2; ++mi)
          sacc[mi][ni] = __builtin_amdgcn_mfma_f32_16x16x32_bf16(
              __builtin_bit_cast(bf16x8_t, aq[mi]),
              __builtin_bit_cast(bf16x8_t, bk),
              sacc[mi][ni], 0, 0, 0);
      }
      __builtin_amdgcn_s_setprio(0);
      __builtin_amdgcn_s_barrier();
    }
#undef STAGE_K
    // ---- online softmax (P stored swizzled) ----
    #pragma unroll
    for (int mi = 0; mi < 2; ++mi) {
      #pragma unroll
      for (int rr = 0; rr < 4; ++rr) {
        float sv[8];
        float mx = -3e38f;
        #pragma unroll
        for (int ni = 0; ni < 8; ++ni) {
          sv[ni] = b2f(f2b(sacc[mi][ni][rr])) * scale;
          mx = fmaxf(mx, sv[ni]);
        }
        #pragma unroll
        for (int d = 1; d < 16; d <<= 1) mx = fmaxf(mx, __shfl_xor(mx, d, 64));
        float mnew = fmaxf(mrow[mi][rr], mx);
        float corr = expf(mrow[mi][rr] - mnew);
        float psum = 0.f;
        short pb[8];
        #pragma unroll
        for (int ni = 0; ni < 8; ++ni) {
          float p = expf(sv[ni] - mnew);
          pb[ni] = f2b(p);
          psum += p;
        }
        #pragma unroll
        for (int d = 1; d < 16; d <<= 1) psum += __shfl_xor(psum, d, 64);
        lrow[mi][rr] = lrow[mi][rr] * corr + psum;
        mrow[mi][rr] = mnew;
        int row = rb + (mi << 4) + (g << 2) + rr;
        int xr = (row >> 1) & 3;
        #pragma unroll
        for (int ni = 0; ni < 8; ++ni) {
          int cc = (ni << 4) + lr;                 // logical column
          int scc = (cc & ~31) | (((((cc >> 3) & 3) ^ xr)) << 3) | (cc & 7);
          smem[33792 + row * 136 + scc] = pb[ni];
        }
        #pragma unroll
        for (int ni = 0; ni < 8; ++ni) oacc[mi][ni][rr] *= corr;
      }
    }
    __syncthreads();
    // ---- O += P V ----
    const short* vbase = vh + (kt << 7);
#define STAGE_V(bi, kk) do { \
    _Pragma("unroll") \
    for (int r = 0; r < 2; ++r) { \
      int rowb = (w << 4) + (r << 6); \
      gload16(vbase + (long long)(rowb + srow) * S_LEN + (kk) * 32 + sunit, \
              &smem[51200 + (bi) * 4096 + rowb * 32]); \
    } } while (0)
    STAGE_V(0, 0);
    for (int ks = 0; ks < 4; ++ks) {
      if (ks < 3) { STAGE_V((ks + 1) & 1, ks + 1); wait_vm2(); }
      else wait_vm0();
      __builtin_amdgcn_s_barrier();
      const int vb = 51200 + (ks & 1) * 4096;
      short8_t ap[2];
      #pragma unroll
      for (int mi = 0; mi < 2; ++mi)
        ap[mi] = *reinterpret_cast<const short8_t*>(
            &smem[33792 + (rb + (mi << 4) + lr) * 136 + ks * 32 + rsw]);
      __builtin_amdgcn_s_setprio(1);
      #pragma unroll
      for (int ni = 0; ni < 8; ++ni) {
        short8_t bv = *reinterpret_cast<const short8_t*>(&smem[vb + ((ni << 4) + lr) * 32 + rsw]);
        #pragma unroll
        for (int mi = 0; mi < 2; ++mi)
          oacc[mi][ni] = __builtin_amdgcn_mfma_f32_16x16x32_bf16(
              __builtin_bit_cast(bf16x8_t, ap[mi]),
              __builtin_bit_cast(bf16x8_t, bv),
              oacc[mi][ni], 0, 0, 0);
      }
      __builtin_amdgcn_s_setprio(0);
      __builtin_amdgcn_s_barrier();
    }
#undef STAGE_V
  }
  // ---- epilogue: O/l -> ps (natural layout) -> vectorized store ----
  __syncthreads();
  #pragma unroll
  for (int mi = 0; mi < 2; ++mi)
    #pragma unroll
    for (int ni = 0; ni < 8; ++ni)
      #pragma unroll
      for (int rr = 0; rr < 4; ++rr) {
        int row = rb + (mi << 4) + (g << 2) + rr;
        smem[33792 + row * 136 + (ni << 4) + lr] = f2b(oacc[mi][ni][rr] / lrow[mi][rr]);
      }
  __syncthreads();
  {
    int row = tid >> 1, half = (tid & 1) << 6;
    #pragma unroll
    for (int j = 0; j < 8; ++j) {
      short8_t v = *reinterpret_cast<const short8_t*>(&smem[33792 + row * 136 + half + (j << 3)]);
      *reinterpret_cast<short8_t*>(&ao[(long long)(q0 + row) * HDIM + (h << 7) + half + (j << 3)]) = v;
    }
  }
}

// ---------------- small kernels ----------------
__global__ void __launch_bounds__(64)
rope_tables_kernel(float* cosT, float* sinT) {
  int s = blockIdx.x, j = threadIdx.x;
  int i = j & 31;
  float inv = powf(10000.0f, -((float)(2 * i) / 64.0f));
  float ang = (float)s * inv;
  cosT[s * 64 + j] = cosf(ang);
  sinT[s * 64 + j] = sinf(ang);
}

__global__ void __launch_bounds__(256)
rmsnorm_bf16_kernel(const short* __restrict__ in, long long istride,
                    const short* __restrict__ w,
                    short* __restrict__ out, long long ostride, int D) {
  const short* x = in + (long long)blockIdx.x * istride;
  short* o = out + (long long)blockIdx.x * ostride;
  const int nc = D >> 3;
  float ss = 0.f;
  for (int c = threadIdx.x; c < nc; c += 256) {
    short8_t v = reinterpret_cast<const short8_t*>(x)[c];
    #pragma unroll
    for (int j = 0; j < 8; ++j) { float f = b2f(v[j]); ss += f * f; }
  }
  __shared__ float red[256];
  red[threadIdx.x] = ss; __syncthreads();
  for (int s2 = 128; s2 > 0; s2 >>= 1) {
    if (threadIdx.x < s2) red[threadIdx.x] += red[threadIdx.x + s2];
    __syncthreads();
  }
  float r = 1.0f / sqrtf(red[0] / (float)D + 1e-6f);
  for (int c = threadIdx.x; c < nc; c += 256) {
    short8_t v = reinterpret_cast<const short8_t*>(x)[c];
    short8_t wv = reinterpret_cast<const short8_t*>(w)[c];
    short8_t ov;
    #pragma unroll
    for (int j = 0; j < 8; ++j) ov[j] = f2b(b2f(wv[j]) * (b2f(v[j]) * r));
    reinterpret_cast<short8_t*>(o)[c] = ov;
  }
}

__global__ void __launch_bounds__(256)
build_qf_kernel(const short* q, const float* cosT, const float* sinT, short* qf) {
  int s = blockIdx.x;
  for (int idx = threadIdx.x; idx < NH_ * DQK_; idx += 256) {
    int h = idx / DQK_, d = idx - h * DQK_;
    const short* qr = q + (long long)s * QN_ + h * DQK_;
    float val;
    if (d < 128) val = b2f(qr[d]);
    else {
      int j = d - 128;
      float c = cosT[s * 64 + j], sn = sinT[s * 64 + j];
      float x0 = b2f(qr[128 + j]);
      float rot = (j < 32) ? -b2f(qr[128 + j + 32]) : b2f(qr[128 + j - 32]);
      val = x0 * c + rot * sn;
    }
    qf[(long long)h * S_LEN * DQK_ + (long long)s * DQK_ + d] = f2b(val);
  }
}

__global__ void __launch_bounds__(256)
build_kf_kernel(const short* kvup, const short* krope, long long kstride,
                const float* cosT, const float* sinT, short* kf) {
  int s = blockIdx.x;
  for (int idx = threadIdx.x; idx < NH_ * DQK_; idx += 256) {
    int h = idx / DQK_, d = idx - h * DQK_;
    float val;
    if (d < 128) val = b2f(kvup[(long long)s * KVUPN + h * 256 + d]);
    else {
      int j = d - 128;
      float c = cosT[s * 64 + j], sn = sinT[s * 64 + j];
      const short* kr = krope + (long long)s * kstride;
      float x0 = b2f(kr[j]);
      float rot = (j < 32) ? -b2f(kr[j + 32]) : b2f(kr[j - 32]);
      val = x0 * c + rot * sn;
    }
    kf[(long long)h * S_LEN * DQK_ + (long long)s * DQK_ + d] = f2b(val);
  }
}

__global__ void __launch_bounds__(256)
transpose_v_kernel(const short* kvup, short* vT) {
  int h = blockIdx.z;
  int r0 = blockIdx.y * 32, c0 = blockIdx.x * 32;
  int tx = threadIdx.x & 31, ty = threadIdx.x >> 5;
  __shared__ short tile[32][33];
  #pragma unroll
  for (int i = 0; i < 4; ++i)
    tile[ty + i * 8][tx] =
        kvup[(long long)(r0 + ty + i * 8) * KVUPN + h * 256 + 128 + c0 + tx];
  __syncthreads();
  short* d = vT + (long long)h * 128 * S_LEN;
  #pragma unroll
  for (int i = 0; i < 4; ++i)
    d[(long long)(c0 + ty + i * 8) * S_LEN + r0 + tx] = tile[tx][ty + i * 8];
}

__global__ void __launch_bounds__(256)
add_bf16_kernel(short* h, const short* a) {
  long long c = (long long)blockIdx.x * 256 + threadIdx.x;
  short8_t hv = reinterpret_cast<short8_t*>(h)[c];
  short8_t av = reinterpret_cast<const short8_t*>(a)[c];
  short8_t ov;
  #pragma unroll
  for (int j = 0; j < 8; ++j) ov[j] = f2b(b2f(hv[j]) + b2f(av[j]));
  reinterpret_cast<short8_t*>(h)[c] = ov;
}

__global__ void __launch_bounds__(256)
gate_kernel(const short* x2, const short* gw, int* cnt, int* elist, float* ewt, int* tok2slot) {
  int t = blockIdx.x;
  int e = threadIdx.x >> 5, j = threadIdx.x & 31;
  const short* x = x2 + (long long)t * HDIM;
  float acc = 0.f;
  for (int k = j; k < HDIM; k += 32) acc += b2f(x[k]) * b2f(gw[(long long)k * EXP_ + e]);
  __shared__ float red[8][32];
  red[e][j] = acc; __syncthreads();
  for (int s2 = 16; s2 > 0; s2 >>= 1) {
    if (j < s2) red[e][j] += red[e][j + s2];
    __syncthreads();
  }
  if (threadIdx.x == 0) {
    float l[8], p[8];
    float m = -1e30f;
    for (int q = 0; q < 8; ++q) { l[q] = b2f(f2b(red[q][0])); m = fmaxf(m, l[q]); }
    float sum = 0.f;
    for (int q = 0; q < 8; ++q) { p[q] = expf(l[q] - m); sum += p[q]; }
    int i0 = 0; for (int q = 1; q < 8; ++q) if (p[q] > p[i0]) i0 = q;
    int i1 = (i0 == 0) ? 1 : 0;
    for (int q = 0; q < 8; ++q) if (q != i0 && p[q] > p[i1]) i1 = q;
    float denom = p[i0] + p[i1];
    float w0 = b2f(f2b(p[i0] / denom));
    float w1 = b2f(f2b(p[i1] / denom));
    int pos0 = atomicAdd(&cnt[i0], 1);
    int pos1 = atomicAdd(&cnt[i1], 1);
    elist[i0 * S_LEN + pos0] = t;  ewt[i0 * S_LEN + pos0] = w0;
    elist[i1 * S_LEN + pos1] = t;  ewt[i1 * S_LEN + pos1] = w1;
    int4* slot = (int4*)tok2slot;
    slot[t] = make_int4(i0, pos0, i1, pos1);
  }
}

__global__ void __launch_bounds__(256)
silu_moe_kernel(short* a, const short* b, const int* cnt, const float* ewt) {
  int pos = blockIdx.x, e = blockIdx.y;
  if (pos >= cnt[e]) return;
  float scale = ewt[e * S_LEN + pos];
  int c = threadIdx.x;
  if (c >= IFF_ / 8) return;
  long long roff = ((long long)e * S_LEN + pos) * IFF_;
  short8_t av = reinterpret_cast<short8_t*>(a + roff)[c];
  short8_t bv = reinterpret_cast<const short8_t*>(b + roff)[c];
  short8_t ov;
  #pragma unroll
  for (int j = 0; j < 8; ++j) {
    float x = b2f(av[j]);
    float s = x / (1.0f + expf(-x));
    ov[j] = f2b(s * b2f(bv[j]) * scale);
  }
  reinterpret_cast<short8_t*>(a + roff)[c] = ov;
}

__global__ void __launch_bounds__(256)
silu_sh_kernel(short* a, const short* b) {
  long long roff = ((long long)blockIdx.y * S_LEN + blockIdx.x) * IFF_;
  int c = threadIdx.x;
  if (c >= IFF_ / 8) return;
  short8_t av = reinterpret_cast<short8_t*>(a + roff)[c];
  short8_t bv = reinterpret_cast<const short8_t*>(b + roff)[c];
  short8_t ov;
  #pragma unroll
  for (int j = 0; j < 8; ++j) {
    float x = b2f(av[j]);
    float s = x / (1.0f + expf(-x));
    ov[j] = f2b(s * b2f(bv[j]));
  }
  reinterpret_cast<short8_t*>(a + roff)[c] = ov;
}

__global__ void __launch_bounds__(256)
moe_combine_kernel(short* h, const short* shared_out, const short* routed,
                   const int* tok2slot) {
  int t = blockIdx.x;
  const int4 sl = ((const int4*)tok2slot)[t];
  const short8_t* s0 = reinterpret_cast<const short8_t*>(shared_out + (long long)t * HDIM);
  const short8_t* s1 = reinterpret_cast<const short8_t*>(shared_out + ((long long)S_LEN + t) * HDIM);
  const short8_t* r0 = reinterpret_cast<const short8_t*>(
      routed + ((long long)sl.x * S_LEN + sl.y) * HDIM);
  const short8_t* r1 = reinterpret_cast<const short8_t*>(
      routed + ((long long)sl.z * S_LEN + sl.w) * HDIM);
  long long c = (long long)t * 256 + threadIdx.x;
  short8_t hv = reinterpret_cast<short8_t*>(h)[c];
  short8_t a0 = s0[threadIdx.x], a1 = s1[threadIdx.x];
  short8_t v0 = r0[threadIdx.x], v1 = r1[threadIdx.x];
  short8_t ov;
  #pragma unroll
  for (int j = 0; j < 8; ++j)
    ov[j] = f2b(b2f(hv[j]) + (b2f(a0[j]) + b2f(a1[j]) + b2f(v0[j]) + b2f(v1[j])));
  reinterpret_cast<short8_t*>(h)[c] = ov;
}

// ---------------- pooling ----------------
template<int AF32, int OUTBF16>
__global__ void __launch_bounds__(256)
gemv_bt_kernel(const void* a, const short* __restrict__ BT, void* out, int K) {
  int n = blockIdx.x;
  const short8_t* row = reinterpret_cast<const short8_t*>(BT + (long long)n * K);
  float acc = 0.f;
  for (int c = threadIdx.x; c < (K >> 3); c += 256) {
    short8_t v = row[c];
    if (AF32) {
      f32x4 a0 = reinterpret_cast<const f32x4*>(a)[2 * c];
      f32x4 a1 = reinterpret_cast<const f32x4*>(a)[2 * c + 1];
      #pragma unroll
      for (int j = 0; j < 4; ++j) {
        acc += a0[j] * b2f(v[j]);
        acc += a1[j] * b2f(v[4 + j]);
      }
    } else {
      short8_t av = reinterpret_cast<const short8_t*>(a)[c];
      #pragma unroll
      for (int j = 0; j < 8; ++j) acc += b2f(av[j]) * b2f(v[j]);
    }
  }
  __shared__ float red[256];
  red[threadIdx.x] = acc; __syncthreads();
  for (int s2 = 128; s2 > 0; s2 >>= 1) {
    if (threadIdx.x < s2) red[threadIdx.x] += red[threadIdx.x + s2];
    __syncthreads();
  }
  if (threadIdx.x == 0) {
    if (OUTBF16) ((short*)out)[n] = f2b(red[0]);
    else         ((float*)out)[n] = red[0];
  }
}

__global__ void __launch_bounds__(256)
pool_score_kernel(const short* qv, const short* kmat, float* score) {
  int s = blockIdx.x;
  const short8_t* kr = reinterpret_cast<const short8_t*>(kmat + (long long)s * HDIM);
  const short8_t* qr = reinterpret_cast<const short8_t*>(qv);
  short8_t kv8 = kr[threadIdx.x], qv8 = qr[threadIdx.x];
  float acc = 0.f;
  #pragma unroll
  for (int j = 0; j < 8; ++j) acc += b2f(qv8[j]) * b2f(kv8[j]);
  __shared__ float red[256];
  red[threadIdx.x] = acc; __syncthreads();
  for (int s2 = 128; s2 > 0; s2 >>= 1) {
    if (threadIdx.x < s2) red[threadIdx.x] += red[threadIdx.x + s2];
    __syncthreads();
  }
  if (threadIdx.x == 0) score[s] = b2f(f2b(red[0])) * 0.022097086912079608f;
}

__global__ void __launch_bounds__(256)
softmax_vec_kernel(float* v) {
  int tid = threadIdx.x;
  float f[8]; float m = -1e30f;
  #pragma unroll
  for (int i = 0; i < 8; ++i) { f[i] = v[i * 256 + tid]; m = fmaxf(m, f[i]); }
  __shared__ float red[256];
  red[tid] = m; __syncthreads();
  for (int s2 = 128; s2 > 0; s2 >>= 1) {
    if (tid < s2) red[tid] = fmaxf(red[tid], red[tid + s2]);
    __syncthreads();
  }
  m = red[0]; __syncthreads();
  float sum = 0.f;
  #pragma unroll
  for (int i = 0; i < 8; ++i) { f[i] = expf(f[i] - m); sum += f[i]; }
  red[tid] = sum; __syncthreads();
  for (int s2 = 128; s2 > 0; s2 >>= 1) {
    if (tid < s2) red[tid] += red[tid + s2];
    __syncthreads();
  }
  float inv = 1.0f / red[0];
  #pragma unroll
  for (int i = 0; i < 8; ++i) v[i * 256 + tid] = f[i] * inv;
}

__global__ void __launch_bounds__(256)
pool_wsum_t_kernel(const float* w, const short* vT, float* pooled) {
  int h = blockIdx.x;
  const short8_t* row = reinterpret_cast<const short8_t*>(vT + (long long)h * S_LEN);
  int c = threadIdx.x;
  short8_t v = row[c];
  f32x4 w0 = reinterpret_cast<const f32x4*>(w)[2 * c];
  f32x4 w1 = reinterpret_cast<const f32x4*>(w)[2 * c + 1];
  float acc = 0.f;
  #pragma unroll
  for (int j = 0; j < 4; ++j) {
    acc += w0[j] * b2f(v[j]);
    acc += w1[j] * b2f(v[4 + j]);
  }
  __shared__ float red[256];
  red[threadIdx.x] = acc; __syncthreads();
  for (int s2 = 128; s2 > 0; s2 >>= 1) {
    if (threadIdx.x < s2) red[threadIdx.x] += red[threadIdx.x + s2];
    __syncthreads();
  }
  if (threadIdx.x == 0) pooled[h] = red[0];
}

__global__ void __launch_bounds__(256)
rmsnorm_f32_kernel(const float* x, const short* w, float* out) {
  int tid = threadIdx.x;
  float f[8]; float ss = 0.f;
  #pragma unroll
  for (int i = 0; i < 8; ++i) { f[i] = x[i * 256 + tid]; ss += f[i] * f[i]; }
  __shared__ float red[256];
  red[tid] = ss; __syncthreads();
  for (int s2 = 128; s2 > 0; s2 >>= 1) {
    if (tid < s2) red[tid] += red[tid + s2];
    __syncthreads();
  }
  float r = 1.0f / sqrtf(red[0] / 2048.0f + 1e-6f);
  #pragma unroll
  for (int i = 0; i < 8; ++i) out[i * 256 + tid] = b2f(w[i * 256 + tid]) * (f[i] * r);
}

// ---------------- host ----------------
extern "C" void kernel_launch(void* const* d_in, const int* in_sizes, int n_in,
                              void* d_out, int out_size, void* d_ws, size_t ws_size,
                              hipStream_t stream)
{
  (void)n_in; (void)out_size; (void)ws_size;
  const int* ids = (const int*)d_in[24];

  char* base = (char*)d_ws;
  size_t off = 0;
  auto alloc = [&](size_t bytes) -> void* {
    void* p = base + off;
    off += (bytes + 255) & ~(size_t)255;
    return p;
  };

  int* dflag = (int*)alloc(256);

  short* qkvdwT = (short*)alloc((size_t)2 * DCAT * HDIM * 2);
  short* quwT  = (short*)alloc((size_t)2 * QN_ * QRANK_ * 2);
  short* kvuwT = (short*)alloc((size_t)2 * KVUPN * KVRANK_ * 2);
  short* opwT  = (short*)alloc((size_t)2 * HDIM * HDIM * 2);
  short* rw1T  = (short*)alloc((size_t)16 * IFF_ * HDIM * 2);
  short* rw2T  = (short*)alloc((size_t)16 * HDIM * IFF_ * 2);
  short* rw3T  = (short*)alloc((size_t)16 * IFF_ * HDIM * 2);
  short* sw1T  = (short*)alloc((size_t)4 * IFF_ * HDIM * 2);
  short* sw2T  = (short*)alloc((size_t)4 * HDIM * IFF_ * 2);
  short* sw3T  = (short*)alloc((size_t)4 * IFF_ * HDIM * 2);
  short* pqwT  = (short*)alloc((size_t)HDIM * HDIM * 2);
  short* pkwT  = (short*)alloc((size_t)HDIM * HDIM * 2);
  short* pvwT  = (short*)alloc((size_t)HDIM * HDIM * 2);
  short* powT  = (short*)alloc((size_t)PD_ * HDIM * 2);
  short* ln1w = (short*)alloc((size_t)in_sizes[1] * 2);
  short* qnw  = (short*)alloc((size_t)in_sizes[3] * 2);
  short* kvnw = (short*)alloc((size_t)in_sizes[6] * 2);
  short* ln2w = (short*)alloc((size_t)in_sizes[9] * 2);
  short* gatw = (short*)alloc((size_t)in_sizes[10] * 2);
  short* fnww = (short*)alloc((size_t)in_sizes[17] * 2);
  short* lqw  = (short*)alloc((size_t)in_sizes[18] * 2);
  short* pnww = (short*)alloc((size_t)in_sizes[23] * 2);

  float* cosT    = (float*)alloc((size_t)S_LEN * 64 * 4);
  float* sinT    = (float*)alloc((size_t)S_LEN * 64 * 4);
  short* hbuf    = (short*)alloc((size_t)S_LEN * HDIM * 2);
  short* xbuf    = (short*)alloc((size_t)S_LEN * HDIM * 2);
  short* dcat    = (short*)alloc((size_t)S_LEN * DCAT * 2);
  short* qlatn   = (short*)alloc((size_t)S_LEN * QRANK_ * 2);
  short* qbuf    = (short*)alloc((size_t)S_LEN * QN_ * 2);
  short* kvn     = (short*)alloc((size_t)S_LEN * KVRANK_ * 2);
  short* kvup    = (short*)alloc((size_t)S_LEN * KVUPN * 2);
  short* qf      = (short*)alloc((size_t)NH_ * S_LEN * DQK_ * 2);
  short* kf      = (short*)alloc((size_t)NH_ * S_LEN * DQK_ * 2);
  short* vT      = (short*)alloc((size_t)NH_ * 128 * S_LEN * 2);
  short* ao      = (short*)alloc((size_t)S_LEN * HDIM * 2);
  short* attnp   = (short*)alloc((size_t)S_LEN * HDIM * 2);
  short* hfin    = (short*)alloc((size_t)S_LEN * HDIM * 2);
  short* kpool   = (short*)alloc((size_t)S_LEN * HDIM * 2);
  short* vpoolT  = (short*)alloc((size_t)HDIM * S_LEN * 2);
  short* qvec    = (short*)alloc((size_t)HDIM * 2);
  float* pscore  = (float*)alloc((size_t)S_LEN * 4);
  float* pooled  = (float*)alloc((size_t)HDIM * 4);
  float* pooledn = (float*)alloc((size_t)HDIM * 4);
  int*   ecnt    = (int*)alloc(64);
  int*   elist   = (int*)alloc((size_t)EXP_ * S_LEN * 4);
  float* ewt     = (float*)alloc((size_t)EXP_ * S_LEN * 4);
  int*   tok2slot= (int*)alloc((size_t)S_LEN * 16);
  short* gba_e   = (short*)alloc((size_t)EXP_ * S_LEN * IFF_ * 2);
  short* gbb_e   = (short*)alloc((size_t)EXP_ * S_LEN * IFF_ * 2);
  short* routed  = (short*)alloc((size_t)EXP_ * S_LEN * HDIM * 2);
  short* gsh1    = (short*)alloc((size_t)2 * S_LEN * IFF_ * 2);
  short* gsh3    = (short*)alloc((size_t)2 * S_LEN * IFF_ * 2);
  short* shared_out = (short*)alloc((size_t)2 * S_LEN * HDIM * 2);

  detect_kernel<<<1, 256, 0, stream>>>(d_in[0], dflag);

  auto tconv = [&](const void* src, short* dst, int R, int C, int nslabs,
                   long long sSrc, long long sDst) {
    dim3 grid(C / 32, R / 32, nslabs);
    transconv_kernel<<<grid, 256, 0, stream>>>(src, dst, R, C, dflag, sSrc, sDst);
  };
  auto pconv = [&](const void* src, short* dst, long long n) {
    long long nchunks = n / 8;
    int blocks = (int)((nchunks + 255) / 256);
    if (blocks > 2048) blocks = 2048;
    if (blocks < 1) blocks = 1;
    convert_kernel<<<blocks, 256, 0, stream>>>(src, dst, nchunks, dflag);
  };

  tconv(d_in[2], qkvdwT, HDIM, QRANK_, 2,
        (long long)HDIM * QRANK_, (long long)DCAT * HDIM);
  tconv(d_in[5], qkvdwT + (size_t)QRANK_ * HDIM, HDIM, KVDN, 2,
        (long long)HDIM * KVDN, (long long)DCAT * HDIM);
  tconv(d_in[4],  quwT,  QRANK_, QN_,  2, (long long)QRANK_ * QN_,  (long long)QN_ * QRANK_);
  tconv(d_in[7],  kvuwT, KVRANK_,KVUPN,2, (long long)KVRANK_ * KVUPN,(long long)KVUPN * KVRANK_);
  tconv(d_in[8],  opwT,  HDIM,   HDIM, 2, (long long)HDIM * HDIM,   (long long)HDIM * HDIM);
  tconv(d_in[11], rw1T,  HDIM,   IFF_, 16,(long long)HDIM * IFF_,   (long long)IFF_ * HDIM);
  tconv(d_in[12], rw2T,  IFF_,   HDIM, 16,(long long)IFF_ * HDIM,   (long long)HDIM * IFF_);
  tconv(d_in[13], rw3T,  HDIM,   IFF_, 16,(long long)HDIM * IFF_,   (long long)IFF_ * HDIM);
  tconv(d_in[14], sw1T,  HDIM,   IFF_, 4, (long long)HDIM * IFF_,   (long long)IFF_ * HDIM);
  tconv(d_in[15], sw2T,  IFF_,   HDIM, 4, (long long)IFF_ * HDIM,   (long long)HDIM * IFF_);
  tconv(d_in[16], sw3T,  HDIM,   IFF_, 4, (long long)HDIM * IFF_,   (long long)IFF_ * HDIM);
  tconv(d_in[19], pqwT,  HDIM,   HDIM, 1, 0, 0);
  tconv(d_in[20], pkwT,  HDIM,   HDIM, 1, 0, 0);
  tconv(d_in[21], pvwT,  HDIM,   HDIM, 1, 0, 0);
  tconv(d_in[22], powT,  HDIM,   PD_,  1, 0, 0);
  pconv(d_in[1],  ln1w, in_sizes[1]);
  pconv(d_in[3],  qnw,  in_sizes[3]);
  pconv(d_in[6],  kvnw, in_sizes[6]);
  pconv(d_in[9],  ln2w, in_sizes[9]);
  pconv(d_in[10], gatw, in_sizes[10]);
  pconv(d_in[17], fnww, in_sizes[17]);
  pconv(d_in[18], lqw,  in_sizes[18]);
  pconv(d_in[23], pnww, in_sizes[23]);

  const float qk_scale = 1.0f / sqrtf((float)DQK_);

  auto gemm = [&](const short* A, const short* B, short* C,
                  int M, int N, int K, int lda, int ldb, int ldc,
                  int batch, long long sA, long long sB, long long sC) {
    dim3 grid(M / 128, (N + 127) / 128, batch);
    gemm_kernel<<<grid, 256, 0, stream>>>(A, B, C, M, N, K, lda, ldb, ldc, sA, sB, sC);
  };

  rope_tables_kernel<<<S_LEN, 64, 0, stream>>>(cosT, sinT);
  embed_convert_kernel<<<S_LEN, 256, 0, stream>>>(ids, d_in[0], dflag, hbuf);

  for (int l = 0; l < 2; ++l) {
    const short* w_ln1  = ln1w + (size_t)l * HDIM;
    const short* w_qkvT = qkvdwT + (size_t)l * DCAT * HDIM;
    const short* w_qn   = qnw  + (size_t)l * QRANK_;
    const short* w_quT  = quwT + (size_t)l * QN_ * QRANK_;
    const short* w_kvn  = kvnw + (size_t)l * KVRANK_;
    const short* w_kvuT = kvuwT+ (size_t)l * KVUPN * KVRANK_;
    const short* w_opT  = opwT + (size_t)l * HDIM * HDIM;
    const short* w_ln2  = ln2w + (size_t)l * HDIM;
    const short* w_gat  = gatw + (size_t)l * HDIM * EXP_;

    // --- attention ---
    rmsnorm_bf16_kernel<<<S_LEN, 256, 0, stream>>>(hbuf, HDIM, w_ln1, xbuf, HDIM, HDIM);
    gemm(xbuf, w_qkvT, dcat, S_LEN, DCAT, HDIM, HDIM, HDIM, DCAT, 1, 0, 0, 0);
    rmsnorm_bf16_kernel<<<S_LEN, 256, 0, stream>>>(dcat, DCAT, w_qn, qlatn, QRANK_, QRANK_);
    gemm(qlatn, w_quT, qbuf, S_LEN, QN_, QRANK_, QRANK_, QRANK_, QN_, 1, 0, 0, 0);
    rmsnorm_bf16_kernel<<<S_LEN, 256, 0, stream>>>(dcat + QRANK_, DCAT, w_kvn, kvn, KVRANK_, KVRANK_);
    gemm(kvn, w_kvuT, kvup, S_LEN, KVUPN, KVRANK_, KVRANK_, KVRANK_, KVUPN, 1, 0, 0, 0);
    build_qf_kernel<<<S_LEN, 256, 0, stream>>>(qbuf, cosT, sinT, qf);
    build_kf_kernel<<<S_LEN, 256, 0, stream>>>(kvup, dcat + QRANK_ + KVRANK_, DCAT, cosT, sinT, kf);
    {
      dim3 tg(128 / 32, S_LEN / 32, NH_);
      transpose_v_kernel<<<tg, 256, 0, stream>>>(kvup, vT);
    }
    {
      dim3 fg(S_LEN / 128, NH_);
      flash_kernel<<<fg, 256, 0, stream>>>(qf, kf, vT, ao, qk_scale);
    }
    gemm(ao, w_opT, attnp, S_LEN, HDIM, HDIM, HDIM, HDIM, HDIM, 1, 0, 0, 0);
    add_bf16_kernel<<<S_LEN, 256, 0, stream>>>(hbuf, attnp);

    // --- MoE ---
    rmsnorm_bf16_kernel<<<S_LEN, 256, 0, stream>>>(hbuf, HDIM, w_ln2, xbuf, HDIM, HDIM);
    hipMemsetAsync(ecnt, 0, 64, stream);
    gate_kernel<<<S_LEN, 256, 0, stream>>>(xbuf, w_gat, ecnt, elist, ewt, tok2slot);
    {
      const short* a1 = sw1T + (size_t)l * 2 * IFF_ * HDIM;
      const short* a3 = sw3T + (size_t)l * 2 * IFF_ * HDIM;
      const short* a2 = sw2T + (size_t)l * 2 * HDIM * IFF_;
      gemm(xbuf, a1, gsh1, S_LEN, IFF_, HDIM, HDIM, HDIM, IFF_, 2,
           0, (long long)IFF_ * HDIM, (long long)S_LEN * IFF_);
      gemm(xbuf, a3, gsh3, S_LEN, IFF_, HDIM, HDIM, HDIM, IFF_, 2,
           0, (long long)IFF_ * HDIM, (long long)S_LEN * IFF_);
      dim3 gs(S_LEN, 2);
      silu_sh_kernel<<<gs, 256, 0, stream>>>(gsh1, gsh3);
      gemm(gsh1, a2, shared_out, S_LEN, HDIM, IFF_, IFF_, IFF_, HDIM, 2,
           (long long)S_LEN * IFF_, (long long)HDIM * IFF_, (long long)S_LEN * HDIM);
    }
    {
      const short* b1 = rw1T + (size_t)l * 8 * IFF_ * HDIM;
      const short* b3 = rw3T + (size_t)l * 8 * IFF_ * HDIM;
      const short* b2 = rw2T + (size_t)l * 8 * HDIM * IFF_;
      dim3 g13(S_LEN / 128, IFF_ / 128, EXP_);
      moe_gemm_kernel<1><<<g13, 256, 0, stream>>>(
          xbuf, elist, ecnt, b1, gba_e, IFF_, HDIM, HDIM, HDIM, IFF_,
          (long long)S_LEN * IFF_, (long long)IFF_ * HDIM, (long long)S_LEN * IFF_);
      moe_gemm_kernel<1><<<g13, 256, 0, stream>>>(
          xbuf, elist, ecnt, b3, gbb_e, IFF_, HDIM, HDIM, HDIM, IFF_,
          (long long)S_LEN * IFF_, (long long)IFF_ * HDIM, (long long)S_LEN * IFF_);
      dim3 gs(S_LEN, EXP_);
      silu_moe_kernel<<<gs, 256, 0, stream>>>(gba_e, gbb_e, ecnt, ewt);
      dim3 g2(S_LEN / 128, HDIM / 128, EXP_);
      moe_gemm_kernel<0><<<g2, 256, 0, stream>>>(
          gba_e, elist, ecnt, b2, routed, HDIM, IFF_, IFF_, IFF_, HDIM,
          (long long)S_LEN * IFF_, (long long)HDIM * IFF_, (long long)S_LEN * HDIM);
      moe_combine_kernel<<<S_LEN, 256, 0, stream>>>(hbuf, shared_out, routed, tok2slot);
    }
  }

  // --- attention pooling head ---
  rmsnorm_bf16_kernel<<<S_LEN, 256, 0, stream>>>(hbuf, HDIM, fnww, hfin, HDIM, HDIM);
  gemm(hfin, pkwT, kpool, S_LEN, HDIM, HDIM, HDIM, HDIM, HDIM, 1, 0, 0, 0);
  gemm(pvwT, hfin, vpoolT, HDIM, S_LEN, HDIM, HDIM, HDIM, S_LEN, 1, 0, 0, 0);
  gemv_bt_kernel<0,1><<<HDIM, 256, 0, stream>>>(lqw, pqwT, qvec, HDIM);
  pool_score_kernel<<<S_LEN, 256, 0, stream>>>(qvec, kpool, pscore);
  softmax_vec_kernel<<<1, 256, 0, stream>>>(pscore);
  pool_wsum_t_kernel<<<HDIM, 256, 0, stream>>>(pscore, vpoolT, pooled);
  rmsnorm_f32_kernel<<<1, 256, 0, stream>>>(pooled, pnww, pooledn);
  gemv_bt_kernel<1,0><<<PD_, 256, 0, stream>>>(pooledn, powT, (float*)d_out, HDIM);
}

// Round 10
// 2055.179 us; speedup vs baseline: 5.7543x; 1.0685x over previous
//
#include <hip/hip_runtime.h>
#include <hip/hip_bf16.h>

#define S_LEN  2048
#define HDIM   2048
#define NH_    16
#define DQK_   192
#define QRANK_ 1024
#define KVRANK_ 512
#define KVDN   576
#define DCAT   1600   // QRANK + KVDN merged down-proj width
#define KVUPN  4096
#define QN_    3072
#define IFF_   1408
#define IFF2   2816   // interleaved w1|w3 width
#define EXP_   8
#define PD_    4096

typedef __attribute__((ext_vector_type(8))) short   short8_t;
typedef __attribute__((ext_vector_type(8))) __bf16  bf16x8_t;
typedef __attribute__((ext_vector_type(4))) float   f32x4;

static __device__ __forceinline__ float b2f(short s) {
  unsigned int u = ((unsigned int)(unsigned short)s) << 16;
  return __builtin_bit_cast(float, u);
}
static __device__ __forceinline__ short f2b(float f) {
  return __builtin_bit_cast(short, __float2bfloat16(f));
}

static __device__ __forceinline__ void gload16(const void* g, void* l) {
  __builtin_amdgcn_global_load_lds(
      (const __attribute__((address_space(1))) void*)g,
      (__attribute__((address_space(3))) void*)l,
      16, 0, 0);
}
static __device__ __forceinline__ void wait_vm4() { asm volatile("s_waitcnt vmcnt(4)" ::: "memory"); }
static __device__ __forceinline__ void wait_vm2() { asm volatile("s_waitcnt vmcnt(2)" ::: "memory"); }
static __device__ __forceinline__ void wait_vm0() { asm volatile("s_waitcnt vmcnt(0)" ::: "memory"); }

// ---------------- dtype detect + convert ----------------
__global__ void __launch_bounds__(256)
detect_kernel(const void* probe, int* flag) {
  const float* f = (const float*)probe;
  int tid = threadIdx.x;
  int cnt = 0;
  for (int i = tid; i < 2048; i += 256) {
    float v = fabsf(f[i]);
    if (v > 1e-6f && v < 10.0f) cnt++;
  }
  __shared__ int red[256];
  red[tid] = cnt; __syncthreads();
  for (int s = 128; s > 0; s >>= 1) {
    if (tid < s) red[tid] += red[tid + s];
    __syncthreads();
  }
  if (tid == 0) *flag = (red[0] > 1600) ? 1 : 0;
}

__global__ void __launch_bounds__(256)
convert_kernel(const void* src, short* dst, long long nchunks, const int* flag) {
  long long idx = (long long)blockIdx.x * 256 + threadIdx.x;
  long long stride = (long long)gridDim.x * 256;
  if (*flag) {
    const f32x4* s = (const f32x4*)src;
    for (long long c = idx; c < nchunks; c += stride) {
      f32x4 a = s[2 * c], b = s[2 * c + 1];
      short8_t o;
      #pragma unroll
      for (int j = 0; j < 4; ++j) { o[j] = f2b(a[j]); o[4 + j] = f2b(b[j]); }
      reinterpret_cast<short8_t*>(dst)[c] = o;
    }
  } else {
    const short8_t* s = (const short8_t*)src;
    for (long long c = idx; c < nchunks; c += stride)
      reinterpret_cast<short8_t*>(dst)[c] = s[c];
  }
}

// transpose-convert: src slab [R][C] -> dst rows (c*rowMul+rowOff) stride R, bf16
__global__ void __launch_bounds__(256)
transconv_kernel(const void* src, short* dst, int R, int C, const int* flag,
                 long long sSrc, long long sDst, int rowMul, int rowOff) {
  long long zs = (long long)blockIdx.z * sSrc;
  long long zd = (long long)blockIdx.z * sDst;
  int r0 = blockIdx.y * 32, c0 = blockIdx.x * 32;
  int tx = threadIdx.x & 31, ty = threadIdx.x >> 5;
  __shared__ short tile[32][33];
  if (*flag) {
    const float* s = (const float*)src + zs;
    #pragma unroll
    for (int i = 0; i < 4; ++i)
      tile[ty + i * 8][tx] = f2b(s[(long long)(r0 + ty + i * 8) * C + c0 + tx]);
  } else {
    const short* s = (const short*)src + zs;
    #pragma unroll
    for (int i = 0; i < 4; ++i)
      tile[ty + i * 8][tx] = s[(long long)(r0 + ty + i * 8) * C + c0 + tx];
  }
  __syncthreads();
  short* d = dst + zd;
  #pragma unroll
  for (int i = 0; i < 4; ++i)
    d[(long long)((c0 + ty + i * 8) * rowMul + rowOff) * R + r0 + tx] = tile[tx][ty + i * 8];
}

__global__ void __launch_bounds__(256)
embed_convert_kernel(const int* ids, const void* emb, const int* flag, short* h) {
  int s = blockIdx.x;
  long long row = ids[s];
  int c = threadIdx.x;
  short8_t o;
  if (*flag) {
    const f32x4* src = (const f32x4*)((const float*)emb + row * HDIM);
    f32x4 a = src[2 * c], b = src[2 * c + 1];
    #pragma unroll
    for (int j = 0; j < 4; ++j) { o[j] = f2b(a[j]); o[4 + j] = f2b(b[j]); }
  } else {
    o = reinterpret_cast<const short8_t*>((const short*)emb + row * HDIM)[c];
  }
  reinterpret_cast<short8_t*>(h + (long long)s * HDIM)[c] = o;
}

// ---------------- pipelined MFMA GEMM (B always [N][K], bf16 C) ----------------
// EPI=0: plain bf16 store. EPI=1: fused SiLU-pair (even=gate, odd=up), writes N/2 cols.
// EPI=2: in-place residual add (C = f2b(b2f(C) + b2f(f2b(acc)))).
template<int EPI>
__global__ void __launch_bounds__(256)
gemm_kernel(const short* __restrict__ A, const short* __restrict__ B,
            short* __restrict__ Cv, int M, int N, int K,
            int lda, int ldb, int ldc,
            long long sAb, long long sBb, long long sCb)
{
  __shared__ short smem[24576];
  short* shA = smem;
  short* shB = smem + 12288;
  const int tid = threadIdx.x;
  const long long bz = blockIdx.z;
  const short* Ab = A + bz * sAb;
  const short* Bb = B + bz * sBb;
  const int m0 = blockIdx.x * 128;
  const int n0 = blockIdx.y * 128;
  const int w = tid >> 6, lane = tid & 63;
  const int wm = (w >> 1) << 6, wn = (w & 1) << 6;
  const int lr = lane & 15, g = lane >> 4;
  const int srow = lane >> 2;
  const int sunit = ((lane & 3) ^ ((lane >> 3) & 3)) << 3;
  const int rsw = ((g ^ ((lr >> 1) & 3)) << 3);
  const f32x4 vzero = {0.f, 0.f, 0.f, 0.f};
  f32x4 acc[4][4];
  #pragma unroll
  for (int i = 0; i < 4; ++i)
    #pragma unroll
    for (int j = 0; j < 4; ++j) acc[i][j] = vzero;

  const int nt = K >> 5;
#define STAGE_G(bi, kk) do { \
    _Pragma("unroll") \
    for (int r = 0; r < 2; ++r) { \
      int rowb = (w << 4) + (r << 6); \
      gload16(Ab + (long long)(m0 + rowb + srow) * lda + (kk) + sunit, &shA[(bi) * 4096 + rowb * 32]); \
      gload16(Bb + (long long)(n0 + rowb + srow) * ldb + (kk) + sunit, &shB[(bi) * 4096 + rowb * 32]); \
    } } while (0)

  STAGE_G(0, 0);
  if (nt > 1) STAGE_G(1, 32);
  int cur = 0, i2 = 2;
  for (int t = 0; t < nt; ++t) {
    if (t + 1 < nt) wait_vm4(); else wait_vm0();
    __builtin_amdgcn_s_barrier();
    if (t + 2 < nt) STAGE_G(i2, (t + 2) << 5);
    short8_t af[4];
    #pragma unroll
    for (int mi = 0; mi < 4; ++mi)
      af[mi] = *reinterpret_cast<const short8_t*>(&shA[cur * 4096 + (wm + (mi << 4) + lr) * 32 + rsw]);
    __builtin_amdgcn_s_setprio(1);
    #pragma unroll
    for (int ni = 0; ni < 4; ++ni) {
      short8_t bfr = *reinterpret_cast<const short8_t*>(&shB[cur * 4096 + (wn + (ni << 4) + lr) * 32 + rsw]);
      #pragma unroll
      for (int mi = 0; mi < 4; ++mi)
        acc[mi][ni] = __builtin_amdgcn_mfma_f32_16x16x32_bf16(
            __builtin_bit_cast(bf16x8_t, af[mi]),
            __builtin_bit_cast(bf16x8_t, bfr),
            acc[mi][ni], 0, 0, 0);
    }
    __builtin_amdgcn_s_setprio(0);
    cur = (cur == 2) ? 0 : cur + 1;
    i2  = (i2 == 2) ? 0 : i2 + 1;
  }
#undef STAGE_G
  // ---- retiled epilogue ----
  __syncthreads();
  #pragma unroll
  for (int ni = 0; ni < 4; ++ni)
    #pragma unroll
    for (int mi = 0; mi < 4; ++mi)
      #pragma unroll
      for (int r = 0; r < 4; ++r)
        smem[(wm + (mi << 4) + (g << 2) + r) * 136 + wn + (ni << 4) + lr] = f2b(acc[mi][ni][r]);
  __syncthreads();
  {
    short* C = Cv + bz * sCb;
    int row = tid >> 1, half = (tid & 1) << 6;
    if (EPI == 1) {
      // interleaved pairs -> silu(even)*odd, 32 outputs per thread
      int ocol = (n0 >> 1) + (half >> 1);
      #pragma unroll
      for (int j = 0; j < 4; ++j) {
        short8_t v0 = *reinterpret_cast<const short8_t*>(&smem[row * 136 + half + (j << 4)]);
        short8_t v1 = *reinterpret_cast<const short8_t*>(&smem[row * 136 + half + (j << 4) + 8]);
        short8_t o;
        #pragma unroll
        for (int q = 0; q < 4; ++q) {
          float x = b2f(v0[2 * q]);
          o[q] = f2b((x / (1.0f + expf(-x))) * b2f(v0[2 * q + 1]));
          float y = b2f(v1[2 * q]);
          o[4 + q] = f2b((y / (1.0f + expf(-y))) * b2f(v1[2 * q + 1]));
        }
        *reinterpret_cast<short8_t*>(&C[(long long)(m0 + row) * ldc + ocol + (j << 3)]) = o;
      }
    } else {
      #pragma unroll
      for (int j = 0; j < 8; ++j) {
        int col = n0 + half + (j << 3);
        if (col + 8 <= N) {
          short8_t v = *reinterpret_cast<const short8_t*>(&smem[row * 136 + half + (j << 3)]);
          short* cp = &C[(long long)(m0 + row) * ldc + col];
          if (EPI == 2) {
            short8_t hv = *reinterpret_cast<const short8_t*>(cp);
            short8_t o;
            #pragma unroll
            for (int q = 0; q < 8; ++q) o[q] = f2b(b2f(hv[q]) + b2f(v[q]));
            *reinterpret_cast<short8_t*>(cp) = o;
          } else {
            *reinterpret_cast<short8_t*>(cp) = v;
          }
        }
      }
    }
  }
}

// ---------------- pipelined sparse MoE gather GEMM ----------------
// SILU=1: interleaved w1|w3 B, fused silu*ewt epilogue writing N/2 compact cols.
template<int GATHER, int SILU>
__global__ void __launch_bounds__(256)
moe_gemm_kernel(const short* __restrict__ A, const int* __restrict__ elist,
                const int* __restrict__ cnt, const short* __restrict__ B,
                short* __restrict__ C, const float* __restrict__ ewt,
                int N, int K, int lda, int ldb, int ldc,
                long long sAe, long long sBe, long long sCe)
{
  const int e = blockIdx.z;
  const int cnt_e = cnt[e];
  const int m0 = blockIdx.x * 128;
  if (m0 >= cnt_e) return;
  const short* Bb = B + (long long)e * sBe;
  short* Cb = C + (long long)e * sCe;
  const int n0 = blockIdx.y * 128;
  const int tid = threadIdx.x;
  const int w = tid >> 6, lane = tid & 63;
  const int wm = (w >> 1) << 6, wn = (w & 1) << 6;
  const int lr = lane & 15, g = lane >> 4;
  const int srow = lane >> 2;
  const int sunit = ((lane & 3) ^ ((lane >> 3) & 3)) << 3;
  const int rsw = ((g ^ ((lr >> 1) & 3)) << 3);

  long long arow[2];
  #pragma unroll
  for (int r = 0; r < 2; ++r) {
    int row = m0 + (w << 4) + (r << 6) + srow;
    if (GATHER) {
      int p = row > cnt_e - 1 ? cnt_e - 1 : row;
      arow[r] = (long long)elist[e * S_LEN + p] * lda;
    } else {
      arow[r] = (long long)e * sAe + (long long)row * lda;
    }
  }

  __shared__ short smem[24576];
  short* shA = smem;
  short* shB = smem + 12288;
  const f32x4 vzero = {0.f, 0.f, 0.f, 0.f};
  f32x4 acc[4][4];
  #pragma unroll
  for (int i = 0; i < 4; ++i)
    #pragma unroll
    for (int j = 0; j < 4; ++j) acc[i][j] = vzero;

  const int nt = K >> 5;
#define STAGE_M(bi, kk) do { \
    _Pragma("unroll") \
    for (int r = 0; r < 2; ++r) { \
      int rowb = (w << 4) + (r << 6); \
      gload16(A + arow[r] + (kk) + sunit, &shA[(bi) * 4096 + rowb * 32]); \
      gload16(Bb + (long long)(n0 + rowb + srow) * ldb + (kk) + sunit, &shB[(bi) * 4096 + rowb * 32]); \
    } } while (0)

  STAGE_M(0, 0);
  if (nt > 1) STAGE_M(1, 32);
  int cur = 0, i2 = 2;
  for (int t = 0; t < nt; ++t) {
    if (t + 1 < nt) wait_vm4(); else wait_vm0();
    __builtin_amdgcn_s_barrier();
    if (t + 2 < nt) STAGE_M(i2, (t + 2) << 5);
    short8_t af[4];
    #pragma unroll
    for (int mi = 0; mi < 4; ++mi)
      af[mi] = *reinterpret_cast<const short8_t*>(&shA[cur * 4096 + (wm + (mi << 4) + lr) * 32 + rsw]);
    __builtin_amdgcn_s_setprio(1);
    #pragma unroll
    for (int ni = 0; ni < 4; ++ni) {
      short8_t bfr = *reinterpret_cast<const short8_t*>(&shB[cur * 4096 + (wn + (ni << 4) + lr) * 32 + rsw]);
      #pragma unroll
      for (int mi = 0; mi < 4; ++mi)
        acc[mi][ni] = __builtin_amdgcn_mfma_f32_16x16x32_bf16(
            __builtin_bit_cast(bf16x8_t, af[mi]),
            __builtin_bit_cast(bf16x8_t, bfr),
            acc[mi][ni], 0, 0, 0);
    }
    __builtin_amdgcn_s_setprio(0);
    cur = (cur == 2) ? 0 : cur + 1;
    i2  = (i2 == 2) ? 0 : i2 + 1;
  }
#undef STAGE_M
  __syncthreads();
  #pragma unroll
  for (int ni = 0; ni < 4; ++ni)
    #pragma unroll
    for (int mi = 0; mi < 4; ++mi)
      #pragma unroll
      for (int r = 0; r < 4; ++r)
        smem[(wm + (mi << 4) + (g << 2) + r) * 136 + wn + (ni << 4) + lr] = f2b(acc[mi][ni][r]);
  __syncthreads();
  {
    int row = tid >> 1, half = (tid & 1) << 6;
    if (m0 + row < cnt_e) {
      if (SILU) {
        float scale = ewt[e * S_LEN + m0 + row];
        int ocol = (n0 >> 1) + (half >> 1);
        #pragma unroll
        for (int j = 0; j < 4; ++j) {
          short8_t v0 = *reinterpret_cast<const short8_t*>(&smem[row * 136 + half + (j << 4)]);
          short8_t v1 = *reinterpret_cast<const short8_t*>(&smem[row * 136 + half + (j << 4) + 8]);
          short8_t o;
          #pragma unroll
          for (int q = 0; q < 4; ++q) {
            float x = b2f(v0[2 * q]);
            o[q] = f2b((x / (1.0f + expf(-x))) * b2f(v0[2 * q + 1]) * scale);
            float y = b2f(v1[2 * q]);
            o[4 + q] = f2b((y / (1.0f + expf(-y))) * b2f(v1[2 * q + 1]) * scale);
          }
          *reinterpret_cast<short8_t*>(&Cb[(long long)(m0 + row) * ldc + ocol + (j << 3)]) = o;
        }
      } else {
        #pragma unroll
        for (int j = 0; j < 8; ++j) {
          int col = n0 + half + (j << 3);
          short8_t v = *reinterpret_cast<const short8_t*>(&smem[row * 136 + half + (j << 3)]);
          *reinterpret_cast<short8_t*>(&Cb[(long long)(m0 + row) * ldc + col]) = v;
        }
      }
    }
  }
}

// ---------------- flash attention (unchanged from round 9, verified) ----------------
__global__ void __launch_bounds__(256, 1)
flash_kernel(const short* __restrict__ qf, const short* __restrict__ kf,
             const short* __restrict__ vT, short* __restrict__ ao, float scale)
{
  __shared__ short smem[59392];
  const int tid = threadIdx.x;
  const int h = blockIdx.y;
  const int q0 = blockIdx.x << 7;
  const int w = tid >> 6, lane = tid & 63;
  const int lr = lane & 15, g = lane >> 4;
  const int rb = w << 5;
  const int srow = lane >> 2;
  const int sunit = ((lane & 3) ^ ((lane >> 3) & 3)) << 3;
  const int rsw = ((g ^ ((lr >> 1) & 3)) << 3);
  const short* qh = qf + (long long)h * S_LEN * DQK_;
  const short* kh = kf + (long long)h * S_LEN * DQK_;
  const short* vh = vT + (long long)h * 128 * S_LEN;

  #pragma unroll
  for (int i = 0; i < 12; ++i) {
    int c = tid + (i << 8);
    int row = c / 24, cc = c % 24;
    int dchunk = (cc & ~3) | ((cc & 3) ^ ((row >> 1) & 3));
    *reinterpret_cast<short8_t*>(&smem[row * 200 + (dchunk << 3)]) =
        *reinterpret_cast<const short8_t*>(qh + (long long)(q0 + row) * DQK_ + (cc << 3));
  }

  const f32x4 vzero = {0.f, 0.f, 0.f, 0.f};
  f32x4 oacc[2][8];
  #pragma unroll
  for (int mi = 0; mi < 2; ++mi)
    #pragma unroll
    for (int ni = 0; ni < 8; ++ni) oacc[mi][ni] = vzero;
  float mrow[2][4], lrow[2][4];
  #pragma unroll
  for (int mi = 0; mi < 2; ++mi)
    #pragma unroll
    for (int rr = 0; rr < 4; ++rr) { mrow[mi][rr] = -3e38f; lrow[mi][rr] = 0.f; }

  __syncthreads();

  for (int kt = 0; kt < 16; ++kt) {
    const short* kbase = kh + (long long)(kt << 7) * DQK_;
    f32x4 sacc[2][8];
    #pragma unroll
    for (int mi = 0; mi < 2; ++mi)
      #pragma unroll
      for (int ni = 0; ni < 8; ++ni) sacc[mi][ni] = vzero;
#define STAGE_K(bi, kk) do { \
    _Pragma("unroll") \
    for (int r = 0; r < 2; ++r) { \
      int rowb = (w << 4) + (r << 6); \
      gload16(kbase + (long long)(rowb + srow) * DQK_ + (kk) * 32 + sunit, \
              &smem[25600 + (bi) * 4096 + rowb * 32]); \
    } } while (0)
    STAGE_K(0, 0);
    for (int ks = 0; ks < 6; ++ks) {
      if (ks < 5) { STAGE_K((ks + 1) & 1, ks + 1); wait_vm2(); }
      else wait_vm0();
      __builtin_amdgcn_s_barrier();
      const int kb = 25600 + (ks & 1) * 4096;
      short8_t aq[2];
      #pragma unroll
      for (int mi = 0; mi < 2; ++mi)
        aq[mi] = *reinterpret_cast<const short8_t*>(
            &smem[(rb + (mi << 4) + lr) * 200 + ks * 32 + rsw]);
      __builtin_amdgcn_s_setprio(1);
      #pragma unroll
      for (int ni = 0; ni < 8; ++ni) {
        short8_t bk = *reinterpret_cast<const short8_t*>(&smem[kb + ((ni << 4) + lr) * 32 + rsw]);
        #pragma unroll
        for (int mi = 0; mi < 2; ++mi)
          sacc[mi][ni] = __builtin_amdgcn_mfma_f32_16x16x32_bf16(
              __builtin_bit_cast(bf16x8_t, aq[mi]),
              __builtin_bit_cast(bf16x8_t, bk),
              sacc[mi][ni], 0, 0, 0);
      }
      __builtin_amdgcn_s_setprio(0);
      __builtin_amdgcn_s_barrier();
    }
#undef STAGE_K
    #pragma unroll
    for (int mi = 0; mi < 2; ++mi) {
      #pragma unroll
      for (int rr = 0; rr < 4; ++rr) {
        float sv[8];
        float mx = -3e38f;
        #pragma unroll
        for (int ni = 0; ni < 8; ++ni) {
          sv[ni] = b2f(f2b(sacc[mi][ni][rr])) * scale;
          mx = fmaxf(mx, sv[ni]);
        }
        #pragma unroll
        for (int d = 1; d < 16; d <<= 1) mx = fmaxf(mx, __shfl_xor(mx, d, 64));
        float mnew = fmaxf(mrow[mi][rr], mx);
        float corr = expf(mrow[mi][rr] - mnew);
        float psum = 0.f;
        short pb[8];
        #pragma unroll
        for (int ni = 0; ni < 8; ++ni) {
          float p = expf(sv[ni] - mnew);
          pb[ni] = f2b(p);
          psum += p;
        }
        #pragma unroll
        for (int d = 1; d < 16; d <<= 1) psum += __shfl_xor(psum, d, 64);
        lrow[mi][rr] = lrow[mi][rr] * corr + psum;
        mrow[mi][rr] = mnew;
        int row = rb + (mi << 4) + (g << 2) + rr;
        int xr = (row >> 1) & 3;
        #pragma unroll
        for (int ni = 0; ni < 8; ++ni) {
          int cc = (ni << 4) + lr;
          int scc = (cc & ~31) | (((((cc >> 3) & 3) ^ xr)) << 3) | (cc & 7);
          smem[33792 + row * 136 + scc] = pb[ni];
        }
        #pragma unroll
        for (int ni = 0; ni < 8; ++ni) oacc[mi][ni][rr] *= corr;
      }
    }
    __syncthreads();
    const short* vbase = vh + (kt << 7);
#define STAGE_V(bi, kk) do { \
    _Pragma("unroll") \
    for (int r = 0; r < 2; ++r) { \
      int rowb = (w << 4) + (r << 6); \
      gload16(vbase + (long long)(rowb + srow) * S_LEN + (kk) * 32 + sunit, \
              &smem[51200 + (bi) * 4096 + rowb * 32]); \
    } } while (0)
    STAGE_V(0, 0);
    for (int ks = 0; ks < 4; ++ks) {
      if (ks < 3) { STAGE_V((ks + 1) & 1, ks + 1); wait_vm2(); }
      else wait_vm0();
      __builtin_amdgcn_s_barrier();
      const int vb = 51200 + (ks & 1) * 4096;
      short8_t ap[2];
      #pragma unroll
      for (int mi = 0; mi < 2; ++mi)
        ap[mi] = *reinterpret_cast<const short8_t*>(
            &smem[33792 + (rb + (mi << 4) + lr) * 136 + ks * 32 + rsw]);
      __builtin_amdgcn_s_setprio(1);
      #pragma unroll
      for (int ni = 0; ni < 8; ++ni) {
        short8_t bv = *reinterpret_cast<const short8_t*>(&smem[vb + ((ni << 4) + lr) * 32 + rsw]);
        #pragma unroll
        for (int mi = 0; mi < 2; ++mi)
          oacc[mi][ni] = __builtin_amdgcn_mfma_f32_16x16x32_bf16(
              __builtin_bit_cast(bf16x8_t, ap[mi]),
              __builtin_bit_cast(bf16x8_t, bv),
              oacc[mi][ni], 0, 0, 0);
      }
      __builtin_amdgcn_s_setprio(0);
      __builtin_amdgcn_s_barrier();
    }
#undef STAGE_V
  }
  __syncthreads();
  #pragma unroll
  for (int mi = 0; mi < 2; ++mi)
    #pragma unroll
    for (int ni = 0; ni < 8; ++ni)
      #pragma unroll
      for (int rr = 0; rr < 4; ++rr) {
        int row = rb + (mi << 4) + (g << 2) + rr;
        smem[33792 + row * 136 + (ni << 4) + lr] = f2b(oacc[mi][ni][rr] / lrow[mi][rr]);
      }
  __syncthreads();
  {
    int row = tid >> 1, half = (tid & 1) << 6;
    #pragma unroll
    for (int j = 0; j < 8; ++j) {
      short8_t v = *reinterpret_cast<const short8_t*>(&smem[33792 + row * 136 + half + (j << 3)]);
      *reinterpret_cast<short8_t*>(&ao[(long long)(q0 + row) * HDIM + (h << 7) + half + (j << 3)]) = v;
    }
  }
}

// ---------------- small kernels ----------------
__global__ void __launch_bounds__(64)
rope_tables_kernel(float* cosT, float* sinT) {
  int s = blockIdx.x, j = threadIdx.x;
  int i = j & 31;
  float inv = powf(10000.0f, -((float)(2 * i) / 64.0f));
  float ang = (float)s * inv;
  cosT[s * 64 + j] = cosf(ang);
  sinT[s * 64 + j] = sinf(ang);
}

__global__ void __launch_bounds__(256)
rmsnorm_bf16_kernel(const short* __restrict__ in, long long istride,
                    const short* __restrict__ w,
                    short* __restrict__ out, long long ostride, int D) {
  const short* x = in + (long long)blockIdx.x * istride;
  short* o = out + (long long)blockIdx.x * ostride;
  const int nc = D >> 3;
  float ss = 0.f;
  for (int c = threadIdx.x; c < nc; c += 256) {
    short8_t v = reinterpret_cast<const short8_t*>(x)[c];
    #pragma unroll
    for (int j = 0; j < 8; ++j) { float f = b2f(v[j]); ss += f * f; }
  }
  __shared__ float red[256];
  red[threadIdx.x] = ss; __syncthreads();
  for (int s2 = 128; s2 > 0; s2 >>= 1) {
    if (threadIdx.x < s2) red[threadIdx.x] += red[threadIdx.x + s2];
    __syncthreads();
  }
  float r = 1.0f / sqrtf(red[0] / (float)D + 1e-6f);
  for (int c = threadIdx.x; c < nc; c += 256) {
    short8_t v = reinterpret_cast<const short8_t*>(x)[c];
    short8_t wv = reinterpret_cast<const short8_t*>(w)[c];
    short8_t ov;
    #pragma unroll
    for (int j = 0; j < 8; ++j) ov[j] = f2b(b2f(wv[j]) * (b2f(v[j]) * r));
    reinterpret_cast<short8_t*>(o)[c] = ov;
  }
}

__global__ void __launch_bounds__(256)
build_qf_kernel(const short* q, const float* cosT, const float* sinT, short* qf) {
  int s = blockIdx.x;
  for (int idx = threadIdx.x; idx < NH_ * DQK_; idx += 256) {
    int h = idx / DQK_, d = idx - h * DQK_;
    const short* qr = q + (long long)s * QN_ + h * DQK_;
    float val;
    if (d < 128) val = b2f(qr[d]);
    else {
      int j = d - 128;
      float c = cosT[s * 64 + j], sn = sinT[s * 64 + j];
      float x0 = b2f(qr[128 + j]);
      float rot = (j < 32) ? -b2f(qr[128 + j + 32]) : b2f(qr[128 + j - 32]);
      val = x0 * c + rot * sn;
    }
    qf[(long long)h * S_LEN * DQK_ + (long long)s * DQK_ + d] = f2b(val);
  }
}

__global__ void __launch_bounds__(256)
build_kf_kernel(const short* kvup, const short* krope, long long kstride,
                const float* cosT, const float* sinT, short* kf) {
  int s = blockIdx.x;
  for (int idx = threadIdx.x; idx < NH_ * DQK_; idx += 256) {
    int h = idx / DQK_, d = idx - h * DQK_;
    float val;
    if (d < 128) val = b2f(kvup[(long long)s * KVUPN + h * 256 + d]);
    else {
      int j = d - 128;
      float c = cosT[s * 64 + j], sn = sinT[s * 64 + j];
      const short* kr = krope + (long long)s * kstride;
      float x0 = b2f(kr[j]);
      float rot = (j < 32) ? -b2f(kr[j + 32]) : b2f(kr[j - 32]);
      val = x0 * c + rot * sn;
    }
    kf[(long long)h * S_LEN * DQK_ + (long long)s * DQK_ + d] = f2b(val);
  }
}

__global__ void __launch_bounds__(256)
transpose_v_kernel(const short* kvup, short* vT) {
  int h = blockIdx.z;
  int r0 = blockIdx.y * 32, c0 = blockIdx.x * 32;
  int tx = threadIdx.x & 31, ty = threadIdx.x >> 5;
  __shared__ short tile[32][33];
  #pragma unroll
  for (int i = 0; i < 4; ++i)
    tile[ty + i * 8][tx] =
        kvup[(long long)(r0 + ty + i * 8) * KVUPN + h * 256 + 128 + c0 + tx];
  __syncthreads();
  short* d = vT + (long long)h * 128 * S_LEN;
  #pragma unroll
  for (int i = 0; i < 4; ++i)
    d[(long long)(c0 + ty + i * 8) * S_LEN + r0 + tx] = tile[tx][ty + i * 8];
}

__global__ void __launch_bounds__(256)
gate_kernel(const short* x2, const short* gw, int* cnt, int* elist, float* ewt, int* tok2slot) {
  int t = blockIdx.x;
  int e = threadIdx.x >> 5, j = threadIdx.x & 31;
  const short* x = x2 + (long long)t * HDIM;
  float acc = 0.f;
  for (int k = j; k < HDIM; k += 32) acc += b2f(x[k]) * b2f(gw[(long long)k * EXP_ + e]);
  __shared__ float red[8][32];
  red[e][j] = acc; __syncthreads();
  for (int s2 = 16; s2 > 0; s2 >>= 1) {
    if (j < s2) red[e][j] += red[e][j + s2];
    __syncthreads();
  }
  if (threadIdx.x == 0) {
    float l[8], p[8];
    float m = -1e30f;
    for (int q = 0; q < 8; ++q) { l[q] = b2f(f2b(red[q][0])); m = fmaxf(m, l[q]); }
    float sum = 0.f;
    for (int q = 0; q < 8; ++q) { p[q] = expf(l[q] - m); sum += p[q]; }
    int i0 = 0; for (int q = 1; q < 8; ++q) if (p[q] > p[i0]) i0 = q;
    int i1 = (i0 == 0) ? 1 : 0;
    for (int q = 0; q < 8; ++q) if (q != i0 && p[q] > p[i1]) i1 = q;
    float denom = p[i0] + p[i1];
    float w0 = b2f(f2b(p[i0] / denom));
    float w1 = b2f(f2b(p[i1] / denom));
    int pos0 = atomicAdd(&cnt[i0], 1);
    int pos1 = atomicAdd(&cnt[i1], 1);
    elist[i0 * S_LEN + pos0] = t;  ewt[i0 * S_LEN + pos0] = w0;
    elist[i1 * S_LEN + pos1] = t;  ewt[i1 * S_LEN + pos1] = w1;
    int4* slot = (int4*)tok2slot;
    slot[t] = make_int4(i0, pos0, i1, pos1);
  }
}

__global__ void __launch_bounds__(256)
moe_combine_kernel(short* h, const short* shared_out, const short* routed,
                   const int* tok2slot) {
  int t = blockIdx.x;
  const int4 sl = ((const int4*)tok2slot)[t];
  const short8_t* s0 = reinterpret_cast<const short8_t*>(shared_out + (long long)t * HDIM);
  const short8_t* s1 = reinterpret_cast<const short8_t*>(shared_out + ((long long)S_LEN + t) * HDIM);
  const short8_t* r0 = reinterpret_cast<const short8_t*>(
      routed + ((long long)sl.x * S_LEN + sl.y) * HDIM);
  const short8_t* r1 = reinterpret_cast<const short8_t*>(
      routed + ((long long)sl.z * S_LEN + sl.w) * HDIM);
  long long c = (long long)t * 256 + threadIdx.x;
  short8_t hv = reinterpret_cast<short8_t*>(h)[c];
  short8_t a0 = s0[threadIdx.x], a1 = s1[threadIdx.x];
  short8_t v0 = r0[threadIdx.x], v1 = r1[threadIdx.x];
  short8_t ov;
  #pragma unroll
  for (int j = 0; j < 8; ++j)
    ov[j] = f2b(b2f(hv[j]) + (b2f(a0[j]) + b2f(a1[j]) + b2f(v0[j]) + b2f(v1[j])));
  reinterpret_cast<short8_t*>(h)[c] = ov;
}

// ---------------- pooling ----------------
template<int AF32, int OUTBF16>
__global__ void __launch_bounds__(256)
gemv_bt_kernel(const void* a, const short* __restrict__ BT, void* out, int K) {
  int n = blockIdx.x;
  const short8_t* row = reinterpret_cast<const short8_t*>(BT + (long long)n * K);
  float acc = 0.f;
  for (int c = threadIdx.x; c < (K >> 3); c += 256) {
    short8_t v = row[c];
    if (AF32) {
      f32x4 a0 = reinterpret_cast<const f32x4*>(a)[2 * c];
      f32x4 a1 = reinterpret_cast<const f32x4*>(a)[2 * c + 1];
      #pragma unroll
      for (int j = 0; j < 4; ++j) {
        acc += a0[j] * b2f(v[j]);
        acc += a1[j] * b2f(v[4 + j]);
      }
    } else {
      short8_t av = reinterpret_cast<const short8_t*>(a)[c];
      #pragma unroll
      for (int j = 0; j < 8; ++j) acc += b2f(av[j]) * b2f(v[j]);
    }
  }
  __shared__ float red[256];
  red[threadIdx.x] = acc; __syncthreads();
  for (int s2 = 128; s2 > 0; s2 >>= 1) {
    if (threadIdx.x < s2) red[threadIdx.x] += red[threadIdx.x + s2];
    __syncthreads();
  }
  if (threadIdx.x == 0) {
    if (OUTBF16) ((short*)out)[n] = f2b(red[0]);
    else         ((float*)out)[n] = red[0];
  }
}

__global__ void __launch_bounds__(256)
pool_score_kernel(const short* qv, const short* kmat, float* score) {
  int s = blockIdx.x;
  const short8_t* kr = reinterpret_cast<const short8_t*>(kmat + (long long)s * HDIM);
  const short8_t* qr = reinterpret_cast<const short8_t*>(qv);
  short8_t kv8 = kr[threadIdx.x], qv8 = qr[threadIdx.x];
  float acc = 0.f;
  #pragma unroll
  for (int j = 0; j < 8; ++j) acc += b2f(qv8[j]) * b2f(kv8[j]);
  __shared__ float red[256];
  red[threadIdx.x] = acc; __syncthreads();
  for (int s2 = 128; s2 > 0; s2 >>= 1) {
    if (threadIdx.x < s2) red[threadIdx.x] += red[threadIdx.x + s2];
    __syncthreads();
  }
  if (threadIdx.x == 0) score[s] = b2f(f2b(red[0])) * 0.022097086912079608f;
}

__global__ void __launch_bounds__(256)
softmax_vec_kernel(float* v) {
  int tid = threadIdx.x;
  float f[8]; float m = -1e30f;
  #pragma unroll
  for (int i = 0; i < 8; ++i) { f[i] = v[i * 256 + tid]; m = fmaxf(m, f[i]); }
  __shared__ float red[256];
  red[tid] = m; __syncthreads();
  for (int s2 = 128; s2 > 0; s2 >>= 1) {
    if (tid < s2) red[tid] = fmaxf(red[tid], red[tid + s2]);
    __syncthreads();
  }
  m = red[0]; __syncthreads();
  float sum = 0.f;
  #pragma unroll
  for (int i = 0; i < 8; ++i) { f[i] = expf(f[i] - m); sum += f[i]; }
  red[tid] = sum; __syncthreads();
  for (int s2 = 128; s2 > 0; s2 >>= 1) {
    if (tid < s2) red[tid] += red[tid + s2];
    __syncthreads();
  }
  float inv = 1.0f / red[0];
  #pragma unroll
  for (int i = 0; i < 8; ++i) v[i * 256 + tid] = f[i] * inv;
}

__global__ void __launch_bounds__(256)
pool_wsum_t_kernel(const float* w, const short* vT, float* pooled) {
  int h = blockIdx.x;
  const short8_t* row = reinterpret_cast<const short8_t*>(vT + (long long)h * S_LEN);
  int c = threadIdx.x;
  short8_t v = row[c];
  f32x4 w0 = reinterpret_cast<const f32x4*>(w)[2 * c];
  f32x4 w1 = reinterpret_cast<const f32x4*>(w)[2 * c + 1];
  float acc = 0.f;
  #pragma unroll
  for (int j = 0; j < 4; ++j) {
    acc += w0[j] * b2f(v[j]);
    acc += w1[j] * b2f(v[4 + j]);
  }
  __shared__ float red[256];
  red[threadIdx.x] = acc; __syncthreads();
  for (int s2 = 128; s2 > 0; s2 >>= 1) {
    if (threadIdx.x < s2) red[threadIdx.x] += red[threadIdx.x + s2];
    __syncthreads();
  }
  if (threadIdx.x == 0) pooled[h] = red[0];
}

__global__ void __launch_bounds__(256)
rmsnorm_f32_kernel(const float* x, const short* w, float* out) {
  int tid = threadIdx.x;
  float f[8]; float ss = 0.f;
  #pragma unroll
  for (int i = 0; i < 8; ++i) { f[i] = x[i * 256 + tid]; ss += f[i] * f[i]; }
  __shared__ float red[256];
  red[tid] = ss; __syncthreads();
  for (int s2 = 128; s2 > 0; s2 >>= 1) {
    if (tid < s2) red[tid] += red[tid + s2];
    __syncthreads();
  }
  float r = 1.0f / sqrtf(red[0] / 2048.0f + 1e-6f);
  #pragma unroll
  for (int i = 0; i < 8; ++i) out[i * 256 + tid] = b2f(w[i * 256 + tid]) * (f[i] * r);
}

// ---------------- host ----------------
extern "C" void kernel_launch(void* const* d_in, const int* in_sizes, int n_in,
                              void* d_out, int out_size, void* d_ws, size_t ws_size,
                              hipStream_t stream)
{
  (void)n_in; (void)out_size; (void)ws_size;
  const int* ids = (const int*)d_in[24];

  char* base = (char*)d_ws;
  size_t off = 0;
  auto alloc = [&](size_t bytes) -> void* {
    void* p = base + off;
    off += (bytes + 255) & ~(size_t)255;
    return p;
  };

  int* dflag = (int*)alloc(256);

  short* qkvdwT = (short*)alloc((size_t)2 * DCAT * HDIM * 2);
  short* quwT  = (short*)alloc((size_t)2 * QN_ * QRANK_ * 2);
  short* kvuwT = (short*)alloc((size_t)2 * KVUPN * KVRANK_ * 2);
  short* opwT  = (short*)alloc((size_t)2 * HDIM * HDIM * 2);
  short* rw13T = (short*)alloc((size_t)16 * IFF2 * HDIM * 2);  // interleaved w1|w3
  short* rw2T  = (short*)alloc((size_t)16 * HDIM * IFF_ * 2);
  short* sw13T = (short*)alloc((size_t)4 * IFF2 * HDIM * 2);
  short* sw2T  = (short*)alloc((size_t)4 * HDIM * IFF_ * 2);
  short* pqwT  = (short*)alloc((size_t)HDIM * HDIM * 2);
  short* pkwT  = (short*)alloc((size_t)HDIM * HDIM * 2);
  short* pvwT  = (short*)alloc((size_t)HDIM * HDIM * 2);
  short* powT  = (short*)alloc((size_t)PD_ * HDIM * 2);
  short* ln1w = (short*)alloc((size_t)in_sizes[1] * 2);
  short* qnw  = (short*)alloc((size_t)in_sizes[3] * 2);
  short* kvnw = (short*)alloc((size_t)in_sizes[6] * 2);
  short* ln2w = (short*)alloc((size_t)in_sizes[9] * 2);
  short* gatw = (short*)alloc((size_t)in_sizes[10] * 2);
  short* fnww = (short*)alloc((size_t)in_sizes[17] * 2);
  short* lqw  = (short*)alloc((size_t)in_sizes[18] * 2);
  short* pnww = (short*)alloc((size_t)in_sizes[23] * 2);

  float* cosT    = (float*)alloc((size_t)S_LEN * 64 * 4);
  float* sinT    = (float*)alloc((size_t)S_LEN * 64 * 4);
  short* hbuf    = (short*)alloc((size_t)S_LEN * HDIM * 2);
  short* xbuf    = (short*)alloc((size_t)S_LEN * HDIM * 2);
  short* dcat    = (short*)alloc((size_t)S_LEN * DCAT * 2);
  short* qlatn   = (short*)alloc((size_t)S_LEN * QRANK_ * 2);
  short* qbuf    = (short*)alloc((size_t)S_LEN * QN_ * 2);
  short* kvn     = (short*)alloc((size_t)S_LEN * KVRANK_ * 2);
  short* kvup    = (short*)alloc((size_t)S_LEN * KVUPN * 2);
  short* qf      = (short*)alloc((size_t)NH_ * S_LEN * DQK_ * 2);
  short* kf      = (short*)alloc((size_t)NH_ * S_LEN * DQK_ * 2);
  short* vT      = (short*)alloc((size_t)NH_ * 128 * S_LEN * 2);
  short* ao      = (short*)alloc((size_t)S_LEN * HDIM * 2);
  short* hfin    = (short*)alloc((size_t)S_LEN * HDIM * 2);
  short* kpool   = (short*)alloc((size_t)S_LEN * HDIM * 2);
  short* vpoolT  = (short*)alloc((size_t)HDIM * S_LEN * 2);
  short* qvec    = (short*)alloc((size_t)HDIM * 2);
  float* pscore  = (float*)alloc((size_t)S_LEN * 4);
  float* pooled  = (float*)alloc((size_t)HDIM * 4);
  float* pooledn = (float*)alloc((size_t)HDIM * 4);
  int*   ecnt    = (int*)alloc(64);
  int*   elist   = (int*)alloc((size_t)EXP_ * S_LEN * 4);
  float* ewt     = (float*)alloc((size_t)EXP_ * S_LEN * 4);
  int*   tok2slot= (int*)alloc((size_t)S_LEN * 16);
  short* gba_e   = (short*)alloc((size_t)EXP_ * S_LEN * IFF_ * 2);
  short* routed  = (short*)alloc((size_t)EXP_ * S_LEN * HDIM * 2);
  short* gsh1    = (short*)alloc((size_t)2 * S_LEN * IFF_ * 2);
  short* shared_out = (short*)alloc((size_t)2 * S_LEN * HDIM * 2);

  detect_kernel<<<1, 256, 0, stream>>>(d_in[0], dflag);

  auto tconv = [&](const void* src, short* dst, int R, int C, int nslabs,
                   long long sSrc, long long sDst, int rowMul, int rowOff) {
    dim3 grid(C / 32, R / 32, nslabs);
    transconv_kernel<<<grid, 256, 0, stream>>>(src, dst, R, C, dflag, sSrc, sDst, rowMul, rowOff);
  };
  auto pconv = [&](const void* src, short* dst, long long n) {
    long long nchunks = n / 8;
    int blocks = (int)((nchunks + 255) / 256);
    if (blocks > 2048) blocks = 2048;
    if (blocks < 1) blocks = 1;
    convert_kernel<<<blocks, 256, 0, stream>>>(src, dst, nchunks, dflag);
  };

  tconv(d_in[2], qkvdwT, HDIM, QRANK_, 2,
        (long long)HDIM * QRANK_, (long long)DCAT * HDIM, 1, 0);
  tconv(d_in[5], qkvdwT + (size_t)QRANK_ * HDIM, HDIM, KVDN, 2,
        (long long)HDIM * KVDN, (long long)DCAT * HDIM, 1, 0);
  tconv(d_in[4],  quwT,  QRANK_, QN_,  2, (long long)QRANK_ * QN_,  (long long)QN_ * QRANK_, 1, 0);
  tconv(d_in[7],  kvuwT, KVRANK_,KVUPN,2, (long long)KVRANK_ * KVUPN,(long long)KVUPN * KVRANK_, 1, 0);
  tconv(d_in[8],  opwT,  HDIM,   HDIM, 2, (long long)HDIM * HDIM,   (long long)HDIM * HDIM, 1, 0);
  tconv(d_in[11], rw13T, HDIM,   IFF_, 16,(long long)HDIM * IFF_,   (long long)IFF2 * HDIM, 2, 0);
  tconv(d_in[13], rw13T, HDIM,   IFF_, 16,(long long)HDIM * IFF_,   (long long)IFF2 * HDIM, 2, 1);
  tconv(d_in[12], rw2T,  IFF_,   HDIM, 16,(long long)IFF_ * HDIM,   (long long)HDIM * IFF_, 1, 0);
  tconv(d_in[14], sw13T, HDIM,   IFF_, 4, (long long)HDIM * IFF_,   (long long)IFF2 * HDIM, 2, 0);
  tconv(d_in[16], sw13T, HDIM,   IFF_, 4, (long long)HDIM * IFF_,   (long long)IFF2 * HDIM, 2, 1);
  tconv(d_in[15], sw2T,  IFF_,   HDIM, 4, (long long)IFF_ * HDIM,   (long long)HDIM * IFF_, 1, 0);
  tconv(d_in[19], pqwT,  HDIM,   HDIM, 1, 0, 0, 1, 0);
  tconv(d_in[20], pkwT,  HDIM,   HDIM, 1, 0, 0, 1, 0);
  tconv(d_in[21], pvwT,  HDIM,   HDIM, 1, 0, 0, 1, 0);
  tconv(d_in[22], powT,  HDIM,   PD_,  1, 0, 0, 1, 0);
  pconv(d_in[1],  ln1w, in_sizes[1]);
  pconv(d_in[3],  qnw,  in_sizes[3]);
  pconv(d_in[6],  kvnw, in_sizes[6]);
  pconv(d_in[9],  ln2w, in_sizes[9]);
  pconv(d_in[10], gatw, in_sizes[10]);
  pconv(d_in[17], fnww, in_sizes[17]);
  pconv(d_in[18], lqw,  in_sizes[18]);
  pconv(d_in[23], pnww, in_sizes[23]);

  const float qk_scale = 1.0f / sqrtf((float)DQK_);

  auto gemm = [&](int epi, const short* A, const short* B, short* C,
                  int M, int N, int K, int lda, int ldb, int ldc,
                  int batch, long long sA, long long sB, long long sC) {
    dim3 grid(M / 128, (N + 127) / 128, batch);
    if (epi == 0)
      gemm_kernel<0><<<grid, 256, 0, stream>>>(A, B, C, M, N, K, lda, ldb, ldc, sA, sB, sC);
    else if (epi == 1)
      gemm_kernel<1><<<grid, 256, 0, stream>>>(A, B, C, M, N, K, lda, ldb, ldc, sA, sB, sC);
    else
      gemm_kernel<2><<<grid, 256, 0, stream>>>(A, B, C, M, N, K, lda, ldb, ldc, sA, sB, sC);
  };

  rope_tables_kernel<<<S_LEN, 64, 0, stream>>>(cosT, sinT);
  embed_convert_kernel<<<S_LEN, 256, 0, stream>>>(ids, d_in[0], dflag, hbuf);

  for (int l = 0; l < 2; ++l) {
    const short* w_ln1  = ln1w + (size_t)l * HDIM;
    const short* w_qkvT = qkvdwT + (size_t)l * DCAT * HDIM;
    const short* w_qn   = qnw  + (size_t)l * QRANK_;
    const short* w_quT  = quwT + (size_t)l * QN_ * QRANK_;
    const short* w_kvn  = kvnw + (size_t)l * KVRANK_;
    const short* w_kvuT = kvuwT+ (size_t)l * KVUPN * KVRANK_;
    const short* w_opT  = opwT + (size_t)l * HDIM * HDIM;
    const short* w_ln2  = ln2w + (size_t)l * HDIM;
    const short* w_gat  = gatw + (size_t)l * HDIM * EXP_;

    // --- attention ---
    rmsnorm_bf16_kernel<<<S_LEN, 256, 0, stream>>>(hbuf, HDIM, w_ln1, xbuf, HDIM, HDIM);
    gemm(0, xbuf, w_qkvT, dcat, S_LEN, DCAT, HDIM, HDIM, HDIM, DCAT, 1, 0, 0, 0);
    rmsnorm_bf16_kernel<<<S_LEN, 256, 0, stream>>>(dcat, DCAT, w_qn, qlatn, QRANK_, QRANK_);
    gemm(0, qlatn, w_quT, qbuf, S_LEN, QN_, QRANK_, QRANK_, QRANK_, QN_, 1, 0, 0, 0);
    rmsnorm_bf16_kernel<<<S_LEN, 256, 0, stream>>>(dcat + QRANK_, DCAT, w_kvn, kvn, KVRANK_, KVRANK_);
    gemm(0, kvn, w_kvuT, kvup, S_LEN, KVUPN, KVRANK_, KVRANK_, KVRANK_, KVUPN, 1, 0, 0, 0);
    build_qf_kernel<<<S_LEN, 256, 0, stream>>>(qbuf, cosT, sinT, qf);
    build_kf_kernel<<<S_LEN, 256, 0, stream>>>(kvup, dcat + QRANK_ + KVRANK_, DCAT, cosT, sinT, kf);
    {
      dim3 tg(128 / 32, S_LEN / 32, NH_);
      transpose_v_kernel<<<tg, 256, 0, stream>>>(kvup, vT);
    }
    {
      dim3 fg(S_LEN / 128, NH_);
      flash_kernel<<<fg, 256, 0, stream>>>(qf, kf, vT, ao, qk_scale);
    }
    gemm(2, ao, w_opT, hbuf, S_LEN, HDIM, HDIM, HDIM, HDIM, HDIM, 1, 0, 0, 0);  // fused residual

    // --- MoE ---
    rmsnorm_bf16_kernel<<<S_LEN, 256, 0, stream>>>(hbuf, HDIM, w_ln2, xbuf, HDIM, HDIM);
    hipMemsetAsync(ecnt, 0, 64, stream);
    gate_kernel<<<S_LEN, 256, 0, stream>>>(xbuf, w_gat, ecnt, elist, ewt, tok2slot);
    // shared experts: fused w1|w3 + silu, then w2
    {
      const short* a13 = sw13T + (size_t)l * 2 * IFF2 * HDIM;
      const short* a2  = sw2T  + (size_t)l * 2 * HDIM * IFF_;
      gemm(1, xbuf, a13, gsh1, S_LEN, IFF2, HDIM, HDIM, HDIM, IFF_, 2,
           0, (long long)IFF2 * HDIM, (long long)S_LEN * IFF_);
      gemm(0, gsh1, a2, shared_out, S_LEN, HDIM, IFF_, IFF_, IFF_, HDIM, 2,
           (long long)S_LEN * IFF_, (long long)HDIM * IFF_, (long long)S_LEN * HDIM);
    }
    // routed experts: fused gather w1|w3 + silu*ewt, then w2, then combine
    {
      const short* b13 = rw13T + (size_t)l * 8 * IFF2 * HDIM;
      const short* b2  = rw2T  + (size_t)l * 8 * HDIM * IFF_;
      dim3 g13(S_LEN / 128, IFF2 / 128, EXP_);
      moe_gemm_kernel<1, 1><<<g13, 256, 0, stream>>>(
          xbuf, elist, ecnt, b13, gba_e, ewt, IFF2, HDIM, HDIM, HDIM, IFF_,
          0, (long long)IFF2 * HDIM, (long long)S_LEN * IFF_);
      dim3 g2(S_LEN / 128, HDIM / 128, EXP_);
      moe_gemm_kernel<0, 0><<<g2, 256, 0, stream>>>(
          gba_e, elist, ecnt, b2, routed, nullptr, HDIM, IFF_, IFF_, IFF_, HDIM,
          (long long)S_LEN * IFF_, (long long)HDIM * IFF_, (long long)S_LEN * HDIM);
      moe_combine_kernel<<<S_LEN, 256, 0, stream>>>(hbuf, shared_out, routed, tok2slot);
    }
  }

  // --- attention pooling head ---
  rmsnorm_bf16_kernel<<<S_LEN, 256, 0, stream>>>(hbuf, HDIM, fnww, hfin, HDIM, HDIM);
  gemm(0, hfin, pkwT, kpool, S_LEN, HDIM, HDIM, HDIM, HDIM, HDIM, 1, 0, 0, 0);
  gemm(0, pvwT, hfin, vpoolT, HDIM, S_LEN, HDIM, HDIM, HDIM, S_LEN, 1, 0, 0, 0);
  gemv_bt_kernel<0,1><<<HDIM, 256, 0, stream>>>(lqw, pqwT, qvec, HDIM);
  pool_score_kernel<<<S_LEN, 256, 0, stream>>>(qvec, kpool, pscore);
  softmax_vec_kernel<<<1, 256, 0, stream>>>(pscore);
  pool_wsum_t_kernel<<<HDIM, 256, 0, stream>>>(pscore, vpoolT, pooled);
  rmsnorm_f32_kernel<<<1, 256, 0, stream>>>(pooled, pnww, pooledn);
  gemv_bt_kernel<1,0><<<PD_, 256, 0, stream>>>(pooledn, powT, (float*)d_out, HDIM);
}

// Round 11
// 1710.464 us; speedup vs baseline: 6.9140x; 1.2015x over previous
//
#include <hip/hip_runtime.h>
#include <hip/hip_bf16.h>

#define S_LEN  2048
#define HDIM   2048
#define NH_    16
#define DQK_   192
#define QRANK_ 1024
#define KVRANK_ 512
#define KVDN   576
#define DCAT   1600   // QRANK + KVDN merged down-proj width
#define KVUPN  4096
#define QN_    3072
#define IFF_   1408
#define IFF2   2816   // interleaved w1|w3 width
#define EXP_   8
#define PD_    4096

typedef __attribute__((ext_vector_type(8))) short   short8_t;
typedef __attribute__((ext_vector_type(8))) __bf16  bf16x8_t;
typedef __attribute__((ext_vector_type(4))) float   f32x4;

static __device__ __forceinline__ float b2f(short s) {
  unsigned int u = ((unsigned int)(unsigned short)s) << 16;
  return __builtin_bit_cast(float, u);
}
static __device__ __forceinline__ short f2b(float f) {
  return __builtin_bit_cast(short, __float2bfloat16(f));
}

static __device__ __forceinline__ void gload16(const void* g, void* l) {
  __builtin_amdgcn_global_load_lds(
      (const __attribute__((address_space(1))) void*)g,
      (__attribute__((address_space(3))) void*)l,
      16, 0, 0);
}
static __device__ __forceinline__ void wait_vm4() { asm volatile("s_waitcnt vmcnt(4)" ::: "memory"); }
static __device__ __forceinline__ void wait_vm2() { asm volatile("s_waitcnt vmcnt(2)" ::: "memory"); }
static __device__ __forceinline__ void wait_vm0() { asm volatile("s_waitcnt vmcnt(0)" ::: "memory"); }

// ---------------- dtype detect + convert ----------------
__global__ void __launch_bounds__(256)
detect_kernel(const void* probe, int* flag) {
  const float* f = (const float*)probe;
  int tid = threadIdx.x;
  int cnt = 0;
  for (int i = tid; i < 2048; i += 256) {
    float v = fabsf(f[i]);
    if (v > 1e-6f && v < 10.0f) cnt++;
  }
  __shared__ int red[256];
  red[tid] = cnt; __syncthreads();
  for (int s = 128; s > 0; s >>= 1) {
    if (tid < s) red[tid] += red[tid + s];
    __syncthreads();
  }
  if (tid == 0) *flag = (red[0] > 1600) ? 1 : 0;
}

__global__ void __launch_bounds__(256)
convert_kernel(const void* src, short* dst, long long nchunks, const int* flag) {
  long long idx = (long long)blockIdx.x * 256 + threadIdx.x;
  long long stride = (long long)gridDim.x * 256;
  if (*flag) {
    const f32x4* s = (const f32x4*)src;
    for (long long c = idx; c < nchunks; c += stride) {
      f32x4 a = s[2 * c], b = s[2 * c + 1];
      short8_t o;
      #pragma unroll
      for (int j = 0; j < 4; ++j) { o[j] = f2b(a[j]); o[4 + j] = f2b(b[j]); }
      reinterpret_cast<short8_t*>(dst)[c] = o;
    }
  } else {
    const short8_t* s = (const short8_t*)src;
    for (long long c = idx; c < nchunks; c += stride)
      reinterpret_cast<short8_t*>(dst)[c] = s[c];
  }
}

// transpose-convert: src slab [R][C] -> dst rows (c*rowMul+rowOff) stride R, bf16
__global__ void __launch_bounds__(256)
transconv_kernel(const void* src, short* dst, int R, int C, const int* flag,
                 long long sSrc, long long sDst, int rowMul, int rowOff) {
  long long zs = (long long)blockIdx.z * sSrc;
  long long zd = (long long)blockIdx.z * sDst;
  int r0 = blockIdx.y * 32, c0 = blockIdx.x * 32;
  int tx = threadIdx.x & 31, ty = threadIdx.x >> 5;
  __shared__ short tile[32][33];
  if (*flag) {
    const float* s = (const float*)src + zs;
    #pragma unroll
    for (int i = 0; i < 4; ++i)
      tile[ty + i * 8][tx] = f2b(s[(long long)(r0 + ty + i * 8) * C + c0 + tx]);
  } else {
    const short* s = (const short*)src + zs;
    #pragma unroll
    for (int i = 0; i < 4; ++i)
      tile[ty + i * 8][tx] = s[(long long)(r0 + ty + i * 8) * C + c0 + tx];
  }
  __syncthreads();
  short* d = dst + zd;
  #pragma unroll
  for (int i = 0; i < 4; ++i)
    d[(long long)((c0 + ty + i * 8) * rowMul + rowOff) * R + r0 + tx] = tile[tx][ty + i * 8];
}

__global__ void __launch_bounds__(256)
embed_convert_kernel(const int* ids, const void* emb, const int* flag, short* h) {
  int s = blockIdx.x;
  long long row = ids[s];
  int c = threadIdx.x;
  short8_t o;
  if (*flag) {
    const f32x4* src = (const f32x4*)((const float*)emb + row * HDIM);
    f32x4 a = src[2 * c], b = src[2 * c + 1];
    #pragma unroll
    for (int j = 0; j < 4; ++j) { o[j] = f2b(a[j]); o[4 + j] = f2b(b[j]); }
  } else {
    o = reinterpret_cast<const short8_t*>((const short*)emb + row * HDIM)[c];
  }
  reinterpret_cast<short8_t*>(h + (long long)s * HDIM)[c] = o;
}

// ---------------- pipelined MFMA GEMM (B always [N][K], bf16 C) ----------------
// EPI=0: plain bf16 store. EPI=1: fused SiLU-pair (even=gate, odd=up), writes N/2 cols.
// EPI=2: in-place residual add.
template<int EPI>
__global__ void __launch_bounds__(256)
gemm_kernel(const short* __restrict__ A, const short* __restrict__ B,
            short* __restrict__ Cv, int M, int N, int K,
            int lda, int ldb, int ldc,
            long long sAb, long long sBb, long long sCb)
{
  __shared__ short smem[24576];
  short* shA = smem;
  short* shB = smem + 12288;
  const int tid = threadIdx.x;
  const long long bz = blockIdx.z;
  const short* Ab = A + bz * sAb;
  const short* Bb = B + bz * sBb;
  const int m0 = blockIdx.x * 128;
  const int n0 = blockIdx.y * 128;
  const int w = tid >> 6, lane = tid & 63;
  const int wm = (w >> 1) << 6, wn = (w & 1) << 6;
  const int lr = lane & 15, g = lane >> 4;
  const int srow = lane >> 2;
  const int sunit = ((lane & 3) ^ ((lane >> 3) & 3)) << 3;
  const int rsw = ((g ^ ((lr >> 1) & 3)) << 3);
  const f32x4 vzero = {0.f, 0.f, 0.f, 0.f};
  f32x4 acc[4][4];
  #pragma unroll
  for (int i = 0; i < 4; ++i)
    #pragma unroll
    for (int j = 0; j < 4; ++j) acc[i][j] = vzero;

  const int nt = K >> 5;
#define STAGE_G(bi, kk) do { \
    _Pragma("unroll") \
    for (int r = 0; r < 2; ++r) { \
      int rowb = (w << 4) + (r << 6); \
      gload16(Ab + (long long)(m0 + rowb + srow) * lda + (kk) + sunit, &shA[(bi) * 4096 + rowb * 32]); \
      gload16(Bb + (long long)(n0 + rowb + srow) * ldb + (kk) + sunit, &shB[(bi) * 4096 + rowb * 32]); \
    } } while (0)

  STAGE_G(0, 0);
  if (nt > 1) STAGE_G(1, 32);
  int cur = 0, i2 = 2;
  for (int t = 0; t < nt; ++t) {
    if (t + 1 < nt) wait_vm4(); else wait_vm0();
    __builtin_amdgcn_s_barrier();
    if (t + 2 < nt) STAGE_G(i2, (t + 2) << 5);
    short8_t af[4];
    #pragma unroll
    for (int mi = 0; mi < 4; ++mi)
      af[mi] = *reinterpret_cast<const short8_t*>(&shA[cur * 4096 + (wm + (mi << 4) + lr) * 32 + rsw]);
    __builtin_amdgcn_s_setprio(1);
    #pragma unroll
    for (int ni = 0; ni < 4; ++ni) {
      short8_t bfr = *reinterpret_cast<const short8_t*>(&shB[cur * 4096 + (wn + (ni << 4) + lr) * 32 + rsw]);
      #pragma unroll
      for (int mi = 0; mi < 4; ++mi)
        acc[mi][ni] = __builtin_amdgcn_mfma_f32_16x16x32_bf16(
            __builtin_bit_cast(bf16x8_t, af[mi]),
            __builtin_bit_cast(bf16x8_t, bfr),
            acc[mi][ni], 0, 0, 0);
    }
    __builtin_amdgcn_s_setprio(0);
    cur = (cur == 2) ? 0 : cur + 1;
    i2  = (i2 == 2) ? 0 : i2 + 1;
  }
#undef STAGE_G
  __syncthreads();
  #pragma unroll
  for (int ni = 0; ni < 4; ++ni)
    #pragma unroll
    for (int mi = 0; mi < 4; ++mi)
      #pragma unroll
      for (int r = 0; r < 4; ++r)
        smem[(wm + (mi << 4) + (g << 2) + r) * 136 + wn + (ni << 4) + lr] = f2b(acc[mi][ni][r]);
  __syncthreads();
  {
    short* C = Cv + bz * sCb;
    int row = tid >> 1, half = (tid & 1) << 6;
    if (EPI == 1) {
      int ocol = (n0 >> 1) + (half >> 1);
      #pragma unroll
      for (int j = 0; j < 4; ++j) {
        short8_t v0 = *reinterpret_cast<const short8_t*>(&smem[row * 136 + half + (j << 4)]);
        short8_t v1 = *reinterpret_cast<const short8_t*>(&smem[row * 136 + half + (j << 4) + 8]);
        short8_t o;
        #pragma unroll
        for (int q = 0; q < 4; ++q) {
          float x = b2f(v0[2 * q]);
          o[q] = f2b((x / (1.0f + expf(-x))) * b2f(v0[2 * q + 1]));
          float y = b2f(v1[2 * q]);
          o[4 + q] = f2b((y / (1.0f + expf(-y))) * b2f(v1[2 * q + 1]));
        }
        *reinterpret_cast<short8_t*>(&C[(long long)(m0 + row) * ldc + ocol + (j << 3)]) = o;
      }
    } else {
      #pragma unroll
      for (int j = 0; j < 8; ++j) {
        int col = n0 + half + (j << 3);
        if (col + 8 <= N) {
          short8_t v = *reinterpret_cast<const short8_t*>(&smem[row * 136 + half + (j << 3)]);
          short* cp = &C[(long long)(m0 + row) * ldc + col];
          if (EPI == 2) {
            short8_t hv = *reinterpret_cast<const short8_t*>(cp);
            short8_t o;
            #pragma unroll
            for (int q = 0; q < 8; ++q) o[q] = f2b(b2f(hv[q]) + b2f(v[q]));
            *reinterpret_cast<short8_t*>(cp) = o;
          } else {
            *reinterpret_cast<short8_t*>(cp) = v;
          }
        }
      }
    }
  }
}

// ---------------- pipelined sparse MoE gather GEMM ----------------
// GRID: (n_tiles, m_tiles, experts) — m on Y so early-exit blocks spread across XCDs.
template<int GATHER, int SILU>
__global__ void __launch_bounds__(256)
moe_gemm_kernel(const short* __restrict__ A, const int* __restrict__ elist,
                const int* __restrict__ cnt, const short* __restrict__ B,
                short* __restrict__ C, const float* __restrict__ ewt,
                int N, int K, int lda, int ldb, int ldc,
                long long sAe, long long sBe, long long sCe)
{
  const int e = blockIdx.z;
  const int cnt_e = cnt[e];
  const int m0 = blockIdx.y << 7;
  if (m0 >= cnt_e) return;
  const short* Bb = B + (long long)e * sBe;
  short* Cb = C + (long long)e * sCe;
  const int n0 = blockIdx.x << 7;
  const int tid = threadIdx.x;
  const int w = tid >> 6, lane = tid & 63;
  const int wm = (w >> 1) << 6, wn = (w & 1) << 6;
  const int lr = lane & 15, g = lane >> 4;
  const int srow = lane >> 2;
  const int sunit = ((lane & 3) ^ ((lane >> 3) & 3)) << 3;
  const int rsw = ((g ^ ((lr >> 1) & 3)) << 3);

  long long arow[2];
  #pragma unroll
  for (int r = 0; r < 2; ++r) {
    int row = m0 + (w << 4) + (r << 6) + srow;
    if (GATHER) {
      int p = row > cnt_e - 1 ? cnt_e - 1 : row;
      arow[r] = (long long)elist[e * S_LEN + p] * lda;
    } else {
      arow[r] = (long long)e * sAe + (long long)row * lda;
    }
  }

  __shared__ short smem[24576];
  short* shA = smem;
  short* shB = smem + 12288;
  const f32x4 vzero = {0.f, 0.f, 0.f, 0.f};
  f32x4 acc[4][4];
  #pragma unroll
  for (int i = 0; i < 4; ++i)
    #pragma unroll
    for (int j = 0; j < 4; ++j) acc[i][j] = vzero;

  const int nt = K >> 5;
#define STAGE_M(bi, kk) do { \
    _Pragma("unroll") \
    for (int r = 0; r < 2; ++r) { \
      int rowb = (w << 4) + (r << 6); \
      gload16(A + arow[r] + (kk) + sunit, &shA[(bi) * 4096 + rowb * 32]); \
      gload16(Bb + (long long)(n0 + rowb + srow) * ldb + (kk) + sunit, &shB[(bi) * 4096 + rowb * 32]); \
    } } while (0)

  STAGE_M(0, 0);
  if (nt > 1) STAGE_M(1, 32);
  int cur = 0, i2 = 2;
  for (int t = 0; t < nt; ++t) {
    if (t + 1 < nt) wait_vm4(); else wait_vm0();
    __builtin_amdgcn_s_barrier();
    if (t + 2 < nt) STAGE_M(i2, (t + 2) << 5);
    short8_t af[4];
    #pragma unroll
    for (int mi = 0; mi < 4; ++mi)
      af[mi] = *reinterpret_cast<const short8_t*>(&shA[cur * 4096 + (wm + (mi << 4) + lr) * 32 + rsw]);
    __builtin_amdgcn_s_setprio(1);
    #pragma unroll
    for (int ni = 0; ni < 4; ++ni) {
      short8_t bfr = *reinterpret_cast<const short8_t*>(&shB[cur * 4096 + (wn + (ni << 4) + lr) * 32 + rsw]);
      #pragma unroll
      for (int mi = 0; mi < 4; ++mi)
        acc[mi][ni] = __builtin_amdgcn_mfma_f32_16x16x32_bf16(
            __builtin_bit_cast(bf16x8_t, af[mi]),
            __builtin_bit_cast(bf16x8_t, bfr),
            acc[mi][ni], 0, 0, 0);
    }
    __builtin_amdgcn_s_setprio(0);
    cur = (cur == 2) ? 0 : cur + 1;
    i2  = (i2 == 2) ? 0 : i2 + 1;
  }
#undef STAGE_M
  __syncthreads();
  #pragma unroll
  for (int ni = 0; ni < 4; ++ni)
    #pragma unroll
    for (int mi = 0; mi < 4; ++mi)
      #pragma unroll
      for (int r = 0; r < 4; ++r)
        smem[(wm + (mi << 4) + (g << 2) + r) * 136 + wn + (ni << 4) + lr] = f2b(acc[mi][ni][r]);
  __syncthreads();
  {
    int row = tid >> 1, half = (tid & 1) << 6;
    if (m0 + row < cnt_e) {
      if (SILU) {
        float scale = ewt[e * S_LEN + m0 + row];
        int ocol = (n0 >> 1) + (half >> 1);
        #pragma unroll
        for (int j = 0; j < 4; ++j) {
          short8_t v0 = *reinterpret_cast<const short8_t*>(&smem[row * 136 + half + (j << 4)]);
          short8_t v1 = *reinterpret_cast<const short8_t*>(&smem[row * 136 + half + (j << 4) + 8]);
          short8_t o;
          #pragma unroll
          for (int q = 0; q < 4; ++q) {
            float x = b2f(v0[2 * q]);
            o[q] = f2b((x / (1.0f + expf(-x))) * b2f(v0[2 * q + 1]) * scale);
            float y = b2f(v1[2 * q]);
            o[4 + q] = f2b((y / (1.0f + expf(-y))) * b2f(v1[2 * q + 1]) * scale);
          }
          *reinterpret_cast<short8_t*>(&Cb[(long long)(m0 + row) * ldc + ocol + (j << 3)]) = o;
        }
      } else {
        #pragma unroll
        for (int j = 0; j < 8; ++j) {
          int col = n0 + half + (j << 3);
          short8_t v = *reinterpret_cast<const short8_t*>(&smem[row * 136 + half + (j << 3)]);
          *reinterpret_cast<short8_t*>(&Cb[(long long)(m0 + row) * ldc + col]) = v;
        }
      }
    }
  }
}

// ---------------- flash attention ----------------
__global__ void __launch_bounds__(256, 1)
flash_kernel(const short* __restrict__ qf, const short* __restrict__ kf,
             const short* __restrict__ vT, short* __restrict__ ao, float scale)
{
  __shared__ short smem[59392];
  const int tid = threadIdx.x;
  const int h = blockIdx.y;
  const int q0 = blockIdx.x << 7;
  const int w = tid >> 6, lane = tid & 63;
  const int lr = lane & 15, g = lane >> 4;
  const int rb = w << 5;
  const int srow = lane >> 2;
  const int sunit = ((lane & 3) ^ ((lane >> 3) & 3)) << 3;
  const int rsw = ((g ^ ((lr >> 1) & 3)) << 3);
  const short* qh = qf + (long long)h * S_LEN * DQK_;
  const short* kh = kf + (long long)h * S_LEN * DQK_;
  const short* vh = vT + (long long)h * 128 * S_LEN;

  #pragma unroll
  for (int i = 0; i < 12; ++i) {
    int c = tid + (i << 8);
    int row = c / 24, cc = c % 24;
    int dchunk = (cc & ~3) | ((cc & 3) ^ ((row >> 1) & 3));
    *reinterpret_cast<short8_t*>(&smem[row * 200 + (dchunk << 3)]) =
        *reinterpret_cast<const short8_t*>(qh + (long long)(q0 + row) * DQK_ + (cc << 3));
  }

  const f32x4 vzero = {0.f, 0.f, 0.f, 0.f};
  f32x4 oacc[2][8];
  #pragma unroll
  for (int mi = 0; mi < 2; ++mi)
    #pragma unroll
    for (int ni = 0; ni < 8; ++ni) oacc[mi][ni] = vzero;
  float mrow[2][4], lrow[2][4];
  #pragma unroll
  for (int mi = 0; mi < 2; ++mi)
    #pragma unroll
    for (int rr = 0; rr < 4; ++rr) { mrow[mi][rr] = -3e38f; lrow[mi][rr] = 0.f; }

  __syncthreads();

  for (int kt = 0; kt < 16; ++kt) {
    const short* kbase = kh + (long long)(kt << 7) * DQK_;
    f32x4 sacc[2][8];
    #pragma unroll
    for (int mi = 0; mi < 2; ++mi)
      #pragma unroll
      for (int ni = 0; ni < 8; ++ni) sacc[mi][ni] = vzero;
#define STAGE_K(bi, kk) do { \
    _Pragma("unroll") \
    for (int r = 0; r < 2; ++r) { \
      int rowb = (w << 4) + (r << 6); \
      gload16(kbase + (long long)(rowb + srow) * DQK_ + (kk) * 32 + sunit, \
              &smem[25600 + (bi) * 4096 + rowb * 32]); \
    } } while (0)
    STAGE_K(0, 0);
    for (int ks = 0; ks < 6; ++ks) {
      if (ks < 5) { STAGE_K((ks + 1) & 1, ks + 1); wait_vm2(); }
      else wait_vm0();
      __builtin_amdgcn_s_barrier();
      const int kb = 25600 + (ks & 1) * 4096;
      short8_t aq[2];
      #pragma unroll
      for (int mi = 0; mi < 2; ++mi)
        aq[mi] = *reinterpret_cast<const short8_t*>(
            &smem[(rb + (mi << 4) + lr) * 200 + ks * 32 + rsw]);
      __builtin_amdgcn_s_setprio(1);
      #pragma unroll
      for (int ni = 0; ni < 8; ++ni) {
        short8_t bk = *reinterpret_cast<const short8_t*>(&smem[kb + ((ni << 4) + lr) * 32 + rsw]);
        #pragma unroll
        for (int mi = 0; mi < 2; ++mi)
          sacc[mi][ni] = __builtin_amdgcn_mfma_f32_16x16x32_bf16(
              __builtin_bit_cast(bf16x8_t, aq[mi]),
              __builtin_bit_cast(bf16x8_t, bk),
              sacc[mi][ni], 0, 0, 0);
      }
      __builtin_amdgcn_s_setprio(0);
      __builtin_amdgcn_s_barrier();
    }
#undef STAGE_K
    #pragma unroll
    for (int mi = 0; mi < 2; ++mi) {
      #pragma unroll
      for (int rr = 0; rr < 4; ++rr) {
        float sv[8];
        float mx = -3e38f;
        #pragma unroll
        for (int ni = 0; ni < 8; ++ni) {
          sv[ni] = b2f(f2b(sacc[mi][ni][rr])) * scale;
          mx = fmaxf(mx, sv[ni]);
        }
        #pragma unroll
        for (int d = 1; d < 16; d <<= 1) mx = fmaxf(mx, __shfl_xor(mx, d, 64));
        float mnew = fmaxf(mrow[mi][rr], mx);
        float corr = expf(mrow[mi][rr] - mnew);
        float psum = 0.f;
        short pb[8];
        #pragma unroll
        for (int ni = 0; ni < 8; ++ni) {
          float p = expf(sv[ni] - mnew);
          pb[ni] = f2b(p);
          psum += p;
        }
        #pragma unroll
        for (int d = 1; d < 16; d <<= 1) psum += __shfl_xor(psum, d, 64);
        lrow[mi][rr] = lrow[mi][rr] * corr + psum;
        mrow[mi][rr] = mnew;
        int row = rb + (mi << 4) + (g << 2) + rr;
        int xr = (row >> 1) & 3;
        #pragma unroll
        for (int ni = 0; ni < 8; ++ni) {
          int cc = (ni << 4) + lr;
          int scc = (cc & ~31) | (((((cc >> 3) & 3) ^ xr)) << 3) | (cc & 7);
          smem[33792 + row * 136 + scc] = pb[ni];
        }
        #pragma unroll
        for (int ni = 0; ni < 8; ++ni) oacc[mi][ni][rr] *= corr;
      }
    }
    __syncthreads();
    const short* vbase = vh + (kt << 7);
#define STAGE_V(bi, kk) do { \
    _Pragma("unroll") \
    for (int r = 0; r < 2; ++r) { \
      int rowb = (w << 4) + (r << 6); \
      gload16(vbase + (long long)(rowb + srow) * S_LEN + (kk) * 32 + sunit, \
              &smem[51200 + (bi) * 4096 + rowb * 32]); \
    } } while (0)
    STAGE_V(0, 0);
    for (int ks = 0; ks < 4; ++ks) {
      if (ks < 3) { STAGE_V((ks + 1) & 1, ks + 1); wait_vm2(); }
      else wait_vm0();
      __builtin_amdgcn_s_barrier();
      const int vb = 51200 + (ks & 1) * 4096;
      short8_t ap[2];
      #pragma unroll
      for (int mi = 0; mi < 2; ++mi)
        ap[mi] = *reinterpret_cast<const short8_t*>(
            &smem[33792 + (rb + (mi << 4) + lr) * 136 + ks * 32 + rsw]);
      __builtin_amdgcn_s_setprio(1);
      #pragma unroll
      for (int ni = 0; ni < 8; ++ni) {
        short8_t bv = *reinterpret_cast<const short8_t*>(&smem[vb + ((ni << 4) + lr) * 32 + rsw]);
        #pragma unroll
        for (int mi = 0; mi < 2; ++mi)
          oacc[mi][ni] = __builtin_amdgcn_mfma_f32_16x16x32_bf16(
              __builtin_bit_cast(bf16x8_t, ap[mi]),
              __builtin_bit_cast(bf16x8_t, bv),
              oacc[mi][ni], 0, 0, 0);
      }
      __builtin_amdgcn_s_setprio(0);
      __builtin_amdgcn_s_barrier();
    }
#undef STAGE_V
  }
  __syncthreads();
  #pragma unroll
  for (int mi = 0; mi < 2; ++mi)
    #pragma unroll
    for (int ni = 0; ni < 8; ++ni)
      #pragma unroll
      for (int rr = 0; rr < 4; ++rr) {
        int row = rb + (mi << 4) + (g << 2) + rr;
        smem[33792 + row * 136 + (ni << 4) + lr] = f2b(oacc[mi][ni][rr] / lrow[mi][rr]);
      }
  __syncthreads();
  {
    int row = tid >> 1, half = (tid & 1) << 6;
    #pragma unroll
    for (int j = 0; j < 8; ++j) {
      short8_t v = *reinterpret_cast<const short8_t*>(&smem[33792 + row * 136 + half + (j << 3)]);
      *reinterpret_cast<short8_t*>(&ao[(long long)(q0 + row) * HDIM + (h << 7) + half + (j << 3)]) = v;
    }
  }
}

// ---------------- small kernels ----------------
__global__ void __launch_bounds__(64)
rope_tables_kernel(float* cosT, float* sinT) {
  int s = blockIdx.x, j = threadIdx.x;
  int i = j & 31;
  float inv = powf(10000.0f, -((float)(2 * i) / 64.0f));
  float ang = (float)s * inv;
  cosT[s * 64 + j] = cosf(ang);
  sinT[s * 64 + j] = sinf(ang);
}

__global__ void __launch_bounds__(256)
rmsnorm_bf16_kernel(const short* __restrict__ in, long long istride,
                    const short* __restrict__ w,
                    short* __restrict__ out, long long ostride, int D) {
  const short* x = in + (long long)blockIdx.x * istride;
  short* o = out + (long long)blockIdx.x * ostride;
  const int nc = D >> 3;
  float ss = 0.f;
  for (int c = threadIdx.x; c < nc; c += 256) {
    short8_t v = reinterpret_cast<const short8_t*>(x)[c];
    #pragma unroll
    for (int j = 0; j < 8; ++j) { float f = b2f(v[j]); ss += f * f; }
  }
  __shared__ float red[256];
  red[threadIdx.x] = ss; __syncthreads();
  for (int s2 = 128; s2 > 0; s2 >>= 1) {
    if (threadIdx.x < s2) red[threadIdx.x] += red[threadIdx.x + s2];
    __syncthreads();
  }
  float r = 1.0f / sqrtf(red[0] / (float)D + 1e-6f);
  for (int c = threadIdx.x; c < nc; c += 256) {
    short8_t v = reinterpret_cast<const short8_t*>(x)[c];
    short8_t wv = reinterpret_cast<const short8_t*>(w)[c];
    short8_t ov;
    #pragma unroll
    for (int j = 0; j < 8; ++j) ov[j] = f2b(b2f(wv[j]) * (b2f(v[j]) * r));
    reinterpret_cast<short8_t*>(o)[c] = ov;
  }
}

__global__ void __launch_bounds__(256)
build_qf_kernel(const short* q, const float* cosT, const float* sinT, short* qf) {
  int s = blockIdx.x;
  for (int idx = threadIdx.x; idx < NH_ * DQK_; idx += 256) {
    int h = idx / DQK_, d = idx - h * DQK_;
    const short* qr = q + (long long)s * QN_ + h * DQK_;
    float val;
    if (d < 128) val = b2f(qr[d]);
    else {
      int j = d - 128;
      float c = cosT[s * 64 + j], sn = sinT[s * 64 + j];
      float x0 = b2f(qr[128 + j]);
      float rot = (j < 32) ? -b2f(qr[128 + j + 32]) : b2f(qr[128 + j - 32]);
      val = x0 * c + rot * sn;
    }
    qf[(long long)h * S_LEN * DQK_ + (long long)s * DQK_ + d] = f2b(val);
  }
}

__global__ void __launch_bounds__(256)
build_kf_kernel(const short* kvup, const short* krope, long long kstride,
                const float* cosT, const float* sinT, short* kf) {
  int s = blockIdx.x;
  for (int idx = threadIdx.x; idx < NH_ * DQK_; idx += 256) {
    int h = idx / DQK_, d = idx - h * DQK_;
    float val;
    if (d < 128) val = b2f(kvup[(long long)s * KVUPN + h * 256 + d]);
    else {
      int j = d - 128;
      float c = cosT[s * 64 + j], sn = sinT[s * 64 + j];
      const short* kr = krope + (long long)s * kstride;
      float x0 = b2f(kr[j]);
      float rot = (j < 32) ? -b2f(kr[j + 32]) : b2f(kr[j - 32]);
      val = x0 * c + rot * sn;
    }
    kf[(long long)h * S_LEN * DQK_ + (long long)s * DQK_ + d] = f2b(val);
  }
}

__global__ void __launch_bounds__(256)
transpose_v_kernel(const short* kvup, short* vT) {
  int h = blockIdx.z;
  int r0 = blockIdx.y * 32, c0 = blockIdx.x * 32;
  int tx = threadIdx.x & 31, ty = threadIdx.x >> 5;
  __shared__ short tile[32][33];
  #pragma unroll
  for (int i = 0; i < 4; ++i)
    tile[ty + i * 8][tx] =
        kvup[(long long)(r0 + ty + i * 8) * KVUPN + h * 256 + 128 + c0 + tx];
  __syncthreads();
  short* d = vT + (long long)h * 128 * S_LEN;
  #pragma unroll
  for (int i = 0; i < 4; ++i)
    d[(long long)(c0 + ty + i * 8) * S_LEN + r0 + tx] = tile[tx][ty + i * 8];
}

__global__ void __launch_bounds__(256)
gate_kernel(const short* x2, const short* gw, int* cnt, int* elist, float* ewt, int* tok2slot) {
  int t = blockIdx.x;
  int e = threadIdx.x >> 5, j = threadIdx.x & 31;
  const short* x = x2 + (long long)t * HDIM;
  float acc = 0.f;
  for (int k = j; k < HDIM; k += 32) acc += b2f(x[k]) * b2f(gw[(long long)k * EXP_ + e]);
  __shared__ float red[8][32];
  red[e][j] = acc; __syncthreads();
  for (int s2 = 16; s2 > 0; s2 >>= 1) {
    if (j < s2) red[e][j] += red[e][j + s2];
    __syncthreads();
  }
  if (threadIdx.x == 0) {
    float l[8], p[8];
    float m = -1e30f;
    for (int q = 0; q < 8; ++q) { l[q] = b2f(f2b(red[q][0])); m = fmaxf(m, l[q]); }
    float sum = 0.f;
    for (int q = 0; q < 8; ++q) { p[q] = expf(l[q] - m); sum += p[q]; }
    int i0 = 0; for (int q = 1; q < 8; ++q) if (p[q] > p[i0]) i0 = q;
    int i1 = (i0 == 0) ? 1 : 0;
    for (int q = 0; q < 8; ++q) if (q != i0 && p[q] > p[i1]) i1 = q;
    float denom = p[i0] + p[i1];
    float w0 = b2f(f2b(p[i0] / denom));
    float w1 = b2f(f2b(p[i1] / denom));
    int pos0 = atomicAdd(&cnt[i0], 1);
    int pos1 = atomicAdd(&cnt[i1], 1);
    elist[i0 * S_LEN + pos0] = t;  ewt[i0 * S_LEN + pos0] = w0;
    elist[i1 * S_LEN + pos1] = t;  ewt[i1 * S_LEN + pos1] = w1;
    int4* slot = (int4*)tok2slot;
    slot[t] = make_int4(i0, pos0, i1, pos1);
  }
}

__global__ void __launch_bounds__(256)
moe_combine_kernel(short* h, const short* shared_out, const short* routed,
                   const int* tok2slot) {
  int t = blockIdx.x;
  const int4 sl = ((const int4*)tok2slot)[t];
  const short8_t* s0 = reinterpret_cast<const short8_t*>(shared_out + (long long)t * HDIM);
  const short8_t* s1 = reinterpret_cast<const short8_t*>(shared_out + ((long long)S_LEN + t) * HDIM);
  const short8_t* r0 = reinterpret_cast<const short8_t*>(
      routed + ((long long)sl.x * S_LEN + sl.y) * HDIM);
  const short8_t* r1 = reinterpret_cast<const short8_t*>(
      routed + ((long long)sl.z * S_LEN + sl.w) * HDIM);
  long long c = (long long)t * 256 + threadIdx.x;
  short8_t hv = reinterpret_cast<short8_t*>(h)[c];
  short8_t a0 = s0[threadIdx.x], a1 = s1[threadIdx.x];
  short8_t v0 = r0[threadIdx.x], v1 = r1[threadIdx.x];
  short8_t ov;
  #pragma unroll
  for (int j = 0; j < 8; ++j)
    ov[j] = f2b(b2f(hv[j]) + (b2f(a0[j]) + b2f(a1[j]) + b2f(v0[j]) + b2f(v1[j])));
  reinterpret_cast<short8_t*>(h)[c] = ov;
}

// ---------------- pooling ----------------
template<int AF32, int OUTBF16>
__global__ void __launch_bounds__(256)
gemv_bt_kernel(const void* a, const short* __restrict__ BT, void* out, int K) {
  int n = blockIdx.x;
  const short8_t* row = reinterpret_cast<const short8_t*>(BT + (long long)n * K);
  float acc = 0.f;
  for (int c = threadIdx.x; c < (K >> 3); c += 256) {
    short8_t v = row[c];
    if (AF32) {
      f32x4 a0 = reinterpret_cast<const f32x4*>(a)[2 * c];
      f32x4 a1 = reinterpret_cast<const f32x4*>(a)[2 * c + 1];
      #pragma unroll
      for (int j = 0; j < 4; ++j) {
        acc += a0[j] * b2f(v[j]);
        acc += a1[j] * b2f(v[4 + j]);
      }
    } else {
      short8_t av = reinterpret_cast<const short8_t*>(a)[c];
      #pragma unroll
      for (int j = 0; j < 8; ++j) acc += b2f(av[j]) * b2f(v[j]);
    }
  }
  __shared__ float red[256];
  red[threadIdx.x] = acc; __syncthreads();
  for (int s2 = 128; s2 > 0; s2 >>= 1) {
    if (threadIdx.x < s2) red[threadIdx.x] += red[threadIdx.x + s2];
    __syncthreads();
  }
  if (threadIdx.x == 0) {
    if (OUTBF16) ((short*)out)[n] = f2b(red[0]);
    else         ((float*)out)[n] = red[0];
  }
}

__global__ void __launch_bounds__(256)
pool_score_kernel(const short* qv, const short* kmat, float* score) {
  int s = blockIdx.x;
  const short8_t* kr = reinterpret_cast<const short8_t*>(kmat + (long long)s * HDIM);
  const short8_t* qr = reinterpret_cast<const short8_t*>(qv);
  short8_t kv8 = kr[threadIdx.x], qv8 = qr[threadIdx.x];
  float acc = 0.f;
  #pragma unroll
  for (int j = 0; j < 8; ++j) acc += b2f(qv8[j]) * b2f(kv8[j]);
  __shared__ float red[256];
  red[threadIdx.x] = acc; __syncthreads();
  for (int s2 = 128; s2 > 0; s2 >>= 1) {
    if (threadIdx.x < s2) red[threadIdx.x] += red[threadIdx.x + s2];
    __syncthreads();
  }
  if (threadIdx.x == 0) score[s] = b2f(f2b(red[0])) * 0.022097086912079608f;
}

__global__ void __launch_bounds__(256)
softmax_vec_kernel(float* v) {
  int tid = threadIdx.x;
  float f[8]; float m = -1e30f;
  #pragma unroll
  for (int i = 0; i < 8; ++i) { f[i] = v[i * 256 + tid]; m = fmaxf(m, f[i]); }
  __shared__ float red[256];
  red[tid] = m; __syncthreads();
  for (int s2 = 128; s2 > 0; s2 >>= 1) {
    if (tid < s2) red[tid] = fmaxf(red[tid], red[tid + s2]);
    __syncthreads();
  }
  m = red[0]; __syncthreads();
  float sum = 0.f;
  #pragma unroll
  for (int i = 0; i < 8; ++i) { f[i] = expf(f[i] - m); sum += f[i]; }
  red[tid] = sum; __syncthreads();
  for (int s2 = 128; s2 > 0; s2 >>= 1) {
    if (tid < s2) red[tid] += red[tid + s2];
    __syncthreads();
  }
  float inv = 1.0f / red[0];
  #pragma unroll
  for (int i = 0; i < 8; ++i) v[i * 256 + tid] = f[i] * inv;
}

__global__ void __launch_bounds__(256)
pool_wsum_t_kernel(const float* w, const short* vT, float* pooled) {
  int h = blockIdx.x;
  const short8_t* row = reinterpret_cast<const short8_t*>(vT + (long long)h * S_LEN);
  int c = threadIdx.x;
  short8_t v = row[c];
  f32x4 w0 = reinterpret_cast<const f32x4*>(w)[2 * c];
  f32x4 w1 = reinterpret_cast<const f32x4*>(w)[2 * c + 1];
  float acc = 0.f;
  #pragma unroll
  for (int j = 0; j < 4; ++j) {
    acc += w0[j] * b2f(v[j]);
    acc += w1[j] * b2f(v[4 + j]);
  }
  __shared__ float red[256];
  red[threadIdx.x] = acc; __syncthreads();
  for (int s2 = 128; s2 > 0; s2 >>= 1) {
    if (threadIdx.x < s2) red[threadIdx.x] += red[threadIdx.x + s2];
    __syncthreads();
  }
  if (threadIdx.x == 0) pooled[h] = red[0];
}

__global__ void __launch_bounds__(256)
rmsnorm_f32_kernel(const float* x, const short* w, float* out) {
  int tid = threadIdx.x;
  float f[8]; float ss = 0.f;
  #pragma unroll
  for (int i = 0; i < 8; ++i) { f[i] = x[i * 256 + tid]; ss += f[i] * f[i]; }
  __shared__ float red[256];
  red[tid] = ss; __syncthreads();
  for (int s2 = 128; s2 > 0; s2 >>= 1) {
    if (tid < s2) red[tid] += red[tid + s2];
    __syncthreads();
  }
  float r = 1.0f / sqrtf(red[0] / 2048.0f + 1e-6f);
  #pragma unroll
  for (int i = 0; i < 8; ++i) out[i * 256 + tid] = b2f(w[i * 256 + tid]) * (f[i] * r);
}

// ---------------- host ----------------
extern "C" void kernel_launch(void* const* d_in, const int* in_sizes, int n_in,
                              void* d_out, int out_size, void* d_ws, size_t ws_size,
                              hipStream_t stream)
{
  (void)n_in; (void)out_size; (void)ws_size;
  const int* ids = (const int*)d_in[24];

  char* base = (char*)d_ws;
  size_t off = 0;
  auto alloc = [&](size_t bytes) -> void* {
    void* p = base + off;
    off += (bytes + 255) & ~(size_t)255;
    return p;
  };

  int* dflag = (int*)alloc(256);

  short* qkvdwT = (short*)alloc((size_t)2 * DCAT * HDIM * 2);
  short* quwT  = (short*)alloc((size_t)2 * QN_ * QRANK_ * 2);
  short* kvuwT = (short*)alloc((size_t)2 * KVUPN * KVRANK_ * 2);
  short* opwT  = (short*)alloc((size_t)2 * HDIM * HDIM * 2);
  short* rw13T = (short*)alloc((size_t)16 * IFF2 * HDIM * 2);
  short* rw2T  = (short*)alloc((size_t)16 * HDIM * IFF_ * 2);
  short* sw13T = (short*)alloc((size_t)4 * IFF2 * HDIM * 2);
  short* sw2T  = (short*)alloc((size_t)4 * HDIM * IFF_ * 2);
  short* pqwT  = (short*)alloc((size_t)HDIM * HDIM * 2);
  short* pkwT  = (short*)alloc((size_t)HDIM * HDIM * 2);
  short* pvwT  = (short*)alloc((size_t)HDIM * HDIM * 2);
  short* powT  = (short*)alloc((size_t)PD_ * HDIM * 2);
  short* ln1w = (short*)alloc((size_t)in_sizes[1] * 2);
  short* qnw  = (short*)alloc((size_t)in_sizes[3] * 2);
  short* kvnw = (short*)alloc((size_t)in_sizes[6] * 2);
  short* ln2w = (short*)alloc((size_t)in_sizes[9] * 2);
  short* gatw = (short*)alloc((size_t)in_sizes[10] * 2);
  short* fnww = (short*)alloc((size_t)in_sizes[17] * 2);
  short* lqw  = (short*)alloc((size_t)in_sizes[18] * 2);
  short* pnww = (short*)alloc((size_t)in_sizes[23] * 2);

  float* cosT    = (float*)alloc((size_t)S_LEN * 64 * 4);
  float* sinT    = (float*)alloc((size_t)S_LEN * 64 * 4);
  short* hbuf    = (short*)alloc((size_t)S_LEN * HDIM * 2);
  short* xbuf    = (short*)alloc((size_t)S_LEN * HDIM * 2);
  short* dcat    = (short*)alloc((size_t)S_LEN * DCAT * 2);
  short* qlatn   = (short*)alloc((size_t)S_LEN * QRANK_ * 2);
  short* qbuf    = (short*)alloc((size_t)S_LEN * QN_ * 2);
  short* kvn     = (short*)alloc((size_t)S_LEN * KVRANK_ * 2);
  short* kvup    = (short*)alloc((size_t)S_LEN * KVUPN * 2);
  short* qf      = (short*)alloc((size_t)NH_ * S_LEN * DQK_ * 2);
  short* kf      = (short*)alloc((size_t)NH_ * S_LEN * DQK_ * 2);
  short* vT      = (short*)alloc((size_t)NH_ * 128 * S_LEN * 2);
  short* ao      = (short*)alloc((size_t)S_LEN * HDIM * 2);
  short* hfin    = (short*)alloc((size_t)S_LEN * HDIM * 2);
  short* kpool   = (short*)alloc((size_t)S_LEN * HDIM * 2);
  short* vpoolT  = (short*)alloc((size_t)HDIM * S_LEN * 2);
  short* qvec    = (short*)alloc((size_t)HDIM * 2);
  float* pscore  = (float*)alloc((size_t)S_LEN * 4);
  float* pooled  = (float*)alloc((size_t)HDIM * 4);
  float* pooledn = (float*)alloc((size_t)HDIM * 4);
  int*   ecnt    = (int*)alloc(64);
  int*   elist   = (int*)alloc((size_t)EXP_ * S_LEN * 4);
  float* ewt     = (float*)alloc((size_t)EXP_ * S_LEN * 4);
  int*   tok2slot= (int*)alloc((size_t)S_LEN * 16);
  short* gba_e   = (short*)alloc((size_t)EXP_ * S_LEN * IFF_ * 2);
  short* routed  = (short*)alloc((size_t)EXP_ * S_LEN * HDIM * 2);
  short* gsh1    = (short*)alloc((size_t)2 * S_LEN * IFF_ * 2);
  short* shared_out = (short*)alloc((size_t)2 * S_LEN * HDIM * 2);

  detect_kernel<<<1, 256, 0, stream>>>(d_in[0], dflag);

  auto tconv = [&](const void* src, short* dst, int R, int C, int nslabs,
                   long long sSrc, long long sDst, int rowMul, int rowOff) {
    dim3 grid(C / 32, R / 32, nslabs);
    transconv_kernel<<<grid, 256, 0, stream>>>(src, dst, R, C, dflag, sSrc, sDst, rowMul, rowOff);
  };
  auto pconv = [&](const void* src, short* dst, long long n) {
    long long nchunks = n / 8;
    int blocks = (int)((nchunks + 255) / 256);
    if (blocks > 2048) blocks = 2048;
    if (blocks < 1) blocks = 1;
    convert_kernel<<<blocks, 256, 0, stream>>>(src, dst, nchunks, dflag);
  };

  tconv(d_in[2], qkvdwT, HDIM, QRANK_, 2,
        (long long)HDIM * QRANK_, (long long)DCAT * HDIM, 1, 0);
  tconv(d_in[5], qkvdwT + (size_t)QRANK_ * HDIM, HDIM, KVDN, 2,
        (long long)HDIM * KVDN, (long long)DCAT * HDIM, 1, 0);
  tconv(d_in[4],  quwT,  QRANK_, QN_,  2, (long long)QRANK_ * QN_,  (long long)QN_ * QRANK_, 1, 0);
  tconv(d_in[7],  kvuwT, KVRANK_,KVUPN,2, (long long)KVRANK_ * KVUPN,(long long)KVUPN * KVRANK_, 1, 0);
  tconv(d_in[8],  opwT,  HDIM,   HDIM, 2, (long long)HDIM * HDIM,   (long long)HDIM * HDIM, 1, 0);
  tconv(d_in[11], rw13T, HDIM,   IFF_, 16,(long long)HDIM * IFF_,   (long long)IFF2 * HDIM, 2, 0);
  tconv(d_in[13], rw13T, HDIM,   IFF_, 16,(long long)HDIM * IFF_,   (long long)IFF2 * HDIM, 2, 1);
  tconv(d_in[12], rw2T,  IFF_,   HDIM, 16,(long long)IFF_ * HDIM,   (long long)HDIM * IFF_, 1, 0);
  tconv(d_in[14], sw13T, HDIM,   IFF_, 4, (long long)HDIM * IFF_,   (long long)IFF2 * HDIM, 2, 0);
  tconv(d_in[16], sw13T, HDIM,   IFF_, 4, (long long)HDIM * IFF_,   (long long)IFF2 * HDIM, 2, 1);
  tconv(d_in[15], sw2T,  IFF_,   HDIM, 4, (long long)IFF_ * HDIM,   (long long)HDIM * IFF_, 1, 0);
  tconv(d_in[19], pqwT,  HDIM,   HDIM, 1, 0, 0, 1, 0);
  tconv(d_in[20], pkwT,  HDIM,   HDIM, 1, 0, 0, 1, 0);
  tconv(d_in[21], pvwT,  HDIM,   HDIM, 1, 0, 0, 1, 0);
  tconv(d_in[22], powT,  HDIM,   PD_,  1, 0, 0, 1, 0);
  pconv(d_in[1],  ln1w, in_sizes[1]);
  pconv(d_in[3],  qnw,  in_sizes[3]);
  pconv(d_in[6],  kvnw, in_sizes[6]);
  pconv(d_in[9],  ln2w, in_sizes[9]);
  pconv(d_in[10], gatw, in_sizes[10]);
  pconv(d_in[17], fnww, in_sizes[17]);
  pconv(d_in[18], lqw,  in_sizes[18]);
  pconv(d_in[23], pnww, in_sizes[23]);

  const float qk_scale = 1.0f / sqrtf((float)DQK_);

  auto gemm = [&](int epi, const short* A, const short* B, short* C,
                  int M, int N, int K, int lda, int ldb, int ldc,
                  int batch, long long sA, long long sB, long long sC) {
    dim3 grid(M / 128, (N + 127) / 128, batch);
    if (epi == 0)
      gemm_kernel<0><<<grid, 256, 0, stream>>>(A, B, C, M, N, K, lda, ldb, ldc, sA, sB, sC);
    else if (epi == 1)
      gemm_kernel<1><<<grid, 256, 0, stream>>>(A, B, C, M, N, K, lda, ldb, ldc, sA, sB, sC);
    else
      gemm_kernel<2><<<grid, 256, 0, stream>>>(A, B, C, M, N, K, lda, ldb, ldc, sA, sB, sC);
  };

  rope_tables_kernel<<<S_LEN, 64, 0, stream>>>(cosT, sinT);
  embed_convert_kernel<<<S_LEN, 256, 0, stream>>>(ids, d_in[0], dflag, hbuf);

  for (int l = 0; l < 2; ++l) {
    const short* w_ln1  = ln1w + (size_t)l * HDIM;
    const short* w_qkvT = qkvdwT + (size_t)l * DCAT * HDIM;
    const short* w_qn   = qnw  + (size_t)l * QRANK_;
    const short* w_quT  = quwT + (size_t)l * QN_ * QRANK_;
    const short* w_kvn  = kvnw + (size_t)l * KVRANK_;
    const short* w_kvuT = kvuwT+ (size_t)l * KVUPN * KVRANK_;
    const short* w_opT  = opwT + (size_t)l * HDIM * HDIM;
    const short* w_ln2  = ln2w + (size_t)l * HDIM;
    const short* w_gat  = gatw + (size_t)l * HDIM * EXP_;

    // --- attention ---
    rmsnorm_bf16_kernel<<<S_LEN, 256, 0, stream>>>(hbuf, HDIM, w_ln1, xbuf, HDIM, HDIM);
    gemm(0, xbuf, w_qkvT, dcat, S_LEN, DCAT, HDIM, HDIM, HDIM, DCAT, 1, 0, 0, 0);
    rmsnorm_bf16_kernel<<<S_LEN, 256, 0, stream>>>(dcat, DCAT, w_qn, qlatn, QRANK_, QRANK_);
    gemm(0, qlatn, w_quT, qbuf, S_LEN, QN_, QRANK_, QRANK_, QRANK_, QN_, 1, 0, 0, 0);
    rmsnorm_bf16_kernel<<<S_LEN, 256, 0, stream>>>(dcat + QRANK_, DCAT, w_kvn, kvn, KVRANK_, KVRANK_);
    gemm(0, kvn, w_kvuT, kvup, S_LEN, KVUPN, KVRANK_, KVRANK_, KVRANK_, KVUPN, 1, 0, 0, 0);
    build_qf_kernel<<<S_LEN, 256, 0, stream>>>(qbuf, cosT, sinT, qf);
    build_kf_kernel<<<S_LEN, 256, 0, stream>>>(kvup, dcat + QRANK_ + KVRANK_, DCAT, cosT, sinT, kf);
    {
      dim3 tg(128 / 32, S_LEN / 32, NH_);
      transpose_v_kernel<<<tg, 256, 0, stream>>>(kvup, vT);
    }
    {
      dim3 fg(S_LEN / 128, NH_);
      flash_kernel<<<fg, 256, 0, stream>>>(qf, kf, vT, ao, qk_scale);
    }
    gemm(2, ao, w_opT, hbuf, S_LEN, HDIM, HDIM, HDIM, HDIM, HDIM, 1, 0, 0, 0);

    // --- MoE ---
    rmsnorm_bf16_kernel<<<S_LEN, 256, 0, stream>>>(hbuf, HDIM, w_ln2, xbuf, HDIM, HDIM);
    hipMemsetAsync(ecnt, 0, 64, stream);
    gate_kernel<<<S_LEN, 256, 0, stream>>>(xbuf, w_gat, ecnt, elist, ewt, tok2slot);
    {
      const short* a13 = sw13T + (size_t)l * 2 * IFF2 * HDIM;
      const short* a2  = sw2T  + (size_t)l * 2 * HDIM * IFF_;
      gemm(1, xbuf, a13, gsh1, S_LEN, IFF2, HDIM, HDIM, HDIM, IFF_, 2,
           0, (long long)IFF2 * HDIM, (long long)S_LEN * IFF_);
      gemm(0, gsh1, a2, shared_out, S_LEN, HDIM, IFF_, IFF_, IFF_, HDIM, 2,
           (long long)S_LEN * IFF_, (long long)HDIM * IFF_, (long long)S_LEN * HDIM);
    }
    {
      const short* b13 = rw13T + (size_t)l * 8 * IFF2 * HDIM;
      const short* b2  = rw2T  + (size_t)l * 8 * HDIM * IFF_;
      // m-tiles on Y so early-exit blocks are spread across XCDs
      dim3 g13(IFF2 / 128, S_LEN / 128, EXP_);
      moe_gemm_kernel<1, 1><<<g13, 256, 0, stream>>>(
          xbuf, elist, ecnt, b13, gba_e, ewt, IFF2, HDIM, HDIM, HDIM, IFF_,
          0, (long long)IFF2 * HDIM, (long long)S_LEN * IFF_);
      dim3 g2(HDIM / 128, S_LEN / 128, EXP_);
      moe_gemm_kernel<0, 0><<<g2, 256, 0, stream>>>(
          gba_e, elist, ecnt, b2, routed, nullptr, HDIM, IFF_, IFF_, IFF_, HDIM,
          (long long)S_LEN * IFF_, (long long)HDIM * IFF_, (long long)S_LEN * HDIM);
      moe_combine_kernel<<<S_LEN, 256, 0, stream>>>(hbuf, shared_out, routed, tok2slot);
    }
  }

  // --- attention pooling head ---
  rmsnorm_bf16_kernel<<<S_LEN, 256, 0, stream>>>(hbuf, HDIM, fnww, hfin, HDIM, HDIM);
  gemm(0, hfin, pkwT, kpool, S_LEN, HDIM, HDIM, HDIM, HDIM, HDIM, 1, 0, 0, 0);
  gemm(0, pvwT, hfin, vpoolT, HDIM, S_LEN, HDIM, HDIM, HDIM, S_LEN, 1, 0, 0, 0);
  gemv_bt_kernel<0,1><<<HDIM, 256, 0, stream>>>(lqw, pqwT, qvec, HDIM);
  pool_score_kernel<<<S_LEN, 256, 0, stream>>>(qvec, kpool, pscore);
  softmax_vec_kernel<<<1, 256, 0, stream>>>(pscore);
  pool_wsum_t_kernel<<<HDIM, 256, 0, stream>>>(pscore, vpoolT, pooled);
  rmsnorm_f32_kernel<<<1, 256, 0, stream>>>(pooled, pnww, pooledn);
  gemv_bt_kernel<1,0><<<PD_, 256, 0, stream>>>(pooledn, powT, (float*)d_out, HDIM);
}

// Round 12
// 1639.592 us; speedup vs baseline: 7.2129x; 1.0432x over previous
//
#include <hip/hip_runtime.h>
#include <hip/hip_bf16.h>

#define S_LEN  2048
#define HDIM   2048
#define NH_    16
#define DQK_   192
#define QRANK_ 1024
#define KVRANK_ 512
#define KVDN   576
#define DCAT   1600   // QRANK + KVDN merged down-proj width
#define KVUPN  4096
#define QN_    3072
#define IFF_   1408
#define IFF2   2816   // interleaved w1|w3 width
#define EXP_   8
#define PD_    4096

typedef __attribute__((ext_vector_type(8))) short   short8_t;
typedef __attribute__((ext_vector_type(8))) __bf16  bf16x8_t;
typedef __attribute__((ext_vector_type(4))) float   f32x4;

static __device__ __forceinline__ float b2f(short s) {
  unsigned int u = ((unsigned int)(unsigned short)s) << 16;
  return __builtin_bit_cast(float, u);
}
static __device__ __forceinline__ short f2b(float f) {
  return __builtin_bit_cast(short, __float2bfloat16(f));
}

static __device__ __forceinline__ void gload16(const void* g, void* l) {
  __builtin_amdgcn_global_load_lds(
      (const __attribute__((address_space(1))) void*)g,
      (__attribute__((address_space(3))) void*)l,
      16, 0, 0);
}
static __device__ __forceinline__ void wait_vm4() { asm volatile("s_waitcnt vmcnt(4)" ::: "memory"); }
static __device__ __forceinline__ void wait_vm2() { asm volatile("s_waitcnt vmcnt(2)" ::: "memory"); }
static __device__ __forceinline__ void wait_vm0() { asm volatile("s_waitcnt vmcnt(0)" ::: "memory"); }

// ---------------- dtype detect + convert ----------------
__global__ void __launch_bounds__(256)
detect_kernel(const void* probe, int* flag) {
  const float* f = (const float*)probe;
  int tid = threadIdx.x;
  int cnt = 0;
  for (int i = tid; i < 2048; i += 256) {
    float v = fabsf(f[i]);
    if (v > 1e-6f && v < 10.0f) cnt++;
  }
  __shared__ int red[256];
  red[tid] = cnt; __syncthreads();
  for (int s = 128; s > 0; s >>= 1) {
    if (tid < s) red[tid] += red[tid + s];
    __syncthreads();
  }
  if (tid == 0) *flag = (red[0] > 1600) ? 1 : 0;
}

__global__ void __launch_bounds__(256)
convert_kernel(const void* src, short* dst, long long nchunks, const int* flag) {
  long long idx = (long long)blockIdx.x * 256 + threadIdx.x;
  long long stride = (long long)gridDim.x * 256;
  if (*flag) {
    const f32x4* s = (const f32x4*)src;
    for (long long c = idx; c < nchunks; c += stride) {
      f32x4 a = s[2 * c], b = s[2 * c + 1];
      short8_t o;
      #pragma unroll
      for (int j = 0; j < 4; ++j) { o[j] = f2b(a[j]); o[4 + j] = f2b(b[j]); }
      reinterpret_cast<short8_t*>(dst)[c] = o;
    }
  } else {
    const short8_t* s = (const short8_t*)src;
    for (long long c = idx; c < nchunks; c += stride)
      reinterpret_cast<short8_t*>(dst)[c] = s[c];
  }
}

// transpose-convert: src slab [R][C] -> dst rows (c*rowMul+rowOff) stride R, bf16
__global__ void __launch_bounds__(256)
transconv_kernel(const void* src, short* dst, int R, int C, const int* flag,
                 long long sSrc, long long sDst, int rowMul, int rowOff) {
  long long zs = (long long)blockIdx.z * sSrc;
  long long zd = (long long)blockIdx.z * sDst;
  int r0 = blockIdx.y * 32, c0 = blockIdx.x * 32;
  int tx = threadIdx.x & 31, ty = threadIdx.x >> 5;
  __shared__ short tile[32][33];
  if (*flag) {
    const float* s = (const float*)src + zs;
    #pragma unroll
    for (int i = 0; i < 4; ++i)
      tile[ty + i * 8][tx] = f2b(s[(long long)(r0 + ty + i * 8) * C + c0 + tx]);
  } else {
    const short* s = (const short*)src + zs;
    #pragma unroll
    for (int i = 0; i < 4; ++i)
      tile[ty + i * 8][tx] = s[(long long)(r0 + ty + i * 8) * C + c0 + tx];
  }
  __syncthreads();
  short* d = dst + zd;
  #pragma unroll
  for (int i = 0; i < 4; ++i)
    d[(long long)((c0 + ty + i * 8) * rowMul + rowOff) * R + r0 + tx] = tile[tx][ty + i * 8];
}

__global__ void __launch_bounds__(256)
embed_convert_kernel(const int* ids, const void* emb, const int* flag, short* h) {
  int s = blockIdx.x;
  long long row = ids[s];
  int c = threadIdx.x;
  short8_t o;
  if (*flag) {
    const f32x4* src = (const f32x4*)((const float*)emb + row * HDIM);
    f32x4 a = src[2 * c], b = src[2 * c + 1];
    #pragma unroll
    for (int j = 0; j < 4; ++j) { o[j] = f2b(a[j]); o[4 + j] = f2b(b[j]); }
  } else {
    o = reinterpret_cast<const short8_t*>((const short*)emb + row * HDIM)[c];
  }
  reinterpret_cast<short8_t*>(h + (long long)s * HDIM)[c] = o;
}

// ---------------- pipelined MFMA GEMM (B always [N][K], bf16 C) ----------------
// EPI=0: plain bf16 store. EPI=1: fused SiLU-pair (even=gate, odd=up), writes N/2 cols.
// EPI=2: in-place residual add.
template<int EPI>
__global__ void __launch_bounds__(256)
gemm_kernel(const short* __restrict__ A, const short* __restrict__ B,
            short* __restrict__ Cv, int M, int N, int K,
            int lda, int ldb, int ldc,
            long long sAb, long long sBb, long long sCb)
{
  __shared__ short smem[24576];
  short* shA = smem;
  short* shB = smem + 12288;
  const int tid = threadIdx.x;
  const long long bz = blockIdx.z;
  const short* Ab = A + bz * sAb;
  const short* Bb = B + bz * sBb;
  const int m0 = blockIdx.x * 128;
  const int n0 = blockIdx.y * 128;
  const int w = tid >> 6, lane = tid & 63;
  const int wm = (w >> 1) << 6, wn = (w & 1) << 6;
  const int lr = lane & 15, g = lane >> 4;
  const int srow = lane >> 2;
  const int sunit = ((lane & 3) ^ ((lane >> 3) & 3)) << 3;
  const int rsw = ((g ^ ((lr >> 1) & 3)) << 3);
  const f32x4 vzero = {0.f, 0.f, 0.f, 0.f};
  f32x4 acc[4][4];
  #pragma unroll
  for (int i = 0; i < 4; ++i)
    #pragma unroll
    for (int j = 0; j < 4; ++j) acc[i][j] = vzero;

  const int nt = K >> 5;
#define STAGE_G(bi, kk) do { \
    _Pragma("unroll") \
    for (int r = 0; r < 2; ++r) { \
      int rowb = (w << 4) + (r << 6); \
      gload16(Ab + (long long)(m0 + rowb + srow) * lda + (kk) + sunit, &shA[(bi) * 4096 + rowb * 32]); \
      gload16(Bb + (long long)(n0 + rowb + srow) * ldb + (kk) + sunit, &shB[(bi) * 4096 + rowb * 32]); \
    } } while (0)

  STAGE_G(0, 0);
  if (nt > 1) STAGE_G(1, 32);
  int cur = 0, i2 = 2;
  for (int t = 0; t < nt; ++t) {
    if (t + 1 < nt) wait_vm4(); else wait_vm0();
    __builtin_amdgcn_s_barrier();
    if (t + 2 < nt) STAGE_G(i2, (t + 2) << 5);
    short8_t af[4];
    #pragma unroll
    for (int mi = 0; mi < 4; ++mi)
      af[mi] = *reinterpret_cast<const short8_t*>(&shA[cur * 4096 + (wm + (mi << 4) + lr) * 32 + rsw]);
    __builtin_amdgcn_s_setprio(1);
    #pragma unroll
    for (int ni = 0; ni < 4; ++ni) {
      short8_t bfr = *reinterpret_cast<const short8_t*>(&shB[cur * 4096 + (wn + (ni << 4) + lr) * 32 + rsw]);
      #pragma unroll
      for (int mi = 0; mi < 4; ++mi)
        acc[mi][ni] = __builtin_amdgcn_mfma_f32_16x16x32_bf16(
            __builtin_bit_cast(bf16x8_t, af[mi]),
            __builtin_bit_cast(bf16x8_t, bfr),
            acc[mi][ni], 0, 0, 0);
    }
    __builtin_amdgcn_s_setprio(0);
    cur = (cur == 2) ? 0 : cur + 1;
    i2  = (i2 == 2) ? 0 : i2 + 1;
  }
#undef STAGE_G
  __syncthreads();
  #pragma unroll
  for (int ni = 0; ni < 4; ++ni)
    #pragma unroll
    for (int mi = 0; mi < 4; ++mi)
      #pragma unroll
      for (int r = 0; r < 4; ++r)
        smem[(wm + (mi << 4) + (g << 2) + r) * 136 + wn + (ni << 4) + lr] = f2b(acc[mi][ni][r]);
  __syncthreads();
  {
    short* C = Cv + bz * sCb;
    int row = tid >> 1, half = (tid & 1) << 6;
    if (EPI == 1) {
      int ocol = (n0 >> 1) + (half >> 1);
      #pragma unroll
      for (int j = 0; j < 4; ++j) {
        short8_t v0 = *reinterpret_cast<const short8_t*>(&smem[row * 136 + half + (j << 4)]);
        short8_t v1 = *reinterpret_cast<const short8_t*>(&smem[row * 136 + half + (j << 4) + 8]);
        short8_t o;
        #pragma unroll
        for (int q = 0; q < 4; ++q) {
          float x = b2f(v0[2 * q]);
          o[q] = f2b((x / (1.0f + expf(-x))) * b2f(v0[2 * q + 1]));
          float y = b2f(v1[2 * q]);
          o[4 + q] = f2b((y / (1.0f + expf(-y))) * b2f(v1[2 * q + 1]));
        }
        *reinterpret_cast<short8_t*>(&C[(long long)(m0 + row) * ldc + ocol + (j << 3)]) = o;
      }
    } else {
      #pragma unroll
      for (int j = 0; j < 8; ++j) {
        int col = n0 + half + (j << 3);
        if (col + 8 <= N) {
          short8_t v = *reinterpret_cast<const short8_t*>(&smem[row * 136 + half + (j << 3)]);
          short* cp = &C[(long long)(m0 + row) * ldc + col];
          if (EPI == 2) {
            short8_t hv = *reinterpret_cast<const short8_t*>(cp);
            short8_t o;
            #pragma unroll
            for (int q = 0; q < 8; ++q) o[q] = f2b(b2f(hv[q]) + b2f(v[q]));
            *reinterpret_cast<short8_t*>(cp) = o;
          } else {
            *reinterpret_cast<short8_t*>(cp) = v;
          }
        }
      }
    }
  }
}

// ---------------- pipelined sparse MoE gather GEMM ----------------
// GRID: (n_tiles, m_tiles, experts) — m on Y so early-exit blocks spread across XCDs.
template<int GATHER, int SILU>
__global__ void __launch_bounds__(256)
moe_gemm_kernel(const short* __restrict__ A, const int* __restrict__ elist,
                const int* __restrict__ cnt, const short* __restrict__ B,
                short* __restrict__ C, const float* __restrict__ ewt,
                int N, int K, int lda, int ldb, int ldc,
                long long sAe, long long sBe, long long sCe)
{
  const int e = blockIdx.z;
  const int cnt_e = cnt[e];
  const int m0 = blockIdx.y << 7;
  if (m0 >= cnt_e) return;
  const short* Bb = B + (long long)e * sBe;
  short* Cb = C + (long long)e * sCe;
  const int n0 = blockIdx.x << 7;
  const int tid = threadIdx.x;
  const int w = tid >> 6, lane = tid & 63;
  const int wm = (w >> 1) << 6, wn = (w & 1) << 6;
  const int lr = lane & 15, g = lane >> 4;
  const int srow = lane >> 2;
  const int sunit = ((lane & 3) ^ ((lane >> 3) & 3)) << 3;
  const int rsw = ((g ^ ((lr >> 1) & 3)) << 3);

  long long arow[2];
  #pragma unroll
  for (int r = 0; r < 2; ++r) {
    int row = m0 + (w << 4) + (r << 6) + srow;
    if (GATHER) {
      int p = row > cnt_e - 1 ? cnt_e - 1 : row;
      arow[r] = (long long)elist[e * S_LEN + p] * lda;
    } else {
      arow[r] = (long long)e * sAe + (long long)row * lda;
    }
  }

  __shared__ short smem[24576];
  short* shA = smem;
  short* shB = smem + 12288;
  const f32x4 vzero = {0.f, 0.f, 0.f, 0.f};
  f32x4 acc[4][4];
  #pragma unroll
  for (int i = 0; i < 4; ++i)
    #pragma unroll
    for (int j = 0; j < 4; ++j) acc[i][j] = vzero;

  const int nt = K >> 5;
#define STAGE_M(bi, kk) do { \
    _Pragma("unroll") \
    for (int r = 0; r < 2; ++r) { \
      int rowb = (w << 4) + (r << 6); \
      gload16(A + arow[r] + (kk) + sunit, &shA[(bi) * 4096 + rowb * 32]); \
      gload16(Bb + (long long)(n0 + rowb + srow) * ldb + (kk) + sunit, &shB[(bi) * 4096 + rowb * 32]); \
    } } while (0)

  STAGE_M(0, 0);
  if (nt > 1) STAGE_M(1, 32);
  int cur = 0, i2 = 2;
  for (int t = 0; t < nt; ++t) {
    if (t + 1 < nt) wait_vm4(); else wait_vm0();
    __builtin_amdgcn_s_barrier();
    if (t + 2 < nt) STAGE_M(i2, (t + 2) << 5);
    short8_t af[4];
    #pragma unroll
    for (int mi = 0; mi < 4; ++mi)
      af[mi] = *reinterpret_cast<const short8_t*>(&shA[cur * 4096 + (wm + (mi << 4) + lr) * 32 + rsw]);
    __builtin_amdgcn_s_setprio(1);
    #pragma unroll
    for (int ni = 0; ni < 4; ++ni) {
      short8_t bfr = *reinterpret_cast<const short8_t*>(&shB[cur * 4096 + (wn + (ni << 4) + lr) * 32 + rsw]);
      #pragma unroll
      for (int mi = 0; mi < 4; ++mi)
        acc[mi][ni] = __builtin_amdgcn_mfma_f32_16x16x32_bf16(
            __builtin_bit_cast(bf16x8_t, af[mi]),
            __builtin_bit_cast(bf16x8_t, bfr),
            acc[mi][ni], 0, 0, 0);
    }
    __builtin_amdgcn_s_setprio(0);
    cur = (cur == 2) ? 0 : cur + 1;
    i2  = (i2 == 2) ? 0 : i2 + 1;
  }
#undef STAGE_M
  __syncthreads();
  #pragma unroll
  for (int ni = 0; ni < 4; ++ni)
    #pragma unroll
    for (int mi = 0; mi < 4; ++mi)
      #pragma unroll
      for (int r = 0; r < 4; ++r)
        smem[(wm + (mi << 4) + (g << 2) + r) * 136 + wn + (ni << 4) + lr] = f2b(acc[mi][ni][r]);
  __syncthreads();
  {
    int row = tid >> 1, half = (tid & 1) << 6;
    if (m0 + row < cnt_e) {
      if (SILU) {
        float scale = ewt[e * S_LEN + m0 + row];
        int ocol = (n0 >> 1) + (half >> 1);
        #pragma unroll
        for (int j = 0; j < 4; ++j) {
          short8_t v0 = *reinterpret_cast<const short8_t*>(&smem[row * 136 + half + (j << 4)]);
          short8_t v1 = *reinterpret_cast<const short8_t*>(&smem[row * 136 + half + (j << 4) + 8]);
          short8_t o;
          #pragma unroll
          for (int q = 0; q < 4; ++q) {
            float x = b2f(v0[2 * q]);
            o[q] = f2b((x / (1.0f + expf(-x))) * b2f(v0[2 * q + 1]) * scale);
            float y = b2f(v1[2 * q]);
            o[4 + q] = f2b((y / (1.0f + expf(-y))) * b2f(v1[2 * q + 1]) * scale);
          }
          *reinterpret_cast<short8_t*>(&Cb[(long long)(m0 + row) * ldc + ocol + (j << 3)]) = o;
        }
      } else {
        #pragma unroll
        for (int j = 0; j < 8; ++j) {
          int col = n0 + half + (j << 3);
          short8_t v = *reinterpret_cast<const short8_t*>(&smem[row * 136 + half + (j << 3)]);
          *reinterpret_cast<short8_t*>(&Cb[(long long)(m0 + row) * ldc + col]) = v;
        }
      }
    }
  }
}

// ---------------- flash attention, QBLK=64 (2 blocks/CU) ----------------
// grid (32 q-tiles, 16 heads), 256 threads (4 waves), wave w owns rows w*16..w*16+15.
// LDS (shorts): qs[64][200] @0, ks[2][128][32] @12800, ps[64][136] @20992, vs[2][128][32] @29696.
// Q and P stored pre-swizzled (chunk c -> (c&3)^((row>>1)&3) within 4-chunk block).
__global__ void __launch_bounds__(256)
flash_kernel(const short* __restrict__ qf, const short* __restrict__ kf,
             const short* __restrict__ vT, short* __restrict__ ao, float scale)
{
  __shared__ short smem[37888];
  const int tid = threadIdx.x;
  const int h = blockIdx.y;
  const int q0 = blockIdx.x << 6;
  const int w = tid >> 6, lane = tid & 63;
  const int lr = lane & 15, g = lane >> 4;
  const int rb = w << 4;           // 16 rows per wave
  const int srow = lane >> 2;
  const int sunit = ((lane & 3) ^ ((lane >> 3) & 3)) << 3;
  const int rsw = ((g ^ ((lr >> 1) & 3)) << 3);
  const short* qh = qf + (long long)h * S_LEN * DQK_;
  const short* kh = kf + (long long)h * S_LEN * DQK_;
  const short* vh = vT + (long long)h * 128 * S_LEN;

  // load Q tile -> qs[64][200], swizzled store
  #pragma unroll
  for (int i = 0; i < 6; ++i) {
    int c = tid + (i << 8);
    int row = c / 24, cc = c % 24;
    int dchunk = (cc & ~3) | ((cc & 3) ^ ((row >> 1) & 3));
    *reinterpret_cast<short8_t*>(&smem[row * 200 + (dchunk << 3)]) =
        *reinterpret_cast<const short8_t*>(qh + (long long)(q0 + row) * DQK_ + (cc << 3));
  }

  const f32x4 vzero = {0.f, 0.f, 0.f, 0.f};
  f32x4 oacc[8];
  #pragma unroll
  for (int ni = 0; ni < 8; ++ni) oacc[ni] = vzero;
  float mrow[4], lrow[4];
  #pragma unroll
  for (int rr = 0; rr < 4; ++rr) { mrow[rr] = -3e38f; lrow[rr] = 0.f; }

  __syncthreads();

  for (int kt = 0; kt < 16; ++kt) {
    const short* kbase = kh + (long long)(kt << 7) * DQK_;
    // ---- S = Q K^T ----
    f32x4 sacc[8];
    #pragma unroll
    for (int ni = 0; ni < 8; ++ni) sacc[ni] = vzero;
#define STAGE_K(bi, kk) do { \
    _Pragma("unroll") \
    for (int r = 0; r < 2; ++r) { \
      int rowb = (w << 4) + (r << 6); \
      gload16(kbase + (long long)(rowb + srow) * DQK_ + (kk) * 32 + sunit, \
              &smem[12800 + (bi) * 4096 + rowb * 32]); \
    } } while (0)
    STAGE_K(0, 0);
    for (int ks = 0; ks < 6; ++ks) {
      if (ks < 5) { STAGE_K((ks + 1) & 1, ks + 1); wait_vm2(); }
      else wait_vm0();
      __builtin_amdgcn_s_barrier();
      const int kb = 12800 + (ks & 1) * 4096;
      short8_t aq = *reinterpret_cast<const short8_t*>(
          &smem[(rb + lr) * 200 + ks * 32 + rsw]);
      __builtin_amdgcn_s_setprio(1);
      #pragma unroll
      for (int ni = 0; ni < 8; ++ni) {
        short8_t bk = *reinterpret_cast<const short8_t*>(&smem[kb + ((ni << 4) + lr) * 32 + rsw]);
        sacc[ni] = __builtin_amdgcn_mfma_f32_16x16x32_bf16(
            __builtin_bit_cast(bf16x8_t, aq),
            __builtin_bit_cast(bf16x8_t, bk),
            sacc[ni], 0, 0, 0);
      }
      __builtin_amdgcn_s_setprio(0);
      __builtin_amdgcn_s_barrier();
    }
#undef STAGE_K
    // ---- online softmax (P stored swizzled) ----
    #pragma unroll
    for (int rr = 0; rr < 4; ++rr) {
      float sv[8];
      float mx = -3e38f;
      #pragma unroll
      for (int ni = 0; ni < 8; ++ni) {
        sv[ni] = b2f(f2b(sacc[ni][rr])) * scale;
        mx = fmaxf(mx, sv[ni]);
      }
      #pragma unroll
      for (int d = 1; d < 16; d <<= 1) mx = fmaxf(mx, __shfl_xor(mx, d, 64));
      float mnew = fmaxf(mrow[rr], mx);
      float corr = expf(mrow[rr] - mnew);
      float psum = 0.f;
      short pb[8];
      #pragma unroll
      for (int ni = 0; ni < 8; ++ni) {
        float p = expf(sv[ni] - mnew);
        pb[ni] = f2b(p);
        psum += p;
      }
      #pragma unroll
      for (int d = 1; d < 16; d <<= 1) psum += __shfl_xor(psum, d, 64);
      lrow[rr] = lrow[rr] * corr + psum;
      mrow[rr] = mnew;
      int row = rb + (g << 2) + rr;
      int xr = (row >> 1) & 3;
      #pragma unroll
      for (int ni = 0; ni < 8; ++ni) {
        int cc = (ni << 4) + lr;
        int scc = (cc & ~31) | (((((cc >> 3) & 3) ^ xr)) << 3) | (cc & 7);
        smem[20992 + row * 136 + scc] = pb[ni];
      }
      #pragma unroll
      for (int ni = 0; ni < 8; ++ni) oacc[ni][rr] *= corr;
    }
    __syncthreads();
    // ---- O += P V ----
    const short* vbase = vh + (kt << 7);
#define STAGE_V(bi, kk) do { \
    _Pragma("unroll") \
    for (int r = 0; r < 2; ++r) { \
      int rowb = (w << 4) + (r << 6); \
      gload16(vbase + (long long)(rowb + srow) * S_LEN + (kk) * 32 + sunit, \
              &smem[29696 + (bi) * 4096 + rowb * 32]); \
    } } while (0)
    STAGE_V(0, 0);
    for (int ks = 0; ks < 4; ++ks) {
      if (ks < 3) { STAGE_V((ks + 1) & 1, ks + 1); wait_vm2(); }
      else wait_vm0();
      __builtin_amdgcn_s_barrier();
      const int vb = 29696 + (ks & 1) * 4096;
      short8_t ap = *reinterpret_cast<const short8_t*>(
          &smem[20992 + (rb + lr) * 136 + ks * 32 + rsw]);
      __builtin_amdgcn_s_setprio(1);
      #pragma unroll
      for (int ni = 0; ni < 8; ++ni) {
        short8_t bv = *reinterpret_cast<const short8_t*>(&smem[vb + ((ni << 4) + lr) * 32 + rsw]);
        oacc[ni] = __builtin_amdgcn_mfma_f32_16x16x32_bf16(
            __builtin_bit_cast(bf16x8_t, ap),
            __builtin_bit_cast(bf16x8_t, bv),
            oacc[ni], 0, 0, 0);
      }
      __builtin_amdgcn_s_setprio(0);
      __builtin_amdgcn_s_barrier();
    }
#undef STAGE_V
  }
  // ---- epilogue: O/l -> ps (natural layout) -> vectorized store ----
  __syncthreads();
  #pragma unroll
  for (int ni = 0; ni < 8; ++ni)
    #pragma unroll
    for (int rr = 0; rr < 4; ++rr) {
      int row = rb + (g << 2) + rr;
      smem[20992 + row * 136 + (ni << 4) + lr] = f2b(oacc[ni][rr] / lrow[rr]);
    }
  __syncthreads();
  {
    int row = tid >> 2, quarter = (tid & 3) << 5;
    #pragma unroll
    for (int j = 0; j < 4; ++j) {
      int col = quarter + (j << 3);
      short8_t v = *reinterpret_cast<const short8_t*>(&smem[20992 + row * 136 + col]);
      *reinterpret_cast<short8_t*>(&ao[(long long)(q0 + row) * HDIM + (h << 7) + col]) = v;
    }
  }
}

// ---------------- small kernels ----------------
__global__ void __launch_bounds__(64)
rope_tables_kernel(float* cosT, float* sinT) {
  int s = blockIdx.x, j = threadIdx.x;
  int i = j & 31;
  float inv = powf(10000.0f, -((float)(2 * i) / 64.0f));
  float ang = (float)s * inv;
  cosT[s * 64 + j] = cosf(ang);
  sinT[s * 64 + j] = sinf(ang);
}

__global__ void __launch_bounds__(256)
rmsnorm_bf16_kernel(const short* __restrict__ in, long long istride,
                    const short* __restrict__ w,
                    short* __restrict__ out, long long ostride, int D) {
  const short* x = in + (long long)blockIdx.x * istride;
  short* o = out + (long long)blockIdx.x * ostride;
  const int nc = D >> 3;
  float ss = 0.f;
  for (int c = threadIdx.x; c < nc; c += 256) {
    short8_t v = reinterpret_cast<const short8_t*>(x)[c];
    #pragma unroll
    for (int j = 0; j < 8; ++j) { float f = b2f(v[j]); ss += f * f; }
  }
  __shared__ float red[256];
  red[threadIdx.x] = ss; __syncthreads();
  for (int s2 = 128; s2 > 0; s2 >>= 1) {
    if (threadIdx.x < s2) red[threadIdx.x] += red[threadIdx.x + s2];
    __syncthreads();
  }
  float r = 1.0f / sqrtf(red[0] / (float)D + 1e-6f);
  for (int c = threadIdx.x; c < nc; c += 256) {
    short8_t v = reinterpret_cast<const short8_t*>(x)[c];
    short8_t wv = reinterpret_cast<const short8_t*>(w)[c];
    short8_t ov;
    #pragma unroll
    for (int j = 0; j < 8; ++j) ov[j] = f2b(b2f(wv[j]) * (b2f(v[j]) * r));
    reinterpret_cast<short8_t*>(o)[c] = ov;
  }
}

__global__ void __launch_bounds__(256)
build_qf_kernel(const short* q, const float* cosT, const float* sinT, short* qf) {
  int s = blockIdx.x;
  for (int idx = threadIdx.x; idx < NH_ * DQK_; idx += 256) {
    int h = idx / DQK_, d = idx - h * DQK_;
    const short* qr = q + (long long)s * QN_ + h * DQK_;
    float val;
    if (d < 128) val = b2f(qr[d]);
    else {
      int j = d - 128;
      float c = cosT[s * 64 + j], sn = sinT[s * 64 + j];
      float x0 = b2f(qr[128 + j]);
      float rot = (j < 32) ? -b2f(qr[128 + j + 32]) : b2f(qr[128 + j - 32]);
      val = x0 * c + rot * sn;
    }
    qf[(long long)h * S_LEN * DQK_ + (long long)s * DQK_ + d] = f2b(val);
  }
}

__global__ void __launch_bounds__(256)
build_kf_kernel(const short* kvup, const short* krope, long long kstride,
                const float* cosT, const float* sinT, short* kf) {
  int s = blockIdx.x;
  for (int idx = threadIdx.x; idx < NH_ * DQK_; idx += 256) {
    int h = idx / DQK_, d = idx - h * DQK_;
    float val;
    if (d < 128) val = b2f(kvup[(long long)s * KVUPN + h * 256 + d]);
    else {
      int j = d - 128;
      float c = cosT[s * 64 + j], sn = sinT[s * 64 + j];
      const short* kr = krope + (long long)s * kstride;
      float x0 = b2f(kr[j]);
      float rot = (j < 32) ? -b2f(kr[j + 32]) : b2f(kr[j - 32]);
      val = x0 * c + rot * sn;
    }
    kf[(long long)h * S_LEN * DQK_ + (long long)s * DQK_ + d] = f2b(val);
  }
}

__global__ void __launch_bounds__(256)
transpose_v_kernel(const short* kvup, short* vT) {
  int h = blockIdx.z;
  int r0 = blockIdx.y * 32, c0 = blockIdx.x * 32;
  int tx = threadIdx.x & 31, ty = threadIdx.x >> 5;
  __shared__ short tile[32][33];
  #pragma unroll
  for (int i = 0; i < 4; ++i)
    tile[ty + i * 8][tx] =
        kvup[(long long)(r0 + ty + i * 8) * KVUPN + h * 256 + 128 + c0 + tx];
  __syncthreads();
  short* d = vT + (long long)h * 128 * S_LEN;
  #pragma unroll
  for (int i = 0; i < 4; ++i)
    d[(long long)(c0 + ty + i * 8) * S_LEN + r0 + tx] = tile[tx][ty + i * 8];
}

__global__ void __launch_bounds__(256)
gate_kernel(const short* x2, const short* gw, int* cnt, int* elist, float* ewt, int* tok2slot) {
  int t = blockIdx.x;
  int e = threadIdx.x >> 5, j = threadIdx.x & 31;
  const short* x = x2 + (long long)t * HDIM;
  float acc = 0.f;
  for (int k = j; k < HDIM; k += 32) acc += b2f(x[k]) * b2f(gw[(long long)k * EXP_ + e]);
  __shared__ float red[8][32];
  red[e][j] = acc; __syncthreads();
  for (int s2 = 16; s2 > 0; s2 >>= 1) {
    if (j < s2) red[e][j] += red[e][j + s2];
    __syncthreads();
  }
  if (threadIdx.x == 0) {
    float l[8], p[8];
    float m = -1e30f;
    for (int q = 0; q < 8; ++q) { l[q] = b2f(f2b(red[q][0])); m = fmaxf(m, l[q]); }
    float sum = 0.f;
    for (int q = 0; q < 8; ++q) { p[q] = expf(l[q] - m); sum += p[q]; }
    int i0 = 0; for (int q = 1; q < 8; ++q) if (p[q] > p[i0]) i0 = q;
    int i1 = (i0 == 0) ? 1 : 0;
    for (int q = 0; q < 8; ++q) if (q != i0 && p[q] > p[i1]) i1 = q;
    float denom = p[i0] + p[i1];
    float w0 = b2f(f2b(p[i0] / denom));
    float w1 = b2f(f2b(p[i1] / denom));
    int pos0 = atomicAdd(&cnt[i0], 1);
    int pos1 = atomicAdd(&cnt[i1], 1);
    elist[i0 * S_LEN + pos0] = t;  ewt[i0 * S_LEN + pos0] = w0;
    elist[i1 * S_LEN + pos1] = t;  ewt[i1 * S_LEN + pos1] = w1;
    int4* slot = (int4*)tok2slot;
    slot[t] = make_int4(i0, pos0, i1, pos1);
  }
}

__global__ void __launch_bounds__(256)
moe_combine_kernel(short* h, const short* shared_out, const short* routed,
                   const int* tok2slot) {
  int t = blockIdx.x;
  const int4 sl = ((const int4*)tok2slot)[t];
  const short8_t* s0 = reinterpret_cast<const short8_t*>(shared_out + (long long)t * HDIM);
  const short8_t* s1 = reinterpret_cast<const short8_t*>(shared_out + ((long long)S_LEN + t) * HDIM);
  const short8_t* r0 = reinterpret_cast<const short8_t*>(
      routed + ((long long)sl.x * S_LEN + sl.y) * HDIM);
  const short8_t* r1 = reinterpret_cast<const short8_t*>(
      routed + ((long long)sl.z * S_LEN + sl.w) * HDIM);
  long long c = (long long)t * 256 + threadIdx.x;
  short8_t hv = reinterpret_cast<short8_t*>(h)[c];
  short8_t a0 = s0[threadIdx.x], a1 = s1[threadIdx.x];
  short8_t v0 = r0[threadIdx.x], v1 = r1[threadIdx.x];
  short8_t ov;
  #pragma unroll
  for (int j = 0; j < 8; ++j)
    ov[j] = f2b(b2f(hv[j]) + (b2f(a0[j]) + b2f(a1[j]) + b2f(v0[j]) + b2f(v1[j])));
  reinterpret_cast<short8_t*>(h)[c] = ov;
}

// ---------------- pooling ----------------
template<int AF32, int OUTBF16>
__global__ void __launch_bounds__(256)
gemv_bt_kernel(const void* a, const short* __restrict__ BT, void* out, int K) {
  int n = blockIdx.x;
  const short8_t* row = reinterpret_cast<const short8_t*>(BT + (long long)n * K);
  float acc = 0.f;
  for (int c = threadIdx.x; c < (K >> 3); c += 256) {
    short8_t v = row[c];
    if (AF32) {
      f32x4 a0 = reinterpret_cast<const f32x4*>(a)[2 * c];
      f32x4 a1 = reinterpret_cast<const f32x4*>(a)[2 * c + 1];
      #pragma unroll
      for (int j = 0; j < 4; ++j) {
        acc += a0[j] * b2f(v[j]);
        acc += a1[j] * b2f(v[4 + j]);
      }
    } else {
      short8_t av = reinterpret_cast<const short8_t*>(a)[c];
      #pragma unroll
      for (int j = 0; j < 8; ++j) acc += b2f(av[j]) * b2f(v[j]);
    }
  }
  __shared__ float red[256];
  red[threadIdx.x] = acc; __syncthreads();
  for (int s2 = 128; s2 > 0; s2 >>= 1) {
    if (threadIdx.x < s2) red[threadIdx.x] += red[threadIdx.x + s2];
    __syncthreads();
  }
  if (threadIdx.x == 0) {
    if (OUTBF16) ((short*)out)[n] = f2b(red[0]);
    else         ((float*)out)[n] = red[0];
  }
}

__global__ void __launch_bounds__(256)
pool_score_kernel(const short* qv, const short* kmat, float* score) {
  int s = blockIdx.x;
  const short8_t* kr = reinterpret_cast<const short8_t*>(kmat + (long long)s * HDIM);
  const short8_t* qr = reinterpret_cast<const short8_t*>(qv);
  short8_t kv8 = kr[threadIdx.x], qv8 = qr[threadIdx.x];
  float acc = 0.f;
  #pragma unroll
  for (int j = 0; j < 8; ++j) acc += b2f(qv8[j]) * b2f(kv8[j]);
  __shared__ float red[256];
  red[threadIdx.x] = acc; __syncthreads();
  for (int s2 = 128; s2 > 0; s2 >>= 1) {
    if (threadIdx.x < s2) red[threadIdx.x] += red[threadIdx.x + s2];
    __syncthreads();
  }
  if (threadIdx.x == 0) score[s] = b2f(f2b(red[0])) * 0.022097086912079608f;
}

__global__ void __launch_bounds__(256)
softmax_vec_kernel(float* v) {
  int tid = threadIdx.x;
  float f[8]; float m = -1e30f;
  #pragma unroll
  for (int i = 0; i < 8; ++i) { f[i] = v[i * 256 + tid]; m = fmaxf(m, f[i]); }
  __shared__ float red[256];
  red[tid] = m; __syncthreads();
  for (int s2 = 128; s2 > 0; s2 >>= 1) {
    if (tid < s2) red[tid] = fmaxf(red[tid], red[tid + s2]);
    __syncthreads();
  }
  m = red[0]; __syncthreads();
  float sum = 0.f;
  #pragma unroll
  for (int i = 0; i < 8; ++i) { f[i] = expf(f[i] - m); sum += f[i]; }
  red[tid] = sum; __syncthreads();
  for (int s2 = 128; s2 > 0; s2 >>= 1) {
    if (tid < s2) red[tid] += red[tid + s2];
    __syncthreads();
  }
  float inv = 1.0f / red[0];
  #pragma unroll
  for (int i = 0; i < 8; ++i) v[i * 256 + tid] = f[i] * inv;
}

__global__ void __launch_bounds__(256)
pool_wsum_t_kernel(const float* w, const short* vT, float* pooled) {
  int h = blockIdx.x;
  const short8_t* row = reinterpret_cast<const short8_t*>(vT + (long long)h * S_LEN);
  int c = threadIdx.x;
  short8_t v = row[c];
  f32x4 w0 = reinterpret_cast<const f32x4*>(w)[2 * c];
  f32x4 w1 = reinterpret_cast<const f32x4*>(w)[2 * c + 1];
  float acc = 0.f;
  #pragma unroll
  for (int j = 0; j < 4; ++j) {
    acc += w0[j] * b2f(v[j]);
    acc += w1[j] * b2f(v[4 + j]);
  }
  __shared__ float red[256];
  red[threadIdx.x] = acc; __syncthreads();
  for (int s2 = 128; s2 > 0; s2 >>= 1) {
    if (threadIdx.x < s2) red[threadIdx.x] += red[threadIdx.x + s2];
    __syncthreads();
  }
  if (threadIdx.x == 0) pooled[h] = red[0];
}

__global__ void __launch_bounds__(256)
rmsnorm_f32_kernel(const float* x, const short* w, float* out) {
  int tid = threadIdx.x;
  float f[8]; float ss = 0.f;
  #pragma unroll
  for (int i = 0; i < 8; ++i) { f[i] = x[i * 256 + tid]; ss += f[i] * f[i]; }
  __shared__ float red[256];
  red[tid] = ss; __syncthreads();
  for (int s2 = 128; s2 > 0; s2 >>= 1) {
    if (tid < s2) red[tid] += red[tid + s2];
    __syncthreads();
  }
  float r = 1.0f / sqrtf(red[0] / 2048.0f + 1e-6f);
  #pragma unroll
  for (int i = 0; i < 8; ++i) out[i * 256 + tid] = b2f(w[i * 256 + tid]) * (f[i] * r);
}

// ---------------- host ----------------
extern "C" void kernel_launch(void* const* d_in, const int* in_sizes, int n_in,
                              void* d_out, int out_size, void* d_ws, size_t ws_size,
                              hipStream_t stream)
{
  (void)n_in; (void)out_size; (void)ws_size;
  const int* ids = (const int*)d_in[24];

  char* base = (char*)d_ws;
  size_t off = 0;
  auto alloc = [&](size_t bytes) -> void* {
    void* p = base + off;
    off += (bytes + 255) & ~(size_t)255;
    return p;
  };

  int* dflag = (int*)alloc(256);

  short* qkvdwT = (short*)alloc((size_t)2 * DCAT * HDIM * 2);
  short* quwT  = (short*)alloc((size_t)2 * QN_ * QRANK_ * 2);
  short* kvuwT = (short*)alloc((size_t)2 * KVUPN * KVRANK_ * 2);
  short* opwT  = (short*)alloc((size_t)2 * HDIM * HDIM * 2);
  short* rw13T = (short*)alloc((size_t)16 * IFF2 * HDIM * 2);
  short* rw2T  = (short*)alloc((size_t)16 * HDIM * IFF_ * 2);
  short* sw13T = (short*)alloc((size_t)4 * IFF2 * HDIM * 2);
  short* sw2T  = (short*)alloc((size_t)4 * HDIM * IFF_ * 2);
  short* pqwT  = (short*)alloc((size_t)HDIM * HDIM * 2);
  short* pkwT  = (short*)alloc((size_t)HDIM * HDIM * 2);
  short* pvwT  = (short*)alloc((size_t)HDIM * HDIM * 2);
  short* powT  = (short*)alloc((size_t)PD_ * HDIM * 2);
  short* ln1w = (short*)alloc((size_t)in_sizes[1] * 2);
  short* qnw  = (short*)alloc((size_t)in_sizes[3] * 2);
  short* kvnw = (short*)alloc((size_t)in_sizes[6] * 2);
  short* ln2w = (short*)alloc((size_t)in_sizes[9] * 2);
  short* gatw = (short*)alloc((size_t)in_sizes[10] * 2);
  short* fnww = (short*)alloc((size_t)in_sizes[17] * 2);
  short* lqw  = (short*)alloc((size_t)in_sizes[18] * 2);
  short* pnww = (short*)alloc((size_t)in_sizes[23] * 2);

  float* cosT    = (float*)alloc((size_t)S_LEN * 64 * 4);
  float* sinT    = (float*)alloc((size_t)S_LEN * 64 * 4);
  short* hbuf    = (short*)alloc((size_t)S_LEN * HDIM * 2);
  short* xbuf    = (short*)alloc((size_t)S_LEN * HDIM * 2);
  short* dcat    = (short*)alloc((size_t)S_LEN * DCAT * 2);
  short* qlatn   = (short*)alloc((size_t)S_LEN * QRANK_ * 2);
  short* qbuf    = (short*)alloc((size_t)S_LEN * QN_ * 2);
  short* kvn     = (short*)alloc((size_t)S_LEN * KVRANK_ * 2);
  short* kvup    = (short*)alloc((size_t)S_LEN * KVUPN * 2);
  short* qf      = (short*)alloc((size_t)NH_ * S_LEN * DQK_ * 2);
  short* kf      = (short*)alloc((size_t)NH_ * S_LEN * DQK_ * 2);
  short* vT      = (short*)alloc((size_t)NH_ * 128 * S_LEN * 2);
  short* ao      = (short*)alloc((size_t)S_LEN * HDIM * 2);
  short* hfin    = (short*)alloc((size_t)S_LEN * HDIM * 2);
  short* kpool   = (short*)alloc((size_t)S_LEN * HDIM * 2);
  short* vpoolT  = (short*)alloc((size_t)HDIM * S_LEN * 2);
  short* qvec    = (short*)alloc((size_t)HDIM * 2);
  float* pscore  = (float*)alloc((size_t)S_LEN * 4);
  float* pooled  = (float*)alloc((size_t)HDIM * 4);
  float* pooledn = (float*)alloc((size_t)HDIM * 4);
  int*   ecnt    = (int*)alloc(64);
  int*   elist   = (int*)alloc((size_t)EXP_ * S_LEN * 4);
  float* ewt     = (float*)alloc((size_t)EXP_ * S_LEN * 4);
  int*   tok2slot= (int*)alloc((size_t)S_LEN * 16);
  short* gba_e   = (short*)alloc((size_t)EXP_ * S_LEN * IFF_ * 2);
  short* routed  = (short*)alloc((size_t)EXP_ * S_LEN * HDIM * 2);
  short* gsh1    = (short*)alloc((size_t)S_LEN * IFF2 * 2);   // [S][2816]
  short* shared_out = (short*)alloc((size_t)2 * S_LEN * HDIM * 2);

  detect_kernel<<<1, 256, 0, stream>>>(d_in[0], dflag);

  auto tconv = [&](const void* src, short* dst, int R, int C, int nslabs,
                   long long sSrc, long long sDst, int rowMul, int rowOff) {
    dim3 grid(C / 32, R / 32, nslabs);
    transconv_kernel<<<grid, 256, 0, stream>>>(src, dst, R, C, dflag, sSrc, sDst, rowMul, rowOff);
  };
  auto pconv = [&](const void* src, short* dst, long long n) {
    long long nchunks = n / 8;
    int blocks = (int)((nchunks + 255) / 256);
    if (blocks > 2048) blocks = 2048;
    if (blocks < 1) blocks = 1;
    convert_kernel<<<blocks, 256, 0, stream>>>(src, dst, nchunks, dflag);
  };

  tconv(d_in[2], qkvdwT, HDIM, QRANK_, 2,
        (long long)HDIM * QRANK_, (long long)DCAT * HDIM, 1, 0);
  tconv(d_in[5], qkvdwT + (size_t)QRANK_ * HDIM, HDIM, KVDN, 2,
        (long long)HDIM * KVDN, (long long)DCAT * HDIM, 1, 0);
  tconv(d_in[4],  quwT,  QRANK_, QN_,  2, (long long)QRANK_ * QN_,  (long long)QN_ * QRANK_, 1, 0);
  tconv(d_in[7],  kvuwT, KVRANK_,KVUPN,2, (long long)KVRANK_ * KVUPN,(long long)KVUPN * KVRANK_, 1, 0);
  tconv(d_in[8],  opwT,  HDIM,   HDIM, 2, (long long)HDIM * HDIM,   (long long)HDIM * HDIM, 1, 0);
  tconv(d_in[11], rw13T, HDIM,   IFF_, 16,(long long)HDIM * IFF_,   (long long)IFF2 * HDIM, 2, 0);
  tconv(d_in[13], rw13T, HDIM,   IFF_, 16,(long long)HDIM * IFF_,   (long long)IFF2 * HDIM, 2, 1);
  tconv(d_in[12], rw2T,  IFF_,   HDIM, 16,(long long)IFF_ * HDIM,   (long long)HDIM * IFF_, 1, 0);
  tconv(d_in[14], sw13T, HDIM,   IFF_, 4, (long long)HDIM * IFF_,   (long long)IFF2 * HDIM, 2, 0);
  tconv(d_in[16], sw13T, HDIM,   IFF_, 4, (long long)HDIM * IFF_,   (long long)IFF2 * HDIM, 2, 1);
  tconv(d_in[15], sw2T,  IFF_,   HDIM, 4, (long long)IFF_ * HDIM,   (long long)HDIM * IFF_, 1, 0);
  tconv(d_in[19], pqwT,  HDIM,   HDIM, 1, 0, 0, 1, 0);
  tconv(d_in[20], pkwT,  HDIM,   HDIM, 1, 0, 0, 1, 0);
  tconv(d_in[21], pvwT,  HDIM,   HDIM, 1, 0, 0, 1, 0);
  tconv(d_in[22], powT,  HDIM,   PD_,  1, 0, 0, 1, 0);
  pconv(d_in[1],  ln1w, in_sizes[1]);
  pconv(d_in[3],  qnw,  in_sizes[3]);
  pconv(d_in[6],  kvnw, in_sizes[6]);
  pconv(d_in[9],  ln2w, in_sizes[9]);
  pconv(d_in[10], gatw, in_sizes[10]);
  pconv(d_in[17], fnww, in_sizes[17]);
  pconv(d_in[18], lqw,  in_sizes[18]);
  pconv(d_in[23], pnww, in_sizes[23]);

  const float qk_scale = 1.0f / sqrtf((float)DQK_);

  auto gemm = [&](int epi, const short* A, const short* B, short* C,
                  int M, int N, int K, int lda, int ldb, int ldc,
                  int batch, long long sA, long long sB, long long sC) {
    dim3 grid(M / 128, (N + 127) / 128, batch);
    if (epi == 0)
      gemm_kernel<0><<<grid, 256, 0, stream>>>(A, B, C, M, N, K, lda, ldb, ldc, sA, sB, sC);
    else if (epi == 1)
      gemm_kernel<1><<<grid, 256, 0, stream>>>(A, B, C, M, N, K, lda, ldb, ldc, sA, sB, sC);
    else
      gemm_kernel<2><<<grid, 256, 0, stream>>>(A, B, C, M, N, K, lda, ldb, ldc, sA, sB, sC);
  };

  rope_tables_kernel<<<S_LEN, 64, 0, stream>>>(cosT, sinT);
  embed_convert_kernel<<<S_LEN, 256, 0, stream>>>(ids, d_in[0], dflag, hbuf);

  for (int l = 0; l < 2; ++l) {
    const short* w_ln1  = ln1w + (size_t)l * HDIM;
    const short* w_qkvT = qkvdwT + (size_t)l * DCAT * HDIM;
    const short* w_qn   = qnw  + (size_t)l * QRANK_;
    const short* w_quT  = quwT + (size_t)l * QN_ * QRANK_;
    const short* w_kvn  = kvnw + (size_t)l * KVRANK_;
    const short* w_kvuT = kvuwT+ (size_t)l * KVUPN * KVRANK_;
    const short* w_opT  = opwT + (size_t)l * HDIM * HDIM;
    const short* w_ln2  = ln2w + (size_t)l * HDIM;
    const short* w_gat  = gatw + (size_t)l * HDIM * EXP_;

    // --- attention ---
    rmsnorm_bf16_kernel<<<S_LEN, 256, 0, stream>>>(hbuf, HDIM, w_ln1, xbuf, HDIM, HDIM);
    gemm(0, xbuf, w_qkvT, dcat, S_LEN, DCAT, HDIM, HDIM, HDIM, DCAT, 1, 0, 0, 0);
    rmsnorm_bf16_kernel<<<S_LEN, 256, 0, stream>>>(dcat, DCAT, w_qn, qlatn, QRANK_, QRANK_);
    gemm(0, qlatn, w_quT, qbuf, S_LEN, QN_, QRANK_, QRANK_, QRANK_, QN_, 1, 0, 0, 0);
    rmsnorm_bf16_kernel<<<S_LEN, 256, 0, stream>>>(dcat + QRANK_, DCAT, w_kvn, kvn, KVRANK_, KVRANK_);
    gemm(0, kvn, w_kvuT, kvup, S_LEN, KVUPN, KVRANK_, KVRANK_, KVRANK_, KVUPN, 1, 0, 0, 0);
    build_qf_kernel<<<S_LEN, 256, 0, stream>>>(qbuf, cosT, sinT, qf);
    build_kf_kernel<<<S_LEN, 256, 0, stream>>>(kvup, dcat + QRANK_ + KVRANK_, DCAT, cosT, sinT, kf);
    {
      dim3 tg(128 / 32, S_LEN / 32, NH_);
      transpose_v_kernel<<<tg, 256, 0, stream>>>(kvup, vT);
    }
    {
      dim3 fg(S_LEN / 64, NH_);
      flash_kernel<<<fg, 256, 0, stream>>>(qf, kf, vT, ao, qk_scale);
    }
    gemm(2, ao, w_opT, hbuf, S_LEN, HDIM, HDIM, HDIM, HDIM, HDIM, 1, 0, 0, 0);

    // --- MoE ---
    rmsnorm_bf16_kernel<<<S_LEN, 256, 0, stream>>>(hbuf, HDIM, w_ln2, xbuf, HDIM, HDIM);
    hipMemsetAsync(ecnt, 0, 64, stream);
    gate_kernel<<<S_LEN, 256, 0, stream>>>(xbuf, w_gat, ecnt, elist, ewt, tok2slot);
    {
      const short* a13 = sw13T + (size_t)l * 2 * IFF2 * HDIM;
      const short* a2  = sw2T  + (size_t)l * 2 * HDIM * IFF_;
      // both shared experts as one wide GEMM (expert slabs are contiguous rows)
      gemm(1, xbuf, a13, gsh1, S_LEN, 2 * IFF2, HDIM, HDIM, HDIM, IFF2, 1, 0, 0, 0);
      gemm(0, gsh1, a2, shared_out, S_LEN, HDIM, IFF_, IFF2, IFF_, HDIM, 2,
           (long long)IFF_, (long long)HDIM * IFF_, (long long)S_LEN * HDIM);
    }
    {
      const short* b13 = rw13T + (size_t)l * 8 * IFF2 * HDIM;
      const short* b2  = rw2T  + (size_t)l * 8 * HDIM * IFF_;
      dim3 g13(IFF2 / 128, S_LEN / 128, EXP_);
      moe_gemm_kernel<1, 1><<<g13, 256, 0, stream>>>(
          xbuf, elist, ecnt, b13, gba_e, ewt, IFF2, HDIM, HDIM, HDIM, IFF_,
          0, (long long)IFF2 * HDIM, (long long)S_LEN * IFF_);
      dim3 g2(HDIM / 128, S_LEN / 128, EXP_);
      moe_gemm_kernel<0, 0><<<g2, 256, 0, stream>>>(
          gba_e, elist, ecnt, b2, routed, nullptr, HDIM, IFF_, IFF_, IFF_, HDIM,
          (long long)S_LEN * IFF_, (long long)HDIM * IFF_, (long long)S_LEN * HDIM);
      moe_combine_kernel<<<S_LEN, 256, 0, stream>>>(hbuf, shared_out, routed, tok2slot);
    }
  }

  // --- attention pooling head ---
  rmsnorm_bf16_kernel<<<S_LEN, 256, 0, stream>>>(hbuf, HDIM, fnww, hfin, HDIM, HDIM);
  gemm(0, hfin, pkwT, kpool, S_LEN, HDIM, HDIM, HDIM, HDIM, HDIM, 1, 0, 0, 0);
  gemm(0, pvwT, hfin, vpoolT, HDIM, S_LEN, HDIM, HDIM, HDIM, S_LEN, 1, 0, 0, 0);
  gemv_bt_kernel<0,1><<<HDIM, 256, 0, stream>>>(lqw, pqwT, qvec, HDIM);
  pool_score_kernel<<<S_LEN, 256, 0, stream>>>(qvec, kpool, pscore);
  softmax_vec_kernel<<<1, 256, 0, stream>>>(pscore);
  pool_wsum_t_kernel<<<HDIM, 256, 0, stream>>>(pscore, vpoolT, pooled);
  rmsnorm_f32_kernel<<<1, 256, 0, stream>>>(pooled, pnww, pooledn);
  gemv_bt_kernel<1,0><<<PD_, 256, 0, stream>>>(pooledn, powT, (float*)d_out, HDIM);
}